// Round 2
// baseline (4342.518 us; speedup 1.0000x reference)
//
#include <hip/hip_runtime.h>
#include <math.h>

// Problem constants
constexpr int kS = 512, kH = 768, kNH = 12, kDH = 64, kF = 3072, kL = 12;
constexpr int kN = 50000, kE = 800000, kGH = 128;

#define CDIV(a,b) (((a)+(b)-1)/(b))

struct Ptr3 { const float* p[3]; };
struct Out3 { float* p[3]; };

// ---------------- generic fill ----------------
__global__ void fill_kernel(float* p, float v, long n) {
    long i = blockIdx.x * (long)blockDim.x + threadIdx.x;
    if (i < n) p[i] = v;
}

// ---------------- embeddings + LN ----------------
__global__ void embed_ln_kernel(const int* ids, const int* tt,
                                const float* we, const float* pe, const float* te,
                                const float* g, const float* b, float* out) {
    int s = blockIdx.x;            // one block per token
    int tid = threadIdx.x;         // 256 threads, 3 elems each
    __shared__ float red[256];
    int id = ids[s], t = tt[s];
    float vals[3]; float sum = 0.f;
    #pragma unroll
    for (int r = 0; r < 3; r++) {
        int j = tid + r * 256;
        float x = we[(long)id * kH + j] + pe[(long)s * kH + j] + te[(long)t * kH + j];
        vals[r] = x; sum += x;
    }
    red[tid] = sum; __syncthreads();
    for (int off = 128; off > 0; off >>= 1) { if (tid < off) red[tid] += red[tid + off]; __syncthreads(); }
    float mean = red[0] / kH; __syncthreads();
    float vs = 0.f;
    #pragma unroll
    for (int r = 0; r < 3; r++) { float d = vals[r] - mean; vs += d * d; }
    red[tid] = vs; __syncthreads();
    for (int off = 128; off > 0; off >>= 1) { if (tid < off) red[tid] += red[tid + off]; __syncthreads(); }
    float rstd = rsqrtf(red[0] / kH + 1e-12f);
    #pragma unroll
    for (int r = 0; r < 3; r++) {
        int j = tid + r * 256;
        out[(long)s * kH + j] = (vals[r] - mean) * rstd * g[j] + b[j];
    }
}

// ---------------- LN(res + a) ----------------
__global__ void ln_residual_kernel(const float* a, const float* res,
                                   const float* g, const float* b, float* out) {
    int s = blockIdx.x; int tid = threadIdx.x;
    __shared__ float red[256];
    float vals[3]; float sum = 0.f;
    #pragma unroll
    for (int r = 0; r < 3; r++) {
        int j = tid + r * 256;
        float x = a[(long)s * kH + j] + res[(long)s * kH + j];
        vals[r] = x; sum += x;
    }
    red[tid] = sum; __syncthreads();
    for (int off = 128; off > 0; off >>= 1) { if (tid < off) red[tid] += red[tid + off]; __syncthreads(); }
    float mean = red[0] / kH; __syncthreads();
    float vs = 0.f;
    #pragma unroll
    for (int r = 0; r < 3; r++) { float d = vals[r] - mean; vs += d * d; }
    red[tid] = vs; __syncthreads();
    for (int off = 128; off > 0; off >>= 1) { if (tid < off) red[tid] += red[tid + off]; __syncthreads(); }
    float rstd = rsqrtf(red[0] / kH + 1e-12f);
    #pragma unroll
    for (int r = 0; r < 3; r++) {
        int j = tid + r * 256;
        out[(long)s * kH + j] = (vals[r] - mean) * rstd * g[j] + b[j];
    }
}

// ---------------- double-buffered 64x64 tile K-chunk MACC loop (used by attn ctx) ----------------
__device__ __forceinline__ void mm_chunk_loop(
    const float* __restrict__ Aptr, bool avalid,
    const float* __restrict__ Bptr, long bstride, int nch,
    float (*As)[16][68], float (*Bs)[16][64],
    int arow, int akq, int brow, int bnq, int tx, int ty, float (&acc)[4][4])
{
    float4 av = avalid ? *(const float4*)Aptr : make_float4(0.f, 0.f, 0.f, 0.f);
    float4 bv = *(const float4*)Bptr;
    As[0][akq + 0][arow] = av.x; As[0][akq + 1][arow] = av.y;
    As[0][akq + 2][arow] = av.z; As[0][akq + 3][arow] = av.w;
    *(float4*)&Bs[0][brow][bnq] = bv;
    for (int c = 0; c < nch; ++c) {
        if (c + 1 < nch) {
            av = avalid ? *(const float4*)(Aptr + (c + 1) * 16) : make_float4(0.f, 0.f, 0.f, 0.f);
            bv = *(const float4*)(Bptr + (long)(c + 1) * 16 * bstride);
        }
        __syncthreads();
        int cb = c & 1;
        #pragma unroll
        for (int kk = 0; kk < 16; ++kk) {
            float4 a = *(const float4*)&As[cb][kk][ty * 4];
            float4 b = *(const float4*)&Bs[cb][kk][tx * 4];
            acc[0][0] += a.x * b.x; acc[0][1] += a.x * b.y; acc[0][2] += a.x * b.z; acc[0][3] += a.x * b.w;
            acc[1][0] += a.y * b.x; acc[1][1] += a.y * b.y; acc[1][2] += a.y * b.z; acc[1][3] += a.y * b.w;
            acc[2][0] += a.z * b.x; acc[2][1] += a.z * b.y; acc[2][2] += a.z * b.z; acc[2][3] += a.z * b.w;
            acc[3][0] += a.w * b.x; acc[3][1] += a.w * b.y; acc[3][2] += a.w * b.z; acc[3][3] += a.w * b.w;
        }
        if (c + 1 < nch) {
            int nb = cb ^ 1;
            As[nb][akq + 0][arow] = av.x; As[nb][akq + 1][arow] = av.y;
            As[nb][akq + 2][arow] = av.z; As[nb][akq + 3][arow] = av.w;
            *(float4*)&Bs[nb][brow][bnq] = bv;
        }
    }
}

// ---------------- split-K GEMM, 128x64 macro / 8x4 micro: C[M,N] = A[M,K] @ B[K,N] ----------------
// gridDim.z = nW * S; w = z/S selects weight variant, s = z%S the K-chunk.
// If Cdirect != nullptr (requires S==1, nW==1): write C directly with bias/act.
// Else: write partials part[(w*S+s)*M*N + ...]; bias/act applied in epilogue.
__global__ __launch_bounds__(256) void gemm_sk128_kernel(
    const float* __restrict__ A, Ptr3 Bp, float* __restrict__ part,
    float* __restrict__ Cdirect, const float* __restrict__ biasD,
    int M, int Nn, int K, int S, int act)
{
    __shared__ float As[2][16][132];   // [k][m], padded
    __shared__ float Bs[2][16][64];    // [k][n]
    int w = blockIdx.z / S, s = blockIdx.z % S;
    const float* B = Bp.p[w];
    int Kc = K / S;                 // all uses: K, Kc multiples of 16
    int kbeg = s * Kc;
    int m0 = blockIdx.y * 128, n0 = blockIdx.x * 64;
    int tid = threadIdx.x;
    int tx = tid & 15, ty = tid >> 4;          // micro: 8 rows (ty*8..) x 4 cols (tx*4..)
    int arow = tid >> 2, akq = (tid & 3) * 4;  // A staging: rows arow, arow+64
    int brow = tid >> 4, bnq = (tid & 15) * 4; // B staging
    int gma0 = m0 + arow, gma1 = m0 + arow + 64;
    bool av0 = gma0 < M, av1 = gma1 < M;
    const float* Ap0 = A + (long)gma0 * K + kbeg + akq;
    const float* Ap1 = A + (long)gma1 * K + kbeg + akq;
    const float* Bptr = B + (long)(kbeg + brow) * Nn + n0 + bnq;
    int nch = Kc / 16;

    float4 a0v = av0 ? *(const float4*)Ap0 : make_float4(0.f, 0.f, 0.f, 0.f);
    float4 a1v = av1 ? *(const float4*)Ap1 : make_float4(0.f, 0.f, 0.f, 0.f);
    float4 bv  = *(const float4*)Bptr;
    As[0][akq + 0][arow] = a0v.x; As[0][akq + 1][arow] = a0v.y;
    As[0][akq + 2][arow] = a0v.z; As[0][akq + 3][arow] = a0v.w;
    As[0][akq + 0][arow + 64] = a1v.x; As[0][akq + 1][arow + 64] = a1v.y;
    As[0][akq + 2][arow + 64] = a1v.z; As[0][akq + 3][arow + 64] = a1v.w;
    *(float4*)&Bs[0][brow][bnq] = bv;

    float acc[8][4] = {};
    for (int c = 0; c < nch; ++c) {
        if (c + 1 < nch) {
            a0v = av0 ? *(const float4*)(Ap0 + (c + 1) * 16) : make_float4(0.f, 0.f, 0.f, 0.f);
            a1v = av1 ? *(const float4*)(Ap1 + (c + 1) * 16) : make_float4(0.f, 0.f, 0.f, 0.f);
            bv  = *(const float4*)(Bptr + (long)(c + 1) * 16 * Nn);
        }
        __syncthreads();
        int cb = c & 1;
        #pragma unroll
        for (int kk = 0; kk < 16; ++kk) {
            float4 a0 = *(const float4*)&As[cb][kk][ty * 8];
            float4 a1 = *(const float4*)&As[cb][kk][ty * 8 + 4];
            float4 b  = *(const float4*)&Bs[cb][kk][tx * 4];
            acc[0][0] += a0.x * b.x; acc[0][1] += a0.x * b.y; acc[0][2] += a0.x * b.z; acc[0][3] += a0.x * b.w;
            acc[1][0] += a0.y * b.x; acc[1][1] += a0.y * b.y; acc[1][2] += a0.y * b.z; acc[1][3] += a0.y * b.w;
            acc[2][0] += a0.z * b.x; acc[2][1] += a0.z * b.y; acc[2][2] += a0.z * b.z; acc[2][3] += a0.z * b.w;
            acc[3][0] += a0.w * b.x; acc[3][1] += a0.w * b.y; acc[3][2] += a0.w * b.z; acc[3][3] += a0.w * b.w;
            acc[4][0] += a1.x * b.x; acc[4][1] += a1.x * b.y; acc[4][2] += a1.x * b.z; acc[4][3] += a1.x * b.w;
            acc[5][0] += a1.y * b.x; acc[5][1] += a1.y * b.y; acc[5][2] += a1.y * b.z; acc[5][3] += a1.y * b.w;
            acc[6][0] += a1.z * b.x; acc[6][1] += a1.z * b.y; acc[6][2] += a1.z * b.z; acc[6][3] += a1.z * b.w;
            acc[7][0] += a1.w * b.x; acc[7][1] += a1.w * b.y; acc[7][2] += a1.w * b.z; acc[7][3] += a1.w * b.w;
        }
        if (c + 1 < nch) {
            int nb = cb ^ 1;
            As[nb][akq + 0][arow] = a0v.x; As[nb][akq + 1][arow] = a0v.y;
            As[nb][akq + 2][arow] = a0v.z; As[nb][akq + 3][arow] = a0v.w;
            As[nb][akq + 0][arow + 64] = a1v.x; As[nb][akq + 1][arow + 64] = a1v.y;
            As[nb][akq + 2][arow + 64] = a1v.z; As[nb][akq + 3][arow + 64] = a1v.w;
            *(float4*)&Bs[nb][brow][bnq] = bv;
        }
    }
    if (Cdirect) {
        float bx = biasD ? biasD[n0 + tx * 4 + 0] : 0.f;
        float by = biasD ? biasD[n0 + tx * 4 + 1] : 0.f;
        float bz = biasD ? biasD[n0 + tx * 4 + 2] : 0.f;
        float bw = biasD ? biasD[n0 + tx * 4 + 3] : 0.f;
        #pragma unroll
        for (int i = 0; i < 8; i++) {
            int gm = m0 + ty * 8 + i; if (gm >= M) continue;
            float4 vv;
            vv.x = acc[i][0] + bx; vv.y = acc[i][1] + by; vv.z = acc[i][2] + bz; vv.w = acc[i][3] + bw;
            if (act == 1) {
                vv.x = 0.5f * vv.x * (1.f + erff(vv.x * 0.70710678118654752f));
                vv.y = 0.5f * vv.y * (1.f + erff(vv.y * 0.70710678118654752f));
                vv.z = 0.5f * vv.z * (1.f + erff(vv.z * 0.70710678118654752f));
                vv.w = 0.5f * vv.w * (1.f + erff(vv.w * 0.70710678118654752f));
            } else if (act == 2) {
                vv.x = fmaxf(vv.x, 0.f); vv.y = fmaxf(vv.y, 0.f);
                vv.z = fmaxf(vv.z, 0.f); vv.w = fmaxf(vv.w, 0.f);
            }
            *(float4*)&Cdirect[(long)gm * Nn + n0 + tx * 4] = vv;
        }
    } else {
        long MN = (long)M * Nn;
        float* Pp = part + (long)(w * S + s) * MN;
        #pragma unroll
        for (int i = 0; i < 8; i++) {
            int gm = m0 + ty * 8 + i; if (gm >= M) continue;
            float4 vv; vv.x = acc[i][0]; vv.y = acc[i][1]; vv.z = acc[i][2]; vv.w = acc[i][3];
            *(float4*)&Pp[(long)gm * Nn + n0 + tx * 4] = vv;
        }
    }
}

// ---------------- split-K epilogue: out = act(sum_s part + bias) ----------------
__global__ void splitk_epi_kernel(const float* __restrict__ part, Ptr3 bias, Out3 outp,
                                  long MN, int Nn, int S, int act) {
    int w = blockIdx.y;
    long i = ((long)blockIdx.x * blockDim.x + threadIdx.x) * 4;
    if (i >= MN) return;
    const float* P = part + (long)w * S * MN + i;
    float4 a = *(const float4*)P;
    for (int s2 = 1; s2 < S; ++s2) {
        float4 b = *(const float4*)(P + (long)s2 * MN);
        a.x += b.x; a.y += b.y; a.z += b.z; a.w += b.w;
    }
    const float* bw = bias.p[w];
    if (bw) {
        int n = (int)(i % Nn);
        a.x += bw[n]; a.y += bw[n + 1]; a.z += bw[n + 2]; a.w += bw[n + 3];
    }
    if (act == 1) {
        a.x = 0.5f * a.x * (1.f + erff(a.x * 0.70710678118654752f));
        a.y = 0.5f * a.y * (1.f + erff(a.y * 0.70710678118654752f));
        a.z = 0.5f * a.z * (1.f + erff(a.z * 0.70710678118654752f));
        a.w = 0.5f * a.w * (1.f + erff(a.w * 0.70710678118654752f));
    } else if (act == 2) {
        a.x = fmaxf(a.x, 0.f); a.y = fmaxf(a.y, 0.f); a.z = fmaxf(a.z, 0.f); a.w = fmaxf(a.w, 0.f);
    }
    *(float4*)(outp.p[w] + i) = a;
}

// ---------------- attention: scores = Q K^T / 8 + maskbias ----------------
__global__ __launch_bounds__(256) void attn_scores_kernel(const float* __restrict__ Q,
                                                          const float* __restrict__ K,
                                                          const float* __restrict__ mb,
                                                          float* __restrict__ scores) {
    int h = blockIdx.z;
    int q0 = blockIdx.y * 64, k0 = blockIdx.x * 64;
    __shared__ float Qs[16][65], Ks[16][65];
    int tid = threadIdx.x; int tx = tid & 15, ty = tid >> 4;
    float acc[4][4] = {};
    for (int d0 = 0; d0 < kDH; d0 += 16) {
        #pragma unroll
        for (int r = 0; r < 4; r++) {
            int ii = r * 256 + tid; int m = ii >> 4, kk = ii & 15;
            Qs[kk][m] = Q[(long)(q0 + m) * kH + h * kDH + d0 + kk];
            Ks[kk][m] = K[(long)(k0 + m) * kH + h * kDH + d0 + kk];
        }
        __syncthreads();
        #pragma unroll
        for (int kk = 0; kk < 16; kk++) {
            float a[4], bb[4];
            #pragma unroll
            for (int i = 0; i < 4; i++) a[i] = Qs[kk][ty * 4 + i];
            #pragma unroll
            for (int j = 0; j < 4; j++) bb[j] = Ks[kk][tx * 4 + j];
            #pragma unroll
            for (int i = 0; i < 4; i++)
                #pragma unroll
                for (int j = 0; j < 4; j++) acc[i][j] += a[i] * bb[j];
        }
        __syncthreads();
    }
    #pragma unroll
    for (int i = 0; i < 4; i++) {
        int qq = q0 + ty * 4 + i;
        #pragma unroll
        for (int j = 0; j < 4; j++) {
            int kkk = k0 + tx * 4 + j;
            scores[((long)h * kS + qq) * kS + kkk] = acc[i][j] * 0.125f + mb[kkk];
        }
    }
}

// ---------------- softmax over rows of 512 ----------------
__global__ void softmax_kernel(float* scores) {
    long row = blockIdx.x;
    float* p = scores + row * kS;
    int tid = threadIdx.x; // 256
    __shared__ float red[256];
    float x0 = p[tid], x1 = p[tid + 256];
    red[tid] = fmaxf(x0, x1); __syncthreads();
    for (int off = 128; off > 0; off >>= 1) { if (tid < off) red[tid] = fmaxf(red[tid], red[tid + off]); __syncthreads(); }
    float mx = red[0]; __syncthreads();
    float e0 = expf(x0 - mx), e1 = expf(x1 - mx);
    red[tid] = e0 + e1; __syncthreads();
    for (int off = 128; off > 0; off >>= 1) { if (tid < off) red[tid] += red[tid + off]; __syncthreads(); }
    float inv = 1.f / red[0];
    p[tid] = e0 * inv; p[tid + 256] = e1 * inv;
}

// ---------------- ctx partial = P @ V over K-chunk (4-way split), per head ----------------
// part layout: [s][m][kH] with head h occupying columns h*64..h*64+63
__global__ __launch_bounds__(256) void attn_ctx_split_kernel(const float* __restrict__ P,
                                                             const float* __restrict__ V,
                                                             float* __restrict__ part) {
    __shared__ float As[2][16][68];
    __shared__ float Bs[2][16][64];
    int q0 = blockIdx.x * 64;
    int h = blockIdx.y >> 2, s = blockIdx.y & 3;
    int tid = threadIdx.x;
    int tx = tid & 15, ty = tid >> 4;
    int arow = tid >> 2, akq = (tid & 3) * 4;
    int brow = tid >> 4, bnq = (tid & 15) * 4;
    int kbeg = s * 128;
    const float* Aptr = P + ((long)h * kS + q0 + arow) * kS + kbeg + akq;
    const float* Bptr = V + (long)(kbeg + brow) * kH + h * kDH + bnq;
    float acc[4][4] = {};
    mm_chunk_loop(Aptr, true, Bptr, kH, 128 / 16, As, Bs, arow, akq, brow, bnq, tx, ty, acc);
    float* Pp = part + (long)s * kS * kH + (long)(q0 + ty * 4) * kH + h * kDH + tx * 4;
    #pragma unroll
    for (int i = 0; i < 4; i++) {
        float4 vv; vv.x = acc[i][0]; vv.y = acc[i][1]; vv.z = acc[i][2]; vv.w = acc[i][3];
        *(float4*)(Pp + (long)i * kH) = vv;
    }
}

// ---------------- GCN kernels ----------------
__global__ void maskbias_kernel(const int* mask, float* mb) {
    int i = blockIdx.x * blockDim.x + threadIdx.x;
    if (i < kS) mb[i] = (1.f - (float)mask[i]) * -1e4f;
}

// count in-edges per destination (int)
__global__ void cnt_kernel(const int* __restrict__ dst, int* __restrict__ cnt, int E) {
    int e = blockIdx.x * blockDim.x + threadIdx.x;
    if (e < E) atomicAdd(&cnt[dst[e]], 1);
}

// block-local exclusive scan (Hillis-Steele inclusive, then subtract self)
__global__ void scan1_kernel(const int* __restrict__ cnt, int* __restrict__ offs,
                             int* __restrict__ bsum, int n) {
    __shared__ int sh[256];
    int i = blockIdx.x * 256 + threadIdx.x;
    int v = (i < n) ? cnt[i] : 0;
    sh[threadIdx.x] = v; __syncthreads();
    for (int off = 1; off < 256; off <<= 1) {
        int t = (threadIdx.x >= off) ? sh[threadIdx.x - off] : 0;
        __syncthreads();
        sh[threadIdx.x] += t;
        __syncthreads();
    }
    if (i < n) offs[i] = sh[threadIdx.x] - v;   // exclusive within block
    if (threadIdx.x == 255) bsum[blockIdx.x] = sh[255];
}

// exclusive scan of block sums (tiny: nb=196) + write offs[n] = total
__global__ void scan2_kernel(int* bsum, int nb, int* offs, int n) {
    if (threadIdx.x == 0) {
        int run = 0;
        for (int b = 0; b < nb; b++) { int t = bsum[b]; bsum[b] = run; run += t; }
        offs[n] = run;
    }
}

// finalize offsets, init running cursors, compute dinv = rsqrt(cnt+1)
__global__ void scan3_kernel(const int* __restrict__ cnt, int* __restrict__ offs,
                             const int* __restrict__ bsum, int* __restrict__ cur,
                             float* __restrict__ dinv, int n) {
    int i = blockIdx.x * 256 + threadIdx.x;
    if (i >= n) return;
    int o = offs[i] + bsum[blockIdx.x];
    offs[i] = o; cur[i] = o;
    dinv[i] = rsqrtf((float)(cnt[i] + 1));
}

// fused: scatter edge sources into dst-CSR slots + accumulate per-src outgoing weight
__global__ void csrfill_edgew_kernel(const int* __restrict__ src, const int* __restrict__ dst,
                                     int* __restrict__ cur, int* __restrict__ csr,
                                     const float* __restrict__ dinv, float* __restrict__ wsum,
                                     int E) {
    int e = blockIdx.x * blockDim.x + threadIdx.x;
    if (e < E) {
        int s2 = src[e], d = dst[e];
        int slot = atomicAdd(&cur[d], 1);
        csr[slot] = s2;
        atomicAdd(&wsum[s2], dinv[s2] * dinv[d]);
    }
}

// gather SpMM + fused self-loop/bias/relu:
//   h[d][j] = relu( dinv[d]*sum_{e:dst=d} dinv[src]*hw[src][j] + dinv[d]^2*hw[d][j] + b1[j] )
// 2 nodes per 256-thread block, 128 lanes per node (one column each).
__global__ __launch_bounds__(256) void spmm_gather_kernel(const int* __restrict__ offs,
                                                          const int* __restrict__ csr,
                                                          const float* __restrict__ dinv,
                                                          const float* __restrict__ hw,
                                                          const float* __restrict__ b1,
                                                          float* __restrict__ hout, int n) {
    int d = blockIdx.x * 2 + (threadIdx.x >> 7);
    int j = threadIdx.x & 127;
    if (d >= n) return;
    int beg = offs[d], end = offs[d + 1];
    float acc = 0.f;
    for (int p = beg; p < end; ++p) {
        int s2 = csr[p];
        acc += dinv[s2] * hw[(long)s2 * kGH + j];
    }
    float dd = dinv[d];
    float v = acc * dd + dd * dd * hw[(long)d * kGH + j] + b1[j];
    hout[(long)d * kGH + j] = fmaxf(v, 0.f);
}

// s[j] = sum_u (w[u] + dinv[u]^2) * h[u][j]
__global__ void wreduce_kernel(const float* __restrict__ h, const float* __restrict__ w,
                               const float* __restrict__ dinv, float* __restrict__ s, int n) {
    int tid = threadIdx.x; int j = tid & 127; int half = tid >> 7;
    float acc = 0.f;
    for (int u = blockIdx.x * 2 + half; u < n; u += gridDim.x * 2) {
        float di = dinv[u];
        acc += (w[u] + di * di) * h[(long)u * kGH + j];
    }
    __shared__ float red[256];
    red[tid] = acc; __syncthreads();
    if (tid < 128) atomicAdd(&s[j], red[tid] + red[tid + 128]);
}

// g[j2] = (s @ W2)[j2]/N + b2[j2]
__global__ void gcn_final_kernel(const float* s, const float* W2, const float* b2, float* g) {
    int j2 = threadIdx.x; // 128
    float acc = 0.f;
    for (int j = 0; j < kGH; j++) acc += s[j] * W2[(long)j * kGH + j2];
    g[j2] = acc * (1.f / (float)kN) + b2[j2];
}

// ---------------- combine head ----------------
__global__ void combine_kernel(const float* __restrict__ cls, const float* __restrict__ gp,
                               const float* __restrict__ gh, const float* __restrict__ Wc,
                               const float* __restrict__ bc, float* __restrict__ feat) {
    int o = blockIdx.x * blockDim.x + threadIdx.x;
    if (o >= kH) return;
    float acc = 0.f;
    for (int i = 0; i < 768; i++)  acc += cls[i] * Wc[(long)i * kH + o];
    for (int i = 0; i < 128; i++)  acc += gp[i] * Wc[(long)(768 + i) * kH + o];
    for (int i = 0; i < 768; i++)  acc += cls[i] * Wc[(long)(896 + i) * kH + o];
    for (int i = 0; i < 128; i++)  acc += gh[i] * Wc[(long)(1664 + i) * kH + o];
    feat[o] = fmaxf(acc + bc[o], 0.f);
}

__global__ void cls_head_kernel(const float* feat, const float* W, const float* b, float* out) {
    int tid = threadIdx.x; // 256
    float a0 = 0.f, a1 = 0.f, a2 = 0.f;
    for (int o = tid; o < kH; o += 256) {
        float f = feat[o];
        a0 += f * W[o * 3 + 0]; a1 += f * W[o * 3 + 1]; a2 += f * W[o * 3 + 2];
    }
    __shared__ float r0[256], r1[256], r2[256];
    r0[tid] = a0; r1[tid] = a1; r2[tid] = a2; __syncthreads();
    for (int off = 128; off > 0; off >>= 1) {
        if (tid < off) { r0[tid] += r0[tid + off]; r1[tid] += r1[tid + off]; r2[tid] += r2[tid + off]; }
        __syncthreads();
    }
    if (tid == 0) { out[0] = r0[0] + b[0]; out[1] = r1[0] + b[1]; out[2] = r2[0] + b[2]; }
}

// ---------------- launch ----------------
extern "C" void kernel_launch(void* const* d_in, const int* in_sizes, int n_in,
                              void* d_out, int out_size, void* d_ws, size_t ws_size,
                              hipStream_t stream) {
    const int*   input_ids = (const int*)d_in[0];
    const int*   attn_mask = (const int*)d_in[1];
    const int*   type_ids  = (const int*)d_in[2];
    const int*   p_edges   = (const int*)d_in[3];
    const int*   h_edges   = (const int*)d_in[4];
    const float* p_nodes   = (const float*)d_in[5];
    const float* h_nodes   = (const float*)d_in[6];
    const float* word_emb  = (const float*)d_in[7];
    const float* pos_emb   = (const float*)d_in[8];
    const float* type_emb  = (const float*)d_in[9];
    const float* eln_s     = (const float*)d_in[10];
    const float* eln_b     = (const float*)d_in[11];
    const float* Wq = (const float*)d_in[12]; const float* bq = (const float*)d_in[13];
    const float* Wk = (const float*)d_in[14]; const float* bk = (const float*)d_in[15];
    const float* Wv = (const float*)d_in[16]; const float* bv = (const float*)d_in[17];
    const float* Wo = (const float*)d_in[18]; const float* bo = (const float*)d_in[19];
    const float* l1s = (const float*)d_in[20]; const float* l1b = (const float*)d_in[21];
    const float* W1 = (const float*)d_in[22]; const float* b1 = (const float*)d_in[23];
    const float* W2 = (const float*)d_in[24]; const float* b2 = (const float*)d_in[25];
    const float* l2s = (const float*)d_in[26]; const float* l2b = (const float*)d_in[27];
    const float* gW1 = (const float*)d_in[28]; const float* gb1 = (const float*)d_in[29];
    const float* gW2 = (const float*)d_in[30]; const float* gb2 = (const float*)d_in[31];
    const float* cW  = (const float*)d_in[32]; const float* cb  = (const float*)d_in[33];
    const float* clsW = (const float*)d_in[34]; const float* clsB = (const float*)d_in[35];
    float* out = (float*)d_out;

    // workspace layout (floats)
    float* W = (float*)d_ws;
    size_t off = 0;
    auto alloc = [&](size_t n) { float* p = W + off; off += n; return p; };
    float* h    = alloc((size_t)kS * kH);
    float* q    = alloc((size_t)kS * kH);
    float* k    = alloc((size_t)kS * kH);
    float* v    = alloc((size_t)kS * kH);
    float* ctx  = alloc((size_t)kS * kH);
    float* tmp  = alloc((size_t)kS * kH);
    float* h1   = alloc((size_t)kS * kH);
    float* ffn2 = alloc((size_t)kS * kH);
    float* deg  = alloc(kN);
    float* wsum = alloc(kN);
    float* svec = alloc(kGH);
    float* gp   = alloc(kGH);
    float* ghv  = alloc(kGH);
    float* mb   = alloc(kS);
    float* feat = alloc(kH);
    float* big  = W + off;   // reused region, 12.8M floats (GCN) / scores+ffn1+part (BERT)
    // GCN phase:
    float* hw1  = big;
    float* agg  = big + (size_t)kN * kGH;
    // GCN CSR scratch aliased onto BERT-phase buffers (dead during GCN):
    int* icnt  = (int*)tmp;   // [kN]   in-edge counts
    int* ioffs = (int*)ctx;   // [kN+1] CSR offsets
    int* icur  = (int*)h1;    // [kN]   running cursors for fill
    int* ibsum = (int*)ffn2;  // [196]  scan block sums
    int* icsr  = (int*)q;     // [kE]   edge sources, spans q..k..v (contiguous)
    // BERT phase (all within the 12.8M-float big region):
    float* scores = big;                                        // 3.146M floats
    float* ffn1   = big + (size_t)kNH * kS * kS;                // 1.573M floats
    float* part   = ffn1 + (size_t)kS * kF;                     // up to 4.72M floats

    const long MN_H = (long)kS * kH;   // 393216
    const long MN_F = (long)kS * kF;   // 1572864
    const int nScanBlk = CDIV(kN, 256); // 196

    // ---------- GCN on both graphs (before BERT; shares `big`) ----------
    const int* gsrc[2] = { p_edges, h_edges };
    const int* gdst[2] = { p_edges + kE, h_edges + kE };
    const float* gx[2] = { p_nodes, h_nodes };
    float* gout[2] = { gp, ghv };
    for (int gi = 0; gi < 2; gi++) {
        fill_kernel<<<CDIV((long)kN, 256), 256, 0, stream>>>((float*)icnt, 0.f, kN); // int 0
        fill_kernel<<<CDIV((long)kN, 256), 256, 0, stream>>>(wsum, 0.f, kN);
        fill_kernel<<<1, 256, 0, stream>>>(svec, 0.f, kGH);
        // ---- build dst-CSR (counting sort) + dinv ----
        cnt_kernel<<<CDIV(kE, 256), 256, 0, stream>>>(gdst[gi], icnt, kE);
        scan1_kernel<<<nScanBlk, 256, 0, stream>>>(icnt, ioffs, ibsum, kN);
        scan2_kernel<<<1, 64, 0, stream>>>(ibsum, nScanBlk, ioffs, kN);
        scan3_kernel<<<nScanBlk, 256, 0, stream>>>(icnt, ioffs, ibsum, icur, deg, kN);
        csrfill_edgew_kernel<<<CDIV(kE, 256), 256, 0, stream>>>(
            gsrc[gi], gdst[gi], icur, icsr, deg, wsum, kE);
        // hw1 = x @ gW1  (50000x768 @ 768x128), direct write path
        gemm_sk128_kernel<<<dim3(kGH / 64, CDIV(kN, 128), 1), 256, 0, stream>>>(
            gx[gi], Ptr3{{gW1, nullptr, nullptr}}, nullptr, hw1, nullptr, kN, kGH, kH, 1, 0);
        // gather SpMM (no atomics) + fused self-loop/bias/relu
        spmm_gather_kernel<<<CDIV(kN, 2), 256, 0, stream>>>(ioffs, icsr, deg, hw1, gb1, agg, kN);
        wreduce_kernel<<<512, 256, 0, stream>>>(agg, wsum, deg, svec, kN);
        gcn_final_kernel<<<1, kGH, 0, stream>>>(svec, gW2, gb2, gout[gi]);
    }

    // ---------- BERT ----------
    maskbias_kernel<<<2, 256, 0, stream>>>(attn_mask, mb);
    embed_ln_kernel<<<kS, 256, 0, stream>>>(input_ids, type_ids, word_emb, pos_emb, type_emb,
                                            eln_s, eln_b, h);
    for (int l = 0; l < kL; l++) {
        const float* Wq_l = Wq + (size_t)l * kH * kH; const float* bq_l = bq + (size_t)l * kH;
        const float* Wk_l = Wk + (size_t)l * kH * kH; const float* bk_l = bk + (size_t)l * kH;
        const float* Wv_l = Wv + (size_t)l * kH * kH; const float* bv_l = bv + (size_t)l * kH;
        const float* Wo_l = Wo + (size_t)l * kH * kH; const float* bo_l = bo + (size_t)l * kH;
        const float* W1_l = W1 + (size_t)l * kH * kF; const float* b1_l = b1 + (size_t)l * kF;
        const float* W2_l = W2 + (size_t)l * kF * kH; const float* b2_l = b2 + (size_t)l * kH;
        const float* l1s_l = l1s + (size_t)l * kH; const float* l1b_l = l1b + (size_t)l * kH;
        const float* l2s_l = l2s + (size_t)l * kH; const float* l2b_l = l2b + (size_t)l * kH;

        // QKV fused: nW=3, S=4 -> 576 blocks (12 partials of MN_H)
        gemm_sk128_kernel<<<dim3(kH / 64, kS / 128, 12), 256, 0, stream>>>(
            h, Ptr3{{Wq_l, Wk_l, Wv_l}}, part, nullptr, nullptr, kS, kH, kH, 4, 0);
        splitk_epi_kernel<<<dim3((int)(MN_H / 4 / 256), 3), 256, 0, stream>>>(
            part, Ptr3{{bq_l, bk_l, bv_l}}, Out3{{q, k, v}}, MN_H, kH, 4, 0);
        attn_scores_kernel<<<dim3(kS / 64, kS / 64, kNH), 256, 0, stream>>>(q, k, mb, scores);
        softmax_kernel<<<kNH * kS, 256, 0, stream>>>(scores);
        // ctx: K-split 4 -> 384 blocks, deterministic partial + epilogue
        attn_ctx_split_kernel<<<dim3(kS / 64, kNH * 4), 256, 0, stream>>>(scores, v, part);
        splitk_epi_kernel<<<dim3((int)(MN_H / 4 / 256), 1), 256, 0, stream>>>(
            part, Ptr3{{nullptr, nullptr, nullptr}}, Out3{{ctx, nullptr, nullptr}}, MN_H, kH, 4, 0);
        // Wo: S=6 -> 288 blocks
        gemm_sk128_kernel<<<dim3(kH / 64, kS / 128, 6), 256, 0, stream>>>(
            ctx, Ptr3{{Wo_l, nullptr, nullptr}}, part, nullptr, nullptr, kS, kH, kH, 6, 0);
        splitk_epi_kernel<<<dim3((int)(MN_H / 4 / 256), 1), 256, 0, stream>>>(
            part, Ptr3{{bo_l, nullptr, nullptr}}, Out3{{tmp, nullptr, nullptr}}, MN_H, kH, 6, 0);
        ln_residual_kernel<<<kS, 256, 0, stream>>>(tmp, h, l1s_l, l1b_l, h1);
        // FFN1: S=3 -> 576 blocks, gelu in epilogue
        gemm_sk128_kernel<<<dim3(kF / 64, kS / 128, 3), 256, 0, stream>>>(
            h1, Ptr3{{W1_l, nullptr, nullptr}}, part, nullptr, nullptr, kS, kF, kH, 3, 0);
        splitk_epi_kernel<<<dim3((int)(MN_F / 4 / 256), 1), 256, 0, stream>>>(
            part, Ptr3{{b1_l, nullptr, nullptr}}, Out3{{ffn1, nullptr, nullptr}}, MN_F, kF, 3, 1);
        // FFN2: S=12 -> 576 blocks
        gemm_sk128_kernel<<<dim3(kH / 64, kS / 128, 12), 256, 0, stream>>>(
            ffn1, Ptr3{{W2_l, nullptr, nullptr}}, part, nullptr, nullptr, kS, kH, kF, 12, 0);
        splitk_epi_kernel<<<dim3((int)(MN_H / 4 / 256), 1), 256, 0, stream>>>(
            part, Ptr3{{b2_l, nullptr, nullptr}}, Out3{{ffn2, nullptr, nullptr}}, MN_H, kH, 12, 0);
        ln_residual_kernel<<<kS, 256, 0, stream>>>(ffn2, h1, l2s_l, l2b_l, h);
    }

    // ---------- combine + classifier ----------
    combine_kernel<<<3, 256, 0, stream>>>(h, gp, ghv, cW, cb, feat);
    cls_head_kernel<<<1, 256, 0, stream>>>(feat, clsW, clsB, out);
}

// Round 3
// 3136.233 us; speedup vs baseline: 1.3846x; 1.3846x over previous
//
#include <hip/hip_runtime.h>
#include <math.h>

// Problem constants
constexpr int kS = 512, kH = 768, kNH = 12, kDH = 64, kF = 3072, kL = 12;
constexpr int kN = 50000, kE = 800000, kGH = 128;

#define CDIV(a,b) (((a)+(b)-1)/(b))

struct Ptr3 { const float* p[3]; };
struct Out3 { float* p[3]; };

typedef __attribute__((ext_vector_type(8))) short bf16x8;
typedef __attribute__((ext_vector_type(4))) float f32x4;

__device__ __forceinline__ unsigned short bf16_rne(float f) {
    unsigned int u = __float_as_uint(f);
    u += 0x7fffu + ((u >> 16) & 1u);
    return (unsigned short)(u >> 16);
}
__device__ __forceinline__ float bf16_f32(unsigned short h) {
    return __uint_as_float(((unsigned int)h) << 16);
}

// ---------------- generic fill ----------------
__global__ void fill_kernel(float* p, float v, long n) {
    long i = blockIdx.x * (long)blockDim.x + threadIdx.x;
    if (i < n) p[i] = v;
}

// ---------------- embeddings + LN ----------------
__global__ void embed_ln_kernel(const int* ids, const int* tt,
                                const float* we, const float* pe, const float* te,
                                const float* g, const float* b, float* out) {
    int s = blockIdx.x;            // one block per token
    int tid = threadIdx.x;         // 256 threads, 3 elems each
    __shared__ float red[256];
    int id = ids[s], t = tt[s];
    float vals[3]; float sum = 0.f;
    #pragma unroll
    for (int r = 0; r < 3; r++) {
        int j = tid + r * 256;
        float x = we[(long)id * kH + j] + pe[(long)s * kH + j] + te[(long)t * kH + j];
        vals[r] = x; sum += x;
    }
    red[tid] = sum; __syncthreads();
    for (int off = 128; off > 0; off >>= 1) { if (tid < off) red[tid] += red[tid + off]; __syncthreads(); }
    float mean = red[0] / kH; __syncthreads();
    float vs = 0.f;
    #pragma unroll
    for (int r = 0; r < 3; r++) { float d = vals[r] - mean; vs += d * d; }
    red[tid] = vs; __syncthreads();
    for (int off = 128; off > 0; off >>= 1) { if (tid < off) red[tid] += red[tid + off]; __syncthreads(); }
    float rstd = rsqrtf(red[0] / kH + 1e-12f);
    #pragma unroll
    for (int r = 0; r < 3; r++) {
        int j = tid + r * 256;
        out[(long)s * kH + j] = (vals[r] - mean) * rstd * g[j] + b[j];
    }
}

// ---------------- LN(res + a) ----------------
__global__ void ln_residual_kernel(const float* a, const float* res,
                                   const float* g, const float* b, float* out) {
    int s = blockIdx.x; int tid = threadIdx.x;
    __shared__ float red[256];
    float vals[3]; float sum = 0.f;
    #pragma unroll
    for (int r = 0; r < 3; r++) {
        int j = tid + r * 256;
        float x = a[(long)s * kH + j] + res[(long)s * kH + j];
        vals[r] = x; sum += x;
    }
    red[tid] = sum; __syncthreads();
    for (int off = 128; off > 0; off >>= 1) { if (tid < off) red[tid] += red[tid + off]; __syncthreads(); }
    float mean = red[0] / kH; __syncthreads();
    float vs = 0.f;
    #pragma unroll
    for (int r = 0; r < 3; r++) { float d = vals[r] - mean; vs += d * d; }
    red[tid] = vs; __syncthreads();
    for (int off = 128; off > 0; off >>= 1) { if (tid < off) red[tid] += red[tid + off]; __syncthreads(); }
    float rstd = rsqrtf(red[0] / kH + 1e-12f);
    #pragma unroll
    for (int r = 0; r < 3; r++) {
        int j = tid + r * 256;
        out[(long)s * kH + j] = (vals[r] - mean) * rstd * g[j] + b[j];
    }
}

// ---------------- double-buffered 64x64 tile K-chunk MACC loop (used by attn ctx) ----------------
__device__ __forceinline__ void mm_chunk_loop(
    const float* __restrict__ Aptr, bool avalid,
    const float* __restrict__ Bptr, long bstride, int nch,
    float (*As)[16][68], float (*Bs)[16][64],
    int arow, int akq, int brow, int bnq, int tx, int ty, float (&acc)[4][4])
{
    float4 av = avalid ? *(const float4*)Aptr : make_float4(0.f, 0.f, 0.f, 0.f);
    float4 bv = *(const float4*)Bptr;
    As[0][akq + 0][arow] = av.x; As[0][akq + 1][arow] = av.y;
    As[0][akq + 2][arow] = av.z; As[0][akq + 3][arow] = av.w;
    *(float4*)&Bs[0][brow][bnq] = bv;
    for (int c = 0; c < nch; ++c) {
        if (c + 1 < nch) {
            av = avalid ? *(const float4*)(Aptr + (c + 1) * 16) : make_float4(0.f, 0.f, 0.f, 0.f);
            bv = *(const float4*)(Bptr + (long)(c + 1) * 16 * bstride);
        }
        __syncthreads();
        int cb = c & 1;
        #pragma unroll
        for (int kk = 0; kk < 16; ++kk) {
            float4 a = *(const float4*)&As[cb][kk][ty * 4];
            float4 b = *(const float4*)&Bs[cb][kk][tx * 4];
            acc[0][0] += a.x * b.x; acc[0][1] += a.x * b.y; acc[0][2] += a.x * b.z; acc[0][3] += a.x * b.w;
            acc[1][0] += a.y * b.x; acc[1][1] += a.y * b.y; acc[1][2] += a.y * b.z; acc[1][3] += a.y * b.w;
            acc[2][0] += a.z * b.x; acc[2][1] += a.z * b.y; acc[2][2] += a.z * b.z; acc[2][3] += a.z * b.w;
            acc[3][0] += a.w * b.x; acc[3][1] += a.w * b.y; acc[3][2] += a.w * b.z; acc[3][3] += a.w * b.w;
        }
        if (c + 1 < nch) {
            int nb = cb ^ 1;
            As[nb][akq + 0][arow] = av.x; As[nb][akq + 1][arow] = av.y;
            As[nb][akq + 2][arow] = av.z; As[nb][akq + 3][arow] = av.w;
            *(float4*)&Bs[nb][brow][bnq] = bv;
        }
    }
}

// ---------------- split-K MFMA GEMM (bf16x3 emulated fp32): C[M,N] = A[M,K] @ B[K,N] ----------------
// 128x128 tile, 4 waves (2x2), each wave 4x4 fragments of 16x16, BK=32.
// A, B staged to LDS pre-split into hi/lo bf16. Partials to part[(w*S+s)*M*N].
__global__ __launch_bounds__(256, 4) void gemm_mfma_kernel(
    const float* __restrict__ A, Ptr3 Bp, float* __restrict__ part,
    int M, int Nn, int K, int S)
{
    constexpr int LDK = 40;   // 32 bf16 + 8 pad: 16B-aligned rows, spread banks
    __shared__ short Ah[128 * LDK], Al[128 * LDK], Bh[128 * LDK], Bl[128 * LDK]; // 40960 B
    int w = blockIdx.z / S, s = blockIdx.z % S;
    const float* B = Bp.p[w];
    int Kc = K / S;                 // multiple of 32 in all uses
    int m0 = blockIdx.y * 128, n0 = blockIdx.x * 128;
    int tid = threadIdx.x;
    // staging: A rows 0..127, 2 threads/row (16 floats each); B cols 0..127, 2 k-halves
    int sar = tid >> 1, sac = (tid & 1) * 16;
    int sbc = tid & 127, sbk = (tid >> 7) * 16;
    int gmA = m0 + sar; if (gmA > M - 1) gmA = M - 1;   // clamp; garbage rows guarded at store
    const float* Ag0 = A + (long)gmA * K + s * Kc + sac;
    const float* Bg0 = B + (long)(s * Kc + sbk) * Nn + n0 + sbc;
    // wave/fragment indices
    int wid = tid >> 6, lane = tid & 63;
    int wm = (wid >> 1) * 64, wn = (wid & 1) * 64;
    int fr = lane & 15, ko = (lane >> 4) * 8;
    f32x4 acc[4][4];
    #pragma unroll
    for (int i = 0; i < 4; i++)
        #pragma unroll
        for (int j = 0; j < 4; j++) acc[i][j] = (f32x4){0.f, 0.f, 0.f, 0.f};
    int nst = Kc / 32;
    for (int st = 0; st < nst; ++st) {
        // ---- stage A tile (128x32) as hi/lo bf16, [m][k] ----
        {
            const float* Ag = Ag0 + st * 32;
            int ob = sar * LDK + sac;
            #pragma unroll
            for (int qg = 0; qg < 4; qg++) {
                float4 f = *(const float4*)(Ag + qg * 4);
                unsigned short h0 = bf16_rne(f.x), h1 = bf16_rne(f.y),
                               h2 = bf16_rne(f.z), h3 = bf16_rne(f.w);
                unsigned short g0 = bf16_rne(f.x - bf16_f32(h0)), g1 = bf16_rne(f.y - bf16_f32(h1)),
                               g2 = bf16_rne(f.z - bf16_f32(h2)), g3 = bf16_rne(f.w - bf16_f32(h3));
                *(short4*)&Ah[ob + qg * 4] = make_short4((short)h0, (short)h1, (short)h2, (short)h3);
                *(short4*)&Al[ob + qg * 4] = make_short4((short)g0, (short)g1, (short)g2, (short)g3);
            }
        }
        // ---- stage B tile (32x128) transposed to [n][k], hi/lo bf16 ----
        {
            const float* Bg = Bg0 + (long)st * 32 * Nn;
            int ob = sbc * LDK + sbk;
            #pragma unroll
            for (int qg = 0; qg < 4; qg++) {
                float f0 = Bg[(long)(qg * 4 + 0) * Nn];
                float f1 = Bg[(long)(qg * 4 + 1) * Nn];
                float f2 = Bg[(long)(qg * 4 + 2) * Nn];
                float f3 = Bg[(long)(qg * 4 + 3) * Nn];
                unsigned short h0 = bf16_rne(f0), h1 = bf16_rne(f1),
                               h2 = bf16_rne(f2), h3 = bf16_rne(f3);
                unsigned short g0 = bf16_rne(f0 - bf16_f32(h0)), g1 = bf16_rne(f1 - bf16_f32(h1)),
                               g2 = bf16_rne(f2 - bf16_f32(h2)), g3 = bf16_rne(f3 - bf16_f32(h3));
                *(short4*)&Bh[ob + qg * 4] = make_short4((short)h0, (short)h1, (short)h2, (short)h3);
                *(short4*)&Bl[ob + qg * 4] = make_short4((short)g0, (short)g1, (short)g2, (short)g3);
            }
        }
        __syncthreads();
        // ---- fragments + 48 MFMAs ----
        bf16x8 bh[4], bl[4];
        #pragma unroll
        for (int j = 0; j < 4; j++) {
            int c = (wn + j * 16 + fr) * LDK + ko;
            bh[j] = *(const bf16x8*)&Bh[c];
            bl[j] = *(const bf16x8*)&Bl[c];
        }
        #pragma unroll
        for (int i = 0; i < 4; i++) {
            int r = (wm + i * 16 + fr) * LDK + ko;
            bf16x8 ah = *(const bf16x8*)&Ah[r];
            bf16x8 al = *(const bf16x8*)&Al[r];
            #pragma unroll
            for (int j = 0; j < 4; j++) {
                acc[i][j] = __builtin_amdgcn_mfma_f32_16x16x32_bf16(ah, bh[j], acc[i][j], 0, 0, 0);
                acc[i][j] = __builtin_amdgcn_mfma_f32_16x16x32_bf16(ah, bl[j], acc[i][j], 0, 0, 0);
                acc[i][j] = __builtin_amdgcn_mfma_f32_16x16x32_bf16(al, bh[j], acc[i][j], 0, 0, 0);
            }
        }
        __syncthreads();
    }
    // ---- write partials. C/D map: col = lane&15, row = (lane>>4)*4 + reg ----
    long MN = (long)M * Nn;
    float* Pp = part + (long)(w * S + s) * MN;
    int cr = (lane >> 4) * 4;
    #pragma unroll
    for (int i = 0; i < 4; i++) {
        #pragma unroll
        for (int r = 0; r < 4; r++) {
            int gm = m0 + wm + i * 16 + cr + r;
            if (gm >= M) continue;
            float* rowp = &Pp[(long)gm * Nn + n0 + wn + fr];
            #pragma unroll
            for (int j = 0; j < 4; j++) rowp[j * 16] = acc[i][j][r];
        }
    }
}

// ---------------- split-K epilogue: out = act(sum_s part + bias) ----------------
// NOTE: no __restrict__ on part — GCN path sums in place (out aliases partial 0).
__global__ void splitk_epi_kernel(const float* part, Ptr3 bias, Out3 outp,
                                  long MN, int Nn, int S, int act) {
    int w = blockIdx.y;
    long i = ((long)blockIdx.x * blockDim.x + threadIdx.x) * 4;
    if (i >= MN) return;
    const float* P = part + (long)w * S * MN + i;
    float4 a = *(const float4*)P;
    for (int s2 = 1; s2 < S; ++s2) {
        float4 b = *(const float4*)(P + (long)s2 * MN);
        a.x += b.x; a.y += b.y; a.z += b.z; a.w += b.w;
    }
    const float* bw = bias.p[w];
    if (bw) {
        int n = (int)(i % Nn);
        a.x += bw[n]; a.y += bw[n + 1]; a.z += bw[n + 2]; a.w += bw[n + 3];
    }
    if (act == 1) {
        a.x = 0.5f * a.x * (1.f + erff(a.x * 0.70710678118654752f));
        a.y = 0.5f * a.y * (1.f + erff(a.y * 0.70710678118654752f));
        a.z = 0.5f * a.z * (1.f + erff(a.z * 0.70710678118654752f));
        a.w = 0.5f * a.w * (1.f + erff(a.w * 0.70710678118654752f));
    } else if (act == 2) {
        a.x = fmaxf(a.x, 0.f); a.y = fmaxf(a.y, 0.f); a.z = fmaxf(a.z, 0.f); a.w = fmaxf(a.w, 0.f);
    }
    *(float4*)(outp.p[w] + i) = a;
}

// ---------------- attention: scores = Q K^T / 8 + maskbias ----------------
__global__ __launch_bounds__(256) void attn_scores_kernel(const float* __restrict__ Q,
                                                          const float* __restrict__ K,
                                                          const float* __restrict__ mb,
                                                          float* __restrict__ scores) {
    int h = blockIdx.z;
    int q0 = blockIdx.y * 64, k0 = blockIdx.x * 64;
    __shared__ float Qs[16][65], Ks[16][65];
    int tid = threadIdx.x; int tx = tid & 15, ty = tid >> 4;
    float acc[4][4] = {};
    for (int d0 = 0; d0 < kDH; d0 += 16) {
        #pragma unroll
        for (int r = 0; r < 4; r++) {
            int ii = r * 256 + tid; int m = ii >> 4, kk = ii & 15;
            Qs[kk][m] = Q[(long)(q0 + m) * kH + h * kDH + d0 + kk];
            Ks[kk][m] = K[(long)(k0 + m) * kH + h * kDH + d0 + kk];
        }
        __syncthreads();
        #pragma unroll
        for (int kk = 0; kk < 16; kk++) {
            float a[4], bb[4];
            #pragma unroll
            for (int i = 0; i < 4; i++) a[i] = Qs[kk][ty * 4 + i];
            #pragma unroll
            for (int j = 0; j < 4; j++) bb[j] = Ks[kk][tx * 4 + j];
            #pragma unroll
            for (int i = 0; i < 4; i++)
                #pragma unroll
                for (int j = 0; j < 4; j++) acc[i][j] += a[i] * bb[j];
        }
        __syncthreads();
    }
    #pragma unroll
    for (int i = 0; i < 4; i++) {
        int qq = q0 + ty * 4 + i;
        #pragma unroll
        for (int j = 0; j < 4; j++) {
            int kkk = k0 + tx * 4 + j;
            scores[((long)h * kS + qq) * kS + kkk] = acc[i][j] * 0.125f + mb[kkk];
        }
    }
}

// ---------------- softmax over rows of 512 ----------------
__global__ void softmax_kernel(float* scores) {
    long row = blockIdx.x;
    float* p = scores + row * kS;
    int tid = threadIdx.x; // 256
    __shared__ float red[256];
    float x0 = p[tid], x1 = p[tid + 256];
    red[tid] = fmaxf(x0, x1); __syncthreads();
    for (int off = 128; off > 0; off >>= 1) { if (tid < off) red[tid] = fmaxf(red[tid], red[tid + off]); __syncthreads(); }
    float mx = red[0]; __syncthreads();
    float e0 = expf(x0 - mx), e1 = expf(x1 - mx);
    red[tid] = e0 + e1; __syncthreads();
    for (int off = 128; off > 0; off >>= 1) { if (tid < off) red[tid] += red[tid + off]; __syncthreads(); }
    float inv = 1.f / red[0];
    p[tid] = e0 * inv; p[tid + 256] = e1 * inv;
}

// ---------------- ctx partial = P @ V over K-chunk (4-way split), per head ----------------
// part layout: [s][m][kH] with head h occupying columns h*64..h*64+63
__global__ __launch_bounds__(256) void attn_ctx_split_kernel(const float* __restrict__ P,
                                                             const float* __restrict__ V,
                                                             float* __restrict__ part) {
    __shared__ float As[2][16][68];
    __shared__ float Bs[2][16][64];
    int q0 = blockIdx.x * 64;
    int h = blockIdx.y >> 2, s = blockIdx.y & 3;
    int tid = threadIdx.x;
    int tx = tid & 15, ty = tid >> 4;
    int arow = tid >> 2, akq = (tid & 3) * 4;
    int brow = tid >> 4, bnq = (tid & 15) * 4;
    int kbeg = s * 128;
    const float* Aptr = P + ((long)h * kS + q0 + arow) * kS + kbeg + akq;
    const float* Bptr = V + (long)(kbeg + brow) * kH + h * kDH + bnq;
    float acc[4][4] = {};
    mm_chunk_loop(Aptr, true, Bptr, kH, 128 / 16, As, Bs, arow, akq, brow, bnq, tx, ty, acc);
    float* Pp = part + (long)s * kS * kH + (long)(q0 + ty * 4) * kH + h * kDH + tx * 4;
    #pragma unroll
    for (int i = 0; i < 4; i++) {
        float4 vv; vv.x = acc[i][0]; vv.y = acc[i][1]; vv.z = acc[i][2]; vv.w = acc[i][3];
        *(float4*)(Pp + (long)i * kH) = vv;
    }
}

// ---------------- GCN kernels ----------------
__global__ void maskbias_kernel(const int* mask, float* mb) {
    int i = blockIdx.x * blockDim.x + threadIdx.x;
    if (i < kS) mb[i] = (1.f - (float)mask[i]) * -1e4f;
}

// count in-edges per destination (int)
__global__ void cnt_kernel(const int* __restrict__ dst, int* __restrict__ cnt, int E) {
    int e = blockIdx.x * blockDim.x + threadIdx.x;
    if (e < E) atomicAdd(&cnt[dst[e]], 1);
}

// block-local exclusive scan (Hillis-Steele inclusive, then subtract self)
__global__ void scan1_kernel(const int* __restrict__ cnt, int* __restrict__ offs,
                             int* __restrict__ bsum, int n) {
    __shared__ int sh[256];
    int i = blockIdx.x * 256 + threadIdx.x;
    int v = (i < n) ? cnt[i] : 0;
    sh[threadIdx.x] = v; __syncthreads();
    for (int off = 1; off < 256; off <<= 1) {
        int t = (threadIdx.x >= off) ? sh[threadIdx.x - off] : 0;
        __syncthreads();
        sh[threadIdx.x] += t;
        __syncthreads();
    }
    if (i < n) offs[i] = sh[threadIdx.x] - v;   // exclusive within block
    if (threadIdx.x == 255) bsum[blockIdx.x] = sh[255];
}

// exclusive scan of block sums (tiny: nb=196) + write offs[n] = total
__global__ void scan2_kernel(int* bsum, int nb, int* offs, int n) {
    if (threadIdx.x == 0) {
        int run = 0;
        for (int b = 0; b < nb; b++) { int t = bsum[b]; bsum[b] = run; run += t; }
        offs[n] = run;
    }
}

// finalize offsets, init running cursors, compute dinv = rsqrt(cnt+1)
__global__ void scan3_kernel(const int* __restrict__ cnt, int* __restrict__ offs,
                             const int* __restrict__ bsum, int* __restrict__ cur,
                             float* __restrict__ dinv, int n) {
    int i = blockIdx.x * 256 + threadIdx.x;
    if (i >= n) return;
    int o = offs[i] + bsum[blockIdx.x];
    offs[i] = o; cur[i] = o;
    dinv[i] = rsqrtf((float)(cnt[i] + 1));
}

// fused: scatter edge sources into dst-CSR slots + accumulate per-src outgoing weight
__global__ void csrfill_edgew_kernel(const int* __restrict__ src, const int* __restrict__ dst,
                                     int* __restrict__ cur, int* __restrict__ csr,
                                     const float* __restrict__ dinv, float* __restrict__ wsum,
                                     int E) {
    int e = blockIdx.x * blockDim.x + threadIdx.x;
    if (e < E) {
        int s2 = src[e], d = dst[e];
        int slot = atomicAdd(&cur[d], 1);
        csr[slot] = s2;
        atomicAdd(&wsum[s2], dinv[s2] * dinv[d]);
    }
}

// gather SpMM + fused self-loop/bias/relu
__global__ __launch_bounds__(256) void spmm_gather_kernel(const int* __restrict__ offs,
                                                          const int* __restrict__ csr,
                                                          const float* __restrict__ dinv,
                                                          const float* __restrict__ hw,
                                                          const float* __restrict__ b1,
                                                          float* __restrict__ hout, int n) {
    int d = blockIdx.x * 2 + (threadIdx.x >> 7);
    int j = threadIdx.x & 127;
    if (d >= n) return;
    int beg = offs[d], end = offs[d + 1];
    float acc = 0.f;
    for (int p = beg; p < end; ++p) {
        int s2 = csr[p];
        acc += dinv[s2] * hw[(long)s2 * kGH + j];
    }
    float dd = dinv[d];
    float v = acc * dd + dd * dd * hw[(long)d * kGH + j] + b1[j];
    hout[(long)d * kGH + j] = fmaxf(v, 0.f);
}

// s[j] = sum_u (w[u] + dinv[u]^2) * h[u][j]
__global__ void wreduce_kernel(const float* __restrict__ h, const float* __restrict__ w,
                               const float* __restrict__ dinv, float* __restrict__ s, int n) {
    int tid = threadIdx.x; int j = tid & 127; int half = tid >> 7;
    float acc = 0.f;
    for (int u = blockIdx.x * 2 + half; u < n; u += gridDim.x * 2) {
        float di = dinv[u];
        acc += (w[u] + di * di) * h[(long)u * kGH + j];
    }
    __shared__ float red[256];
    red[tid] = acc; __syncthreads();
    if (tid < 128) atomicAdd(&s[j], red[tid] + red[tid + 128]);
}

// g[j2] = (s @ W2)[j2]/N + b2[j2]
__global__ void gcn_final_kernel(const float* s, const float* W2, const float* b2, float* g) {
    int j2 = threadIdx.x; // 128
    float acc = 0.f;
    for (int j = 0; j < kGH; j++) acc += s[j] * W2[(long)j * kGH + j2];
    g[j2] = acc * (1.f / (float)kN) + b2[j2];
}

// ---------------- combine head ----------------
__global__ void combine_kernel(const float* __restrict__ cls, const float* __restrict__ gp,
                               const float* __restrict__ gh, const float* __restrict__ Wc,
                               const float* __restrict__ bc, float* __restrict__ feat) {
    int o = blockIdx.x * blockDim.x + threadIdx.x;
    if (o >= kH) return;
    float acc = 0.f;
    for (int i = 0; i < 768; i++)  acc += cls[i] * Wc[(long)i * kH + o];
    for (int i = 0; i < 128; i++)  acc += gp[i] * Wc[(long)(768 + i) * kH + o];
    for (int i = 0; i < 768; i++)  acc += cls[i] * Wc[(long)(896 + i) * kH + o];
    for (int i = 0; i < 128; i++)  acc += gh[i] * Wc[(long)(1664 + i) * kH + o];
    feat[o] = fmaxf(acc + bc[o], 0.f);
}

__global__ void cls_head_kernel(const float* feat, const float* W, const float* b, float* out) {
    int tid = threadIdx.x; // 256
    float a0 = 0.f, a1 = 0.f, a2 = 0.f;
    for (int o = tid; o < kH; o += 256) {
        float f = feat[o];
        a0 += f * W[o * 3 + 0]; a1 += f * W[o * 3 + 1]; a2 += f * W[o * 3 + 2];
    }
    __shared__ float r0[256], r1[256], r2[256];
    r0[tid] = a0; r1[tid] = a1; r2[tid] = a2; __syncthreads();
    for (int off = 128; off > 0; off >>= 1) {
        if (tid < off) { r0[tid] += r0[tid + off]; r1[tid] += r1[tid + off]; r2[tid] += r2[tid + off]; }
        __syncthreads();
    }
    if (tid == 0) { out[0] = r0[0] + b[0]; out[1] = r1[0] + b[1]; out[2] = r2[0] + b[2]; }
}

// ---------------- launch ----------------
extern "C" void kernel_launch(void* const* d_in, const int* in_sizes, int n_in,
                              void* d_out, int out_size, void* d_ws, size_t ws_size,
                              hipStream_t stream) {
    const int*   input_ids = (const int*)d_in[0];
    const int*   attn_mask = (const int*)d_in[1];
    const int*   type_ids  = (const int*)d_in[2];
    const int*   p_edges   = (const int*)d_in[3];
    const int*   h_edges   = (const int*)d_in[4];
    const float* p_nodes   = (const float*)d_in[5];
    const float* h_nodes   = (const float*)d_in[6];
    const float* word_emb  = (const float*)d_in[7];
    const float* pos_emb   = (const float*)d_in[8];
    const float* type_emb  = (const float*)d_in[9];
    const float* eln_s     = (const float*)d_in[10];
    const float* eln_b     = (const float*)d_in[11];
    const float* Wq = (const float*)d_in[12]; const float* bq = (const float*)d_in[13];
    const float* Wk = (const float*)d_in[14]; const float* bk = (const float*)d_in[15];
    const float* Wv = (const float*)d_in[16]; const float* bv = (const float*)d_in[17];
    const float* Wo = (const float*)d_in[18]; const float* bo = (const float*)d_in[19];
    const float* l1s = (const float*)d_in[20]; const float* l1b = (const float*)d_in[21];
    const float* W1 = (const float*)d_in[22]; const float* b1 = (const float*)d_in[23];
    const float* W2 = (const float*)d_in[24]; const float* b2 = (const float*)d_in[25];
    const float* l2s = (const float*)d_in[26]; const float* l2b = (const float*)d_in[27];
    const float* gW1 = (const float*)d_in[28]; const float* gb1 = (const float*)d_in[29];
    const float* gW2 = (const float*)d_in[30]; const float* gb2 = (const float*)d_in[31];
    const float* cW  = (const float*)d_in[32]; const float* cb  = (const float*)d_in[33];
    const float* clsW = (const float*)d_in[34]; const float* clsB = (const float*)d_in[35];
    float* out = (float*)d_out;

    // workspace layout (floats)
    float* W = (float*)d_ws;
    size_t off = 0;
    auto alloc = [&](size_t n) { float* p = W + off; off += n; return p; };
    float* h    = alloc((size_t)kS * kH);
    float* q    = alloc((size_t)kS * kH);
    float* k    = alloc((size_t)kS * kH);
    float* v    = alloc((size_t)kS * kH);
    float* ctx  = alloc((size_t)kS * kH);
    float* tmp  = alloc((size_t)kS * kH);
    float* h1   = alloc((size_t)kS * kH);
    float* ffn2 = alloc((size_t)kS * kH);
    float* deg  = alloc(kN);
    float* wsum = alloc(kN);
    float* svec = alloc(kGH);
    float* gp   = alloc(kGH);
    float* ghv  = alloc(kGH);
    float* mb   = alloc(kS);
    float* feat = alloc(kH);
    float* big  = W + off;   // reused region, 12.8M floats (GCN) / scores+ffn1+part (BERT)
    // GCN phase:
    float* hw1  = big;                         // also split-K partial base (2 x 6.4M)
    float* agg  = big + (size_t)kN * kGH;
    // GCN CSR scratch aliased onto BERT-phase buffers (dead during GCN):
    int* icnt  = (int*)tmp;   // [kN]   in-edge counts
    int* ioffs = (int*)ctx;   // [kN+1] CSR offsets
    int* icur  = (int*)h1;    // [kN]   running cursors for fill
    int* ibsum = (int*)ffn2;  // [196]  scan block sums
    int* icsr  = (int*)q;     // [kE]   edge sources, spans q..k..v (contiguous)
    // BERT phase (all within the 12.8M-float big region):
    float* scores = big;                                        // 3.146M floats
    float* ffn1   = big + (size_t)kNH * kS * kS;                // 1.573M floats
    float* part   = ffn1 + (size_t)kS * kF;                     // up to 4.72M floats

    const long MN_H = (long)kS * kH;   // 393216
    const long MN_F = (long)kS * kF;   // 1572864
    const long MN_G = (long)kN * kGH;  // 6400000
    const int nScanBlk = CDIV(kN, 256); // 196

    // ---------- GCN on both graphs (before BERT; shares `big`) ----------
    const int* gsrc[2] = { p_edges, h_edges };
    const int* gdst[2] = { p_edges + kE, h_edges + kE };
    const float* gx[2] = { p_nodes, h_nodes };
    float* gout[2] = { gp, ghv };
    for (int gi = 0; gi < 2; gi++) {
        fill_kernel<<<CDIV((long)kN, 256), 256, 0, stream>>>((float*)icnt, 0.f, kN); // int 0
        fill_kernel<<<CDIV((long)kN, 256), 256, 0, stream>>>(wsum, 0.f, kN);
        fill_kernel<<<1, 256, 0, stream>>>(svec, 0.f, kGH);
        // ---- build dst-CSR (counting sort) + dinv ----
        cnt_kernel<<<CDIV(kE, 256), 256, 0, stream>>>(gdst[gi], icnt, kE);
        scan1_kernel<<<nScanBlk, 256, 0, stream>>>(icnt, ioffs, ibsum, kN);
        scan2_kernel<<<1, 64, 0, stream>>>(ibsum, nScanBlk, ioffs, kN);
        scan3_kernel<<<nScanBlk, 256, 0, stream>>>(icnt, ioffs, ibsum, icur, deg, kN);
        csrfill_edgew_kernel<<<CDIV(kE, 256), 256, 0, stream>>>(
            gsrc[gi], gdst[gi], icur, icsr, deg, wsum, kE);
        // hw1 = x @ gW1 (50000x768 @ 768x128): MFMA split-K 2, partials in hw1+agg, sum in place
        gemm_mfma_kernel<<<dim3(1, CDIV(kN, 128), 2), 256, 0, stream>>>(
            gx[gi], Ptr3{{gW1, nullptr, nullptr}}, hw1, kN, kGH, kH, 2);
        splitk_epi_kernel<<<dim3((int)(MN_G / 4 / 256), 1), 256, 0, stream>>>(
            hw1, Ptr3{{nullptr, nullptr, nullptr}}, Out3{{hw1, nullptr, nullptr}}, MN_G, kGH, 2, 0);
        // gather SpMM (no atomics) + fused self-loop/bias/relu
        spmm_gather_kernel<<<CDIV(kN, 2), 256, 0, stream>>>(ioffs, icsr, deg, hw1, gb1, agg, kN);
        wreduce_kernel<<<512, 256, 0, stream>>>(agg, wsum, deg, svec, kN);
        gcn_final_kernel<<<1, kGH, 0, stream>>>(svec, gW2, gb2, gout[gi]);
    }

    // ---------- BERT ----------
    maskbias_kernel<<<2, 256, 0, stream>>>(attn_mask, mb);
    embed_ln_kernel<<<kS, 256, 0, stream>>>(input_ids, type_ids, word_emb, pos_emb, type_emb,
                                            eln_s, eln_b, h);
    for (int l = 0; l < kL; l++) {
        const float* Wq_l = Wq + (size_t)l * kH * kH; const float* bq_l = bq + (size_t)l * kH;
        const float* Wk_l = Wk + (size_t)l * kH * kH; const float* bk_l = bk + (size_t)l * kH;
        const float* Wv_l = Wv + (size_t)l * kH * kH; const float* bv_l = bv + (size_t)l * kH;
        const float* Wo_l = Wo + (size_t)l * kH * kH; const float* bo_l = bo + (size_t)l * kH;
        const float* W1_l = W1 + (size_t)l * kH * kF; const float* b1_l = b1 + (size_t)l * kF;
        const float* W2_l = W2 + (size_t)l * kF * kH; const float* b2_l = b2 + (size_t)l * kH;
        const float* l1s_l = l1s + (size_t)l * kH; const float* l1b_l = l1b + (size_t)l * kH;
        const float* l2s_l = l2s + (size_t)l * kH; const float* l2b_l = l2b + (size_t)l * kH;

        // QKV fused: nW=3, S=4 -> 288 blocks, 12 partials
        gemm_mfma_kernel<<<dim3(kH / 128, kS / 128, 12), 256, 0, stream>>>(
            h, Ptr3{{Wq_l, Wk_l, Wv_l}}, part, kS, kH, kH, 4);
        splitk_epi_kernel<<<dim3((int)(MN_H / 4 / 256), 3), 256, 0, stream>>>(
            part, Ptr3{{bq_l, bk_l, bv_l}}, Out3{{q, k, v}}, MN_H, kH, 4, 0);
        attn_scores_kernel<<<dim3(kS / 64, kS / 64, kNH), 256, 0, stream>>>(q, k, mb, scores);
        softmax_kernel<<<kNH * kS, 256, 0, stream>>>(scores);
        // ctx: K-split 4 -> 384 blocks, deterministic partial + epilogue
        attn_ctx_split_kernel<<<dim3(kS / 64, kNH * 4), 256, 0, stream>>>(scores, v, part);
        splitk_epi_kernel<<<dim3((int)(MN_H / 4 / 256), 1), 256, 0, stream>>>(
            part, Ptr3{{nullptr, nullptr, nullptr}}, Out3{{ctx, nullptr, nullptr}}, MN_H, kH, 4, 0);
        // Wo: S=8 -> 192 blocks
        gemm_mfma_kernel<<<dim3(kH / 128, kS / 128, 8), 256, 0, stream>>>(
            ctx, Ptr3{{Wo_l, nullptr, nullptr}}, part, kS, kH, kH, 8);
        splitk_epi_kernel<<<dim3((int)(MN_H / 4 / 256), 1), 256, 0, stream>>>(
            part, Ptr3{{bo_l, nullptr, nullptr}}, Out3{{tmp, nullptr, nullptr}}, MN_H, kH, 8, 0);
        ln_residual_kernel<<<kS, 256, 0, stream>>>(tmp, h, l1s_l, l1b_l, h1);
        // FFN1: S=3 -> 288 blocks, gelu in epilogue
        gemm_mfma_kernel<<<dim3(kF / 128, kS / 128, 3), 256, 0, stream>>>(
            h1, Ptr3{{W1_l, nullptr, nullptr}}, part, kS, kF, kH, 3);
        splitk_epi_kernel<<<dim3((int)(MN_F / 4 / 256), 1), 256, 0, stream>>>(
            part, Ptr3{{b1_l, nullptr, nullptr}}, Out3{{ffn1, nullptr, nullptr}}, MN_F, kF, 3, 1);
        // FFN2: S=12 -> 288 blocks
        gemm_mfma_kernel<<<dim3(kH / 128, kS / 128, 12), 256, 0, stream>>>(
            ffn1, Ptr3{{W2_l, nullptr, nullptr}}, part, kS, kH, kF, 12);
        splitk_epi_kernel<<<dim3((int)(MN_H / 4 / 256), 1), 256, 0, stream>>>(
            part, Ptr3{{b2_l, nullptr, nullptr}}, Out3{{ffn2, nullptr, nullptr}}, MN_H, kH, 12, 0);
        ln_residual_kernel<<<kS, 256, 0, stream>>>(ffn2, h1, l2s_l, l2b_l, h);
    }

    // ---------- combine + classifier ----------
    combine_kernel<<<3, 256, 0, stream>>>(h, gp, ghv, cW, cb, feat);
    cls_head_kernel<<<1, 256, 0, stream>>>(feat, clsW, clsB, out);
}

// Round 4
// 2985.820 us; speedup vs baseline: 1.4544x; 1.0504x over previous
//
#include <hip/hip_runtime.h>
#include <math.h>

// Problem constants
constexpr int kS = 512, kH = 768, kNH = 12, kDH = 64, kF = 3072, kL = 12;
constexpr int kN = 50000, kE = 800000, kGH = 128;

#define CDIV(a,b) (((a)+(b)-1)/(b))

struct Ptr3 { const float* p[3]; };
struct Out3 { float* p[3]; };

typedef __attribute__((ext_vector_type(8))) short bf16x8;
typedef __attribute__((ext_vector_type(4))) float f32x4;

__device__ __forceinline__ unsigned short bf16_rne(float f) {
    unsigned int u = __float_as_uint(f);
    u += 0x7fffu + ((u >> 16) & 1u);
    return (unsigned short)(u >> 16);
}
__device__ __forceinline__ float bf16_f32(unsigned short h) {
    return __uint_as_float(((unsigned int)h) << 16);
}

// ---------------- generic fill ----------------
__global__ void fill_kernel(float* p, float v, long n) {
    long i = blockIdx.x * (long)blockDim.x + threadIdx.x;
    if (i < n) p[i] = v;
}

// ---------------- embeddings + LN ----------------
__global__ void embed_ln_kernel(const int* ids, const int* tt,
                                const float* we, const float* pe, const float* te,
                                const float* g, const float* b, float* out) {
    int s = blockIdx.x;            // one block per token
    int tid = threadIdx.x;         // 256 threads, 3 elems each
    __shared__ float red[256];
    int id = ids[s], t = tt[s];
    float vals[3]; float sum = 0.f;
    #pragma unroll
    for (int r = 0; r < 3; r++) {
        int j = tid + r * 256;
        float x = we[(long)id * kH + j] + pe[(long)s * kH + j] + te[(long)t * kH + j];
        vals[r] = x; sum += x;
    }
    red[tid] = sum; __syncthreads();
    for (int off = 128; off > 0; off >>= 1) { if (tid < off) red[tid] += red[tid + off]; __syncthreads(); }
    float mean = red[0] / kH; __syncthreads();
    float vs = 0.f;
    #pragma unroll
    for (int r = 0; r < 3; r++) { float d = vals[r] - mean; vs += d * d; }
    red[tid] = vs; __syncthreads();
    for (int off = 128; off > 0; off >>= 1) { if (tid < off) red[tid] += red[tid + off]; __syncthreads(); }
    float rstd = rsqrtf(red[0] / kH + 1e-12f);
    #pragma unroll
    for (int r = 0; r < 3; r++) {
        int j = tid + r * 256;
        out[(long)s * kH + j] = (vals[r] - mean) * rstd * g[j] + b[j];
    }
}

// ---------------- split-K MFMA GEMM (bf16x3 emulated fp32): C[M,N] = A[M,K] @ B[K,N] ----------------
// 128x128 tile, 4 waves (2x2), each wave 4x4 fragments of 16x16, BK=32.
// A, B staged to LDS pre-split into hi/lo bf16.
// If Cdirect != nullptr (requires nW==1, S==1): write C directly (+bias/act).
// Else write partials part[(w*S+s)*M*N].
__global__ __launch_bounds__(256, 4) void gemm_mfma_kernel(
    const float* __restrict__ A, Ptr3 Bp, float* __restrict__ part,
    float* __restrict__ Cdirect, const float* __restrict__ biasD,
    int M, int Nn, int K, int S, int act)
{
    constexpr int LDK = 40;   // 32 bf16 + 8 pad
    __shared__ short Ah[128 * LDK], Al[128 * LDK], Bh[128 * LDK], Bl[128 * LDK]; // 40960 B
    int w = blockIdx.z / S, s = blockIdx.z % S;
    const float* B = Bp.p[w];
    int Kc = K / S;                 // multiple of 32 in all uses
    int m0 = blockIdx.y * 128, n0 = blockIdx.x * 128;
    int tid = threadIdx.x;
    // staging: A rows 0..127, 2 threads/row (16 floats each); B cols 0..127, 2 k-halves
    int sar = tid >> 1, sac = (tid & 1) * 16;
    int sbc = tid & 127, sbk = (tid >> 7) * 16;
    int gmA = m0 + sar; if (gmA > M - 1) gmA = M - 1;   // clamp; garbage rows guarded at store
    const float* Ag0 = A + (long)gmA * K + s * Kc + sac;
    const float* Bg0 = B + (long)(s * Kc + sbk) * Nn + n0 + sbc;
    // wave/fragment indices
    int wid = tid >> 6, lane = tid & 63;
    int wm = (wid >> 1) * 64, wn = (wid & 1) * 64;
    int fr = lane & 15, ko = (lane >> 4) * 8;
    f32x4 acc[4][4];
    #pragma unroll
    for (int i = 0; i < 4; i++)
        #pragma unroll
        for (int j = 0; j < 4; j++) acc[i][j] = (f32x4){0.f, 0.f, 0.f, 0.f};
    int nst = Kc / 32;
    for (int st = 0; st < nst; ++st) {
        // ---- stage A tile (128x32) as hi/lo bf16, [m][k] ----
        {
            const float* Ag = Ag0 + st * 32;
            int ob = sar * LDK + sac;
            #pragma unroll
            for (int qg = 0; qg < 4; qg++) {
                float4 f = *(const float4*)(Ag + qg * 4);
                unsigned short h0 = bf16_rne(f.x), h1 = bf16_rne(f.y),
                               h2 = bf16_rne(f.z), h3 = bf16_rne(f.w);
                unsigned short g0 = bf16_rne(f.x - bf16_f32(h0)), g1 = bf16_rne(f.y - bf16_f32(h1)),
                               g2 = bf16_rne(f.z - bf16_f32(h2)), g3 = bf16_rne(f.w - bf16_f32(h3));
                *(short4*)&Ah[ob + qg * 4] = make_short4((short)h0, (short)h1, (short)h2, (short)h3);
                *(short4*)&Al[ob + qg * 4] = make_short4((short)g0, (short)g1, (short)g2, (short)g3);
            }
        }
        // ---- stage B tile (32x128) transposed to [n][k], hi/lo bf16 ----
        {
            const float* Bg = Bg0 + (long)st * 32 * Nn;
            int ob = sbc * LDK + sbk;
            #pragma unroll
            for (int qg = 0; qg < 4; qg++) {
                float f0 = Bg[(long)(qg * 4 + 0) * Nn];
                float f1 = Bg[(long)(qg * 4 + 1) * Nn];
                float f2 = Bg[(long)(qg * 4 + 2) * Nn];
                float f3 = Bg[(long)(qg * 4 + 3) * Nn];
                unsigned short h0 = bf16_rne(f0), h1 = bf16_rne(f1),
                               h2 = bf16_rne(f2), h3 = bf16_rne(f3);
                unsigned short g0 = bf16_rne(f0 - bf16_f32(h0)), g1 = bf16_rne(f1 - bf16_f32(h1)),
                               g2 = bf16_rne(f2 - bf16_f32(h2)), g3 = bf16_rne(f3 - bf16_f32(h3));
                *(short4*)&Bh[ob + qg * 4] = make_short4((short)h0, (short)h1, (short)h2, (short)h3);
                *(short4*)&Bl[ob + qg * 4] = make_short4((short)g0, (short)g1, (short)g2, (short)g3);
            }
        }
        __syncthreads();
        // ---- fragments + 48 MFMAs ----
        bf16x8 bh[4], bl[4];
        #pragma unroll
        for (int j = 0; j < 4; j++) {
            int c = (wn + j * 16 + fr) * LDK + ko;
            bh[j] = *(const bf16x8*)&Bh[c];
            bl[j] = *(const bf16x8*)&Bl[c];
        }
        #pragma unroll
        for (int i = 0; i < 4; i++) {
            int r = (wm + i * 16 + fr) * LDK + ko;
            bf16x8 ah = *(const bf16x8*)&Ah[r];
            bf16x8 al = *(const bf16x8*)&Al[r];
            #pragma unroll
            for (int j = 0; j < 4; j++) {
                acc[i][j] = __builtin_amdgcn_mfma_f32_16x16x32_bf16(ah, bh[j], acc[i][j], 0, 0, 0);
                acc[i][j] = __builtin_amdgcn_mfma_f32_16x16x32_bf16(ah, bl[j], acc[i][j], 0, 0, 0);
                acc[i][j] = __builtin_amdgcn_mfma_f32_16x16x32_bf16(al, bh[j], acc[i][j], 0, 0, 0);
            }
        }
        __syncthreads();
    }
    // ---- write. C/D map: col = lane&15, row = (lane>>4)*4 + reg ----
    int cr = (lane >> 4) * 4;
    if (Cdirect) {
        #pragma unroll
        for (int i = 0; i < 4; i++) {
            #pragma unroll
            for (int r = 0; r < 4; r++) {
                int gm = m0 + wm + i * 16 + cr + r;
                if (gm >= M) continue;
                float* rowp = &Cdirect[(long)gm * Nn + n0 + wn + fr];
                #pragma unroll
                for (int j = 0; j < 4; j++) {
                    float vv = acc[i][j][r];
                    if (biasD) vv += biasD[n0 + wn + j * 16 + fr];
                    if (act == 1) vv = 0.5f * vv * (1.f + erff(vv * 0.70710678118654752f));
                    else if (act == 2) vv = fmaxf(vv, 0.f);
                    rowp[j * 16] = vv;
                }
            }
        }
    } else {
        long MN = (long)M * Nn;
        float* Pp = part + (long)(w * S + s) * MN;
        #pragma unroll
        for (int i = 0; i < 4; i++) {
            #pragma unroll
            for (int r = 0; r < 4; r++) {
                int gm = m0 + wm + i * 16 + cr + r;
                if (gm >= M) continue;
                float* rowp = &Pp[(long)gm * Nn + n0 + wn + fr];
                #pragma unroll
                for (int j = 0; j < 4; j++) rowp[j * 16] = acc[i][j][r];
            }
        }
    }
}

// ---------------- split-K epilogue: out = act(sum_s part + bias) ----------------
// NOTE: no __restrict__ on part — may sum in place.
__global__ void splitk_epi_kernel(const float* part, Ptr3 bias, Out3 outp,
                                  long MN, int Nn, int S, int act) {
    int w = blockIdx.y;
    long i = ((long)blockIdx.x * blockDim.x + threadIdx.x) * 4;
    if (i >= MN) return;
    const float* P = part + (long)w * S * MN + i;
    float4 a = *(const float4*)P;
    for (int s2 = 1; s2 < S; ++s2) {
        float4 b = *(const float4*)(P + (long)s2 * MN);
        a.x += b.x; a.y += b.y; a.z += b.z; a.w += b.w;
    }
    const float* bw = bias.p[w];
    if (bw) {
        int n = (int)(i % Nn);
        a.x += bw[n]; a.y += bw[n + 1]; a.z += bw[n + 2]; a.w += bw[n + 3];
    }
    if (act == 1) {
        a.x = 0.5f * a.x * (1.f + erff(a.x * 0.70710678118654752f));
        a.y = 0.5f * a.y * (1.f + erff(a.y * 0.70710678118654752f));
        a.z = 0.5f * a.z * (1.f + erff(a.z * 0.70710678118654752f));
        a.w = 0.5f * a.w * (1.f + erff(a.w * 0.70710678118654752f));
    } else if (act == 2) {
        a.x = fmaxf(a.x, 0.f); a.y = fmaxf(a.y, 0.f); a.z = fmaxf(a.z, 0.f); a.w = fmaxf(a.w, 0.f);
    }
    *(float4*)(outp.p[w] + i) = a;
}

// ---------------- fused split-K + bias + residual + LayerNorm (rows of kH) ----------------
__global__ void splitk_epi_ln_kernel(const float* __restrict__ part, const float* __restrict__ bias,
                                     const float* __restrict__ res, const float* __restrict__ g,
                                     const float* __restrict__ b, float* __restrict__ out, int S) {
    int row = blockIdx.x; int tid = threadIdx.x;   // 512 blocks x 256 threads
    __shared__ float red[256];
    const long MN = (long)kS * kH;
    float vals[3]; float sum = 0.f;
    #pragma unroll
    for (int r = 0; r < 3; r++) {
        int j = tid + r * 256;
        const float* P = part + (long)row * kH + j;
        float x = res[(long)row * kH + j] + bias[j];
        for (int s2 = 0; s2 < S; ++s2) x += P[(long)s2 * MN];
        vals[r] = x; sum += x;
    }
    red[tid] = sum; __syncthreads();
    for (int off = 128; off > 0; off >>= 1) { if (tid < off) red[tid] += red[tid + off]; __syncthreads(); }
    float mean = red[0] / kH; __syncthreads();
    float vs = 0.f;
    #pragma unroll
    for (int r = 0; r < 3; r++) { float d = vals[r] - mean; vs += d * d; }
    red[tid] = vs; __syncthreads();
    for (int off = 128; off > 0; off >>= 1) { if (tid < off) red[tid] += red[tid + off]; __syncthreads(); }
    float rstd = rsqrtf(red[0] / kH + 1e-12f);
    #pragma unroll
    for (int r = 0; r < 3; r++) {
        int j = tid + r * 256;
        out[(long)row * kH + j] = (vals[r] - mean) * rstd * g[j] + b[j];
    }
}

// ---------------- attention scores via MFMA bf16x3: scores = Q K^T / 8 + mb ----------------
// Tile 128(q) x 128(k), 4 waves 2x2, d-depth 64 = 2 K-steps.
__global__ __launch_bounds__(256, 4) void attn_scores_mfma_kernel(
    const float* __restrict__ Q, const float* __restrict__ K,
    const float* __restrict__ mb, float* __restrict__ scores)
{
    constexpr int LDK = 40;
    __shared__ short Ah[128 * LDK], Al[128 * LDK], Bh[128 * LDK], Bl[128 * LDK];
    int h = blockIdx.z;
    int q0 = blockIdx.y * 128, k0 = blockIdx.x * 128;
    int tid = threadIdx.x;
    int sar = tid >> 1, sac = (tid & 1) * 16;
    const float* Ag0 = Q + (long)(q0 + sar) * kH + h * kDH;
    const float* Bg0 = K + (long)(k0 + sar) * kH + h * kDH;  // B[n][k] = K rows: direct copy
    int wid = tid >> 6, lane = tid & 63;
    int wm = (wid >> 1) * 64, wn = (wid & 1) * 64;
    int fr = lane & 15, ko = (lane >> 4) * 8;
    f32x4 acc[4][4];
    #pragma unroll
    for (int i = 0; i < 4; i++)
        #pragma unroll
        for (int j = 0; j < 4; j++) acc[i][j] = (f32x4){0.f, 0.f, 0.f, 0.f};
    #pragma unroll
    for (int st = 0; st < 2; ++st) {
        int ob = sar * LDK + sac;
        {
            const float* Ag = Ag0 + st * 32 + sac;
            #pragma unroll
            for (int qg = 0; qg < 4; qg++) {
                float4 f = *(const float4*)(Ag + qg * 4);
                unsigned short h0 = bf16_rne(f.x), h1 = bf16_rne(f.y),
                               h2 = bf16_rne(f.z), h3 = bf16_rne(f.w);
                unsigned short g0 = bf16_rne(f.x - bf16_f32(h0)), g1 = bf16_rne(f.y - bf16_f32(h1)),
                               g2 = bf16_rne(f.z - bf16_f32(h2)), g3 = bf16_rne(f.w - bf16_f32(h3));
                *(short4*)&Ah[ob + qg * 4] = make_short4((short)h0, (short)h1, (short)h2, (short)h3);
                *(short4*)&Al[ob + qg * 4] = make_short4((short)g0, (short)g1, (short)g2, (short)g3);
            }
        }
        {
            const float* Bg = Bg0 + st * 32 + sac;
            #pragma unroll
            for (int qg = 0; qg < 4; qg++) {
                float4 f = *(const float4*)(Bg + qg * 4);
                unsigned short h0 = bf16_rne(f.x), h1 = bf16_rne(f.y),
                               h2 = bf16_rne(f.z), h3 = bf16_rne(f.w);
                unsigned short g0 = bf16_rne(f.x - bf16_f32(h0)), g1 = bf16_rne(f.y - bf16_f32(h1)),
                               g2 = bf16_rne(f.z - bf16_f32(h2)), g3 = bf16_rne(f.w - bf16_f32(h3));
                *(short4*)&Bh[ob + qg * 4] = make_short4((short)h0, (short)h1, (short)h2, (short)h3);
                *(short4*)&Bl[ob + qg * 4] = make_short4((short)g0, (short)g1, (short)g2, (short)g3);
            }
        }
        __syncthreads();
        bf16x8 bh[4], bl[4];
        #pragma unroll
        for (int j = 0; j < 4; j++) {
            int c = (wn + j * 16 + fr) * LDK + ko;
            bh[j] = *(const bf16x8*)&Bh[c];
            bl[j] = *(const bf16x8*)&Bl[c];
        }
        #pragma unroll
        for (int i = 0; i < 4; i++) {
            int r = (wm + i * 16 + fr) * LDK + ko;
            bf16x8 ah = *(const bf16x8*)&Ah[r];
            bf16x8 al = *(const bf16x8*)&Al[r];
            #pragma unroll
            for (int j = 0; j < 4; j++) {
                acc[i][j] = __builtin_amdgcn_mfma_f32_16x16x32_bf16(ah, bh[j], acc[i][j], 0, 0, 0);
                acc[i][j] = __builtin_amdgcn_mfma_f32_16x16x32_bf16(ah, bl[j], acc[i][j], 0, 0, 0);
                acc[i][j] = __builtin_amdgcn_mfma_f32_16x16x32_bf16(al, bh[j], acc[i][j], 0, 0, 0);
            }
        }
        __syncthreads();
    }
    int cr = (lane >> 4) * 4;
    #pragma unroll
    for (int i = 0; i < 4; i++) {
        #pragma unroll
        for (int r = 0; r < 4; r++) {
            int qq = q0 + wm + i * 16 + cr + r;
            float* rowp = &scores[((long)h * kS + qq) * kS + k0 + wn + fr];
            #pragma unroll
            for (int j = 0; j < 4; j++)
                rowp[j * 16] = acc[i][j][r] * 0.125f + mb[k0 + wn + j * 16 + fr];
        }
    }
}

// ---------------- softmax over rows of 512 ----------------
__global__ void softmax_kernel(float* scores) {
    long row = blockIdx.x;
    float* p = scores + row * kS;
    int tid = threadIdx.x; // 256
    __shared__ float red[256];
    float x0 = p[tid], x1 = p[tid + 256];
    red[tid] = fmaxf(x0, x1); __syncthreads();
    for (int off = 128; off > 0; off >>= 1) { if (tid < off) red[tid] = fmaxf(red[tid], red[tid + off]); __syncthreads(); }
    float mx = red[0]; __syncthreads();
    float e0 = expf(x0 - mx), e1 = expf(x1 - mx);
    red[tid] = e0 + e1; __syncthreads();
    for (int off = 128; off > 0; off >>= 1) { if (tid < off) red[tid] += red[tid + off]; __syncthreads(); }
    float inv = 1.f / red[0];
    p[tid] = e0 * inv; p[tid + 256] = e1 * inv;
}

// ---------------- ctx partial = P @ V over K-chunk (4-way split), per head, MFMA bf16x3 ----------------
// Tile 128(q) x 64(d), 4 waves stacked on M (32 rows each), K-chunk 128 = 4 steps.
// part layout: [s][q][kH] with head h occupying columns h*64..h*64+63
__global__ __launch_bounds__(256, 4) void attn_ctx_mfma_kernel(
    const float* __restrict__ P, const float* __restrict__ V, float* __restrict__ part)
{
    constexpr int LDK = 40;
    __shared__ short Ah[128 * LDK], Al[128 * LDK], Bh[64 * LDK], Bl[64 * LDK];
    int q0 = blockIdx.x * 128;
    int h = blockIdx.y >> 2, s = blockIdx.y & 3;
    int kbeg = s * 128;
    int tid = threadIdx.x;
    int sar = tid >> 1, sac = (tid & 1) * 16;
    int sbc = tid & 63, sbr = (tid >> 6) * 8;
    const float* Ag0 = P + ((long)h * kS + q0 + sar) * kS + kbeg + sac;
    const float* Bg0 = V + (long)(kbeg + sbr) * kH + h * kDH + sbc;
    int wid = tid >> 6, lane = tid & 63;
    int wm = wid * 32;
    int fr = lane & 15, ko = (lane >> 4) * 8;
    f32x4 acc[2][4];
    #pragma unroll
    for (int i = 0; i < 2; i++)
        #pragma unroll
        for (int j = 0; j < 4; j++) acc[i][j] = (f32x4){0.f, 0.f, 0.f, 0.f};
    #pragma unroll
    for (int st = 0; st < 4; ++st) {
        // A: P tile 128x32, [m][k]
        {
            const float* Ag = Ag0 + st * 32;
            int ob = sar * LDK + sac;
            #pragma unroll
            for (int qg = 0; qg < 4; qg++) {
                float4 f = *(const float4*)(Ag + qg * 4);
                unsigned short h0 = bf16_rne(f.x), h1 = bf16_rne(f.y),
                               h2 = bf16_rne(f.z), h3 = bf16_rne(f.w);
                unsigned short g0 = bf16_rne(f.x - bf16_f32(h0)), g1 = bf16_rne(f.y - bf16_f32(h1)),
                               g2 = bf16_rne(f.z - bf16_f32(h2)), g3 = bf16_rne(f.w - bf16_f32(h3));
                *(short4*)&Ah[ob + qg * 4] = make_short4((short)h0, (short)h1, (short)h2, (short)h3);
                *(short4*)&Al[ob + qg * 4] = make_short4((short)g0, (short)g1, (short)g2, (short)g3);
            }
        }
        // B: V tile 32x64 transposed to [n=d][k], 8 strided rows per thread
        {
            const float* Bg = Bg0 + (long)st * 32 * kH;
            int ob = sbc * LDK + sbr;
            float f[8];
            #pragma unroll
            for (int r = 0; r < 8; r++) f[r] = Bg[(long)r * kH];
            short hh[8], ll[8];
            #pragma unroll
            for (int r = 0; r < 8; r++) {
                unsigned short hv = bf16_rne(f[r]);
                hh[r] = (short)hv; ll[r] = (short)bf16_rne(f[r] - bf16_f32(hv));
            }
            *(short4*)&Bh[ob + 0] = make_short4(hh[0], hh[1], hh[2], hh[3]);
            *(short4*)&Bh[ob + 4] = make_short4(hh[4], hh[5], hh[6], hh[7]);
            *(short4*)&Bl[ob + 0] = make_short4(ll[0], ll[1], ll[2], ll[3]);
            *(short4*)&Bl[ob + 4] = make_short4(ll[4], ll[5], ll[6], ll[7]);
        }
        __syncthreads();
        bf16x8 bh[4], bl[4];
        #pragma unroll
        for (int j = 0; j < 4; j++) {
            int c = (j * 16 + fr) * LDK + ko;
            bh[j] = *(const bf16x8*)&Bh[c];
            bl[j] = *(const bf16x8*)&Bl[c];
        }
        #pragma unroll
        for (int i = 0; i < 2; i++) {
            int r = (wm + i * 16 + fr) * LDK + ko;
            bf16x8 ah = *(const bf16x8*)&Ah[r];
            bf16x8 al = *(const bf16x8*)&Al[r];
            #pragma unroll
            for (int j = 0; j < 4; j++) {
                acc[i][j] = __builtin_amdgcn_mfma_f32_16x16x32_bf16(ah, bh[j], acc[i][j], 0, 0, 0);
                acc[i][j] = __builtin_amdgcn_mfma_f32_16x16x32_bf16(ah, bl[j], acc[i][j], 0, 0, 0);
                acc[i][j] = __builtin_amdgcn_mfma_f32_16x16x32_bf16(al, bh[j], acc[i][j], 0, 0, 0);
            }
        }
        __syncthreads();
    }
    long Pbase = (long)s * ((long)kS * kH);
    int cr = (lane >> 4) * 4;
    #pragma unroll
    for (int i = 0; i < 2; i++) {
        #pragma unroll
        for (int r = 0; r < 4; r++) {
            int gq = q0 + wm + i * 16 + cr + r;
            float* rowp = &part[Pbase + (long)gq * kH + h * kDH + fr];
            #pragma unroll
            for (int j = 0; j < 4; j++) rowp[j * 16] = acc[i][j][r];
        }
    }
}

// ---------------- GCN kernels ----------------
__global__ void maskbias_kernel(const int* mask, float* mb) {
    int i = blockIdx.x * blockDim.x + threadIdx.x;
    if (i < kS) mb[i] = (1.f - (float)mask[i]) * -1e4f;
}

// count in-edges per destination (int)
__global__ void cnt_kernel(const int* __restrict__ dst, int* __restrict__ cnt, int E) {
    int e = blockIdx.x * blockDim.x + threadIdx.x;
    if (e < E) atomicAdd(&cnt[dst[e]], 1);
}

// block-local exclusive scan (Hillis-Steele inclusive, then subtract self)
__global__ void scan1_kernel(const int* __restrict__ cnt, int* __restrict__ offs,
                             int* __restrict__ bsum, int n) {
    __shared__ int sh[256];
    int i = blockIdx.x * 256 + threadIdx.x;
    int v = (i < n) ? cnt[i] : 0;
    sh[threadIdx.x] = v; __syncthreads();
    for (int off = 1; off < 256; off <<= 1) {
        int t = (threadIdx.x >= off) ? sh[threadIdx.x - off] : 0;
        __syncthreads();
        sh[threadIdx.x] += t;
        __syncthreads();
    }
    if (i < n) offs[i] = sh[threadIdx.x] - v;   // exclusive within block
    if (threadIdx.x == 255) bsum[blockIdx.x] = sh[255];
}

// exclusive scan of block sums (tiny: nb=196) + write offs[n] = total
__global__ void scan2_kernel(int* bsum, int nb, int* offs, int n) {
    if (threadIdx.x == 0) {
        int run = 0;
        for (int b = 0; b < nb; b++) { int t = bsum[b]; bsum[b] = run; run += t; }
        offs[n] = run;
    }
}

// finalize offsets, init running cursors, compute dinv = rsqrt(cnt+1)
__global__ void scan3_kernel(const int* __restrict__ cnt, int* __restrict__ offs,
                             const int* __restrict__ bsum, int* __restrict__ cur,
                             float* __restrict__ dinv, int n) {
    int i = blockIdx.x * 256 + threadIdx.x;
    if (i >= n) return;
    int o = offs[i] + bsum[blockIdx.x];
    offs[i] = o; cur[i] = o;
    dinv[i] = rsqrtf((float)(cnt[i] + 1));
}

// fused: scatter edge sources into dst-CSR slots + accumulate per-src outgoing weight
__global__ void csrfill_edgew_kernel(const int* __restrict__ src, const int* __restrict__ dst,
                                     int* __restrict__ cur, int* __restrict__ csr,
                                     const float* __restrict__ dinv, float* __restrict__ wsum,
                                     int E) {
    int e = blockIdx.x * blockDim.x + threadIdx.x;
    if (e < E) {
        int s2 = src[e], d = dst[e];
        int slot = atomicAdd(&cur[d], 1);
        csr[slot] = s2;
        atomicAdd(&wsum[s2], dinv[s2] * dinv[d]);
    }
}

// gather SpMM + fused self-loop/bias/relu, 4-way ILP unroll
__global__ __launch_bounds__(256) void spmm_gather_kernel(const int* __restrict__ offs,
                                                          const int* __restrict__ csr,
                                                          const float* __restrict__ dinv,
                                                          const float* __restrict__ hw,
                                                          const float* __restrict__ b1,
                                                          float* __restrict__ hout, int n) {
    int d = blockIdx.x * 2 + (threadIdx.x >> 7);
    int j = threadIdx.x & 127;
    if (d >= n) return;
    int beg = offs[d], end = offs[d + 1];
    float a0 = 0.f, a1 = 0.f, a2 = 0.f, a3 = 0.f;
    int p = beg;
    for (; p + 4 <= end; p += 4) {
        int s0 = csr[p], s1 = csr[p + 1], s2 = csr[p + 2], s3 = csr[p + 3];
        a0 += dinv[s0] * hw[(long)s0 * kGH + j];
        a1 += dinv[s1] * hw[(long)s1 * kGH + j];
        a2 += dinv[s2] * hw[(long)s2 * kGH + j];
        a3 += dinv[s3] * hw[(long)s3 * kGH + j];
    }
    for (; p < end; ++p) {
        int s4 = csr[p];
        a0 += dinv[s4] * hw[(long)s4 * kGH + j];
    }
    float acc = (a0 + a1) + (a2 + a3);
    float dd = dinv[d];
    float v = acc * dd + dd * dd * hw[(long)d * kGH + j] + b1[j];
    hout[(long)d * kGH + j] = fmaxf(v, 0.f);
}

// s[j] = sum_u (w[u] + dinv[u]^2) * h[u][j]
__global__ void wreduce_kernel(const float* __restrict__ h, const float* __restrict__ w,
                               const float* __restrict__ dinv, float* __restrict__ s, int n) {
    int tid = threadIdx.x; int j = tid & 127; int half = tid >> 7;
    float acc = 0.f;
    for (int u = blockIdx.x * 2 + half; u < n; u += gridDim.x * 2) {
        float di = dinv[u];
        acc += (w[u] + di * di) * h[(long)u * kGH + j];
    }
    __shared__ float red[256];
    red[tid] = acc; __syncthreads();
    if (tid < 128) atomicAdd(&s[j], red[tid] + red[tid + 128]);
}

// g[j2] = (s @ W2)[j2]/N + b2[j2]
__global__ void gcn_final_kernel(const float* s, const float* W2, const float* b2, float* g) {
    int j2 = threadIdx.x; // 128
    float acc = 0.f;
    for (int j = 0; j < kGH; j++) acc += s[j] * W2[(long)j * kGH + j2];
    g[j2] = acc * (1.f / (float)kN) + b2[j2];
}

// ---------------- combine head ----------------
__global__ void combine_kernel(const float* __restrict__ cls, const float* __restrict__ gp,
                               const float* __restrict__ gh, const float* __restrict__ Wc,
                               const float* __restrict__ bc, float* __restrict__ feat) {
    int o = blockIdx.x * blockDim.x + threadIdx.x;
    if (o >= kH) return;
    float acc = 0.f;
    for (int i = 0; i < 768; i++)  acc += cls[i] * Wc[(long)i * kH + o];
    for (int i = 0; i < 128; i++)  acc += gp[i] * Wc[(long)(768 + i) * kH + o];
    for (int i = 0; i < 768; i++)  acc += cls[i] * Wc[(long)(896 + i) * kH + o];
    for (int i = 0; i < 128; i++)  acc += gh[i] * Wc[(long)(1664 + i) * kH + o];
    feat[o] = fmaxf(acc + bc[o], 0.f);
}

__global__ void cls_head_kernel(const float* feat, const float* W, const float* b, float* out) {
    int tid = threadIdx.x; // 256
    float a0 = 0.f, a1 = 0.f, a2 = 0.f;
    for (int o = tid; o < kH; o += 256) {
        float f = feat[o];
        a0 += f * W[o * 3 + 0]; a1 += f * W[o * 3 + 1]; a2 += f * W[o * 3 + 2];
    }
    __shared__ float r0[256], r1[256], r2[256];
    r0[tid] = a0; r1[tid] = a1; r2[tid] = a2; __syncthreads();
    for (int off = 128; off > 0; off >>= 1) {
        if (tid < off) { r0[tid] += r0[tid + off]; r1[tid] += r1[tid + off]; r2[tid] += r2[tid + off]; }
        __syncthreads();
    }
    if (tid == 0) { out[0] = r0[0] + b[0]; out[1] = r1[0] + b[1]; out[2] = r2[0] + b[2]; }
}

// ---------------- launch ----------------
extern "C" void kernel_launch(void* const* d_in, const int* in_sizes, int n_in,
                              void* d_out, int out_size, void* d_ws, size_t ws_size,
                              hipStream_t stream) {
    const int*   input_ids = (const int*)d_in[0];
    const int*   attn_mask = (const int*)d_in[1];
    const int*   type_ids  = (const int*)d_in[2];
    const int*   p_edges   = (const int*)d_in[3];
    const int*   h_edges   = (const int*)d_in[4];
    const float* p_nodes   = (const float*)d_in[5];
    const float* h_nodes   = (const float*)d_in[6];
    const float* word_emb  = (const float*)d_in[7];
    const float* pos_emb   = (const float*)d_in[8];
    const float* type_emb  = (const float*)d_in[9];
    const float* eln_s     = (const float*)d_in[10];
    const float* eln_b     = (const float*)d_in[11];
    const float* Wq = (const float*)d_in[12]; const float* bq = (const float*)d_in[13];
    const float* Wk = (const float*)d_in[14]; const float* bk = (const float*)d_in[15];
    const float* Wv = (const float*)d_in[16]; const float* bv = (const float*)d_in[17];
    const float* Wo = (const float*)d_in[18]; const float* bo = (const float*)d_in[19];
    const float* l1s = (const float*)d_in[20]; const float* l1b = (const float*)d_in[21];
    const float* W1 = (const float*)d_in[22]; const float* b1 = (const float*)d_in[23];
    const float* W2 = (const float*)d_in[24]; const float* b2 = (const float*)d_in[25];
    const float* l2s = (const float*)d_in[26]; const float* l2b = (const float*)d_in[27];
    const float* gW1 = (const float*)d_in[28]; const float* gb1 = (const float*)d_in[29];
    const float* gW2 = (const float*)d_in[30]; const float* gb2 = (const float*)d_in[31];
    const float* cW  = (const float*)d_in[32]; const float* cb  = (const float*)d_in[33];
    const float* clsW = (const float*)d_in[34]; const float* clsB = (const float*)d_in[35];
    float* out = (float*)d_out;

    // workspace layout (floats)
    float* W = (float*)d_ws;
    size_t off = 0;
    auto alloc = [&](size_t n) { float* p = W + off; off += n; return p; };
    float* h    = alloc((size_t)kS * kH);
    float* q    = alloc((size_t)kS * kH);
    float* k    = alloc((size_t)kS * kH);
    float* v    = alloc((size_t)kS * kH);
    float* ctx  = alloc((size_t)kS * kH);
    float* tmp  = alloc((size_t)kS * kH);
    float* h1   = alloc((size_t)kS * kH);
    float* ffn2 = alloc((size_t)kS * kH);
    float* deg  = alloc(kN);
    float* wsum = alloc(kN);
    float* svec = alloc(kGH);
    float* gp   = alloc(kGH);
    float* ghv  = alloc(kGH);
    float* mb   = alloc(kS);
    float* feat = alloc(kH);
    float* big  = W + off;   // reused region, 12.8M floats (GCN) / scores+ffn1+part (BERT)
    // GCN phase:
    float* hw1  = big;
    float* agg  = big + (size_t)kN * kGH;
    // GCN CSR scratch aliased onto BERT-phase buffers (dead during GCN):
    int* icnt  = (int*)tmp;   // [kN]   in-edge counts
    int* ioffs = (int*)ctx;   // [kN+1] CSR offsets
    int* icur  = (int*)h1;    // [kN]   running cursors for fill
    int* ibsum = (int*)ffn2;  // [196]  scan block sums
    int* icsr  = (int*)q;     // [kE]   edge sources, spans q..k..v (contiguous)
    // BERT phase (all within the 12.8M-float big region):
    float* scores = big;                                        // 3.146M floats
    float* ffn1   = big + (size_t)kNH * kS * kS;                // 1.573M floats
    float* part   = ffn1 + (size_t)kS * kF;                     // up to 4.72M floats

    const long MN_H = (long)kS * kH;   // 393216
    const long MN_F = (long)kS * kF;   // 1572864
    const int nScanBlk = CDIV(kN, 256); // 196

    // ---------- GCN on both graphs (before BERT; shares `big`) ----------
    const int* gsrc[2] = { p_edges, h_edges };
    const int* gdst[2] = { p_edges + kE, h_edges + kE };
    const float* gx[2] = { p_nodes, h_nodes };
    float* gout[2] = { gp, ghv };
    for (int gi = 0; gi < 2; gi++) {
        fill_kernel<<<CDIV((long)kN, 256), 256, 0, stream>>>((float*)icnt, 0.f, kN); // int 0
        fill_kernel<<<CDIV((long)kN, 256), 256, 0, stream>>>(wsum, 0.f, kN);
        fill_kernel<<<1, 256, 0, stream>>>(svec, 0.f, kGH);
        // ---- build dst-CSR (counting sort) + dinv ----
        cnt_kernel<<<CDIV(kE, 256), 256, 0, stream>>>(gdst[gi], icnt, kE);
        scan1_kernel<<<nScanBlk, 256, 0, stream>>>(icnt, ioffs, ibsum, kN);
        scan2_kernel<<<1, 64, 0, stream>>>(ibsum, nScanBlk, ioffs, kN);
        scan3_kernel<<<nScanBlk, 256, 0, stream>>>(icnt, ioffs, ibsum, icur, deg, kN);
        csrfill_edgew_kernel<<<CDIV(kE, 256), 256, 0, stream>>>(
            gsrc[gi], gdst[gi], icur, icsr, deg, wsum, kE);
        // hw1 = x @ gW1 (50000x768 @ 768x128): MFMA, direct write (391 blocks, no split-K)
        gemm_mfma_kernel<<<dim3(1, CDIV(kN, 128), 1), 256, 0, stream>>>(
            gx[gi], Ptr3{{gW1, nullptr, nullptr}}, nullptr, hw1, nullptr, kN, kGH, kH, 1, 0);
        // gather SpMM (no atomics) + fused self-loop/bias/relu
        spmm_gather_kernel<<<CDIV(kN, 2), 256, 0, stream>>>(ioffs, icsr, deg, hw1, gb1, agg, kN);
        wreduce_kernel<<<512, 256, 0, stream>>>(agg, wsum, deg, svec, kN);
        gcn_final_kernel<<<1, kGH, 0, stream>>>(svec, gW2, gb2, gout[gi]);
    }

    // ---------- BERT ----------
    maskbias_kernel<<<2, 256, 0, stream>>>(attn_mask, mb);
    embed_ln_kernel<<<kS, 256, 0, stream>>>(input_ids, type_ids, word_emb, pos_emb, type_emb,
                                            eln_s, eln_b, h);
    for (int l = 0; l < kL; l++) {
        const float* Wq_l = Wq + (size_t)l * kH * kH; const float* bq_l = bq + (size_t)l * kH;
        const float* Wk_l = Wk + (size_t)l * kH * kH; const float* bk_l = bk + (size_t)l * kH;
        const float* Wv_l = Wv + (size_t)l * kH * kH; const float* bv_l = bv + (size_t)l * kH;
        const float* Wo_l = Wo + (size_t)l * kH * kH; const float* bo_l = bo + (size_t)l * kH;
        const float* W1_l = W1 + (size_t)l * kH * kF; const float* b1_l = b1 + (size_t)l * kF;
        const float* W2_l = W2 + (size_t)l * kF * kH; const float* b2_l = b2 + (size_t)l * kH;
        const float* l1s_l = l1s + (size_t)l * kH; const float* l1b_l = l1b + (size_t)l * kH;
        const float* l2s_l = l2s + (size_t)l * kH; const float* l2b_l = l2b + (size_t)l * kH;

        // QKV fused: nW=3, S=4 -> 288 blocks, 12 partials
        gemm_mfma_kernel<<<dim3(kH / 128, kS / 128, 12), 256, 0, stream>>>(
            h, Ptr3{{Wq_l, Wk_l, Wv_l}}, part, nullptr, nullptr, kS, kH, kH, 4, 0);
        splitk_epi_kernel<<<dim3((int)(MN_H / 4 / 256), 3), 256, 0, stream>>>(
            part, Ptr3{{bq_l, bk_l, bv_l}}, Out3{{q, k, v}}, MN_H, kH, 4, 0);
        // scores: MFMA, 4x4x12 = 192 blocks
        attn_scores_mfma_kernel<<<dim3(kS / 128, kS / 128, kNH), 256, 0, stream>>>(q, k, mb, scores);
        softmax_kernel<<<kNH * kS, 256, 0, stream>>>(scores);
        // ctx: MFMA, K-split 4 -> 4 x 48 = 192 blocks, deterministic partial + epilogue
        attn_ctx_mfma_kernel<<<dim3(kS / 128, kNH * 4), 256, 0, stream>>>(scores, v, part);
        splitk_epi_kernel<<<dim3((int)(MN_H / 4 / 256), 1), 256, 0, stream>>>(
            part, Ptr3{{nullptr, nullptr, nullptr}}, Out3{{ctx, nullptr, nullptr}}, MN_H, kH, 4, 0);
        // Wo: S=8 -> 192 blocks; fused epi+bias+residual+LN
        gemm_mfma_kernel<<<dim3(kH / 128, kS / 128, 8), 256, 0, stream>>>(
            ctx, Ptr3{{Wo_l, nullptr, nullptr}}, part, nullptr, nullptr, kS, kH, kH, 8, 0);
        splitk_epi_ln_kernel<<<kS, 256, 0, stream>>>(part, bo_l, h, l1s_l, l1b_l, h1, 8);
        // FFN1: S=3 -> 288 blocks, gelu in epilogue
        gemm_mfma_kernel<<<dim3(kF / 128, kS / 128, 3), 256, 0, stream>>>(
            h1, Ptr3{{W1_l, nullptr, nullptr}}, part, nullptr, nullptr, kS, kF, kH, 3, 0);
        splitk_epi_kernel<<<dim3((int)(MN_F / 4 / 256), 1), 256, 0, stream>>>(
            part, Ptr3{{b1_l, nullptr, nullptr}}, Out3{{ffn1, nullptr, nullptr}}, MN_F, kF, 3, 1);
        // FFN2: S=12 -> 288 blocks; fused epi+bias+residual+LN
        gemm_mfma_kernel<<<dim3(kH / 128, kS / 128, 12), 256, 0, stream>>>(
            ffn1, Ptr3{{W2_l, nullptr, nullptr}}, part, nullptr, nullptr, kS, kH, kF, 12, 0);
        splitk_epi_ln_kernel<<<kS, 256, 0, stream>>>(part, b2_l, h1, l2s_l, l2b_l, h, 12);
    }

    // ---------- combine + classifier ----------
    combine_kernel<<<3, 256, 0, stream>>>(h, gp, ghv, cW, cb, feat);
    cls_head_kernel<<<1, 256, 0, stream>>>(feat, clsW, clsB, out);
}

// Round 5
// 2905.051 us; speedup vs baseline: 1.4948x; 1.0278x over previous
//
#include <hip/hip_runtime.h>
#include <math.h>

// Problem constants
constexpr int kS = 512, kH = 768, kNH = 12, kDH = 64, kF = 3072, kL = 12;
constexpr int kN = 50000, kE = 800000, kGH = 128;

#define CDIV(a,b) (((a)+(b)-1)/(b))

struct Ptr3 { const float* p[3]; };

typedef __attribute__((ext_vector_type(8))) short bf16x8;
typedef __attribute__((ext_vector_type(4))) float f32x4;

__device__ __forceinline__ unsigned short bf16_rne(float f) {
    unsigned int u = __float_as_uint(f);
    u += 0x7fffu + ((u >> 16) & 1u);
    return (unsigned short)(u >> 16);
}
__device__ __forceinline__ float bf16_f32(unsigned short h) {
    return __uint_as_float(((unsigned int)h) << 16);
}
__device__ __forceinline__ void split2(float f, short& hi, short& lo) {
    unsigned short h = bf16_rne(f);
    hi = (short)h;
    lo = (short)bf16_rne(f - bf16_f32(h));
}

constexpr int LDR = 72;  // LDS row: 32 hi | 32 lo | 8 pad shorts (144 B, 16B-aligned)

// ---------------- generic fill ----------------
__global__ void fill_kernel(float* p, float v, long n) {
    long i = blockIdx.x * (long)blockDim.x + threadIdx.x;
    if (i < n) p[i] = v;
}

// ---------------- embeddings + LN (+ hi/lo emit) ----------------
__global__ void embed_ln_kernel(const int* ids, const int* tt,
                                const float* we, const float* pe, const float* te,
                                const float* g, const float* b, float* out,
                                short* oh, short* ol) {
    int s = blockIdx.x;            // one block per token
    int tid = threadIdx.x;         // 256 threads, 3 elems each
    __shared__ float red[256];
    int id = ids[s], t = tt[s];
    float vals[3]; float sum = 0.f;
    #pragma unroll
    for (int r = 0; r < 3; r++) {
        int j = tid + r * 256;
        float x = we[(long)id * kH + j] + pe[(long)s * kH + j] + te[(long)t * kH + j];
        vals[r] = x; sum += x;
    }
    red[tid] = sum; __syncthreads();
    for (int off = 128; off > 0; off >>= 1) { if (tid < off) red[tid] += red[tid + off]; __syncthreads(); }
    float mean = red[0] / kH; __syncthreads();
    float vs = 0.f;
    #pragma unroll
    for (int r = 0; r < 3; r++) { float d = vals[r] - mean; vs += d * d; }
    red[tid] = vs; __syncthreads();
    for (int off = 128; off > 0; off >>= 1) { if (tid < off) red[tid] += red[tid + off]; __syncthreads(); }
    float rstd = rsqrtf(red[0] / kH + 1e-12f);
    #pragma unroll
    for (int r = 0; r < 3; r++) {
        int j = tid + r * 256;
        float o = (vals[r] - mean) * rstd * g[j] + b[j];
        out[(long)s * kH + j] = o;
        short hi, lo; split2(o, hi, lo);
        oh[(long)s * kH + j] = hi; ol[(long)s * kH + j] = lo;
    }
}

// ---------------- weight transpose + split: W[K][N] -> Th/Tl [N][K] ----------------
// grid (N/32, K/32, nmat); 256 threads per 32x32 tile
__global__ void wtrans_kernel(Ptr3 Wp, short* __restrict__ Th, short* __restrict__ Tl,
                              int K, int N) {
    const float* Wm = Wp.p[blockIdx.z];
    long moff = (long)blockIdx.z * K * N;
    __shared__ short th[32][33], tl[32][33];
    int n0 = blockIdx.x * 32, k0 = blockIdx.y * 32;
    int c = threadIdx.x & 31, r = threadIdx.x >> 5;  // 8 rows/pass
    #pragma unroll
    for (int p = 0; p < 4; p++) {
        int rr = p * 8 + r;
        float f = Wm[(long)(k0 + rr) * N + n0 + c];
        short hi, lo; split2(f, hi, lo);
        th[rr][c] = hi; tl[rr][c] = lo;
    }
    __syncthreads();
    #pragma unroll
    for (int p = 0; p < 4; p++) {
        int rr = p * 8 + r;
        Th[moff + (long)(n0 + rr) * K + k0 + c] = th[c][rr];
        Tl[moff + (long)(n0 + rr) * K + k0 + c] = tl[c][rr];
    }
}

// ---------------- V transpose: v[s][kH] (head slices) -> vt[h][d][s] ----------------
// grid (kS/32, kNH*2)
__global__ void vtrans_kernel(const short* __restrict__ vh, const short* __restrict__ vl,
                              short* __restrict__ vth, short* __restrict__ vtl) {
    __shared__ short th[32][33], tl[32][33];
    int s0 = blockIdx.x * 32;
    int h = blockIdx.y >> 1, d0 = (blockIdx.y & 1) * 32;
    int c = threadIdx.x & 31, r = threadIdx.x >> 5;
    #pragma unroll
    for (int p = 0; p < 4; p++) {
        int rr = p * 8 + r;
        th[rr][c] = vh[(long)(s0 + rr) * kH + h * kDH + d0 + c];
        tl[rr][c] = vl[(long)(s0 + rr) * kH + h * kDH + d0 + c];
    }
    __syncthreads();
    #pragma unroll
    for (int p = 0; p < 4; p++) {
        int rr = p * 8 + r;
        vth[((long)h * kDH + d0 + rr) * kS + s0 + c] = th[c][rr];
        vtl[((long)h * kDH + d0 + rr) * kS + s0 + c] = tl[c][rr];
    }
}

// ---------------- pre-split MFMA GEMM: C[M,N] = A[M,K] @ B[K,N], B pre-transposed [N][K] ----------------
// 128x128 tile, 4 waves 2x2, BK=32; writes split-K partials part[(w*S+s)*M*N].
__global__ __launch_bounds__(256, 4) void gemm_pre_kernel(
    const short* __restrict__ Ah, const short* __restrict__ Al,
    const short* __restrict__ Bth, const short* __restrict__ Btl, long wstride,
    float* __restrict__ part, int M, int Nn, int K, int S)
{
    __shared__ short As[128 * LDR], Bs[128 * LDR];  // 36864 B
    int w = blockIdx.z / S, s = blockIdx.z % S;
    const short* Bh_ = Bth + (long)w * wstride;
    const short* Bl_ = Btl + (long)w * wstride;
    int Kc = K / S;
    int kbeg = s * Kc;
    int m0 = blockIdx.y * 128, n0 = blockIdx.x * 128;
    int tid = threadIdx.x;
    int sr = tid >> 1, sh16 = (tid & 1) * 16;
    const short* Agh = Ah + (long)(m0 + sr) * K + kbeg + sh16;
    const short* Agl = Al + (long)(m0 + sr) * K + kbeg + sh16;
    const short* Bgh = Bh_ + (long)(n0 + sr) * K + kbeg + sh16;
    const short* Bgl = Bl_ + (long)(n0 + sr) * K + kbeg + sh16;
    int lofs = sr * LDR + sh16;
    int wid = tid >> 6, lane = tid & 63;
    int wm = (wid >> 1) * 64, wn = (wid & 1) * 64;
    int fr = lane & 15, ko = (lane >> 4) * 8;
    f32x4 acc[4][4];
    #pragma unroll
    for (int i = 0; i < 4; i++)
        #pragma unroll
        for (int j = 0; j < 4; j++) acc[i][j] = (f32x4){0.f, 0.f, 0.f, 0.f};
    int nst = Kc / 32;
    for (int st = 0; st < nst; ++st) {
        int go = st * 32;
        *(bf16x8*)&As[lofs]      = *(const bf16x8*)(Agh + go);
        *(bf16x8*)&As[lofs + 8]  = *(const bf16x8*)(Agh + go + 8);
        *(bf16x8*)&As[lofs + 32] = *(const bf16x8*)(Agl + go);
        *(bf16x8*)&As[lofs + 40] = *(const bf16x8*)(Agl + go + 8);
        *(bf16x8*)&Bs[lofs]      = *(const bf16x8*)(Bgh + go);
        *(bf16x8*)&Bs[lofs + 8]  = *(const bf16x8*)(Bgh + go + 8);
        *(bf16x8*)&Bs[lofs + 32] = *(const bf16x8*)(Bgl + go);
        *(bf16x8*)&Bs[lofs + 40] = *(const bf16x8*)(Bgl + go + 8);
        __syncthreads();
        bf16x8 bh[4], bl[4];
        #pragma unroll
        for (int j = 0; j < 4; j++) {
            int c = (wn + j * 16 + fr) * LDR + ko;
            bh[j] = *(const bf16x8*)&Bs[c];
            bl[j] = *(const bf16x8*)&Bs[c + 32];
        }
        #pragma unroll
        for (int i = 0; i < 4; i++) {
            int r = (wm + i * 16 + fr) * LDR + ko;
            bf16x8 ah = *(const bf16x8*)&As[r];
            bf16x8 al = *(const bf16x8*)&As[r + 32];
            #pragma unroll
            for (int j = 0; j < 4; j++) {
                acc[i][j] = __builtin_amdgcn_mfma_f32_16x16x32_bf16(ah, bh[j], acc[i][j], 0, 0, 0);
                acc[i][j] = __builtin_amdgcn_mfma_f32_16x16x32_bf16(ah, bl[j], acc[i][j], 0, 0, 0);
                acc[i][j] = __builtin_amdgcn_mfma_f32_16x16x32_bf16(al, bh[j], acc[i][j], 0, 0, 0);
            }
        }
        __syncthreads();
    }
    long MN = (long)M * Nn;
    float* Pp = part + (long)(w * S + s) * MN;
    int cr = (lane >> 4) * 4;
    #pragma unroll
    for (int i = 0; i < 4; i++) {
        #pragma unroll
        for (int r = 0; r < 4; r++) {
            int gm = m0 + wm + i * 16 + cr + r;
            float* rowp = &Pp[(long)gm * Nn + n0 + wn + fr];
            #pragma unroll
            for (int j = 0; j < 4; j++) rowp[j * 16] = acc[i][j][r];
        }
    }
}

// ---------------- QKV epilogue: sum partials + bias -> hi/lo shorts ----------------
__global__ void splitk_epi_qkv_kernel(const float* __restrict__ part, Ptr3 bias,
                                      short* __restrict__ qh, short* __restrict__ ql,
                                      short* __restrict__ kh, short* __restrict__ kl,
                                      short* __restrict__ vh, short* __restrict__ vl,
                                      int S) {
    const long MN = (long)kS * kH;
    int w = blockIdx.y;
    long i = ((long)blockIdx.x * blockDim.x + threadIdx.x) * 4;
    if (i >= MN) return;
    const float* P = part + (long)w * S * MN + i;
    float4 a = *(const float4*)P;
    for (int s2 = 1; s2 < S; ++s2) {
        float4 b2 = *(const float4*)(P + (long)s2 * MN);
        a.x += b2.x; a.y += b2.y; a.z += b2.z; a.w += b2.w;
    }
    const float* bw = bias.p[w];
    int n = (int)(i % kH);
    a.x += bw[n]; a.y += bw[n + 1]; a.z += bw[n + 2]; a.w += bw[n + 3];
    short* oh = (w == 0) ? qh : (w == 1) ? kh : vh;
    short* ol = (w == 0) ? ql : (w == 1) ? kl : vl;
    short h0, l0, h1, l1, h2, l2, h3, l3;
    split2(a.x, h0, l0); split2(a.y, h1, l1); split2(a.z, h2, l2); split2(a.w, h3, l3);
    *(short4*)&oh[i] = make_short4(h0, h1, h2, h3);
    *(short4*)&ol[i] = make_short4(l0, l1, l2, l3);
}

// ---------------- generic epilogue: sum partials (+bias, +act) -> hi/lo shorts ----------------
__global__ void splitk_epi_sh_kernel(const float* __restrict__ part, const float* __restrict__ bias,
                                     short* __restrict__ oh, short* __restrict__ ol,
                                     long MN, int Nn, int S, int act) {
    long i = ((long)blockIdx.x * blockDim.x + threadIdx.x) * 4;
    if (i >= MN) return;
    const float* P = part + i;
    float4 a = *(const float4*)P;
    for (int s2 = 1; s2 < S; ++s2) {
        float4 b2 = *(const float4*)(P + (long)s2 * MN);
        a.x += b2.x; a.y += b2.y; a.z += b2.z; a.w += b2.w;
    }
    if (bias) {
        int n = (int)(i % Nn);
        a.x += bias[n]; a.y += bias[n + 1]; a.z += bias[n + 2]; a.w += bias[n + 3];
    }
    if (act == 1) {
        a.x = 0.5f * a.x * (1.f + erff(a.x * 0.70710678118654752f));
        a.y = 0.5f * a.y * (1.f + erff(a.y * 0.70710678118654752f));
        a.z = 0.5f * a.z * (1.f + erff(a.z * 0.70710678118654752f));
        a.w = 0.5f * a.w * (1.f + erff(a.w * 0.70710678118654752f));
    }
    short h0, l0, h1, l1, h2, l2, h3, l3;
    split2(a.x, h0, l0); split2(a.y, h1, l1); split2(a.z, h2, l2); split2(a.w, h3, l3);
    *(short4*)&oh[i] = make_short4(h0, h1, h2, h3);
    *(short4*)&ol[i] = make_short4(l0, l1, l2, l3);
}

// ---------------- fused split-K + bias + residual + LN -> fp32 + hi/lo ----------------
__global__ void splitk_epi_ln2_kernel(const float* __restrict__ part, const float* __restrict__ bias,
                                      const float* __restrict__ res, const float* __restrict__ g,
                                      const float* __restrict__ b, float* __restrict__ out,
                                      short* __restrict__ oh, short* __restrict__ ol, int S) {
    int row = blockIdx.x; int tid = threadIdx.x;
    __shared__ float red[256];
    const long MN = (long)kS * kH;
    float vals[3]; float sum = 0.f;
    #pragma unroll
    for (int r = 0; r < 3; r++) {
        int j = tid + r * 256;
        const float* P = part + (long)row * kH + j;
        float x = res[(long)row * kH + j] + bias[j];
        for (int s2 = 0; s2 < S; ++s2) x += P[(long)s2 * MN];
        vals[r] = x; sum += x;
    }
    red[tid] = sum; __syncthreads();
    for (int off = 128; off > 0; off >>= 1) { if (tid < off) red[tid] += red[tid + off]; __syncthreads(); }
    float mean = red[0] / kH; __syncthreads();
    float vs = 0.f;
    #pragma unroll
    for (int r = 0; r < 3; r++) { float d = vals[r] - mean; vs += d * d; }
    red[tid] = vs; __syncthreads();
    for (int off = 128; off > 0; off >>= 1) { if (tid < off) red[tid] += red[tid + off]; __syncthreads(); }
    float rstd = rsqrtf(red[0] / kH + 1e-12f);
    #pragma unroll
    for (int r = 0; r < 3; r++) {
        int j = tid + r * 256;
        float o = (vals[r] - mean) * rstd * g[j] + b[j];
        out[(long)row * kH + j] = o;
        short hi, lo; split2(o, hi, lo);
        oh[(long)row * kH + j] = hi; ol[(long)row * kH + j] = lo;
    }
}

// ---------------- attention scores (pre-split): scores = Q K^T / 8 + mb ----------------
__global__ __launch_bounds__(256, 4) void attn_scores_pre_kernel(
    const short* __restrict__ qh, const short* __restrict__ ql,
    const short* __restrict__ kh, const short* __restrict__ kl,
    const float* __restrict__ mb, float* __restrict__ scores)
{
    __shared__ short As[128 * LDR], Bs[128 * LDR];
    int h = blockIdx.z;
    int q0 = blockIdx.y * 128, k0 = blockIdx.x * 128;
    int tid = threadIdx.x;
    int sr = tid >> 1, sh16 = (tid & 1) * 16;
    const short* Agh = qh + (long)(q0 + sr) * kH + h * kDH + sh16;
    const short* Agl = ql + (long)(q0 + sr) * kH + h * kDH + sh16;
    const short* Bgh = kh + (long)(k0 + sr) * kH + h * kDH + sh16;
    const short* Bgl = kl + (long)(k0 + sr) * kH + h * kDH + sh16;
    int lofs = sr * LDR + sh16;
    int wid = tid >> 6, lane = tid & 63;
    int wm = (wid >> 1) * 64, wn = (wid & 1) * 64;
    int fr = lane & 15, ko = (lane >> 4) * 8;
    f32x4 acc[4][4];
    #pragma unroll
    for (int i = 0; i < 4; i++)
        #pragma unroll
        for (int j = 0; j < 4; j++) acc[i][j] = (f32x4){0.f, 0.f, 0.f, 0.f};
    #pragma unroll
    for (int st = 0; st < 2; ++st) {
        int go = st * 32;
        *(bf16x8*)&As[lofs]      = *(const bf16x8*)(Agh + go);
        *(bf16x8*)&As[lofs + 8]  = *(const bf16x8*)(Agh + go + 8);
        *(bf16x8*)&As[lofs + 32] = *(const bf16x8*)(Agl + go);
        *(bf16x8*)&As[lofs + 40] = *(const bf16x8*)(Agl + go + 8);
        *(bf16x8*)&Bs[lofs]      = *(const bf16x8*)(Bgh + go);
        *(bf16x8*)&Bs[lofs + 8]  = *(const bf16x8*)(Bgh + go + 8);
        *(bf16x8*)&Bs[lofs + 32] = *(const bf16x8*)(Bgl + go);
        *(bf16x8*)&Bs[lofs + 40] = *(const bf16x8*)(Bgl + go + 8);
        __syncthreads();
        bf16x8 bh[4], bl[4];
        #pragma unroll
        for (int j = 0; j < 4; j++) {
            int c = (wn + j * 16 + fr) * LDR + ko;
            bh[j] = *(const bf16x8*)&Bs[c];
            bl[j] = *(const bf16x8*)&Bs[c + 32];
        }
        #pragma unroll
        for (int i = 0; i < 4; i++) {
            int r = (wm + i * 16 + fr) * LDR + ko;
            bf16x8 ah = *(const bf16x8*)&As[r];
            bf16x8 al = *(const bf16x8*)&As[r + 32];
            #pragma unroll
            for (int j = 0; j < 4; j++) {
                acc[i][j] = __builtin_amdgcn_mfma_f32_16x16x32_bf16(ah, bh[j], acc[i][j], 0, 0, 0);
                acc[i][j] = __builtin_amdgcn_mfma_f32_16x16x32_bf16(ah, bl[j], acc[i][j], 0, 0, 0);
                acc[i][j] = __builtin_amdgcn_mfma_f32_16x16x32_bf16(al, bh[j], acc[i][j], 0, 0, 0);
            }
        }
        __syncthreads();
    }
    int cr = (lane >> 4) * 4;
    #pragma unroll
    for (int i = 0; i < 4; i++) {
        #pragma unroll
        for (int r = 0; r < 4; r++) {
            int qq = q0 + wm + i * 16 + cr + r;
            float* rowp = &scores[((long)h * kS + qq) * kS + k0 + wn + fr];
            #pragma unroll
            for (int j = 0; j < 4; j++)
                rowp[j * 16] = acc[i][j][r] * 0.125f + mb[k0 + wn + j * 16 + fr];
        }
    }
}

// ---------------- softmax over rows of 512 -> P hi/lo ----------------
__global__ void softmax_split_kernel(const float* __restrict__ scores,
                                     short* __restrict__ ph, short* __restrict__ pl) {
    long row = blockIdx.x;
    const float* p = scores + row * kS;
    int tid = threadIdx.x; // 256
    __shared__ float red[256];
    float x0 = p[tid], x1 = p[tid + 256];
    red[tid] = fmaxf(x0, x1); __syncthreads();
    for (int off = 128; off > 0; off >>= 1) { if (tid < off) red[tid] = fmaxf(red[tid], red[tid + off]); __syncthreads(); }
    float mx = red[0]; __syncthreads();
    float e0 = expf(x0 - mx), e1 = expf(x1 - mx);
    red[tid] = e0 + e1; __syncthreads();
    for (int off = 128; off > 0; off >>= 1) { if (tid < off) red[tid] += red[tid + off]; __syncthreads(); }
    float inv = 1.f / red[0];
    float r0 = e0 * inv, r1 = e1 * inv;
    short h0, l0, h1, l1;
    split2(r0, h0, l0); split2(r1, h1, l1);
    ph[row * kS + tid] = h0; pl[row * kS + tid] = l0;
    ph[row * kS + tid + 256] = h1; pl[row * kS + tid + 256] = l1;
}

// ---------------- ctx partial = P @ V (pre-split, V transposed), 4-way K-split ----------------
// Tile 128(q) x 64(d) per head; part layout [s][q][kH], head h at cols h*64..h*64+63
__global__ __launch_bounds__(256, 4) void attn_ctx_pre_kernel(
    const short* __restrict__ ph, const short* __restrict__ pl,
    const short* __restrict__ vth, const short* __restrict__ vtl,
    float* __restrict__ part)
{
    __shared__ short As[128 * LDR];  // 18432 B
    __shared__ short Bs[64 * LDR];   //  9216 B
    int q0 = blockIdx.x * 128;
    int h = blockIdx.y >> 2, s = blockIdx.y & 3;
    int kbeg = s * 128;
    int tid = threadIdx.x;
    int sr = tid >> 1, sh16 = (tid & 1) * 16;
    const short* Agh = ph + ((long)h * kS + q0 + sr) * kS + kbeg + sh16;
    const short* Agl = pl + ((long)h * kS + q0 + sr) * kS + kbeg + sh16;
    int sbr = tid >> 2, sq = tid & 3;
    const short* Bg = (sq < 2 ? vth : vtl) + ((long)h * kDH + sbr) * kS + kbeg + (sq & 1) * 16;
    int bofs = sbr * LDR + (sq >= 2 ? 32 : 0) + (sq & 1) * 16;
    int aofs = sr * LDR + sh16;
    int wid = tid >> 6, lane = tid & 63;
    int wm = wid * 32;
    int fr = lane & 15, ko = (lane >> 4) * 8;
    f32x4 acc[2][4];
    #pragma unroll
    for (int i = 0; i < 2; i++)
        #pragma unroll
        for (int j = 0; j < 4; j++) acc[i][j] = (f32x4){0.f, 0.f, 0.f, 0.f};
    #pragma unroll
    for (int st = 0; st < 4; ++st) {
        int go = st * 32;
        *(bf16x8*)&As[aofs]      = *(const bf16x8*)(Agh + go);
        *(bf16x8*)&As[aofs + 8]  = *(const bf16x8*)(Agh + go + 8);
        *(bf16x8*)&As[aofs + 32] = *(const bf16x8*)(Agl + go);
        *(bf16x8*)&As[aofs + 40] = *(const bf16x8*)(Agl + go + 8);
        *(bf16x8*)&Bs[bofs]      = *(const bf16x8*)(Bg + go);
        *(bf16x8*)&Bs[bofs + 8]  = *(const bf16x8*)(Bg + go + 8);
        __syncthreads();
        bf16x8 bh[4], bl[4];
        #pragma unroll
        for (int j = 0; j < 4; j++) {
            int c = (j * 16 + fr) * LDR + ko;
            bh[j] = *(const bf16x8*)&Bs[c];
            bl[j] = *(const bf16x8*)&Bs[c + 32];
        }
        #pragma unroll
        for (int i = 0; i < 2; i++) {
            int r = (wm + i * 16 + fr) * LDR + ko;
            bf16x8 ah = *(const bf16x8*)&As[r];
            bf16x8 al = *(const bf16x8*)&As[r + 32];
            #pragma unroll
            for (int j = 0; j < 4; j++) {
                acc[i][j] = __builtin_amdgcn_mfma_f32_16x16x32_bf16(ah, bh[j], acc[i][j], 0, 0, 0);
                acc[i][j] = __builtin_amdgcn_mfma_f32_16x16x32_bf16(ah, bl[j], acc[i][j], 0, 0, 0);
                acc[i][j] = __builtin_amdgcn_mfma_f32_16x16x32_bf16(al, bh[j], acc[i][j], 0, 0, 0);
            }
        }
        __syncthreads();
    }
    long Pbase = (long)s * ((long)kS * kH);
    int cr = (lane >> 4) * 4;
    #pragma unroll
    for (int i = 0; i < 2; i++) {
        #pragma unroll
        for (int r = 0; r < 4; r++) {
            int gq = q0 + wm + i * 16 + cr + r;
            float* rowp = &part[Pbase + (long)gq * kH + h * kDH + fr];
            #pragma unroll
            for (int j = 0; j < 4; j++) rowp[j * 16] = acc[i][j][r];
        }
    }
}

// ---------------- GCN MFMA GEMM (inline split, unchanged from prev round) ----------------
__global__ __launch_bounds__(256, 4) void gemm_mfma_kernel(
    const float* __restrict__ A, Ptr3 Bp, float* __restrict__ part,
    float* __restrict__ Cdirect, const float* __restrict__ biasD,
    int M, int Nn, int K, int S, int act)
{
    constexpr int LDK = 40;
    __shared__ short Ah[128 * LDK], Al[128 * LDK], Bh[128 * LDK], Bl[128 * LDK];
    int w = blockIdx.z / S, s = blockIdx.z % S;
    const float* B = Bp.p[w];
    int Kc = K / S;
    int kbeg = s * Kc;
    int m0 = blockIdx.y * 128, n0 = blockIdx.x * 128;
    int tid = threadIdx.x;
    int sar = tid >> 1, sac = (tid & 1) * 16;
    int sbc = tid & 127, sbk = (tid >> 7) * 16;
    int gmA = m0 + sar; if (gmA > M - 1) gmA = M - 1;
    const float* Ag0 = A + (long)gmA * K + kbeg + sac;
    const float* Bg0 = B + (long)(kbeg + sbk) * Nn + n0 + sbc;
    int wid = tid >> 6, lane = tid & 63;
    int wm = (wid >> 1) * 64, wn = (wid & 1) * 64;
    int fr = lane & 15, ko = (lane >> 4) * 8;
    f32x4 acc[4][4];
    #pragma unroll
    for (int i = 0; i < 4; i++)
        #pragma unroll
        for (int j = 0; j < 4; j++) acc[i][j] = (f32x4){0.f, 0.f, 0.f, 0.f};
    int nst = Kc / 32;
    for (int st = 0; st < nst; ++st) {
        {
            const float* Ag = Ag0 + st * 32;
            int ob = sar * LDK + sac;
            #pragma unroll
            for (int qg = 0; qg < 4; qg++) {
                float4 f = *(const float4*)(Ag + qg * 4);
                unsigned short h0 = bf16_rne(f.x), h1 = bf16_rne(f.y),
                               h2 = bf16_rne(f.z), h3 = bf16_rne(f.w);
                unsigned short g0 = bf16_rne(f.x - bf16_f32(h0)), g1 = bf16_rne(f.y - bf16_f32(h1)),
                               g2 = bf16_rne(f.z - bf16_f32(h2)), g3 = bf16_rne(f.w - bf16_f32(h3));
                *(short4*)&Ah[ob + qg * 4] = make_short4((short)h0, (short)h1, (short)h2, (short)h3);
                *(short4*)&Al[ob + qg * 4] = make_short4((short)g0, (short)g1, (short)g2, (short)g3);
            }
        }
        {
            const float* Bg = Bg0 + (long)st * 32 * Nn;
            int ob = sbc * LDK + sbk;
            #pragma unroll
            for (int qg = 0; qg < 4; qg++) {
                float f0 = Bg[(long)(qg * 4 + 0) * Nn];
                float f1 = Bg[(long)(qg * 4 + 1) * Nn];
                float f2 = Bg[(long)(qg * 4 + 2) * Nn];
                float f3 = Bg[(long)(qg * 4 + 3) * Nn];
                unsigned short h0 = bf16_rne(f0), h1 = bf16_rne(f1),
                               h2 = bf16_rne(f2), h3 = bf16_rne(f3);
                unsigned short g0 = bf16_rne(f0 - bf16_f32(h0)), g1 = bf16_rne(f1 - bf16_f32(h1)),
                               g2 = bf16_rne(f2 - bf16_f32(h2)), g3 = bf16_rne(f3 - bf16_f32(h3));
                *(short4*)&Bh[ob + qg * 4] = make_short4((short)h0, (short)h1, (short)h2, (short)h3);
                *(short4*)&Bl[ob + qg * 4] = make_short4((short)g0, (short)g1, (short)g2, (short)g3);
            }
        }
        __syncthreads();
        bf16x8 bh[4], bl[4];
        #pragma unroll
        for (int j = 0; j < 4; j++) {
            int c = (wn + j * 16 + fr) * LDK + ko;
            bh[j] = *(const bf16x8*)&Bh[c];
            bl[j] = *(const bf16x8*)&Bl[c];
        }
        #pragma unroll
        for (int i = 0; i < 4; i++) {
            int r = (wm + i * 16 + fr) * LDK + ko;
            bf16x8 ah = *(const bf16x8*)&Ah[r];
            bf16x8 al = *(const bf16x8*)&Al[r];
            #pragma unroll
            for (int j = 0; j < 4; j++) {
                acc[i][j] = __builtin_amdgcn_mfma_f32_16x16x32_bf16(ah, bh[j], acc[i][j], 0, 0, 0);
                acc[i][j] = __builtin_amdgcn_mfma_f32_16x16x32_bf16(ah, bl[j], acc[i][j], 0, 0, 0);
                acc[i][j] = __builtin_amdgcn_mfma_f32_16x16x32_bf16(al, bh[j], acc[i][j], 0, 0, 0);
            }
        }
        __syncthreads();
    }
    int cr = (lane >> 4) * 4;
    if (Cdirect) {
        #pragma unroll
        for (int i = 0; i < 4; i++) {
            #pragma unroll
            for (int r = 0; r < 4; r++) {
                int gm = m0 + wm + i * 16 + cr + r;
                if (gm >= M) continue;
                float* rowp = &Cdirect[(long)gm * Nn + n0 + wn + fr];
                #pragma unroll
                for (int j = 0; j < 4; j++) {
                    float vv = acc[i][j][r];
                    if (biasD) vv += biasD[n0 + wn + j * 16 + fr];
                    if (act == 2) vv = fmaxf(vv, 0.f);
                    rowp[j * 16] = vv;
                }
            }
        }
    } else {
        long MN = (long)M * Nn;
        float* Pp = part + (long)(w * S + s) * MN;
        #pragma unroll
        for (int i = 0; i < 4; i++) {
            #pragma unroll
            for (int r = 0; r < 4; r++) {
                int gm = m0 + wm + i * 16 + cr + r;
                if (gm >= M) continue;
                float* rowp = &Pp[(long)gm * Nn + n0 + wn + fr];
                #pragma unroll
                for (int j = 0; j < 4; j++) rowp[j * 16] = acc[i][j][r];
            }
        }
    }
}

// ---------------- GCN sparse kernels ----------------
__global__ void maskbias_kernel(const int* mask, float* mb) {
    int i = blockIdx.x * blockDim.x + threadIdx.x;
    if (i < kS) mb[i] = (1.f - (float)mask[i]) * -1e4f;
}

__global__ void cnt_kernel(const int* __restrict__ dst, int* __restrict__ cnt, int E) {
    int e = blockIdx.x * blockDim.x + threadIdx.x;
    if (e < E) atomicAdd(&cnt[dst[e]], 1);
}

__global__ void scan1_kernel(const int* __restrict__ cnt, int* __restrict__ offs,
                             int* __restrict__ bsum, int n) {
    __shared__ int sh[256];
    int i = blockIdx.x * 256 + threadIdx.x;
    int v = (i < n) ? cnt[i] : 0;
    sh[threadIdx.x] = v; __syncthreads();
    for (int off = 1; off < 256; off <<= 1) {
        int t = (threadIdx.x >= off) ? sh[threadIdx.x - off] : 0;
        __syncthreads();
        sh[threadIdx.x] += t;
        __syncthreads();
    }
    if (i < n) offs[i] = sh[threadIdx.x] - v;
    if (threadIdx.x == 255) bsum[blockIdx.x] = sh[255];
}

__global__ void scan2_kernel(int* bsum, int nb, int* offs, int n) {
    if (threadIdx.x == 0) {
        int run = 0;
        for (int b = 0; b < nb; b++) { int t = bsum[b]; bsum[b] = run; run += t; }
        offs[n] = run;
    }
}

__global__ void scan3_kernel(const int* __restrict__ cnt, int* __restrict__ offs,
                             const int* __restrict__ bsum, int* __restrict__ cur,
                             float* __restrict__ dinv, int n) {
    int i = blockIdx.x * 256 + threadIdx.x;
    if (i >= n) return;
    int o = offs[i] + bsum[blockIdx.x];
    offs[i] = o; cur[i] = o;
    dinv[i] = rsqrtf((float)(cnt[i] + 1));
}

__global__ void csrfill_edgew_kernel(const int* __restrict__ src, const int* __restrict__ dst,
                                     int* __restrict__ cur, int* __restrict__ csr,
                                     const float* __restrict__ dinv, float* __restrict__ wsum,
                                     int E) {
    int e = blockIdx.x * blockDim.x + threadIdx.x;
    if (e < E) {
        int s2 = src[e], d = dst[e];
        int slot = atomicAdd(&cur[d], 1);
        csr[slot] = s2;
        atomicAdd(&wsum[s2], dinv[s2] * dinv[d]);
    }
}

__global__ __launch_bounds__(256) void spmm_gather_kernel(const int* __restrict__ offs,
                                                          const int* __restrict__ csr,
                                                          const float* __restrict__ dinv,
                                                          const float* __restrict__ hw,
                                                          const float* __restrict__ b1,
                                                          float* __restrict__ hout, int n) {
    int d = blockIdx.x * 2 + (threadIdx.x >> 7);
    int j = threadIdx.x & 127;
    if (d >= n) return;
    int beg = offs[d], end = offs[d + 1];
    float a0 = 0.f, a1 = 0.f, a2 = 0.f, a3 = 0.f;
    int p = beg;
    for (; p + 4 <= end; p += 4) {
        int s0 = csr[p], s1 = csr[p + 1], s2 = csr[p + 2], s3 = csr[p + 3];
        a0 += dinv[s0] * hw[(long)s0 * kGH + j];
        a1 += dinv[s1] * hw[(long)s1 * kGH + j];
        a2 += dinv[s2] * hw[(long)s2 * kGH + j];
        a3 += dinv[s3] * hw[(long)s3 * kGH + j];
    }
    for (; p < end; ++p) {
        int s4 = csr[p];
        a0 += dinv[s4] * hw[(long)s4 * kGH + j];
    }
    float acc = (a0 + a1) + (a2 + a3);
    float dd = dinv[d];
    float v = acc * dd + dd * dd * hw[(long)d * kGH + j] + b1[j];
    hout[(long)d * kGH + j] = fmaxf(v, 0.f);
}

__global__ void wreduce_kernel(const float* __restrict__ h, const float* __restrict__ w,
                               const float* __restrict__ dinv, float* __restrict__ s, int n) {
    int tid = threadIdx.x; int j = tid & 127; int half = tid >> 7;
    float acc = 0.f;
    for (int u = blockIdx.x * 2 + half; u < n; u += gridDim.x * 2) {
        float di = dinv[u];
        acc += (w[u] + di * di) * h[(long)u * kGH + j];
    }
    __shared__ float red[256];
    red[tid] = acc; __syncthreads();
    if (tid < 128) atomicAdd(&s[j], red[tid] + red[tid + 128]);
}

__global__ void gcn_final_kernel(const float* s, const float* W2, const float* b2, float* g) {
    int j2 = threadIdx.x; // 128
    float acc = 0.f;
    for (int j = 0; j < kGH; j++) acc += s[j] * W2[(long)j * kGH + j2];
    g[j2] = acc * (1.f / (float)kN) + b2[j2];
}

// ---------------- combine head ----------------
__global__ void combine_kernel(const float* __restrict__ cls, const float* __restrict__ gp,
                               const float* __restrict__ gh, const float* __restrict__ Wc,
                               const float* __restrict__ bc, float* __restrict__ feat) {
    int o = blockIdx.x * blockDim.x + threadIdx.x;
    if (o >= kH) return;
    float acc = 0.f;
    for (int i = 0; i < 768; i++)  acc += cls[i] * Wc[(long)i * kH + o];
    for (int i = 0; i < 128; i++)  acc += gp[i] * Wc[(long)(768 + i) * kH + o];
    for (int i = 0; i < 768; i++)  acc += cls[i] * Wc[(long)(896 + i) * kH + o];
    for (int i = 0; i < 128; i++)  acc += gh[i] * Wc[(long)(1664 + i) * kH + o];
    feat[o] = fmaxf(acc + bc[o], 0.f);
}

__global__ void cls_head_kernel(const float* feat, const float* W, const float* b, float* out) {
    int tid = threadIdx.x; // 256
    float a0 = 0.f, a1 = 0.f, a2 = 0.f;
    for (int o = tid; o < kH; o += 256) {
        float f = feat[o];
        a0 += f * W[o * 3 + 0]; a1 += f * W[o * 3 + 1]; a2 += f * W[o * 3 + 2];
    }
    __shared__ float r0[256], r1[256], r2[256];
    r0[tid] = a0; r1[tid] = a1; r2[tid] = a2; __syncthreads();
    for (int off = 128; off > 0; off >>= 1) {
        if (tid < off) { r0[tid] += r0[tid + off]; r1[tid] += r1[tid + off]; r2[tid] += r2[tid + off]; }
        __syncthreads();
    }
    if (tid == 0) { out[0] = r0[0] + b[0]; out[1] = r1[0] + b[1]; out[2] = r2[0] + b[2]; }
}

// ---------------- launch ----------------
extern "C" void kernel_launch(void* const* d_in, const int* in_sizes, int n_in,
                              void* d_out, int out_size, void* d_ws, size_t ws_size,
                              hipStream_t stream) {
    const int*   input_ids = (const int*)d_in[0];
    const int*   attn_mask = (const int*)d_in[1];
    const int*   type_ids  = (const int*)d_in[2];
    const int*   p_edges   = (const int*)d_in[3];
    const int*   h_edges   = (const int*)d_in[4];
    const float* p_nodes   = (const float*)d_in[5];
    const float* h_nodes   = (const float*)d_in[6];
    const float* word_emb  = (const float*)d_in[7];
    const float* pos_emb   = (const float*)d_in[8];
    const float* type_emb  = (const float*)d_in[9];
    const float* eln_s     = (const float*)d_in[10];
    const float* eln_b     = (const float*)d_in[11];
    const float* Wq = (const float*)d_in[12]; const float* bq = (const float*)d_in[13];
    const float* Wk = (const float*)d_in[14]; const float* bk = (const float*)d_in[15];
    const float* Wv = (const float*)d_in[16]; const float* bv = (const float*)d_in[17];
    const float* Wo = (const float*)d_in[18]; const float* bo = (const float*)d_in[19];
    const float* l1s = (const float*)d_in[20]; const float* l1b = (const float*)d_in[21];
    const float* W1 = (const float*)d_in[22]; const float* b1 = (const float*)d_in[23];
    const float* W2 = (const float*)d_in[24]; const float* b2 = (const float*)d_in[25];
    const float* l2s = (const float*)d_in[26]; const float* l2b = (const float*)d_in[27];
    const float* gW1 = (const float*)d_in[28]; const float* gb1 = (const float*)d_in[29];
    const float* gW2 = (const float*)d_in[30]; const float* gb2 = (const float*)d_in[31];
    const float* cW  = (const float*)d_in[32]; const float* cb  = (const float*)d_in[33];
    const float* clsW = (const float*)d_in[34]; const float* clsB = (const float*)d_in[35];
    float* out = (float*)d_out;

    // ---------------- workspace layout (float slots) ----------------
    float* W = (float*)d_ws;
    size_t off = 0;
    auto alloc = [&](size_t n) { float* p = W + off; off += n; return p; };
    float* h    = alloc((size_t)kS * kH);   // fp32 hidden (residual source)
    float* h1   = alloc((size_t)kS * kH);   // fp32 post-attn hidden
    float* deg  = alloc(kN);
    float* wsum = alloc(kN);
    float* svec = alloc(kGH);
    float* gp   = alloc(kGH);
    float* ghv  = alloc(kGH);
    float* mb   = alloc(kS);
    float* feat = alloc(kH);
    float* big  = W + off;

    // BERT-phase big layout (slots)
    float* part  = big;                                  // 4,718,592 (also scores fp32)
    float* scores = part;
    short* p_h   = (short*)(big + 4718592);              // 3,145,728 shorts
    short* p_l   = p_h + (size_t)3145728;
    short* ffn1_h = (short*)(big + 7864320);             // 1,572,864 shorts
    short* ffn1_l = ffn1_h + (size_t)1572864;
    short* wt_h  = (short*)(big + 9437184);              // 2,359,296 shorts (max weight)
    short* wt_l  = wt_h + (size_t)2359296;
    short* sm    = (short*)(big + 11796480);             // 14 x 393,216 shorts
    const size_t SMN = (size_t)kS * kH;                  // 393,216
    short* q_h = sm;            short* q_l = q_h + SMN;
    short* k_h = q_l + SMN;     short* k_l = k_h + SMN;
    short* v_h = k_l + SMN;     short* v_l = v_h + SMN;
    short* vt_h = v_l + SMN;    short* vt_l = vt_h + SMN;
    short* ctx_h = vt_l + SMN;  short* ctx_l = ctx_h + SMN;
    short* h1_h = ctx_l + SMN;  short* h1_l = h1_h + SMN;
    short* hh_h = h1_l + SMN;   short* hh_l = hh_h + SMN;

    // GCN-phase overlay on big
    float* hw1 = big;                                    // 6.4M
    float* agg = big + (size_t)kN * kGH;                 // 6.4M
    int* icnt  = (int*)(big + 2 * (size_t)kN * kGH);     // 50000
    int* ioffs = icnt + 50048;                           // 50001
    int* icur  = ioffs + 50048;
    int* ibsum = icur + 50048;                           // 256
    int* icsr  = ibsum + 256;                            // 800000

    const long MN_H = (long)kS * kH;   // 393216
    const long MN_F = (long)kS * kF;   // 1572864
    const int nScanBlk = CDIV(kN, 256); // 196

    // ---------- GCN on both graphs ----------
    const int* gsrc[2] = { p_edges, h_edges };
    const int* gdst[2] = { p_edges + kE, h_edges + kE };
    const float* gx[2] = { p_nodes, h_nodes };
    float* gout[2] = { gp, ghv };
    for (int gi = 0; gi < 2; gi++) {
        fill_kernel<<<CDIV((long)kN, 256), 256, 0, stream>>>((float*)icnt, 0.f, kN); // int 0
        fill_kernel<<<CDIV((long)kN, 256), 256, 0, stream>>>(wsum, 0.f, kN);
        fill_kernel<<<1, 256, 0, stream>>>(svec, 0.f, kGH);
        cnt_kernel<<<CDIV(kE, 256), 256, 0, stream>>>(gdst[gi], icnt, kE);
        scan1_kernel<<<nScanBlk, 256, 0, stream>>>(icnt, ioffs, ibsum, kN);
        scan2_kernel<<<1, 64, 0, stream>>>(ibsum, nScanBlk, ioffs, kN);
        scan3_kernel<<<nScanBlk, 256, 0, stream>>>(icnt, ioffs, ibsum, icur, deg, kN);
        csrfill_edgew_kernel<<<CDIV(kE, 256), 256, 0, stream>>>(
            gsrc[gi], gdst[gi], icur, icsr, deg, wsum, kE);
        gemm_mfma_kernel<<<dim3(1, CDIV(kN, 128), 1), 256, 0, stream>>>(
            gx[gi], Ptr3{{gW1, nullptr, nullptr}}, nullptr, hw1, nullptr, kN, kGH, kH, 1, 0);
        spmm_gather_kernel<<<CDIV(kN, 2), 256, 0, stream>>>(ioffs, icsr, deg, hw1, gb1, agg, kN);
        wreduce_kernel<<<512, 256, 0, stream>>>(agg, wsum, deg, svec, kN);
        gcn_final_kernel<<<1, kGH, 0, stream>>>(svec, gW2, gb2, gout[gi]);
    }

    // ---------- BERT ----------
    maskbias_kernel<<<2, 256, 0, stream>>>(attn_mask, mb);
    embed_ln_kernel<<<kS, 256, 0, stream>>>(input_ids, type_ids, word_emb, pos_emb, type_emb,
                                            eln_s, eln_b, h, hh_h, hh_l);
    for (int l = 0; l < kL; l++) {
        const float* Wq_l = Wq + (size_t)l * kH * kH; const float* bq_l = bq + (size_t)l * kH;
        const float* Wk_l = Wk + (size_t)l * kH * kH; const float* bk_l = bk + (size_t)l * kH;
        const float* Wv_l = Wv + (size_t)l * kH * kH; const float* bv_l = bv + (size_t)l * kH;
        const float* Wo_l = Wo + (size_t)l * kH * kH; const float* bo_l = bo + (size_t)l * kH;
        const float* W1_l = W1 + (size_t)l * kH * kF; const float* b1_l = b1 + (size_t)l * kF;
        const float* W2_l = W2 + (size_t)l * kF * kH; const float* b2_l = b2 + (size_t)l * kH;
        const float* l1s_l = l1s + (size_t)l * kH; const float* l1b_l = l1b + (size_t)l * kH;
        const float* l2s_l = l2s + (size_t)l * kH; const float* l2b_l = l2b + (size_t)l * kH;

        // QKV: convert weights, GEMM (S=4, 3 weights -> 288 blocks), epilogue -> q/k/v hi/lo
        wtrans_kernel<<<dim3(24, 24, 3), 256, 0, stream>>>(
            Ptr3{{Wq_l, Wk_l, Wv_l}}, wt_h, wt_l, kH, kH);
        gemm_pre_kernel<<<dim3(kH / 128, kS / 128, 12), 256, 0, stream>>>(
            hh_h, hh_l, wt_h, wt_l, (long)kH * kH, part, kS, kH, kH, 4);
        splitk_epi_qkv_kernel<<<dim3((int)(MN_H / 4 / 256), 3), 256, 0, stream>>>(
            part, Ptr3{{bq_l, bk_l, bv_l}}, q_h, q_l, k_h, k_l, v_h, v_l, 4);
        vtrans_kernel<<<dim3(kS / 32, kNH * 2), 256, 0, stream>>>(v_h, v_l, vt_h, vt_l);
        // scores + softmax -> P hi/lo
        attn_scores_pre_kernel<<<dim3(kS / 128, kS / 128, kNH), 256, 0, stream>>>(
            q_h, q_l, k_h, k_l, mb, scores);
        softmax_split_kernel<<<kNH * kS, 256, 0, stream>>>(scores, p_h, p_l);
        // ctx (K-split 4) -> ctx hi/lo
        attn_ctx_pre_kernel<<<dim3(kS / 128, kNH * 4), 256, 0, stream>>>(p_h, p_l, vt_h, vt_l, part);
        splitk_epi_sh_kernel<<<dim3((int)(MN_H / 4 / 256)), 256, 0, stream>>>(
            part, nullptr, ctx_h, ctx_l, MN_H, kH, 4, 0);
        // Wo (S=8) + fused LN -> h1 fp32 + hi/lo
        wtrans_kernel<<<dim3(24, 24, 1), 256, 0, stream>>>(
            Ptr3{{Wo_l, nullptr, nullptr}}, wt_h, wt_l, kH, kH);
        gemm_pre_kernel<<<dim3(kH / 128, kS / 128, 8), 256, 0, stream>>>(
            ctx_h, ctx_l, wt_h, wt_l, 0, part, kS, kH, kH, 8);
        splitk_epi_ln2_kernel<<<kS, 256, 0, stream>>>(part, bo_l, h, l1s_l, l1b_l, h1, h1_h, h1_l, 8);
        // FFN1 (S=3) + gelu -> ffn1 hi/lo
        wtrans_kernel<<<dim3(96, 24, 1), 256, 0, stream>>>(
            Ptr3{{W1_l, nullptr, nullptr}}, wt_h, wt_l, kH, kF);
        gemm_pre_kernel<<<dim3(kF / 128, kS / 128, 3), 256, 0, stream>>>(
            h1_h, h1_l, wt_h, wt_l, 0, part, kS, kF, kH, 3);
        splitk_epi_sh_kernel<<<dim3((int)(MN_F / 4 / 256)), 256, 0, stream>>>(
            part, b1_l, ffn1_h, ffn1_l, MN_F, kF, 3, 1);
        // FFN2 (S=12) + fused LN -> h fp32 + hi/lo
        wtrans_kernel<<<dim3(24, 96, 1), 256, 0, stream>>>(
            Ptr3{{W2_l, nullptr, nullptr}}, wt_h, wt_l, kF, kH);
        gemm_pre_kernel<<<dim3(kH / 128, kS / 128, 12), 256, 0, stream>>>(
            ffn1_h, ffn1_l, wt_h, wt_l, 0, part, kS, kH, kF, 12);
        splitk_epi_ln2_kernel<<<kS, 256, 0, stream>>>(part, b2_l, h1, l2s_l, l2b_l, h, hh_h, hh_l, 12);
    }

    // ---------- combine + classifier ----------
    combine_kernel<<<3, 256, 0, stream>>>(h, gp, ghv, cW, cb, feat);
    cls_head_kernel<<<1, 256, 0, stream>>>(feat, clsW, clsB, out);
}

// Round 6
// 2881.345 us; speedup vs baseline: 1.5071x; 1.0082x over previous
//
#include <hip/hip_runtime.h>
#include <math.h>

// Problem constants
constexpr int kS = 512, kH = 768, kNH = 12, kDH = 64, kF = 3072, kL = 12;
constexpr int kN = 50000, kE = 800000, kGH = 128;

#define CDIV(a,b) (((a)+(b)-1)/(b))

struct Ptr3 { const float* p[3]; };

typedef __attribute__((ext_vector_type(8))) short bf16x8;
typedef __attribute__((ext_vector_type(4))) float f32x4;

__device__ __forceinline__ unsigned short bf16_rne(float f) {
    unsigned int u = __float_as_uint(f);
    u += 0x7fffu + ((u >> 16) & 1u);
    return (unsigned short)(u >> 16);
}
__device__ __forceinline__ float bf16_f32(unsigned short h) {
    return __uint_as_float(((unsigned int)h) << 16);
}
__device__ __forceinline__ void split2(float f, short& hi, short& lo) {
    unsigned short h = bf16_rne(f);
    hi = (short)h;
    lo = (short)bf16_rne(f - bf16_f32(h));
}

constexpr int LDR = 72;  // LDS row: 32 hi | 32 lo | 8 pad shorts (144 B)

// ---------------- generic fill ----------------
__global__ void fill_kernel(float* p, float v, long n) {
    long i = blockIdx.x * (long)blockDim.x + threadIdx.x;
    if (i < n) p[i] = v;
}

// ---------------- embeddings + LN (+ hi/lo emit) ----------------
__global__ void embed_ln_kernel(const int* ids, const int* tt,
                                const float* we, const float* pe, const float* te,
                                const float* g, const float* b, float* out,
                                short* oh, short* ol) {
    int s = blockIdx.x;
    int tid = threadIdx.x;
    __shared__ float red[256];
    int id = ids[s], t = tt[s];
    float vals[3]; float sum = 0.f;
    #pragma unroll
    for (int r = 0; r < 3; r++) {
        int j = tid + r * 256;
        float x = we[(long)id * kH + j] + pe[(long)s * kH + j] + te[(long)t * kH + j];
        vals[r] = x; sum += x;
    }
    red[tid] = sum; __syncthreads();
    for (int off = 128; off > 0; off >>= 1) { if (tid < off) red[tid] += red[tid + off]; __syncthreads(); }
    float mean = red[0] / kH; __syncthreads();
    float vs = 0.f;
    #pragma unroll
    for (int r = 0; r < 3; r++) { float d = vals[r] - mean; vs += d * d; }
    red[tid] = vs; __syncthreads();
    for (int off = 128; off > 0; off >>= 1) { if (tid < off) red[tid] += red[tid + off]; __syncthreads(); }
    float rstd = rsqrtf(red[0] / kH + 1e-12f);
    #pragma unroll
    for (int r = 0; r < 3; r++) {
        int j = tid + r * 256;
        float o = (vals[r] - mean) * rstd * g[j] + b[j];
        out[(long)s * kH + j] = o;
        short hi, lo; split2(o, hi, lo);
        oh[(long)s * kH + j] = hi; ol[(long)s * kH + j] = lo;
    }
}

// ---------------- weight transpose + split: W[K][N] -> Th/Tl [N][K] ----------------
__global__ void wtrans_kernel(Ptr3 Wp, short* __restrict__ Th, short* __restrict__ Tl,
                              int K, int N) {
    const float* Wm = Wp.p[blockIdx.z];
    long moff = (long)blockIdx.z * K * N;
    __shared__ short th[32][33], tl[32][33];
    int n0 = blockIdx.x * 32, k0 = blockIdx.y * 32;
    int c = threadIdx.x & 31, r = threadIdx.x >> 5;
    #pragma unroll
    for (int p = 0; p < 4; p++) {
        int rr = p * 8 + r;
        float f = Wm[(long)(k0 + rr) * N + n0 + c];
        short hi, lo; split2(f, hi, lo);
        th[rr][c] = hi; tl[rr][c] = lo;
    }
    __syncthreads();
    #pragma unroll
    for (int p = 0; p < 4; p++) {
        int rr = p * 8 + r;
        Th[moff + (long)(n0 + rr) * K + k0 + c] = th[c][rr];
        Tl[moff + (long)(n0 + rr) * K + k0 + c] = tl[c][rr];
    }
}

// ---------------- V transpose: v[s][kH] (head slices) -> vt[h][d][s] ----------------
__global__ void vtrans_kernel(const short* __restrict__ vh, const short* __restrict__ vl,
                              short* __restrict__ vth, short* __restrict__ vtl) {
    __shared__ short th[32][33], tl[32][33];
    int s0 = blockIdx.x * 32;
    int h = blockIdx.y >> 1, d0 = (blockIdx.y & 1) * 32;
    int c = threadIdx.x & 31, r = threadIdx.x >> 5;
    #pragma unroll
    for (int p = 0; p < 4; p++) {
        int rr = p * 8 + r;
        th[rr][c] = vh[(long)(s0 + rr) * kH + h * kDH + d0 + c];
        tl[rr][c] = vl[(long)(s0 + rr) * kH + h * kDH + d0 + c];
    }
    __syncthreads();
    #pragma unroll
    for (int p = 0; p < 4; p++) {
        int rr = p * 8 + r;
        vth[((long)h * kDH + d0 + rr) * kS + s0 + c] = th[c][rr];
        vtl[((long)h * kDH + d0 + rr) * kS + s0 + c] = tl[c][rr];
    }
}

// ======== 64x128-tile pre-split MFMA GEMM: C[M,N] = A[M,K] @ B[K,N], B pre-transposed [N][K] ========
// 4 waves (2M x 2N), each wave 32x64 = 2x4 frags of 16x16, BK=32. Split-K partials.
__global__ __launch_bounds__(256, 4) void gemm64_pre(
    const short* __restrict__ Ah, const short* __restrict__ Al,
    const short* __restrict__ Bth, const short* __restrict__ Btl, long wstride,
    float* __restrict__ part, int M, int Nn, int K, int S)
{
    __shared__ short As[64 * LDR], Bs[128 * LDR];  // 27648 B
    int w = blockIdx.z / S, s = blockIdx.z % S;
    const short* Bh_ = Bth + (long)w * wstride;
    const short* Bl_ = Btl + (long)w * wstride;
    int Kc = K / S, kbeg = s * Kc;
    int m0 = blockIdx.y * 64, n0 = blockIdx.x * 128;
    int tid = threadIdx.x;
    int ar = tid >> 2, aq = (tid & 3) * 8;       // A: 4 thr/row, 1 hi + 1 lo chunk
    const short* Agh = Ah + (long)(m0 + ar) * K + kbeg + aq;
    const short* Agl = Al + (long)(m0 + ar) * K + kbeg + aq;
    int aofs = ar * LDR + aq;
    int br = tid >> 1, bq = (tid & 1) * 16;      // B: 2 thr/row, 2 hi + 2 lo chunks
    const short* Bgh = Bh_ + (long)(n0 + br) * K + kbeg + bq;
    const short* Bgl = Bl_ + (long)(n0 + br) * K + kbeg + bq;
    int bofs = br * LDR + bq;
    int wid = tid >> 6, lane = tid & 63;
    int wm = (wid >> 1) * 32, wn = (wid & 1) * 64;
    int fr = lane & 15, ko = (lane >> 4) * 8;
    f32x4 acc[2][4];
    #pragma unroll
    for (int i = 0; i < 2; i++)
        #pragma unroll
        for (int j = 0; j < 4; j++) acc[i][j] = (f32x4){0.f, 0.f, 0.f, 0.f};
    int nst = Kc / 32;
    for (int st = 0; st < nst; ++st) {
        int go = st * 32;
        *(bf16x8*)&As[aofs]      = *(const bf16x8*)(Agh + go);
        *(bf16x8*)&As[aofs + 32] = *(const bf16x8*)(Agl + go);
        *(bf16x8*)&Bs[bofs]      = *(const bf16x8*)(Bgh + go);
        *(bf16x8*)&Bs[bofs + 8]  = *(const bf16x8*)(Bgh + go + 8);
        *(bf16x8*)&Bs[bofs + 32] = *(const bf16x8*)(Bgl + go);
        *(bf16x8*)&Bs[bofs + 40] = *(const bf16x8*)(Bgl + go + 8);
        __syncthreads();
        bf16x8 bh[4], bl[4];
        #pragma unroll
        for (int j = 0; j < 4; j++) {
            int c = (wn + j * 16 + fr) * LDR + ko;
            bh[j] = *(const bf16x8*)&Bs[c];
            bl[j] = *(const bf16x8*)&Bs[c + 32];
        }
        #pragma unroll
        for (int i = 0; i < 2; i++) {
            int r = (wm + i * 16 + fr) * LDR + ko;
            bf16x8 ah = *(const bf16x8*)&As[r];
            bf16x8 al = *(const bf16x8*)&As[r + 32];
            #pragma unroll
            for (int j = 0; j < 4; j++) {
                acc[i][j] = __builtin_amdgcn_mfma_f32_16x16x32_bf16(ah, bh[j], acc[i][j], 0, 0, 0);
                acc[i][j] = __builtin_amdgcn_mfma_f32_16x16x32_bf16(ah, bl[j], acc[i][j], 0, 0, 0);
                acc[i][j] = __builtin_amdgcn_mfma_f32_16x16x32_bf16(al, bh[j], acc[i][j], 0, 0, 0);
            }
        }
        __syncthreads();
    }
    long MN = (long)M * Nn;
    float* Pp = part + (long)(w * S + s) * MN;
    int cr = (lane >> 4) * 4;
    #pragma unroll
    for (int i = 0; i < 2; i++) {
        #pragma unroll
        for (int r = 0; r < 4; r++) {
            int gm = m0 + wm + i * 16 + cr + r;
            float* rowp = &Pp[(long)gm * Nn + n0 + wn + fr];
            #pragma unroll
            for (int j = 0; j < 4; j++) rowp[j * 16] = acc[i][j][r];
        }
    }
}

// ======== GCN GEMM: A fp32 inline-split, B pre-split [N][K]; 64x128 tile; M guard ========
__global__ __launch_bounds__(256, 4) void gemm64_gcn(
    const float* __restrict__ A,
    const short* __restrict__ Bth, const short* __restrict__ Btl,
    float* __restrict__ part, int M, int Nn, int K, int S)
{
    __shared__ short As[64 * LDR], Bs[128 * LDR];
    int s = blockIdx.z;
    int Kc = K / S, kbeg = s * Kc;
    int m0 = blockIdx.y * 64, n0 = blockIdx.x * 128;
    int tid = threadIdx.x;
    int ar = tid >> 2, aqf = (tid & 3) * 8;      // A: 4 thr/row, 8 floats each
    int gmA = m0 + ar; if (gmA > M - 1) gmA = M - 1;
    const float* Agf = A + (long)gmA * K + kbeg + aqf;
    int aofs = ar * LDR + aqf;
    int br = tid >> 1, bq = (tid & 1) * 16;
    const short* Bgh = Bth + (long)(n0 + br) * K + kbeg + bq;
    const short* Bgl = Btl + (long)(n0 + br) * K + kbeg + bq;
    int bofs = br * LDR + bq;
    int wid = tid >> 6, lane = tid & 63;
    int wm = (wid >> 1) * 32, wn = (wid & 1) * 64;
    int fr = lane & 15, ko = (lane >> 4) * 8;
    f32x4 acc[2][4];
    #pragma unroll
    for (int i = 0; i < 2; i++)
        #pragma unroll
        for (int j = 0; j < 4; j++) acc[i][j] = (f32x4){0.f, 0.f, 0.f, 0.f};
    int nst = Kc / 32;
    for (int st = 0; st < nst; ++st) {
        int go = st * 32;
        float4 f0 = *(const float4*)(Agf + go);
        float4 f1 = *(const float4*)(Agf + go + 4);
        short h0, l0, h1, l1, h2, l2, h3, l3, h4, l4, h5, l5, h6, l6, h7, l7;
        split2(f0.x, h0, l0); split2(f0.y, h1, l1); split2(f0.z, h2, l2); split2(f0.w, h3, l3);
        split2(f1.x, h4, l4); split2(f1.y, h5, l5); split2(f1.z, h6, l6); split2(f1.w, h7, l7);
        *(short4*)&As[aofs]      = make_short4(h0, h1, h2, h3);
        *(short4*)&As[aofs + 4]  = make_short4(h4, h5, h6, h7);
        *(short4*)&As[aofs + 32] = make_short4(l0, l1, l2, l3);
        *(short4*)&As[aofs + 36] = make_short4(l4, l5, l6, l7);
        *(bf16x8*)&Bs[bofs]      = *(const bf16x8*)(Bgh + go);
        *(bf16x8*)&Bs[bofs + 8]  = *(const bf16x8*)(Bgh + go + 8);
        *(bf16x8*)&Bs[bofs + 32] = *(const bf16x8*)(Bgl + go);
        *(bf16x8*)&Bs[bofs + 40] = *(const bf16x8*)(Bgl + go + 8);
        __syncthreads();
        bf16x8 bh[4], bl[4];
        #pragma unroll
        for (int j = 0; j < 4; j++) {
            int c = (wn + j * 16 + fr) * LDR + ko;
            bh[j] = *(const bf16x8*)&Bs[c];
            bl[j] = *(const bf16x8*)&Bs[c + 32];
        }
        #pragma unroll
        for (int i = 0; i < 2; i++) {
            int r = (wm + i * 16 + fr) * LDR + ko;
            bf16x8 ah = *(const bf16x8*)&As[r];
            bf16x8 al = *(const bf16x8*)&As[r + 32];
            #pragma unroll
            for (int j = 0; j < 4; j++) {
                acc[i][j] = __builtin_amdgcn_mfma_f32_16x16x32_bf16(ah, bh[j], acc[i][j], 0, 0, 0);
                acc[i][j] = __builtin_amdgcn_mfma_f32_16x16x32_bf16(ah, bl[j], acc[i][j], 0, 0, 0);
                acc[i][j] = __builtin_amdgcn_mfma_f32_16x16x32_bf16(al, bh[j], acc[i][j], 0, 0, 0);
            }
        }
        __syncthreads();
    }
    long MN = (long)M * Nn;
    float* Pp = part + (long)s * MN;
    int cr = (lane >> 4) * 4;
    #pragma unroll
    for (int i = 0; i < 2; i++) {
        #pragma unroll
        for (int r = 0; r < 4; r++) {
            int gm = m0 + wm + i * 16 + cr + r;
            if (gm >= M) continue;
            float* rowp = &Pp[(long)gm * Nn + n0 + wn + fr];
            #pragma unroll
            for (int j = 0; j < 4; j++) rowp[j * 16] = acc[i][j][r];
        }
    }
}

// ---------------- f32 split-K epilogue (in-place safe) ----------------
__global__ void splitk_epi_f32(const float* part, float* out, long MN, int S) {
    long i = ((long)blockIdx.x * blockDim.x + threadIdx.x) * 4;
    if (i >= MN) return;
    float4 a = *(const float4*)(part + i);
    for (int s2 = 1; s2 < S; ++s2) {
        float4 b = *(const float4*)(part + (long)s2 * MN + i);
        a.x += b.x; a.y += b.y; a.z += b.z; a.w += b.w;
    }
    *(float4*)(out + i) = a;
}

// ---------------- QKV epilogue: sum partials + bias -> hi/lo shorts ----------------
__global__ void splitk_epi_qkv_kernel(const float* __restrict__ part, Ptr3 bias,
                                      short* __restrict__ qh, short* __restrict__ ql,
                                      short* __restrict__ kh, short* __restrict__ kl,
                                      short* __restrict__ vh, short* __restrict__ vl,
                                      int S) {
    const long MN = (long)kS * kH;
    int w = blockIdx.y;
    long i = ((long)blockIdx.x * blockDim.x + threadIdx.x) * 4;
    if (i >= MN) return;
    const float* P = part + (long)w * S * MN + i;
    float4 a = *(const float4*)P;
    for (int s2 = 1; s2 < S; ++s2) {
        float4 b2 = *(const float4*)(P + (long)s2 * MN);
        a.x += b2.x; a.y += b2.y; a.z += b2.z; a.w += b2.w;
    }
    const float* bw = bias.p[w];
    int n = (int)(i % kH);
    a.x += bw[n]; a.y += bw[n + 1]; a.z += bw[n + 2]; a.w += bw[n + 3];
    short* oh = (w == 0) ? qh : (w == 1) ? kh : vh;
    short* ol = (w == 0) ? ql : (w == 1) ? kl : vl;
    short h0, l0, h1, l1, h2, l2, h3, l3;
    split2(a.x, h0, l0); split2(a.y, h1, l1); split2(a.z, h2, l2); split2(a.w, h3, l3);
    *(short4*)&oh[i] = make_short4(h0, h1, h2, h3);
    *(short4*)&ol[i] = make_short4(l0, l1, l2, l3);
}

// ---------------- generic epilogue: sum partials (+bias, +act) -> hi/lo shorts ----------------
__global__ void splitk_epi_sh_kernel(const float* __restrict__ part, const float* __restrict__ bias,
                                     short* __restrict__ oh, short* __restrict__ ol,
                                     long MN, int Nn, int S, int act) {
    long i = ((long)blockIdx.x * blockDim.x + threadIdx.x) * 4;
    if (i >= MN) return;
    const float* P = part + i;
    float4 a = *(const float4*)P;
    for (int s2 = 1; s2 < S; ++s2) {
        float4 b2 = *(const float4*)(P + (long)s2 * MN);
        a.x += b2.x; a.y += b2.y; a.z += b2.z; a.w += b2.w;
    }
    if (bias) {
        int n = (int)(i % Nn);
        a.x += bias[n]; a.y += bias[n + 1]; a.z += bias[n + 2]; a.w += bias[n + 3];
    }
    if (act == 1) {
        a.x = 0.5f * a.x * (1.f + erff(a.x * 0.70710678118654752f));
        a.y = 0.5f * a.y * (1.f + erff(a.y * 0.70710678118654752f));
        a.z = 0.5f * a.z * (1.f + erff(a.z * 0.70710678118654752f));
        a.w = 0.5f * a.w * (1.f + erff(a.w * 0.70710678118654752f));
    }
    short h0, l0, h1, l1, h2, l2, h3, l3;
    split2(a.x, h0, l0); split2(a.y, h1, l1); split2(a.z, h2, l2); split2(a.w, h3, l3);
    *(short4*)&oh[i] = make_short4(h0, h1, h2, h3);
    *(short4*)&ol[i] = make_short4(l0, l1, l2, l3);
}

// ---------------- fused split-K + bias + residual + LN -> fp32 + hi/lo ----------------
__global__ void splitk_epi_ln2_kernel(const float* __restrict__ part, const float* __restrict__ bias,
                                      const float* __restrict__ res, const float* __restrict__ g,
                                      const float* __restrict__ b, float* __restrict__ out,
                                      short* __restrict__ oh, short* __restrict__ ol, int S) {
    int row = blockIdx.x; int tid = threadIdx.x;
    __shared__ float red[256];
    const long MN = (long)kS * kH;
    float vals[3]; float sum = 0.f;
    #pragma unroll
    for (int r = 0; r < 3; r++) {
        int j = tid + r * 256;
        const float* P = part + (long)row * kH + j;
        float x = res[(long)row * kH + j] + bias[j];
        for (int s2 = 0; s2 < S; ++s2) x += P[(long)s2 * MN];
        vals[r] = x; sum += x;
    }
    red[tid] = sum; __syncthreads();
    for (int off = 128; off > 0; off >>= 1) { if (tid < off) red[tid] += red[tid + off]; __syncthreads(); }
    float mean = red[0] / kH; __syncthreads();
    float vs = 0.f;
    #pragma unroll
    for (int r = 0; r < 3; r++) { float d = vals[r] - mean; vs += d * d; }
    red[tid] = vs; __syncthreads();
    for (int off = 128; off > 0; off >>= 1) { if (tid < off) red[tid] += red[tid + off]; __syncthreads(); }
    float rstd = rsqrtf(red[0] / kH + 1e-12f);
    #pragma unroll
    for (int r = 0; r < 3; r++) {
        int j = tid + r * 256;
        float o = (vals[r] - mean) * rstd * g[j] + b[j];
        out[(long)row * kH + j] = o;
        short hi, lo; split2(o, hi, lo);
        oh[(long)row * kH + j] = hi; ol[(long)row * kH + j] = lo;
    }
}

// ---------------- attention scores: 64(q) x 128(k) tile ----------------
__global__ __launch_bounds__(256, 4) void attn_scores64_kernel(
    const short* __restrict__ qh, const short* __restrict__ ql,
    const short* __restrict__ kh, const short* __restrict__ kl,
    const float* __restrict__ mb, float* __restrict__ scores)
{
    __shared__ short As[64 * LDR], Bs[128 * LDR];
    int h = blockIdx.z;
    int k0 = blockIdx.x * 128, q0 = blockIdx.y * 64;
    int tid = threadIdx.x;
    int ar = tid >> 2, aq = (tid & 3) * 8;
    const short* Agh = qh + (long)(q0 + ar) * kH + h * kDH + aq;
    const short* Agl = ql + (long)(q0 + ar) * kH + h * kDH + aq;
    int aofs = ar * LDR + aq;
    int br = tid >> 1, bq = (tid & 1) * 16;
    const short* Bgh = kh + (long)(k0 + br) * kH + h * kDH + bq;
    const short* Bgl = kl + (long)(k0 + br) * kH + h * kDH + bq;
    int bofs = br * LDR + bq;
    int wid = tid >> 6, lane = tid & 63;
    int wm = (wid >> 1) * 32, wn = (wid & 1) * 64;
    int fr = lane & 15, ko = (lane >> 4) * 8;
    f32x4 acc[2][4];
    #pragma unroll
    for (int i = 0; i < 2; i++)
        #pragma unroll
        for (int j = 0; j < 4; j++) acc[i][j] = (f32x4){0.f, 0.f, 0.f, 0.f};
    #pragma unroll
    for (int st = 0; st < 2; ++st) {
        int go = st * 32;
        *(bf16x8*)&As[aofs]      = *(const bf16x8*)(Agh + go);
        *(bf16x8*)&As[aofs + 32] = *(const bf16x8*)(Agl + go);
        *(bf16x8*)&Bs[bofs]      = *(const bf16x8*)(Bgh + go);
        *(bf16x8*)&Bs[bofs + 8]  = *(const bf16x8*)(Bgh + go + 8);
        *(bf16x8*)&Bs[bofs + 32] = *(const bf16x8*)(Bgl + go);
        *(bf16x8*)&Bs[bofs + 40] = *(const bf16x8*)(Bgl + go + 8);
        __syncthreads();
        bf16x8 bh[4], bl[4];
        #pragma unroll
        for (int j = 0; j < 4; j++) {
            int c = (wn + j * 16 + fr) * LDR + ko;
            bh[j] = *(const bf16x8*)&Bs[c];
            bl[j] = *(const bf16x8*)&Bs[c + 32];
        }
        #pragma unroll
        for (int i = 0; i < 2; i++) {
            int r = (wm + i * 16 + fr) * LDR + ko;
            bf16x8 ah = *(const bf16x8*)&As[r];
            bf16x8 al = *(const bf16x8*)&As[r + 32];
            #pragma unroll
            for (int j = 0; j < 4; j++) {
                acc[i][j] = __builtin_amdgcn_mfma_f32_16x16x32_bf16(ah, bh[j], acc[i][j], 0, 0, 0);
                acc[i][j] = __builtin_amdgcn_mfma_f32_16x16x32_bf16(ah, bl[j], acc[i][j], 0, 0, 0);
                acc[i][j] = __builtin_amdgcn_mfma_f32_16x16x32_bf16(al, bh[j], acc[i][j], 0, 0, 0);
            }
        }
        __syncthreads();
    }
    int cr = (lane >> 4) * 4;
    #pragma unroll
    for (int i = 0; i < 2; i++) {
        #pragma unroll
        for (int r = 0; r < 4; r++) {
            int qq = q0 + wm + i * 16 + cr + r;
            float* rowp = &scores[((long)h * kS + qq) * kS + k0 + wn + fr];
            #pragma unroll
            for (int j = 0; j < 4; j++)
                rowp[j * 16] = acc[i][j][r] * 0.125f + mb[k0 + wn + j * 16 + fr];
        }
    }
}

// ---------------- softmax over rows of 512 -> P hi/lo ----------------
__global__ void softmax_split_kernel(const float* __restrict__ scores,
                                     short* __restrict__ ph, short* __restrict__ pl) {
    long row = blockIdx.x;
    const float* p = scores + row * kS;
    int tid = threadIdx.x;
    __shared__ float red[256];
    float x0 = p[tid], x1 = p[tid + 256];
    red[tid] = fmaxf(x0, x1); __syncthreads();
    for (int off = 128; off > 0; off >>= 1) { if (tid < off) red[tid] = fmaxf(red[tid], red[tid + off]); __syncthreads(); }
    float mx = red[0]; __syncthreads();
    float e0 = expf(x0 - mx), e1 = expf(x1 - mx);
    red[tid] = e0 + e1; __syncthreads();
    for (int off = 128; off > 0; off >>= 1) { if (tid < off) red[tid] += red[tid + off]; __syncthreads(); }
    float inv = 1.f / red[0];
    float r0 = e0 * inv, r1 = e1 * inv;
    short h0, l0, h1, l1;
    split2(r0, h0, l0); split2(r1, h1, l1);
    ph[row * kS + tid] = h0; pl[row * kS + tid] = l0;
    ph[row * kS + tid + 256] = h1; pl[row * kS + tid + 256] = l1;
}

// ---------------- ctx partial = P @ V (pre-split, V transposed), 8-way K-split ----------------
// Tile 128(q) x 64(d) per head, Kc=64; part layout [s][q][kH], head h at cols h*64..
__global__ __launch_bounds__(256, 4) void attn_ctx64_kernel(
    const short* __restrict__ ph, const short* __restrict__ pl,
    const short* __restrict__ vth, const short* __restrict__ vtl,
    float* __restrict__ part)
{
    __shared__ short As[128 * LDR], Bs[64 * LDR];
    int q0 = blockIdx.x * 128;
    int h = blockIdx.y >> 3, s = blockIdx.y & 7;
    int kbeg = s * 64;
    int tid = threadIdx.x;
    int ar = tid >> 1, aq = (tid & 1) * 16;      // A (P): 2 thr/row, 4 chunks
    const short* Agh = ph + ((long)h * kS + q0 + ar) * kS + kbeg + aq;
    const short* Agl = pl + ((long)h * kS + q0 + ar) * kS + kbeg + aq;
    int aofs = ar * LDR + aq;
    int brr = tid >> 2, bq = (tid & 3) * 8;      // B (V^T): 4 thr/row, 2 chunks
    const short* Bgh = vth + ((long)h * kDH + brr) * kS + kbeg + bq;
    const short* Bgl = vtl + ((long)h * kDH + brr) * kS + kbeg + bq;
    int bofs = brr * LDR + bq;
    int wid = tid >> 6, lane = tid & 63;
    int wm = wid * 32;
    int fr = lane & 15, ko = (lane >> 4) * 8;
    f32x4 acc[2][4];
    #pragma unroll
    for (int i = 0; i < 2; i++)
        #pragma unroll
        for (int j = 0; j < 4; j++) acc[i][j] = (f32x4){0.f, 0.f, 0.f, 0.f};
    #pragma unroll
    for (int st = 0; st < 2; ++st) {
        int go = st * 32;
        *(bf16x8*)&As[aofs]      = *(const bf16x8*)(Agh + go);
        *(bf16x8*)&As[aofs + 8]  = *(const bf16x8*)(Agh + go + 8);
        *(bf16x8*)&As[aofs + 32] = *(const bf16x8*)(Agl + go);
        *(bf16x8*)&As[aofs + 40] = *(const bf16x8*)(Agl + go + 8);
        *(bf16x8*)&Bs[bofs]      = *(const bf16x8*)(Bgh + go);
        *(bf16x8*)&Bs[bofs + 32] = *(const bf16x8*)(Bgl + go);
        __syncthreads();
        bf16x8 bh[4], bl[4];
        #pragma unroll
        for (int j = 0; j < 4; j++) {
            int c = (j * 16 + fr) * LDR + ko;
            bh[j] = *(const bf16x8*)&Bs[c];
            bl[j] = *(const bf16x8*)&Bs[c + 32];
        }
        #pragma unroll
        for (int i = 0; i < 2; i++) {
            int r = (wm + i * 16 + fr) * LDR + ko;
            bf16x8 ah = *(const bf16x8*)&As[r];
            bf16x8 al = *(const bf16x8*)&As[r + 32];
            #pragma unroll
            for (int j = 0; j < 4; j++) {
                acc[i][j] = __builtin_amdgcn_mfma_f32_16x16x32_bf16(ah, bh[j], acc[i][j], 0, 0, 0);
                acc[i][j] = __builtin_amdgcn_mfma_f32_16x16x32_bf16(ah, bl[j], acc[i][j], 0, 0, 0);
                acc[i][j] = __builtin_amdgcn_mfma_f32_16x16x32_bf16(al, bh[j], acc[i][j], 0, 0, 0);
            }
        }
        __syncthreads();
    }
    long Pbase = (long)s * ((long)kS * kH);
    int cr = (lane >> 4) * 4;
    #pragma unroll
    for (int i = 0; i < 2; i++) {
        #pragma unroll
        for (int r = 0; r < 4; r++) {
            int gq = q0 + wm + i * 16 + cr + r;
            float* rowp = &part[Pbase + (long)gq * kH + h * kDH + fr];
            #pragma unroll
            for (int j = 0; j < 4; j++) rowp[j * 16] = acc[i][j][r];
        }
    }
}

// ---------------- GCN sparse kernels ----------------
__global__ void maskbias_kernel(const int* mask, float* mb) {
    int i = blockIdx.x * blockDim.x + threadIdx.x;
    if (i < kS) mb[i] = (1.f - (float)mask[i]) * -1e4f;
}

__global__ void cnt_kernel(const int* __restrict__ dst, int* __restrict__ cnt, int E) {
    int e = blockIdx.x * blockDim.x + threadIdx.x;
    if (e < E) atomicAdd(&cnt[dst[e]], 1);
}

__global__ void scan1_kernel(const int* __restrict__ cnt, int* __restrict__ offs,
                             int* __restrict__ bsum, int n) {
    __shared__ int sh[256];
    int i = blockIdx.x * 256 + threadIdx.x;
    int v = (i < n) ? cnt[i] : 0;
    sh[threadIdx.x] = v; __syncthreads();
    for (int off = 1; off < 256; off <<= 1) {
        int t = (threadIdx.x >= off) ? sh[threadIdx.x - off] : 0;
        __syncthreads();
        sh[threadIdx.x] += t;
        __syncthreads();
    }
    if (i < n) offs[i] = sh[threadIdx.x] - v;
    if (threadIdx.x == 255) bsum[blockIdx.x] = sh[255];
}

__global__ void scan2_kernel(int* bsum, int nb, int* offs, int n) {
    if (threadIdx.x == 0) {
        int run = 0;
        for (int b = 0; b < nb; b++) { int t = bsum[b]; bsum[b] = run; run += t; }
        offs[n] = run;
    }
}

__global__ void scan3_kernel(const int* __restrict__ cnt, int* __restrict__ offs,
                             const int* __restrict__ bsum, int* __restrict__ cur,
                             float* __restrict__ dinv, int n) {
    int i = blockIdx.x * 256 + threadIdx.x;
    if (i >= n) return;
    int o = offs[i] + bsum[blockIdx.x];
    offs[i] = o; cur[i] = o;
    dinv[i] = rsqrtf((float)(cnt[i] + 1));
}

__global__ void csrfill_edgew_kernel(const int* __restrict__ src, const int* __restrict__ dst,
                                     int* __restrict__ cur, int* __restrict__ csr,
                                     const float* __restrict__ dinv, float* __restrict__ wsum,
                                     int E) {
    int e = blockIdx.x * blockDim.x + threadIdx.x;
    if (e < E) {
        int s2 = src[e], d = dst[e];
        int slot = atomicAdd(&cur[d], 1);
        csr[slot] = s2;
        atomicAdd(&wsum[s2], dinv[s2] * dinv[d]);
    }
}

__global__ __launch_bounds__(256) void spmm_gather_kernel(const int* __restrict__ offs,
                                                          const int* __restrict__ csr,
                                                          const float* __restrict__ dinv,
                                                          const float* __restrict__ hw,
                                                          const float* __restrict__ b1,
                                                          float* __restrict__ hout, int n) {
    int d = blockIdx.x * 2 + (threadIdx.x >> 7);
    int j = threadIdx.x & 127;
    if (d >= n) return;
    int beg = offs[d], end = offs[d + 1];
    float a0 = 0.f, a1 = 0.f, a2 = 0.f, a3 = 0.f;
    int p = beg;
    for (; p + 4 <= end; p += 4) {
        int s0 = csr[p], s1 = csr[p + 1], s2 = csr[p + 2], s3 = csr[p + 3];
        a0 += dinv[s0] * hw[(long)s0 * kGH + j];
        a1 += dinv[s1] * hw[(long)s1 * kGH + j];
        a2 += dinv[s2] * hw[(long)s2 * kGH + j];
        a3 += dinv[s3] * hw[(long)s3 * kGH + j];
    }
    for (; p < end; ++p) {
        int s4 = csr[p];
        a0 += dinv[s4] * hw[(long)s4 * kGH + j];
    }
    float acc = (a0 + a1) + (a2 + a3);
    float dd = dinv[d];
    float v = acc * dd + dd * dd * hw[(long)d * kGH + j] + b1[j];
    hout[(long)d * kGH + j] = fmaxf(v, 0.f);
}

__global__ void wreduce_kernel(const float* __restrict__ h, const float* __restrict__ w,
                               const float* __restrict__ dinv, float* __restrict__ s, int n) {
    int tid = threadIdx.x; int j = tid & 127; int half = tid >> 7;
    float acc = 0.f;
    for (int u = blockIdx.x * 2 + half; u < n; u += gridDim.x * 2) {
        float di = dinv[u];
        acc += (w[u] + di * di) * h[(long)u * kGH + j];
    }
    __shared__ float red[256];
    red[tid] = acc; __syncthreads();
    if (tid < 128) atomicAdd(&s[j], red[tid] + red[tid + 128]);
}

__global__ void gcn_final_kernel(const float* s, const float* W2, const float* b2, float* g) {
    int j2 = threadIdx.x;
    float acc = 0.f;
    for (int j = 0; j < kGH; j++) acc += s[j] * W2[(long)j * kGH + j2];
    g[j2] = acc * (1.f / (float)kN) + b2[j2];
}

// ---------------- combine head ----------------
__global__ void combine_kernel(const float* __restrict__ cls, const float* __restrict__ gp,
                               const float* __restrict__ gh, const float* __restrict__ Wc,
                               const float* __restrict__ bc, float* __restrict__ feat) {
    int o = blockIdx.x * blockDim.x + threadIdx.x;
    if (o >= kH) return;
    float acc = 0.f;
    for (int i = 0; i < 768; i++)  acc += cls[i] * Wc[(long)i * kH + o];
    for (int i = 0; i < 128; i++)  acc += gp[i] * Wc[(long)(768 + i) * kH + o];
    for (int i = 0; i < 768; i++)  acc += cls[i] * Wc[(long)(896 + i) * kH + o];
    for (int i = 0; i < 128; i++)  acc += gh[i] * Wc[(long)(1664 + i) * kH + o];
    feat[o] = fmaxf(acc + bc[o], 0.f);
}

__global__ void cls_head_kernel(const float* feat, const float* W, const float* b, float* out) {
    int tid = threadIdx.x;
    float a0 = 0.f, a1 = 0.f, a2 = 0.f;
    for (int o = tid; o < kH; o += 256) {
        float f = feat[o];
        a0 += f * W[o * 3 + 0]; a1 += f * W[o * 3 + 1]; a2 += f * W[o * 3 + 2];
    }
    __shared__ float r0[256], r1[256], r2[256];
    r0[tid] = a0; r1[tid] = a1; r2[tid] = a2; __syncthreads();
    for (int off = 128; off > 0; off >>= 1) {
        if (tid < off) { r0[tid] += r0[tid + off]; r1[tid] += r1[tid + off]; r2[tid] += r2[tid + off]; }
        __syncthreads();
    }
    if (tid == 0) { out[0] = r0[0] + b[0]; out[1] = r1[0] + b[1]; out[2] = r2[0] + b[2]; }
}

// ---------------- launch ----------------
extern "C" void kernel_launch(void* const* d_in, const int* in_sizes, int n_in,
                              void* d_out, int out_size, void* d_ws, size_t ws_size,
                              hipStream_t stream) {
    const int*   input_ids = (const int*)d_in[0];
    const int*   attn_mask = (const int*)d_in[1];
    const int*   type_ids  = (const int*)d_in[2];
    const int*   p_edges   = (const int*)d_in[3];
    const int*   h_edges   = (const int*)d_in[4];
    const float* p_nodes   = (const float*)d_in[5];
    const float* h_nodes   = (const float*)d_in[6];
    const float* word_emb  = (const float*)d_in[7];
    const float* pos_emb   = (const float*)d_in[8];
    const float* type_emb  = (const float*)d_in[9];
    const float* eln_s     = (const float*)d_in[10];
    const float* eln_b     = (const float*)d_in[11];
    const float* Wq = (const float*)d_in[12]; const float* bq = (const float*)d_in[13];
    const float* Wk = (const float*)d_in[14]; const float* bk = (const float*)d_in[15];
    const float* Wv = (const float*)d_in[16]; const float* bv = (const float*)d_in[17];
    const float* Wo = (const float*)d_in[18]; const float* bo = (const float*)d_in[19];
    const float* l1s = (const float*)d_in[20]; const float* l1b = (const float*)d_in[21];
    const float* W1 = (const float*)d_in[22]; const float* b1 = (const float*)d_in[23];
    const float* W2 = (const float*)d_in[24]; const float* b2 = (const float*)d_in[25];
    const float* l2s = (const float*)d_in[26]; const float* l2b = (const float*)d_in[27];
    const float* gW1 = (const float*)d_in[28]; const float* gb1 = (const float*)d_in[29];
    const float* gW2 = (const float*)d_in[30]; const float* gb2 = (const float*)d_in[31];
    const float* cW  = (const float*)d_in[32]; const float* cb  = (const float*)d_in[33];
    const float* clsW = (const float*)d_in[34]; const float* clsB = (const float*)d_in[35];
    float* out = (float*)d_out;

    // ---------------- workspace layout ----------------
    float* W = (float*)d_ws;
    size_t off = 0;
    auto alloc = [&](size_t n) { float* p = W + off; off += n; return p; };
    float* h    = alloc((size_t)kS * kH);
    float* h1   = alloc((size_t)kS * kH);
    float* deg  = alloc(kN);
    float* wsum = alloc(kN);
    float* svec = alloc(kGH);
    float* gp   = alloc(kGH);
    float* ghv  = alloc(kGH);
    float* mb   = alloc(kS);
    float* feat = alloc(kH);
    float* big  = W + off;

    // BERT-phase big layout (float slots)
    float* part  = big;                                  // up to 4,718,592 (QKV S=4 / FFN2 S=12 exact; FFN1 S=4 spills into p region, dead then)
    float* scores = part;
    short* p_h   = (short*)(big + 4718592);
    short* p_l   = p_h + (size_t)3145728;
    short* ffn1_h = (short*)(big + 7864320);
    short* ffn1_l = ffn1_h + (size_t)1572864;
    short* wt_h  = (short*)(big + 9437184);
    short* wt_l  = wt_h + (size_t)2359296;
    short* sm    = (short*)(big + 11796480);
    const size_t SMN = (size_t)kS * kH;
    short* q_h = sm;            short* q_l = q_h + SMN;
    short* k_h = q_l + SMN;     short* k_l = k_h + SMN;
    short* v_h = k_l + SMN;     short* v_l = v_h + SMN;
    short* vt_h = v_l + SMN;    short* vt_l = vt_h + SMN;
    short* ctx_h = vt_l + SMN;  short* ctx_l = ctx_h + SMN;
    short* h1_h = ctx_l + SMN;  short* h1_l = h1_h + SMN;
    short* hh_h = h1_l + SMN;   short* hh_l = hh_h + SMN;

    // GCN-phase overlay on big
    float* hw1 = big;                                    // partial 0 + final
    float* agg = big + (size_t)kN * kGH;                 // partial 1, then agg
    int* icnt  = (int*)(big + 2 * (size_t)kN * kGH);
    int* ioffs = icnt + 50048;
    int* icur  = ioffs + 50048;
    int* ibsum = icur + 50048;
    int* icsr  = ibsum + 256;
    short* gwt_h = (short*)(icsr + kE);                  // 768*128 shorts (16B-aligned)
    short* gwt_l = gwt_h + (size_t)kH * kGH;

    const long MN_H = (long)kS * kH;   // 393216
    const long MN_F = (long)kS * kF;   // 1572864
    const long MN_G = (long)kN * kGH;  // 6400000
    const int nScanBlk = CDIV(kN, 256);

    // ---------- GCN on both graphs ----------
    const int* gsrc[2] = { p_edges, h_edges };
    const int* gdst[2] = { p_edges + kE, h_edges + kE };
    const float* gx[2] = { p_nodes, h_nodes };
    float* gout[2] = { gp, ghv };
    // pre-split gW1 -> [N][K] hi/lo (once, shared by both graphs)
    wtrans_kernel<<<dim3(kGH / 32, kH / 32, 1), 256, 0, stream>>>(
        Ptr3{{gW1, nullptr, nullptr}}, gwt_h, gwt_l, kH, kGH);
    for (int gi = 0; gi < 2; gi++) {
        fill_kernel<<<CDIV((long)kN, 256), 256, 0, stream>>>((float*)icnt, 0.f, kN); // int 0
        fill_kernel<<<CDIV((long)kN, 256), 256, 0, stream>>>(wsum, 0.f, kN);
        fill_kernel<<<1, 256, 0, stream>>>(svec, 0.f, kGH);
        cnt_kernel<<<CDIV(kE, 256), 256, 0, stream>>>(gdst[gi], icnt, kE);
        scan1_kernel<<<nScanBlk, 256, 0, stream>>>(icnt, ioffs, ibsum, kN);
        scan2_kernel<<<1, 64, 0, stream>>>(ibsum, nScanBlk, ioffs, kN);
        scan3_kernel<<<nScanBlk, 256, 0, stream>>>(icnt, ioffs, ibsum, icur, deg, kN);
        csrfill_edgew_kernel<<<CDIV(kE, 256), 256, 0, stream>>>(
            gsrc[gi], gdst[gi], icur, icsr, deg, wsum, kE);
        // hw1 = x @ gW1: 64x128 tile, S=2 -> 1564 blocks; partials at hw1, agg slots
        gemm64_gcn<<<dim3(1, CDIV(kN, 64), 2), 256, 0, stream>>>(
            gx[gi], gwt_h, gwt_l, hw1, kN, kGH, kH, 2);
        splitk_epi_f32<<<(int)(MN_G / 4 / 256), 256, 0, stream>>>(hw1, hw1, MN_G, 2);
        spmm_gather_kernel<<<CDIV(kN, 2), 256, 0, stream>>>(ioffs, icsr, deg, hw1, gb1, agg, kN);
        wreduce_kernel<<<512, 256, 0, stream>>>(agg, wsum, deg, svec, kN);
        gcn_final_kernel<<<1, kGH, 0, stream>>>(svec, gW2, gb2, gout[gi]);
    }

    // ---------- BERT ----------
    maskbias_kernel<<<2, 256, 0, stream>>>(attn_mask, mb);
    embed_ln_kernel<<<kS, 256, 0, stream>>>(input_ids, type_ids, word_emb, pos_emb, type_emb,
                                            eln_s, eln_b, h, hh_h, hh_l);
    for (int l = 0; l < kL; l++) {
        const float* Wq_l = Wq + (size_t)l * kH * kH; const float* bq_l = bq + (size_t)l * kH;
        const float* Wk_l = Wk + (size_t)l * kH * kH; const float* bk_l = bk + (size_t)l * kH;
        const float* Wv_l = Wv + (size_t)l * kH * kH; const float* bv_l = bv + (size_t)l * kH;
        const float* Wo_l = Wo + (size_t)l * kH * kH; const float* bo_l = bo + (size_t)l * kH;
        const float* W1_l = W1 + (size_t)l * kH * kF; const float* b1_l = b1 + (size_t)l * kF;
        const float* W2_l = W2 + (size_t)l * kF * kH; const float* b2_l = b2 + (size_t)l * kH;
        const float* l1s_l = l1s + (size_t)l * kH; const float* l1b_l = l1b + (size_t)l * kH;
        const float* l2s_l = l2s + (size_t)l * kH; const float* l2b_l = l2b + (size_t)l * kH;

        // QKV: S=4, 3 weights -> 576 blocks
        wtrans_kernel<<<dim3(24, 24, 3), 256, 0, stream>>>(
            Ptr3{{Wq_l, Wk_l, Wv_l}}, wt_h, wt_l, kH, kH);
        gemm64_pre<<<dim3(kH / 128, kS / 64, 12), 256, 0, stream>>>(
            hh_h, hh_l, wt_h, wt_l, (long)kH * kH, part, kS, kH, kH, 4);
        splitk_epi_qkv_kernel<<<dim3((int)(MN_H / 4 / 256), 3), 256, 0, stream>>>(
            part, Ptr3{{bq_l, bk_l, bv_l}}, q_h, q_l, k_h, k_l, v_h, v_l, 4);
        vtrans_kernel<<<dim3(kS / 32, kNH * 2), 256, 0, stream>>>(v_h, v_l, vt_h, vt_l);
        // scores: 64q x 128k tiles -> 384 blocks
        attn_scores64_kernel<<<dim3(kS / 128, kS / 64, kNH), 256, 0, stream>>>(
            q_h, q_l, k_h, k_l, mb, scores);
        softmax_split_kernel<<<kNH * kS, 256, 0, stream>>>(scores, p_h, p_l);
        // ctx: K-split 8 -> 384 blocks
        attn_ctx64_kernel<<<dim3(kS / 128, kNH * 8), 256, 0, stream>>>(p_h, p_l, vt_h, vt_l, part);
        splitk_epi_sh_kernel<<<(int)(MN_H / 4 / 256), 256, 0, stream>>>(
            part, nullptr, ctx_h, ctx_l, MN_H, kH, 8, 0);
        // Wo: S=12 -> 576 blocks; fused LN
        wtrans_kernel<<<dim3(24, 24, 1), 256, 0, stream>>>(
            Ptr3{{Wo_l, nullptr, nullptr}}, wt_h, wt_l, kH, kH);
        gemm64_pre<<<dim3(kH / 128, kS / 64, 12), 256, 0, stream>>>(
            ctx_h, ctx_l, wt_h, wt_l, 0, part, kS, kH, kH, 12);
        splitk_epi_ln2_kernel<<<kS, 256, 0, stream>>>(part, bo_l, h, l1s_l, l1b_l, h1, h1_h, h1_l, 12);
        // FFN1: S=4 -> 768 blocks, gelu
        wtrans_kernel<<<dim3(96, 24, 1), 256, 0, stream>>>(
            Ptr3{{W1_l, nullptr, nullptr}}, wt_h, wt_l, kH, kF);
        gemm64_pre<<<dim3(kF / 128, kS / 64, 4), 256, 0, stream>>>(
            h1_h, h1_l, wt_h, wt_l, 0, part, kS, kF, kH, 4);
        splitk_epi_sh_kernel<<<(int)(MN_F / 4 / 256), 256, 0, stream>>>(
            part, b1_l, ffn1_h, ffn1_l, MN_F, kF, 4, 1);
        // FFN2: S=12 -> 576 blocks; fused LN
        wtrans_kernel<<<dim3(24, 96, 1), 256, 0, stream>>>(
            Ptr3{{W2_l, nullptr, nullptr}}, wt_h, wt_l, kF, kH);
        gemm64_pre<<<dim3(kH / 128, kS / 64, 12), 256, 0, stream>>>(
            ffn1_h, ffn1_l, wt_h, wt_l, 0, part, kS, kH, kF, 12);
        splitk_epi_ln2_kernel<<<kS, 256, 0, stream>>>(part, b2_l, h1, l2s_l, l2b_l, h, hh_h, hh_l, 12);
    }

    // ---------- combine + classifier ----------
    combine_kernel<<<3, 256, 0, stream>>>(h, gp, ghv, cW, cb, feat);
    cls_head_kernel<<<1, 256, 0, stream>>>(feat, clsW, clsB, out);
}

// Round 7
// 2625.540 us; speedup vs baseline: 1.6540x; 1.0974x over previous
//
#include <hip/hip_runtime.h>
#include <math.h>

// Problem constants
constexpr int kS = 512, kH = 768, kNH = 12, kDH = 64, kF = 3072, kL = 12;
constexpr int kN = 50000, kE = 800000, kGH = 128;

#define CDIV(a,b) (((a)+(b)-1)/(b))

struct Ptr3 { const float* p[3]; };

typedef __attribute__((ext_vector_type(8))) short bf16x8;
typedef __attribute__((ext_vector_type(4))) float f32x4;

__device__ __forceinline__ unsigned short bf16_rne(float f) {
    unsigned int u = __float_as_uint(f);
    u += 0x7fffu + ((u >> 16) & 1u);
    return (unsigned short)(u >> 16);
}
__device__ __forceinline__ float bf16_f32(unsigned short h) {
    return __uint_as_float(((unsigned int)h) << 16);
}
__device__ __forceinline__ void split2(float f, short& hi, short& lo) {
    unsigned short h = bf16_rne(f);
    hi = (short)h;
    lo = (short)bf16_rne(f - bf16_f32(h));
}

constexpr int LDR = 72;  // LDS row: 32 hi | 32 lo | 8 pad shorts (144 B)

// ---------------- generic fill ----------------
__global__ void fill_kernel(float* p, float v, long n) {
    long i = blockIdx.x * (long)blockDim.x + threadIdx.x;
    if (i < n) p[i] = v;
}

// ---------------- embeddings + LN (+ hi/lo emit) ----------------
__global__ void embed_ln_kernel(const int* ids, const int* tt,
                                const float* we, const float* pe, const float* te,
                                const float* g, const float* b, float* out,
                                short* oh, short* ol) {
    int s = blockIdx.x;
    int tid = threadIdx.x;
    __shared__ float red[256];
    int id = ids[s], t = tt[s];
    float vals[3]; float sum = 0.f;
    #pragma unroll
    for (int r = 0; r < 3; r++) {
        int j = tid + r * 256;
        float x = we[(long)id * kH + j] + pe[(long)s * kH + j] + te[(long)t * kH + j];
        vals[r] = x; sum += x;
    }
    red[tid] = sum; __syncthreads();
    for (int off = 128; off > 0; off >>= 1) { if (tid < off) red[tid] += red[tid + off]; __syncthreads(); }
    float mean = red[0] / kH; __syncthreads();
    float vs = 0.f;
    #pragma unroll
    for (int r = 0; r < 3; r++) { float d = vals[r] - mean; vs += d * d; }
    red[tid] = vs; __syncthreads();
    for (int off = 128; off > 0; off >>= 1) { if (tid < off) red[tid] += red[tid + off]; __syncthreads(); }
    float rstd = rsqrtf(red[0] / kH + 1e-12f);
    #pragma unroll
    for (int r = 0; r < 3; r++) {
        int j = tid + r * 256;
        float o = (vals[r] - mean) * rstd * g[j] + b[j];
        out[(long)s * kH + j] = o;
        short hi, lo; split2(o, hi, lo);
        oh[(long)s * kH + j] = hi; ol[(long)s * kH + j] = lo;
    }
}

// ---------------- weight transpose + split: W[K][N] -> Th/Tl [N][K] ----------------
__global__ void wtrans_kernel(Ptr3 Wp, short* __restrict__ Th, short* __restrict__ Tl,
                              int K, int N) {
    const float* Wm = Wp.p[blockIdx.z];
    long moff = (long)blockIdx.z * K * N;
    __shared__ short th[32][33], tl[32][33];
    int n0 = blockIdx.x * 32, k0 = blockIdx.y * 32;
    int c = threadIdx.x & 31, r = threadIdx.x >> 5;
    #pragma unroll
    for (int p = 0; p < 4; p++) {
        int rr = p * 8 + r;
        float f = Wm[(long)(k0 + rr) * N + n0 + c];
        short hi, lo; split2(f, hi, lo);
        th[rr][c] = hi; tl[rr][c] = lo;
    }
    __syncthreads();
    #pragma unroll
    for (int p = 0; p < 4; p++) {
        int rr = p * 8 + r;
        Th[moff + (long)(n0 + rr) * K + k0 + c] = th[c][rr];
        Tl[moff + (long)(n0 + rr) * K + k0 + c] = tl[c][rr];
    }
}

// ---------------- V transpose: v[s][kH] (head slices) -> vt[h][d][s] ----------------
__global__ void vtrans_kernel(const short* __restrict__ vh, const short* __restrict__ vl,
                              short* __restrict__ vth, short* __restrict__ vtl) {
    __shared__ short th[32][33], tl[32][33];
    int s0 = blockIdx.x * 32;
    int h = blockIdx.y >> 1, d0 = (blockIdx.y & 1) * 32;
    int c = threadIdx.x & 31, r = threadIdx.x >> 5;
    #pragma unroll
    for (int p = 0; p < 4; p++) {
        int rr = p * 8 + r;
        th[rr][c] = vh[(long)(s0 + rr) * kH + h * kDH + d0 + c];
        tl[rr][c] = vl[(long)(s0 + rr) * kH + h * kDH + d0 + c];
    }
    __syncthreads();
    #pragma unroll
    for (int p = 0; p < 4; p++) {
        int rr = p * 8 + r;
        vth[((long)h * kDH + d0 + rr) * kS + s0 + c] = th[c][rr];
        vtl[((long)h * kDH + d0 + rr) * kS + s0 + c] = tl[c][rr];
    }
}

// ======== 64x128-tile pre-split MFMA GEMM, register-prefetch double-buffered ========
// C[M,N] = A[M,K] @ B[K,N], B pre-transposed [N][K]. 4 waves 2x2, BK=32. Split-K partials.
__global__ __launch_bounds__(256, 4) void gemm64_pre(
    const short* __restrict__ Ah, const short* __restrict__ Al,
    const short* __restrict__ Bth, const short* __restrict__ Btl, long wstride,
    float* __restrict__ part, int M, int Nn, int K, int S)
{
    __shared__ short As[64 * LDR], Bs[128 * LDR];  // 27648 B
    int w = blockIdx.z / S, s = blockIdx.z % S;
    const short* Bh_ = Bth + (long)w * wstride;
    const short* Bl_ = Btl + (long)w * wstride;
    int Kc = K / S, kbeg = s * Kc;
    int m0 = blockIdx.y * 64, n0 = blockIdx.x * 128;
    int tid = threadIdx.x;
    int ar = tid >> 2, aq = (tid & 3) * 8;
    const short* Agh = Ah + (long)(m0 + ar) * K + kbeg + aq;
    const short* Agl = Al + (long)(m0 + ar) * K + kbeg + aq;
    int aofs = ar * LDR + aq;
    int br = tid >> 1, bq = (tid & 1) * 16;
    const short* Bgh = Bh_ + (long)(n0 + br) * K + kbeg + bq;
    const short* Bgl = Bl_ + (long)(n0 + br) * K + kbeg + bq;
    int bofs = br * LDR + bq;
    int wid = tid >> 6, lane = tid & 63;
    int wm = (wid >> 1) * 32, wn = (wid & 1) * 64;
    int fr = lane & 15, ko = (lane >> 4) * 8;
    f32x4 acc[2][4];
    #pragma unroll
    for (int i = 0; i < 2; i++)
        #pragma unroll
        for (int j = 0; j < 4; j++) acc[i][j] = (f32x4){0.f, 0.f, 0.f, 0.f};
    int nst = Kc / 32;
    // prologue: prefetch step 0
    bf16x8 pa0 = *(const bf16x8*)(Agh);
    bf16x8 pa1 = *(const bf16x8*)(Agl);
    bf16x8 pb0 = *(const bf16x8*)(Bgh);
    bf16x8 pb1 = *(const bf16x8*)(Bgh + 8);
    bf16x8 pb2 = *(const bf16x8*)(Bgl);
    bf16x8 pb3 = *(const bf16x8*)(Bgl + 8);
    for (int st = 0; st < nst; ++st) {
        *(bf16x8*)&As[aofs]      = pa0;
        *(bf16x8*)&As[aofs + 32] = pa1;
        *(bf16x8*)&Bs[bofs]      = pb0;
        *(bf16x8*)&Bs[bofs + 8]  = pb1;
        *(bf16x8*)&Bs[bofs + 32] = pb2;
        *(bf16x8*)&Bs[bofs + 40] = pb3;
        if (st + 1 < nst) {   // issue next-step loads; in flight across compute
            int go = (st + 1) * 32;
            pa0 = *(const bf16x8*)(Agh + go);
            pa1 = *(const bf16x8*)(Agl + go);
            pb0 = *(const bf16x8*)(Bgh + go);
            pb1 = *(const bf16x8*)(Bgh + go + 8);
            pb2 = *(const bf16x8*)(Bgl + go);
            pb3 = *(const bf16x8*)(Bgl + go + 8);
        }
        __syncthreads();
        bf16x8 bh[4], bl[4];
        #pragma unroll
        for (int j = 0; j < 4; j++) {
            int c = (wn + j * 16 + fr) * LDR + ko;
            bh[j] = *(const bf16x8*)&Bs[c];
            bl[j] = *(const bf16x8*)&Bs[c + 32];
        }
        #pragma unroll
        for (int i = 0; i < 2; i++) {
            int r = (wm + i * 16 + fr) * LDR + ko;
            bf16x8 ah = *(const bf16x8*)&As[r];
            bf16x8 al = *(const bf16x8*)&As[r + 32];
            #pragma unroll
            for (int j = 0; j < 4; j++) {
                acc[i][j] = __builtin_amdgcn_mfma_f32_16x16x32_bf16(ah, bh[j], acc[i][j], 0, 0, 0);
                acc[i][j] = __builtin_amdgcn_mfma_f32_16x16x32_bf16(ah, bl[j], acc[i][j], 0, 0, 0);
                acc[i][j] = __builtin_amdgcn_mfma_f32_16x16x32_bf16(al, bh[j], acc[i][j], 0, 0, 0);
            }
        }
        __syncthreads();
    }
    long MN = (long)M * Nn;
    float* Pp = part + (long)(w * S + s) * MN;
    int cr = (lane >> 4) * 4;
    #pragma unroll
    for (int i = 0; i < 2; i++) {
        #pragma unroll
        for (int r = 0; r < 4; r++) {
            int gm = m0 + wm + i * 16 + cr + r;
            float* rowp = &Pp[(long)gm * Nn + n0 + wn + fr];
            #pragma unroll
            for (int j = 0; j < 4; j++) rowp[j * 16] = acc[i][j][r];
        }
    }
}

// ======== GCN GEMM: A fp32 inline-split (prefetched), B pre-split; 64x128 tile; M guard ========
__global__ __launch_bounds__(256, 4) void gemm64_gcn(
    const float* __restrict__ A,
    const short* __restrict__ Bth, const short* __restrict__ Btl,
    float* __restrict__ part, int M, int Nn, int K, int S)
{
    __shared__ short As[64 * LDR], Bs[128 * LDR];
    int s = blockIdx.z;
    int Kc = K / S, kbeg = s * Kc;
    int m0 = blockIdx.y * 64, n0 = blockIdx.x * 128;
    int tid = threadIdx.x;
    int ar = tid >> 2, aqf = (tid & 3) * 8;
    int gmA = m0 + ar; if (gmA > M - 1) gmA = M - 1;
    const float* Agf = A + (long)gmA * K + kbeg + aqf;
    int aofs = ar * LDR + aqf;
    int br = tid >> 1, bq = (tid & 1) * 16;
    const short* Bgh = Bth + (long)(n0 + br) * K + kbeg + bq;
    const short* Bgl = Btl + (long)(n0 + br) * K + kbeg + bq;
    int bofs = br * LDR + bq;
    int wid = tid >> 6, lane = tid & 63;
    int wm = (wid >> 1) * 32, wn = (wid & 1) * 64;
    int fr = lane & 15, ko = (lane >> 4) * 8;
    f32x4 acc[2][4];
    #pragma unroll
    for (int i = 0; i < 2; i++)
        #pragma unroll
        for (int j = 0; j < 4; j++) acc[i][j] = (f32x4){0.f, 0.f, 0.f, 0.f};
    int nst = Kc / 32;
    float4 pf0 = *(const float4*)(Agf);
    float4 pf1 = *(const float4*)(Agf + 4);
    bf16x8 pb0 = *(const bf16x8*)(Bgh);
    bf16x8 pb1 = *(const bf16x8*)(Bgh + 8);
    bf16x8 pb2 = *(const bf16x8*)(Bgl);
    bf16x8 pb3 = *(const bf16x8*)(Bgl + 8);
    for (int st = 0; st < nst; ++st) {
        short h0, l0, h1, l1, h2, l2, h3, l3, h4, l4, h5, l5, h6, l6, h7, l7;
        split2(pf0.x, h0, l0); split2(pf0.y, h1, l1); split2(pf0.z, h2, l2); split2(pf0.w, h3, l3);
        split2(pf1.x, h4, l4); split2(pf1.y, h5, l5); split2(pf1.z, h6, l6); split2(pf1.w, h7, l7);
        *(short4*)&As[aofs]      = make_short4(h0, h1, h2, h3);
        *(short4*)&As[aofs + 4]  = make_short4(h4, h5, h6, h7);
        *(short4*)&As[aofs + 32] = make_short4(l0, l1, l2, l3);
        *(short4*)&As[aofs + 36] = make_short4(l4, l5, l6, l7);
        *(bf16x8*)&Bs[bofs]      = pb0;
        *(bf16x8*)&Bs[bofs + 8]  = pb1;
        *(bf16x8*)&Bs[bofs + 32] = pb2;
        *(bf16x8*)&Bs[bofs + 40] = pb3;
        if (st + 1 < nst) {
            int go = (st + 1) * 32;
            pf0 = *(const float4*)(Agf + go);
            pf1 = *(const float4*)(Agf + go + 4);
            pb0 = *(const bf16x8*)(Bgh + go);
            pb1 = *(const bf16x8*)(Bgh + go + 8);
            pb2 = *(const bf16x8*)(Bgl + go);
            pb3 = *(const bf16x8*)(Bgl + go + 8);
        }
        __syncthreads();
        bf16x8 bh[4], bl[4];
        #pragma unroll
        for (int j = 0; j < 4; j++) {
            int c = (wn + j * 16 + fr) * LDR + ko;
            bh[j] = *(const bf16x8*)&Bs[c];
            bl[j] = *(const bf16x8*)&Bs[c + 32];
        }
        #pragma unroll
        for (int i = 0; i < 2; i++) {
            int r = (wm + i * 16 + fr) * LDR + ko;
            bf16x8 ah = *(const bf16x8*)&As[r];
            bf16x8 al = *(const bf16x8*)&As[r + 32];
            #pragma unroll
            for (int j = 0; j < 4; j++) {
                acc[i][j] = __builtin_amdgcn_mfma_f32_16x16x32_bf16(ah, bh[j], acc[i][j], 0, 0, 0);
                acc[i][j] = __builtin_amdgcn_mfma_f32_16x16x32_bf16(ah, bl[j], acc[i][j], 0, 0, 0);
                acc[i][j] = __builtin_amdgcn_mfma_f32_16x16x32_bf16(al, bh[j], acc[i][j], 0, 0, 0);
            }
        }
        __syncthreads();
    }
    long MN = (long)M * Nn;
    float* Pp = part + (long)s * MN;
    int cr = (lane >> 4) * 4;
    #pragma unroll
    for (int i = 0; i < 2; i++) {
        #pragma unroll
        for (int r = 0; r < 4; r++) {
            int gm = m0 + wm + i * 16 + cr + r;
            if (gm >= M) continue;
            float* rowp = &Pp[(long)gm * Nn + n0 + wn + fr];
            #pragma unroll
            for (int j = 0; j < 4; j++) rowp[j * 16] = acc[i][j][r];
        }
    }
}

// ---------------- f32 split-K epilogue (in-place safe) ----------------
__global__ void splitk_epi_f32(const float* part, float* out, long MN, int S) {
    long i = ((long)blockIdx.x * blockDim.x + threadIdx.x) * 4;
    if (i >= MN) return;
    float4 a = *(const float4*)(part + i);
    for (int s2 = 1; s2 < S; ++s2) {
        float4 b = *(const float4*)(part + (long)s2 * MN + i);
        a.x += b.x; a.y += b.y; a.z += b.z; a.w += b.w;
    }
    *(float4*)(out + i) = a;
}

// ---------------- QKV epilogue: sum partials + bias -> hi/lo shorts ----------------
__global__ void splitk_epi_qkv_kernel(const float* __restrict__ part, Ptr3 bias,
                                      short* __restrict__ qh, short* __restrict__ ql,
                                      short* __restrict__ kh, short* __restrict__ kl,
                                      short* __restrict__ vh, short* __restrict__ vl,
                                      int S) {
    const long MN = (long)kS * kH;
    int w = blockIdx.y;
    long i = ((long)blockIdx.x * blockDim.x + threadIdx.x) * 4;
    if (i >= MN) return;
    const float* P = part + (long)w * S * MN + i;
    float4 a = *(const float4*)P;
    for (int s2 = 1; s2 < S; ++s2) {
        float4 b2 = *(const float4*)(P + (long)s2 * MN);
        a.x += b2.x; a.y += b2.y; a.z += b2.z; a.w += b2.w;
    }
    const float* bw = bias.p[w];
    int n = (int)(i % kH);
    a.x += bw[n]; a.y += bw[n + 1]; a.z += bw[n + 2]; a.w += bw[n + 3];
    short* oh = (w == 0) ? qh : (w == 1) ? kh : vh;
    short* ol = (w == 0) ? ql : (w == 1) ? kl : vl;
    short h0, l0, h1, l1, h2, l2, h3, l3;
    split2(a.x, h0, l0); split2(a.y, h1, l1); split2(a.z, h2, l2); split2(a.w, h3, l3);
    *(short4*)&oh[i] = make_short4(h0, h1, h2, h3);
    *(short4*)&ol[i] = make_short4(l0, l1, l2, l3);
}

// ---------------- generic epilogue: sum partials (+bias, +act) -> hi/lo shorts ----------------
__global__ void splitk_epi_sh_kernel(const float* __restrict__ part, const float* __restrict__ bias,
                                     short* __restrict__ oh, short* __restrict__ ol,
                                     long MN, int Nn, int S, int act) {
    long i = ((long)blockIdx.x * blockDim.x + threadIdx.x) * 4;
    if (i >= MN) return;
    const float* P = part + i;
    float4 a = *(const float4*)P;
    for (int s2 = 1; s2 < S; ++s2) {
        float4 b2 = *(const float4*)(P + (long)s2 * MN);
        a.x += b2.x; a.y += b2.y; a.z += b2.z; a.w += b2.w;
    }
    if (bias) {
        int n = (int)(i % Nn);
        a.x += bias[n]; a.y += bias[n + 1]; a.z += bias[n + 2]; a.w += bias[n + 3];
    }
    if (act == 1) {
        a.x = 0.5f * a.x * (1.f + erff(a.x * 0.70710678118654752f));
        a.y = 0.5f * a.y * (1.f + erff(a.y * 0.70710678118654752f));
        a.z = 0.5f * a.z * (1.f + erff(a.z * 0.70710678118654752f));
        a.w = 0.5f * a.w * (1.f + erff(a.w * 0.70710678118654752f));
    }
    short h0, l0, h1, l1, h2, l2, h3, l3;
    split2(a.x, h0, l0); split2(a.y, h1, l1); split2(a.z, h2, l2); split2(a.w, h3, l3);
    *(short4*)&oh[i] = make_short4(h0, h1, h2, h3);
    *(short4*)&ol[i] = make_short4(l0, l1, l2, l3);
}

// ---------------- fused split-K + bias + residual + LN -> fp32 + hi/lo ----------------
__global__ void splitk_epi_ln2_kernel(const float* __restrict__ part, const float* __restrict__ bias,
                                      const float* __restrict__ res, const float* __restrict__ g,
                                      const float* __restrict__ b, float* __restrict__ out,
                                      short* __restrict__ oh, short* __restrict__ ol, int S) {
    int row = blockIdx.x; int tid = threadIdx.x;
    __shared__ float red[256];
    const long MN = (long)kS * kH;
    float vals[3]; float sum = 0.f;
    #pragma unroll
    for (int r = 0; r < 3; r++) {
        int j = tid + r * 256;
        const float* P = part + (long)row * kH + j;
        float x = res[(long)row * kH + j] + bias[j];
        for (int s2 = 0; s2 < S; ++s2) x += P[(long)s2 * MN];
        vals[r] = x; sum += x;
    }
    red[tid] = sum; __syncthreads();
    for (int off = 128; off > 0; off >>= 1) { if (tid < off) red[tid] += red[tid + off]; __syncthreads(); }
    float mean = red[0] / kH; __syncthreads();
    float vs = 0.f;
    #pragma unroll
    for (int r = 0; r < 3; r++) { float d = vals[r] - mean; vs += d * d; }
    red[tid] = vs; __syncthreads();
    for (int off = 128; off > 0; off >>= 1) { if (tid < off) red[tid] += red[tid + off]; __syncthreads(); }
    float rstd = rsqrtf(red[0] / kH + 1e-12f);
    #pragma unroll
    for (int r = 0; r < 3; r++) {
        int j = tid + r * 256;
        float o = (vals[r] - mean) * rstd * g[j] + b[j];
        out[(long)row * kH + j] = o;
        short hi, lo; split2(o, hi, lo);
        oh[(long)row * kH + j] = hi; ol[(long)row * kH + j] = lo;
    }
}

// ---------------- attention scores: 64(q) x 128(k) tile, dbuf ----------------
__global__ __launch_bounds__(256, 4) void attn_scores64_kernel(
    const short* __restrict__ qh, const short* __restrict__ ql,
    const short* __restrict__ kh, const short* __restrict__ kl,
    const float* __restrict__ mb, float* __restrict__ scores)
{
    __shared__ short As[64 * LDR], Bs[128 * LDR];
    int h = blockIdx.z;
    int k0 = blockIdx.x * 128, q0 = blockIdx.y * 64;
    int tid = threadIdx.x;
    int ar = tid >> 2, aq = (tid & 3) * 8;
    const short* Agh = qh + (long)(q0 + ar) * kH + h * kDH + aq;
    const short* Agl = ql + (long)(q0 + ar) * kH + h * kDH + aq;
    int aofs = ar * LDR + aq;
    int br = tid >> 1, bq = (tid & 1) * 16;
    const short* Bgh = kh + (long)(k0 + br) * kH + h * kDH + bq;
    const short* Bgl = kl + (long)(k0 + br) * kH + h * kDH + bq;
    int bofs = br * LDR + bq;
    int wid = tid >> 6, lane = tid & 63;
    int wm = (wid >> 1) * 32, wn = (wid & 1) * 64;
    int fr = lane & 15, ko = (lane >> 4) * 8;
    f32x4 acc[2][4];
    #pragma unroll
    for (int i = 0; i < 2; i++)
        #pragma unroll
        for (int j = 0; j < 4; j++) acc[i][j] = (f32x4){0.f, 0.f, 0.f, 0.f};
    bf16x8 pa0 = *(const bf16x8*)(Agh);
    bf16x8 pa1 = *(const bf16x8*)(Agl);
    bf16x8 pb0 = *(const bf16x8*)(Bgh);
    bf16x8 pb1 = *(const bf16x8*)(Bgh + 8);
    bf16x8 pb2 = *(const bf16x8*)(Bgl);
    bf16x8 pb3 = *(const bf16x8*)(Bgl + 8);
    #pragma unroll
    for (int st = 0; st < 2; ++st) {
        *(bf16x8*)&As[aofs]      = pa0;
        *(bf16x8*)&As[aofs + 32] = pa1;
        *(bf16x8*)&Bs[bofs]      = pb0;
        *(bf16x8*)&Bs[bofs + 8]  = pb1;
        *(bf16x8*)&Bs[bofs + 32] = pb2;
        *(bf16x8*)&Bs[bofs + 40] = pb3;
        if (st == 0) {
            pa0 = *(const bf16x8*)(Agh + 32);
            pa1 = *(const bf16x8*)(Agl + 32);
            pb0 = *(const bf16x8*)(Bgh + 32);
            pb1 = *(const bf16x8*)(Bgh + 40);
            pb2 = *(const bf16x8*)(Bgl + 32);
            pb3 = *(const bf16x8*)(Bgl + 40);
        }
        __syncthreads();
        bf16x8 bh[4], bl[4];
        #pragma unroll
        for (int j = 0; j < 4; j++) {
            int c = (wn + j * 16 + fr) * LDR + ko;
            bh[j] = *(const bf16x8*)&Bs[c];
            bl[j] = *(const bf16x8*)&Bs[c + 32];
        }
        #pragma unroll
        for (int i = 0; i < 2; i++) {
            int r = (wm + i * 16 + fr) * LDR + ko;
            bf16x8 ah = *(const bf16x8*)&As[r];
            bf16x8 al = *(const bf16x8*)&As[r + 32];
            #pragma unroll
            for (int j = 0; j < 4; j++) {
                acc[i][j] = __builtin_amdgcn_mfma_f32_16x16x32_bf16(ah, bh[j], acc[i][j], 0, 0, 0);
                acc[i][j] = __builtin_amdgcn_mfma_f32_16x16x32_bf16(ah, bl[j], acc[i][j], 0, 0, 0);
                acc[i][j] = __builtin_amdgcn_mfma_f32_16x16x32_bf16(al, bh[j], acc[i][j], 0, 0, 0);
            }
        }
        __syncthreads();
    }
    int cr = (lane >> 4) * 4;
    #pragma unroll
    for (int i = 0; i < 2; i++) {
        #pragma unroll
        for (int r = 0; r < 4; r++) {
            int qq = q0 + wm + i * 16 + cr + r;
            float* rowp = &scores[((long)h * kS + qq) * kS + k0 + wn + fr];
            #pragma unroll
            for (int j = 0; j < 4; j++)
                rowp[j * 16] = acc[i][j][r] * 0.125f + mb[k0 + wn + j * 16 + fr];
        }
    }
}

// ---------------- softmax over rows of 512 -> P hi/lo ----------------
__global__ void softmax_split_kernel(const float* __restrict__ scores,
                                     short* __restrict__ ph, short* __restrict__ pl) {
    long row = blockIdx.x;
    const float* p = scores + row * kS;
    int tid = threadIdx.x;
    __shared__ float red[256];
    float x0 = p[tid], x1 = p[tid + 256];
    red[tid] = fmaxf(x0, x1); __syncthreads();
    for (int off = 128; off > 0; off >>= 1) { if (tid < off) red[tid] = fmaxf(red[tid], red[tid + off]); __syncthreads(); }
    float mx = red[0]; __syncthreads();
    float e0 = expf(x0 - mx), e1 = expf(x1 - mx);
    red[tid] = e0 + e1; __syncthreads();
    for (int off = 128; off > 0; off >>= 1) { if (tid < off) red[tid] += red[tid + off]; __syncthreads(); }
    float inv = 1.f / red[0];
    float r0 = e0 * inv, r1 = e1 * inv;
    short h0, l0, h1, l1;
    split2(r0, h0, l0); split2(r1, h1, l1);
    ph[row * kS + tid] = h0; pl[row * kS + tid] = l0;
    ph[row * kS + tid + 256] = h1; pl[row * kS + tid + 256] = l1;
}

// ---------------- ctx partial = P @ V (pre-split, V transposed), 8-way K-split, dbuf ----------------
__global__ __launch_bounds__(256, 4) void attn_ctx64_kernel(
    const short* __restrict__ ph, const short* __restrict__ pl,
    const short* __restrict__ vth, const short* __restrict__ vtl,
    float* __restrict__ part)
{
    __shared__ short As[128 * LDR], Bs[64 * LDR];
    int q0 = blockIdx.x * 128;
    int h = blockIdx.y >> 3, s = blockIdx.y & 7;
    int kbeg = s * 64;
    int tid = threadIdx.x;
    int ar = tid >> 1, aq = (tid & 1) * 16;
    const short* Agh = ph + ((long)h * kS + q0 + ar) * kS + kbeg + aq;
    const short* Agl = pl + ((long)h * kS + q0 + ar) * kS + kbeg + aq;
    int aofs = ar * LDR + aq;
    int brr = tid >> 2, bq = (tid & 3) * 8;
    const short* Bgh = vth + ((long)h * kDH + brr) * kS + kbeg + bq;
    const short* Bgl = vtl + ((long)h * kDH + brr) * kS + kbeg + bq;
    int bofs = brr * LDR + bq;
    int wid = tid >> 6, lane = tid & 63;
    int wm = wid * 32;
    int fr = lane & 15, ko = (lane >> 4) * 8;
    f32x4 acc[2][4];
    #pragma unroll
    for (int i = 0; i < 2; i++)
        #pragma unroll
        for (int j = 0; j < 4; j++) acc[i][j] = (f32x4){0.f, 0.f, 0.f, 0.f};
    bf16x8 pa0 = *(const bf16x8*)(Agh);
    bf16x8 pa1 = *(const bf16x8*)(Agh + 8);
    bf16x8 pa2 = *(const bf16x8*)(Agl);
    bf16x8 pa3 = *(const bf16x8*)(Agl + 8);
    bf16x8 pb0 = *(const bf16x8*)(Bgh);
    bf16x8 pb1 = *(const bf16x8*)(Bgl);
    #pragma unroll
    for (int st = 0; st < 2; ++st) {
        *(bf16x8*)&As[aofs]      = pa0;
        *(bf16x8*)&As[aofs + 8]  = pa1;
        *(bf16x8*)&As[aofs + 32] = pa2;
        *(bf16x8*)&As[aofs + 40] = pa3;
        *(bf16x8*)&Bs[bofs]      = pb0;
        *(bf16x8*)&Bs[bofs + 32] = pb1;
        if (st == 0) {
            pa0 = *(const bf16x8*)(Agh + 32);
            pa1 = *(const bf16x8*)(Agh + 40);
            pa2 = *(const bf16x8*)(Agl + 32);
            pa3 = *(const bf16x8*)(Agl + 40);
            pb0 = *(const bf16x8*)(Bgh + 32);
            pb1 = *(const bf16x8*)(Bgl + 32);
        }
        __syncthreads();
        bf16x8 bh[4], bl[4];
        #pragma unroll
        for (int j = 0; j < 4; j++) {
            int c = (j * 16 + fr) * LDR + ko;
            bh[j] = *(const bf16x8*)&Bs[c];
            bl[j] = *(const bf16x8*)&Bs[c + 32];
        }
        #pragma unroll
        for (int i = 0; i < 2; i++) {
            int r = (wm + i * 16 + fr) * LDR + ko;
            bf16x8 ah = *(const bf16x8*)&As[r];
            bf16x8 al = *(const bf16x8*)&As[r + 32];
            #pragma unroll
            for (int j = 0; j < 4; j++) {
                acc[i][j] = __builtin_amdgcn_mfma_f32_16x16x32_bf16(ah, bh[j], acc[i][j], 0, 0, 0);
                acc[i][j] = __builtin_amdgcn_mfma_f32_16x16x32_bf16(ah, bl[j], acc[i][j], 0, 0, 0);
                acc[i][j] = __builtin_amdgcn_mfma_f32_16x16x32_bf16(al, bh[j], acc[i][j], 0, 0, 0);
            }
        }
        __syncthreads();
    }
    long Pbase = (long)s * ((long)kS * kH);
    int cr = (lane >> 4) * 4;
    #pragma unroll
    for (int i = 0; i < 2; i++) {
        #pragma unroll
        for (int r = 0; r < 4; r++) {
            int gq = q0 + wm + i * 16 + cr + r;
            float* rowp = &part[Pbase + (long)gq * kH + h * kDH + fr];
            #pragma unroll
            for (int j = 0; j < 4; j++) rowp[j * 16] = acc[i][j][r];
        }
    }
}

// ---------------- GCN sparse kernels ----------------
__global__ void maskbias_kernel(const int* mask, float* mb) {
    int i = blockIdx.x * blockDim.x + threadIdx.x;
    if (i < kS) mb[i] = (1.f - (float)mask[i]) * -1e4f;
}

__global__ void cnt_kernel(const int* __restrict__ dst, int* __restrict__ cnt, int E) {
    int e = blockIdx.x * blockDim.x + threadIdx.x;
    if (e < E) atomicAdd(&cnt[dst[e]], 1);
}

__global__ void scan1_kernel(const int* __restrict__ cnt, int* __restrict__ offs,
                             int* __restrict__ bsum, int n) {
    __shared__ int sh[256];
    int i = blockIdx.x * 256 + threadIdx.x;
    int v = (i < n) ? cnt[i] : 0;
    sh[threadIdx.x] = v; __syncthreads();
    for (int off = 1; off < 256; off <<= 1) {
        int t = (threadIdx.x >= off) ? sh[threadIdx.x - off] : 0;
        __syncthreads();
        sh[threadIdx.x] += t;
        __syncthreads();
    }
    if (i < n) offs[i] = sh[threadIdx.x] - v;
    if (threadIdx.x == 255) bsum[blockIdx.x] = sh[255];
}

__global__ void scan2_kernel(int* bsum, int nb, int* offs, int n) {
    if (threadIdx.x == 0) {
        int run = 0;
        for (int b = 0; b < nb; b++) { int t = bsum[b]; bsum[b] = run; run += t; }
        offs[n] = run;
    }
}

__global__ void scan3_kernel(const int* __restrict__ cnt, int* __restrict__ offs,
                             const int* __restrict__ bsum, int* __restrict__ cur,
                             float* __restrict__ dinv, int n) {
    int i = blockIdx.x * 256 + threadIdx.x;
    if (i >= n) return;
    int o = offs[i] + bsum[blockIdx.x];
    offs[i] = o; cur[i] = o;
    dinv[i] = rsqrtf((float)(cnt[i] + 1));
}

__global__ void csrfill_edgew_kernel(const int* __restrict__ src, const int* __restrict__ dst,
                                     int* __restrict__ cur, int* __restrict__ csr,
                                     const float* __restrict__ dinv, float* __restrict__ wsum,
                                     int E) {
    int e = blockIdx.x * blockDim.x + threadIdx.x;
    if (e < E) {
        int s2 = src[e], d = dst[e];
        int slot = atomicAdd(&cur[d], 1);
        csr[slot] = s2;
        atomicAdd(&wsum[s2], dinv[s2] * dinv[d]);
    }
}

__global__ __launch_bounds__(256) void spmm_gather_kernel(const int* __restrict__ offs,
                                                          const int* __restrict__ csr,
                                                          const float* __restrict__ dinv,
                                                          const float* __restrict__ hw,
                                                          const float* __restrict__ b1,
                                                          float* __restrict__ hout, int n) {
    int d = blockIdx.x * 2 + (threadIdx.x >> 7);
    int j = threadIdx.x & 127;
    if (d >= n) return;
    int beg = offs[d], end = offs[d + 1];
    float a0 = 0.f, a1 = 0.f, a2 = 0.f, a3 = 0.f;
    int p = beg;
    for (; p + 4 <= end; p += 4) {
        int s0 = csr[p], s1 = csr[p + 1], s2 = csr[p + 2], s3 = csr[p + 3];
        a0 += dinv[s0] * hw[(long)s0 * kGH + j];
        a1 += dinv[s1] * hw[(long)s1 * kGH + j];
        a2 += dinv[s2] * hw[(long)s2 * kGH + j];
        a3 += dinv[s3] * hw[(long)s3 * kGH + j];
    }
    for (; p < end; ++p) {
        int s4 = csr[p];
        a0 += dinv[s4] * hw[(long)s4 * kGH + j];
    }
    float acc = (a0 + a1) + (a2 + a3);
    float dd = dinv[d];
    float v = acc * dd + dd * dd * hw[(long)d * kGH + j] + b1[j];
    hout[(long)d * kGH + j] = fmaxf(v, 0.f);
}

__global__ void wreduce_kernel(const float* __restrict__ h, const float* __restrict__ w,
                               const float* __restrict__ dinv, float* __restrict__ s, int n) {
    int tid = threadIdx.x; int j = tid & 127; int half = tid >> 7;
    float acc = 0.f;
    for (int u = blockIdx.x * 2 + half; u < n; u += gridDim.x * 2) {
        float di = dinv[u];
        acc += (w[u] + di * di) * h[(long)u * kGH + j];
    }
    __shared__ float red[256];
    red[tid] = acc; __syncthreads();
    if (tid < 128) atomicAdd(&s[j], red[tid] + red[tid + 128]);
}

__global__ void gcn_final_kernel(const float* s, const float* W2, const float* b2, float* g) {
    int j2 = threadIdx.x;
    float acc = 0.f;
    for (int j = 0; j < kGH; j++) acc += s[j] * W2[(long)j * kGH + j2];
    g[j2] = acc * (1.f / (float)kN) + b2[j2];
}

// ---------------- combine head (parallel): partial over 32-row chunks + atomic ----------------
__global__ void combine_part_kernel(const float* __restrict__ cls, const float* __restrict__ gp,
                                    const float* __restrict__ gh, const float* __restrict__ Wc,
                                    float* __restrict__ feat) {
    int i0 = blockIdx.x * 32;   // 56 blocks x 32 rows = 1792
    int tid = threadIdx.x;      // 256 threads, 3 cols each
    float a0 = 0.f, a1 = 0.f, a2 = 0.f;
    for (int r = 0; r < 32; r++) {
        int i = i0 + r;
        float x = (i < 768) ? cls[i] : (i < 896) ? gp[i - 768]
                : (i < 1664) ? cls[i - 896] : gh[i - 1664];
        const float* row = Wc + (long)i * kH;
        a0 += x * row[tid]; a1 += x * row[tid + 256]; a2 += x * row[tid + 512];
    }
    atomicAdd(&feat[tid], a0);
    atomicAdd(&feat[tid + 256], a1);
    atomicAdd(&feat[tid + 512], a2);
}

__global__ void combine_fin_kernel(float* feat, const float* bc) {
    int o = blockIdx.x * 256 + threadIdx.x;
    if (o < kH) feat[o] = fmaxf(feat[o] + bc[o], 0.f);
}

__global__ void cls_head_kernel(const float* feat, const float* W, const float* b, float* out) {
    int tid = threadIdx.x;
    float a0 = 0.f, a1 = 0.f, a2 = 0.f;
    for (int o = tid; o < kH; o += 256) {
        float f = feat[o];
        a0 += f * W[o * 3 + 0]; a1 += f * W[o * 3 + 1]; a2 += f * W[o * 3 + 2];
    }
    __shared__ float r0[256], r1[256], r2[256];
    r0[tid] = a0; r1[tid] = a1; r2[tid] = a2; __syncthreads();
    for (int off = 128; off > 0; off >>= 1) {
        if (tid < off) { r0[tid] += r0[tid + off]; r1[tid] += r1[tid + off]; r2[tid] += r2[tid + off]; }
        __syncthreads();
    }
    if (tid == 0) { out[0] = r0[0] + b[0]; out[1] = r1[0] + b[1]; out[2] = r2[0] + b[2]; }
}

// ---------------- launch ----------------
extern "C" void kernel_launch(void* const* d_in, const int* in_sizes, int n_in,
                              void* d_out, int out_size, void* d_ws, size_t ws_size,
                              hipStream_t stream) {
    const int*   input_ids = (const int*)d_in[0];
    const int*   attn_mask = (const int*)d_in[1];
    const int*   type_ids  = (const int*)d_in[2];
    const int*   p_edges   = (const int*)d_in[3];
    const int*   h_edges   = (const int*)d_in[4];
    const float* p_nodes   = (const float*)d_in[5];
    const float* h_nodes   = (const float*)d_in[6];
    const float* word_emb  = (const float*)d_in[7];
    const float* pos_emb   = (const float*)d_in[8];
    const float* type_emb  = (const float*)d_in[9];
    const float* eln_s     = (const float*)d_in[10];
    const float* eln_b     = (const float*)d_in[11];
    const float* Wq = (const float*)d_in[12]; const float* bq = (const float*)d_in[13];
    const float* Wk = (const float*)d_in[14]; const float* bk = (const float*)d_in[15];
    const float* Wv = (const float*)d_in[16]; const float* bv = (const float*)d_in[17];
    const float* Wo = (const float*)d_in[18]; const float* bo = (const float*)d_in[19];
    const float* l1s = (const float*)d_in[20]; const float* l1b = (const float*)d_in[21];
    const float* W1 = (const float*)d_in[22]; const float* b1 = (const float*)d_in[23];
    const float* W2 = (const float*)d_in[24]; const float* b2 = (const float*)d_in[25];
    const float* l2s = (const float*)d_in[26]; const float* l2b = (const float*)d_in[27];
    const float* gW1 = (const float*)d_in[28]; const float* gb1 = (const float*)d_in[29];
    const float* gW2 = (const float*)d_in[30]; const float* gb2 = (const float*)d_in[31];
    const float* cW  = (const float*)d_in[32]; const float* cb  = (const float*)d_in[33];
    const float* clsW = (const float*)d_in[34]; const float* clsB = (const float*)d_in[35];
    float* out = (float*)d_out;

    // ---------------- workspace layout ----------------
    float* W = (float*)d_ws;
    size_t off = 0;
    auto alloc = [&](size_t n) { float* p = W + off; off += n; return p; };
    float* h    = alloc((size_t)kS * kH);
    float* h1   = alloc((size_t)kS * kH);
    float* deg  = alloc(kN);
    float* wsum = alloc(kN);
    float* svec = alloc(kGH);
    float* gp   = alloc(kGH);
    float* ghv  = alloc(kGH);
    float* mb   = alloc(kS);
    float* feat = alloc(kH);
    float* big  = W + off;

    // BERT-phase big layout (float slots)
    float* part  = big;
    float* scores = part;
    short* p_h   = (short*)(big + 4718592);
    short* p_l   = p_h + (size_t)3145728;
    short* ffn1_h = (short*)(big + 7864320);
    short* ffn1_l = ffn1_h + (size_t)1572864;
    short* wt_h  = (short*)(big + 9437184);
    short* wt_l  = wt_h + (size_t)2359296;
    short* sm    = (short*)(big + 11796480);
    const size_t SMN = (size_t)kS * kH;
    short* q_h = sm;            short* q_l = q_h + SMN;
    short* k_h = q_l + SMN;     short* k_l = k_h + SMN;
    short* v_h = k_l + SMN;     short* v_l = v_h + SMN;
    short* vt_h = v_l + SMN;    short* vt_l = vt_h + SMN;
    short* ctx_h = vt_l + SMN;  short* ctx_l = ctx_h + SMN;
    short* h1_h = ctx_l + SMN;  short* h1_l = h1_h + SMN;
    short* hh_h = h1_l + SMN;   short* hh_l = hh_h + SMN;

    // GCN-phase overlay on big
    float* hw1 = big;
    float* agg = big + (size_t)kN * kGH;
    int* icnt  = (int*)(big + 2 * (size_t)kN * kGH);
    int* ioffs = icnt + 50048;
    int* icur  = ioffs + 50048;
    int* ibsum = icur + 50048;
    int* icsr  = ibsum + 256;
    short* gwt_h = (short*)(icsr + kE);
    short* gwt_l = gwt_h + (size_t)kH * kGH;

    const long MN_H = (long)kS * kH;   // 393216
    const long MN_F = (long)kS * kF;   // 1572864
    const long MN_G = (long)kN * kGH;  // 6400000
    const int nScanBlk = CDIV(kN, 256);

    // ---------- GCN on both graphs ----------
    const int* gsrc[2] = { p_edges, h_edges };
    const int* gdst[2] = { p_edges + kE, h_edges + kE };
    const float* gx[2] = { p_nodes, h_nodes };
    float* gout[2] = { gp, ghv };
    wtrans_kernel<<<dim3(kGH / 32, kH / 32, 1), 256, 0, stream>>>(
        Ptr3{{gW1, nullptr, nullptr}}, gwt_h, gwt_l, kH, kGH);
    for (int gi = 0; gi < 2; gi++) {
        fill_kernel<<<CDIV((long)kN, 256), 256, 0, stream>>>((float*)icnt, 0.f, kN); // int 0
        fill_kernel<<<CDIV((long)kN, 256), 256, 0, stream>>>(wsum, 0.f, kN);
        fill_kernel<<<1, 256, 0, stream>>>(svec, 0.f, kGH);
        cnt_kernel<<<CDIV(kE, 256), 256, 0, stream>>>(gdst[gi], icnt, kE);
        scan1_kernel<<<nScanBlk, 256, 0, stream>>>(icnt, ioffs, ibsum, kN);
        scan2_kernel<<<1, 64, 0, stream>>>(ibsum, nScanBlk, ioffs, kN);
        scan3_kernel<<<nScanBlk, 256, 0, stream>>>(icnt, ioffs, ibsum, icur, deg, kN);
        csrfill_edgew_kernel<<<CDIV(kE, 256), 256, 0, stream>>>(
            gsrc[gi], gdst[gi], icur, icsr, deg, wsum, kE);
        gemm64_gcn<<<dim3(1, CDIV(kN, 64), 2), 256, 0, stream>>>(
            gx[gi], gwt_h, gwt_l, hw1, kN, kGH, kH, 2);
        splitk_epi_f32<<<(int)(MN_G / 4 / 256), 256, 0, stream>>>(hw1, hw1, MN_G, 2);
        spmm_gather_kernel<<<CDIV(kN, 2), 256, 0, stream>>>(ioffs, icsr, deg, hw1, gb1, agg, kN);
        wreduce_kernel<<<512, 256, 0, stream>>>(agg, wsum, deg, svec, kN);
        gcn_final_kernel<<<1, kGH, 0, stream>>>(svec, gW2, gb2, gout[gi]);
    }

    // ---------- BERT ----------
    maskbias_kernel<<<2, 256, 0, stream>>>(attn_mask, mb);
    embed_ln_kernel<<<kS, 256, 0, stream>>>(input_ids, type_ids, word_emb, pos_emb, type_emb,
                                            eln_s, eln_b, h, hh_h, hh_l);
    for (int l = 0; l < kL; l++) {
        const float* Wq_l = Wq + (size_t)l * kH * kH; const float* bq_l = bq + (size_t)l * kH;
        const float* Wk_l = Wk + (size_t)l * kH * kH; const float* bk_l = bk + (size_t)l * kH;
        const float* Wv_l = Wv + (size_t)l * kH * kH; const float* bv_l = bv + (size_t)l * kH;
        const float* Wo_l = Wo + (size_t)l * kH * kH; const float* bo_l = bo + (size_t)l * kH;
        const float* W1_l = W1 + (size_t)l * kH * kF; const float* b1_l = b1 + (size_t)l * kF;
        const float* W2_l = W2 + (size_t)l * kF * kH; const float* b2_l = b2 + (size_t)l * kH;
        const float* l1s_l = l1s + (size_t)l * kH; const float* l1b_l = l1b + (size_t)l * kH;
        const float* l2s_l = l2s + (size_t)l * kH; const float* l2b_l = l2b + (size_t)l * kH;

        // QKV: S=4, 3 weights -> 576 blocks
        wtrans_kernel<<<dim3(24, 24, 3), 256, 0, stream>>>(
            Ptr3{{Wq_l, Wk_l, Wv_l}}, wt_h, wt_l, kH, kH);
        gemm64_pre<<<dim3(kH / 128, kS / 64, 12), 256, 0, stream>>>(
            hh_h, hh_l, wt_h, wt_l, (long)kH * kH, part, kS, kH, kH, 4);
        splitk_epi_qkv_kernel<<<dim3((int)(MN_H / 4 / 256), 3), 256, 0, stream>>>(
            part, Ptr3{{bq_l, bk_l, bv_l}}, q_h, q_l, k_h, k_l, v_h, v_l, 4);
        vtrans_kernel<<<dim3(kS / 32, kNH * 2), 256, 0, stream>>>(v_h, v_l, vt_h, vt_l);
        // scores: 64q x 128k tiles -> 384 blocks
        attn_scores64_kernel<<<dim3(kS / 128, kS / 64, kNH), 256, 0, stream>>>(
            q_h, q_l, k_h, k_l, mb, scores);
        softmax_split_kernel<<<kNH * kS, 256, 0, stream>>>(scores, p_h, p_l);
        // ctx: K-split 8 -> 384 blocks
        attn_ctx64_kernel<<<dim3(kS / 128, kNH * 8), 256, 0, stream>>>(p_h, p_l, vt_h, vt_l, part);
        splitk_epi_sh_kernel<<<(int)(MN_H / 4 / 256), 256, 0, stream>>>(
            part, nullptr, ctx_h, ctx_l, MN_H, kH, 8, 0);
        // Wo: S=12 -> 576 blocks; fused LN
        wtrans_kernel<<<dim3(24, 24, 1), 256, 0, stream>>>(
            Ptr3{{Wo_l, nullptr, nullptr}}, wt_h, wt_l, kH, kH);
        gemm64_pre<<<dim3(kH / 128, kS / 64, 12), 256, 0, stream>>>(
            ctx_h, ctx_l, wt_h, wt_l, 0, part, kS, kH, kH, 12);
        splitk_epi_ln2_kernel<<<kS, 256, 0, stream>>>(part, bo_l, h, l1s_l, l1b_l, h1, h1_h, h1_l, 12);
        // FFN1: S=4 -> 768 blocks, gelu
        wtrans_kernel<<<dim3(96, 24, 1), 256, 0, stream>>>(
            Ptr3{{W1_l, nullptr, nullptr}}, wt_h, wt_l, kH, kF);
        gemm64_pre<<<dim3(kF / 128, kS / 64, 4), 256, 0, stream>>>(
            h1_h, h1_l, wt_h, wt_l, 0, part, kS, kF, kH, 4);
        splitk_epi_sh_kernel<<<(int)(MN_F / 4 / 256), 256, 0, stream>>>(
            part, b1_l, ffn1_h, ffn1_l, MN_F, kF, 4, 1);
        // FFN2: S=12 -> 576 blocks; fused LN
        wtrans_kernel<<<dim3(24, 96, 1), 256, 0, stream>>>(
            Ptr3{{W2_l, nullptr, nullptr}}, wt_h, wt_l, kF, kH);
        gemm64_pre<<<dim3(kH / 128, kS / 64, 12), 256, 0, stream>>>(
            ffn1_h, ffn1_l, wt_h, wt_l, 0, part, kS, kH, kF, 12);
        splitk_epi_ln2_kernel<<<kS, 256, 0, stream>>>(part, b2_l, h1, l2s_l, l2b_l, h, hh_h, hh_l, 12);
    }

    // ---------- combine + classifier ----------
    fill_kernel<<<3, 256, 0, stream>>>(feat, 0.f, kH);
    combine_part_kernel<<<56, 256, 0, stream>>>(h, gp, ghv, cW, feat);
    combine_fin_kernel<<<3, 256, 0, stream>>>(feat, cb);
    cls_head_kernel<<<1, 256, 0, stream>>>(feat, clsW, clsB, out);
}

// Round 8
// 2562.264 us; speedup vs baseline: 1.6948x; 1.0247x over previous
//
#include <hip/hip_runtime.h>
#include <math.h>

// Problem constants
constexpr int kS = 512, kH = 768, kNH = 12, kDH = 64, kF = 3072, kL = 12;
constexpr int kN = 50000, kE = 800000, kGH = 128;

#define CDIV(a,b) (((a)+(b)-1)/(b))

struct Ptr3 { const float* p[3]; };

typedef __attribute__((ext_vector_type(8))) short bf16x8;
typedef __attribute__((ext_vector_type(4))) float f32x4;

__device__ __forceinline__ unsigned short bf16_rne(float f) {
    unsigned int u = __float_as_uint(f);
    u += 0x7fffu + ((u >> 16) & 1u);
    return (unsigned short)(u >> 16);
}
__device__ __forceinline__ float bf16_f32(unsigned short h) {
    return __uint_as_float(((unsigned int)h) << 16);
}
__device__ __forceinline__ void split2(float f, short& hi, short& lo) {
    unsigned short h = bf16_rne(f);
    hi = (short)h;
    lo = (short)bf16_rne(f - bf16_f32(h));
}

constexpr int LDR = 72;  // LDS row: 32 hi | 32 lo | 8 pad shorts (144 B)

// ---------------- generic fill ----------------
__global__ void fill_kernel(float* p, float v, long n) {
    long i = blockIdx.x * (long)blockDim.x + threadIdx.x;
    if (i < n) p[i] = v;
}

// ---------------- GCN per-graph zero init (icnt, wsum, svec) ----------------
__global__ void gcn_zero_kernel(int* icnt, float* wsum, float* svec) {
    int i = blockIdx.x * 256 + threadIdx.x;
    if (i < kN) { icnt[i] = 0; wsum[i] = 0.f; }
    if (i < kGH) svec[i] = 0.f;
}

// ---------------- embeddings + LN (+ hi/lo emit) ----------------
__global__ void embed_ln_kernel(const int* ids, const int* tt,
                                const float* we, const float* pe, const float* te,
                                const float* g, const float* b, float* out,
                                short* oh, short* ol) {
    int s = blockIdx.x;
    int tid = threadIdx.x;
    __shared__ float red[256];
    int id = ids[s], t = tt[s];
    float vals[3]; float sum = 0.f;
    #pragma unroll
    for (int r = 0; r < 3; r++) {
        int j = tid + r * 256;
        float x = we[(long)id * kH + j] + pe[(long)s * kH + j] + te[(long)t * kH + j];
        vals[r] = x; sum += x;
    }
    red[tid] = sum; __syncthreads();
    for (int off = 128; off > 0; off >>= 1) { if (tid < off) red[tid] += red[tid + off]; __syncthreads(); }
    float mean = red[0] / kH; __syncthreads();
    float vs = 0.f;
    #pragma unroll
    for (int r = 0; r < 3; r++) { float d = vals[r] - mean; vs += d * d; }
    red[tid] = vs; __syncthreads();
    for (int off = 128; off > 0; off >>= 1) { if (tid < off) red[tid] += red[tid + off]; __syncthreads(); }
    float rstd = rsqrtf(red[0] / kH + 1e-12f);
    #pragma unroll
    for (int r = 0; r < 3; r++) {
        int j = tid + r * 256;
        float o = (vals[r] - mean) * rstd * g[j] + b[j];
        out[(long)s * kH + j] = o;
        short hi, lo; split2(o, hi, lo);
        oh[(long)s * kH + j] = hi; ol[(long)s * kH + j] = lo;
    }
}

// ---------------- batched weight transpose + split: W[z][K][N] -> Th/Tl at z*ostride, [N][K] ----------------
__global__ void wtrans_all_kernel(const float* __restrict__ W, short* __restrict__ Th,
                                  short* __restrict__ Tl, int K, int N, long ostride) {
    int z = blockIdx.z;
    const float* Wm = W + (long)z * K * N;
    long moff = (long)z * ostride;
    __shared__ short th[32][33], tl[32][33];
    int n0 = blockIdx.x * 32, k0 = blockIdx.y * 32;
    int c = threadIdx.x & 31, r = threadIdx.x >> 5;
    #pragma unroll
    for (int p = 0; p < 4; p++) {
        int rr = p * 8 + r;
        float f = Wm[(long)(k0 + rr) * N + n0 + c];
        short hi, lo; split2(f, hi, lo);
        th[rr][c] = hi; tl[rr][c] = lo;
    }
    __syncthreads();
    #pragma unroll
    for (int p = 0; p < 4; p++) {
        int rr = p * 8 + r;
        Th[moff + (long)(n0 + rr) * K + k0 + c] = th[c][rr];
        Tl[moff + (long)(n0 + rr) * K + k0 + c] = tl[c][rr];
    }
}

// ---------------- V transpose: v[s][kH] (head slices) -> vt[h][d][s] ----------------
__global__ void vtrans_kernel(const short* __restrict__ vh, const short* __restrict__ vl,
                              short* __restrict__ vth, short* __restrict__ vtl) {
    __shared__ short th[32][33], tl[32][33];
    int s0 = blockIdx.x * 32;
    int h = blockIdx.y >> 1, d0 = (blockIdx.y & 1) * 32;
    int c = threadIdx.x & 31, r = threadIdx.x >> 5;
    #pragma unroll
    for (int p = 0; p < 4; p++) {
        int rr = p * 8 + r;
        th[rr][c] = vh[(long)(s0 + rr) * kH + h * kDH + d0 + c];
        tl[rr][c] = vl[(long)(s0 + rr) * kH + h * kDH + d0 + c];
    }
    __syncthreads();
    #pragma unroll
    for (int p = 0; p < 4; p++) {
        int rr = p * 8 + r;
        vth[((long)h * kDH + d0 + rr) * kS + s0 + c] = th[c][rr];
        vtl[((long)h * kDH + d0 + rr) * kS + s0 + c] = tl[c][rr];
    }
}

// ======== 64x128-tile pre-split MFMA GEMM, register-prefetch double-buffered ========
__global__ __launch_bounds__(256, 4) void gemm64_pre(
    const short* __restrict__ Ah, const short* __restrict__ Al,
    const short* __restrict__ Bth, const short* __restrict__ Btl, long wstride,
    float* __restrict__ part, int M, int Nn, int K, int S)
{
    __shared__ short As[64 * LDR], Bs[128 * LDR];  // 27648 B
    int w = blockIdx.z / S, s = blockIdx.z % S;
    const short* Bh_ = Bth + (long)w * wstride;
    const short* Bl_ = Btl + (long)w * wstride;
    int Kc = K / S, kbeg = s * Kc;
    int m0 = blockIdx.y * 64, n0 = blockIdx.x * 128;
    int tid = threadIdx.x;
    int ar = tid >> 2, aq = (tid & 3) * 8;
    const short* Agh = Ah + (long)(m0 + ar) * K + kbeg + aq;
    const short* Agl = Al + (long)(m0 + ar) * K + kbeg + aq;
    int aofs = ar * LDR + aq;
    int br = tid >> 1, bq = (tid & 1) * 16;
    const short* Bgh = Bh_ + (long)(n0 + br) * K + kbeg + bq;
    const short* Bgl = Bl_ + (long)(n0 + br) * K + kbeg + bq;
    int bofs = br * LDR + bq;
    int wid = tid >> 6, lane = tid & 63;
    int wm = (wid >> 1) * 32, wn = (wid & 1) * 64;
    int fr = lane & 15, ko = (lane >> 4) * 8;
    f32x4 acc[2][4];
    #pragma unroll
    for (int i = 0; i < 2; i++)
        #pragma unroll
        for (int j = 0; j < 4; j++) acc[i][j] = (f32x4){0.f, 0.f, 0.f, 0.f};
    int nst = Kc / 32;
    bf16x8 pa0 = *(const bf16x8*)(Agh);
    bf16x8 pa1 = *(const bf16x8*)(Agl);
    bf16x8 pb0 = *(const bf16x8*)(Bgh);
    bf16x8 pb1 = *(const bf16x8*)(Bgh + 8);
    bf16x8 pb2 = *(const bf16x8*)(Bgl);
    bf16x8 pb3 = *(const bf16x8*)(Bgl + 8);
    for (int st = 0; st < nst; ++st) {
        *(bf16x8*)&As[aofs]      = pa0;
        *(bf16x8*)&As[aofs + 32] = pa1;
        *(bf16x8*)&Bs[bofs]      = pb0;
        *(bf16x8*)&Bs[bofs + 8]  = pb1;
        *(bf16x8*)&Bs[bofs + 32] = pb2;
        *(bf16x8*)&Bs[bofs + 40] = pb3;
        if (st + 1 < nst) {
            int go = (st + 1) * 32;
            pa0 = *(const bf16x8*)(Agh + go);
            pa1 = *(const bf16x8*)(Agl + go);
            pb0 = *(const bf16x8*)(Bgh + go);
            pb1 = *(const bf16x8*)(Bgh + go + 8);
            pb2 = *(const bf16x8*)(Bgl + go);
            pb3 = *(const bf16x8*)(Bgl + go + 8);
        }
        __syncthreads();
        bf16x8 bh[4], bl[4];
        #pragma unroll
        for (int j = 0; j < 4; j++) {
            int c = (wn + j * 16 + fr) * LDR + ko;
            bh[j] = *(const bf16x8*)&Bs[c];
            bl[j] = *(const bf16x8*)&Bs[c + 32];
        }
        #pragma unroll
        for (int i = 0; i < 2; i++) {
            int r = (wm + i * 16 + fr) * LDR + ko;
            bf16x8 ah = *(const bf16x8*)&As[r];
            bf16x8 al = *(const bf16x8*)&As[r + 32];
            #pragma unroll
            for (int j = 0; j < 4; j++) {
                acc[i][j] = __builtin_amdgcn_mfma_f32_16x16x32_bf16(ah, bh[j], acc[i][j], 0, 0, 0);
                acc[i][j] = __builtin_amdgcn_mfma_f32_16x16x32_bf16(ah, bl[j], acc[i][j], 0, 0, 0);
                acc[i][j] = __builtin_amdgcn_mfma_f32_16x16x32_bf16(al, bh[j], acc[i][j], 0, 0, 0);
            }
        }
        __syncthreads();
    }
    long MN = (long)M * Nn;
    float* Pp = part + (long)(w * S + s) * MN;
    int cr = (lane >> 4) * 4;
    #pragma unroll
    for (int i = 0; i < 2; i++) {
        #pragma unroll
        for (int r = 0; r < 4; r++) {
            int gm = m0 + wm + i * 16 + cr + r;
            float* rowp = &Pp[(long)gm * Nn + n0 + wn + fr];
            #pragma unroll
            for (int j = 0; j < 4; j++) rowp[j * 16] = acc[i][j][r];
        }
    }
}

// ======== GCN GEMM: A fp32 inline-split (prefetched), B pre-split; 64x128 tile; M guard ========
__global__ __launch_bounds__(256, 4) void gemm64_gcn(
    const float* __restrict__ A,
    const short* __restrict__ Bth, const short* __restrict__ Btl,
    float* __restrict__ part, int M, int Nn, int K, int S)
{
    __shared__ short As[64 * LDR], Bs[128 * LDR];
    int s = blockIdx.z;
    int Kc = K / S, kbeg = s * Kc;
    int m0 = blockIdx.y * 64, n0 = blockIdx.x * 128;
    int tid = threadIdx.x;
    int ar = tid >> 2, aqf = (tid & 3) * 8;
    int gmA = m0 + ar; if (gmA > M - 1) gmA = M - 1;
    const float* Agf = A + (long)gmA * K + kbeg + aqf;
    int aofs = ar * LDR + aqf;
    int br = tid >> 1, bq = (tid & 1) * 16;
    const short* Bgh = Bth + (long)(n0 + br) * K + kbeg + bq;
    const short* Bgl = Btl + (long)(n0 + br) * K + kbeg + bq;
    int bofs = br * LDR + bq;
    int wid = tid >> 6, lane = tid & 63;
    int wm = (wid >> 1) * 32, wn = (wid & 1) * 64;
    int fr = lane & 15, ko = (lane >> 4) * 8;
    f32x4 acc[2][4];
    #pragma unroll
    for (int i = 0; i < 2; i++)
        #pragma unroll
        for (int j = 0; j < 4; j++) acc[i][j] = (f32x4){0.f, 0.f, 0.f, 0.f};
    int nst = Kc / 32;
    float4 pf0 = *(const float4*)(Agf);
    float4 pf1 = *(const float4*)(Agf + 4);
    bf16x8 pb0 = *(const bf16x8*)(Bgh);
    bf16x8 pb1 = *(const bf16x8*)(Bgh + 8);
    bf16x8 pb2 = *(const bf16x8*)(Bgl);
    bf16x8 pb3 = *(const bf16x8*)(Bgl + 8);
    for (int st = 0; st < nst; ++st) {
        short h0, l0, h1, l1, h2, l2, h3, l3, h4, l4, h5, l5, h6, l6, h7, l7;
        split2(pf0.x, h0, l0); split2(pf0.y, h1, l1); split2(pf0.z, h2, l2); split2(pf0.w, h3, l3);
        split2(pf1.x, h4, l4); split2(pf1.y, h5, l5); split2(pf1.z, h6, l6); split2(pf1.w, h7, l7);
        *(short4*)&As[aofs]      = make_short4(h0, h1, h2, h3);
        *(short4*)&As[aofs + 4]  = make_short4(h4, h5, h6, h7);
        *(short4*)&As[aofs + 32] = make_short4(l0, l1, l2, l3);
        *(short4*)&As[aofs + 36] = make_short4(l4, l5, l6, l7);
        *(bf16x8*)&Bs[bofs]      = pb0;
        *(bf16x8*)&Bs[bofs + 8]  = pb1;
        *(bf16x8*)&Bs[bofs + 32] = pb2;
        *(bf16x8*)&Bs[bofs + 40] = pb3;
        if (st + 1 < nst) {
            int go = (st + 1) * 32;
            pf0 = *(const float4*)(Agf + go);
            pf1 = *(const float4*)(Agf + go + 4);
            pb0 = *(const bf16x8*)(Bgh + go);
            pb1 = *(const bf16x8*)(Bgh + go + 8);
            pb2 = *(const bf16x8*)(Bgl + go);
            pb3 = *(const bf16x8*)(Bgl + go + 8);
        }
        __syncthreads();
        bf16x8 bh[4], bl[4];
        #pragma unroll
        for (int j = 0; j < 4; j++) {
            int c = (wn + j * 16 + fr) * LDR + ko;
            bh[j] = *(const bf16x8*)&Bs[c];
            bl[j] = *(const bf16x8*)&Bs[c + 32];
        }
        #pragma unroll
        for (int i = 0; i < 2; i++) {
            int r = (wm + i * 16 + fr) * LDR + ko;
            bf16x8 ah = *(const bf16x8*)&As[r];
            bf16x8 al = *(const bf16x8*)&As[r + 32];
            #pragma unroll
            for (int j = 0; j < 4; j++) {
                acc[i][j] = __builtin_amdgcn_mfma_f32_16x16x32_bf16(ah, bh[j], acc[i][j], 0, 0, 0);
                acc[i][j] = __builtin_amdgcn_mfma_f32_16x16x32_bf16(ah, bl[j], acc[i][j], 0, 0, 0);
                acc[i][j] = __builtin_amdgcn_mfma_f32_16x16x32_bf16(al, bh[j], acc[i][j], 0, 0, 0);
            }
        }
        __syncthreads();
    }
    long MN = (long)M * Nn;
    float* Pp = part + (long)s * MN;
    int cr = (lane >> 4) * 4;
    #pragma unroll
    for (int i = 0; i < 2; i++) {
        #pragma unroll
        for (int r = 0; r < 4; r++) {
            int gm = m0 + wm + i * 16 + cr + r;
            if (gm >= M) continue;
            float* rowp = &Pp[(long)gm * Nn + n0 + wn + fr];
            #pragma unroll
            for (int j = 0; j < 4; j++) rowp[j * 16] = acc[i][j][r];
        }
    }
}

// ---------------- f32 split-K epilogue (in-place safe) ----------------
__global__ void splitk_epi_f32(const float* part, float* out, long MN, int S) {
    long i = ((long)blockIdx.x * blockDim.x + threadIdx.x) * 4;
    if (i >= MN) return;
    float4 a = *(const float4*)(part + i);
    for (int s2 = 1; s2 < S; ++s2) {
        float4 b = *(const float4*)(part + (long)s2 * MN + i);
        a.x += b.x; a.y += b.y; a.z += b.z; a.w += b.w;
    }
    *(float4*)(out + i) = a;
}

// ---------------- QKV epilogue: sum partials + bias -> hi/lo shorts ----------------
__global__ void splitk_epi_qkv_kernel(const float* __restrict__ part, Ptr3 bias,
                                      short* __restrict__ qh, short* __restrict__ ql,
                                      short* __restrict__ kh, short* __restrict__ kl,
                                      short* __restrict__ vh, short* __restrict__ vl,
                                      int S) {
    const long MN = (long)kS * kH;
    int w = blockIdx.y;
    long i = ((long)blockIdx.x * blockDim.x + threadIdx.x) * 4;
    if (i >= MN) return;
    const float* P = part + (long)w * S * MN + i;
    float4 a = *(const float4*)P;
    for (int s2 = 1; s2 < S; ++s2) {
        float4 b2 = *(const float4*)(P + (long)s2 * MN);
        a.x += b2.x; a.y += b2.y; a.z += b2.z; a.w += b2.w;
    }
    const float* bw = bias.p[w];
    int n = (int)(i % kH);
    a.x += bw[n]; a.y += bw[n + 1]; a.z += bw[n + 2]; a.w += bw[n + 3];
    short* oh = (w == 0) ? qh : (w == 1) ? kh : vh;
    short* ol = (w == 0) ? ql : (w == 1) ? kl : vl;
    short h0, l0, h1, l1, h2, l2, h3, l3;
    split2(a.x, h0, l0); split2(a.y, h1, l1); split2(a.z, h2, l2); split2(a.w, h3, l3);
    *(short4*)&oh[i] = make_short4(h0, h1, h2, h3);
    *(short4*)&ol[i] = make_short4(l0, l1, l2, l3);
}

// ---------------- generic epilogue: sum partials (+bias, +act) -> hi/lo shorts ----------------
__global__ void splitk_epi_sh_kernel(const float* __restrict__ part, const float* __restrict__ bias,
                                     short* __restrict__ oh, short* __restrict__ ol,
                                     long MN, int Nn, int S, int act) {
    long i = ((long)blockIdx.x * blockDim.x + threadIdx.x) * 4;
    if (i >= MN) return;
    const float* P = part + i;
    float4 a = *(const float4*)P;
    for (int s2 = 1; s2 < S; ++s2) {
        float4 b2 = *(const float4*)(P + (long)s2 * MN);
        a.x += b2.x; a.y += b2.y; a.z += b2.z; a.w += b2.w;
    }
    if (bias) {
        int n = (int)(i % Nn);
        a.x += bias[n]; a.y += bias[n + 1]; a.z += bias[n + 2]; a.w += bias[n + 3];
    }
    if (act == 1) {
        a.x = 0.5f * a.x * (1.f + erff(a.x * 0.70710678118654752f));
        a.y = 0.5f * a.y * (1.f + erff(a.y * 0.70710678118654752f));
        a.z = 0.5f * a.z * (1.f + erff(a.z * 0.70710678118654752f));
        a.w = 0.5f * a.w * (1.f + erff(a.w * 0.70710678118654752f));
    }
    short h0, l0, h1, l1, h2, l2, h3, l3;
    split2(a.x, h0, l0); split2(a.y, h1, l1); split2(a.z, h2, l2); split2(a.w, h3, l3);
    *(short4*)&oh[i] = make_short4(h0, h1, h2, h3);
    *(short4*)&ol[i] = make_short4(l0, l1, l2, l3);
}

// ---------------- fused split-K + bias + residual + LN -> fp32 + hi/lo ----------------
__global__ void splitk_epi_ln2_kernel(const float* __restrict__ part, const float* __restrict__ bias,
                                      const float* __restrict__ res, const float* __restrict__ g,
                                      const float* __restrict__ b, float* __restrict__ out,
                                      short* __restrict__ oh, short* __restrict__ ol, int S) {
    int row = blockIdx.x; int tid = threadIdx.x;
    __shared__ float red[256];
    const long MN = (long)kS * kH;
    float vals[3]; float sum = 0.f;
    #pragma unroll
    for (int r = 0; r < 3; r++) {
        int j = tid + r * 256;
        const float* P = part + (long)row * kH + j;
        float x = res[(long)row * kH + j] + bias[j];
        for (int s2 = 0; s2 < S; ++s2) x += P[(long)s2 * MN];
        vals[r] = x; sum += x;
    }
    red[tid] = sum; __syncthreads();
    for (int off = 128; off > 0; off >>= 1) { if (tid < off) red[tid] += red[tid + off]; __syncthreads(); }
    float mean = red[0] / kH; __syncthreads();
    float vs = 0.f;
    #pragma unroll
    for (int r = 0; r < 3; r++) { float d = vals[r] - mean; vs += d * d; }
    red[tid] = vs; __syncthreads();
    for (int off = 128; off > 0; off >>= 1) { if (tid < off) red[tid] += red[tid + off]; __syncthreads(); }
    float rstd = rsqrtf(red[0] / kH + 1e-12f);
    #pragma unroll
    for (int r = 0; r < 3; r++) {
        int j = tid + r * 256;
        float o = (vals[r] - mean) * rstd * g[j] + b[j];
        out[(long)row * kH + j] = o;
        short hi, lo; split2(o, hi, lo);
        oh[(long)row * kH + j] = hi; ol[(long)row * kH + j] = lo;
    }
}

// ---------------- attention scores: 64(q) x 128(k) tile, dbuf ----------------
__global__ __launch_bounds__(256, 4) void attn_scores64_kernel(
    const short* __restrict__ qh, const short* __restrict__ ql,
    const short* __restrict__ kh, const short* __restrict__ kl,
    const float* __restrict__ mb, float* __restrict__ scores)
{
    __shared__ short As[64 * LDR], Bs[128 * LDR];
    int h = blockIdx.z;
    int k0 = blockIdx.x * 128, q0 = blockIdx.y * 64;
    int tid = threadIdx.x;
    int ar = tid >> 2, aq = (tid & 3) * 8;
    const short* Agh = qh + (long)(q0 + ar) * kH + h * kDH + aq;
    const short* Agl = ql + (long)(q0 + ar) * kH + h * kDH + aq;
    int aofs = ar * LDR + aq;
    int br = tid >> 1, bq = (tid & 1) * 16;
    const short* Bgh = kh + (long)(k0 + br) * kH + h * kDH + bq;
    const short* Bgl = kl + (long)(k0 + br) * kH + h * kDH + bq;
    int bofs = br * LDR + bq;
    int wid = tid >> 6, lane = tid & 63;
    int wm = (wid >> 1) * 32, wn = (wid & 1) * 64;
    int fr = lane & 15, ko = (lane >> 4) * 8;
    f32x4 acc[2][4];
    #pragma unroll
    for (int i = 0; i < 2; i++)
        #pragma unroll
        for (int j = 0; j < 4; j++) acc[i][j] = (f32x4){0.f, 0.f, 0.f, 0.f};
    bf16x8 pa0 = *(const bf16x8*)(Agh);
    bf16x8 pa1 = *(const bf16x8*)(Agl);
    bf16x8 pb0 = *(const bf16x8*)(Bgh);
    bf16x8 pb1 = *(const bf16x8*)(Bgh + 8);
    bf16x8 pb2 = *(const bf16x8*)(Bgl);
    bf16x8 pb3 = *(const bf16x8*)(Bgl + 8);
    #pragma unroll
    for (int st = 0; st < 2; ++st) {
        *(bf16x8*)&As[aofs]      = pa0;
        *(bf16x8*)&As[aofs + 32] = pa1;
        *(bf16x8*)&Bs[bofs]      = pb0;
        *(bf16x8*)&Bs[bofs + 8]  = pb1;
        *(bf16x8*)&Bs[bofs + 32] = pb2;
        *(bf16x8*)&Bs[bofs + 40] = pb3;
        if (st == 0) {
            pa0 = *(const bf16x8*)(Agh + 32);
            pa1 = *(const bf16x8*)(Agl + 32);
            pb0 = *(const bf16x8*)(Bgh + 32);
            pb1 = *(const bf16x8*)(Bgh + 40);
            pb2 = *(const bf16x8*)(Bgl + 32);
            pb3 = *(const bf16x8*)(Bgl + 40);
        }
        __syncthreads();
        bf16x8 bh[4], bl[4];
        #pragma unroll
        for (int j = 0; j < 4; j++) {
            int c = (wn + j * 16 + fr) * LDR + ko;
            bh[j] = *(const bf16x8*)&Bs[c];
            bl[j] = *(const bf16x8*)&Bs[c + 32];
        }
        #pragma unroll
        for (int i = 0; i < 2; i++) {
            int r = (wm + i * 16 + fr) * LDR + ko;
            bf16x8 ah = *(const bf16x8*)&As[r];
            bf16x8 al = *(const bf16x8*)&As[r + 32];
            #pragma unroll
            for (int j = 0; j < 4; j++) {
                acc[i][j] = __builtin_amdgcn_mfma_f32_16x16x32_bf16(ah, bh[j], acc[i][j], 0, 0, 0);
                acc[i][j] = __builtin_amdgcn_mfma_f32_16x16x32_bf16(ah, bl[j], acc[i][j], 0, 0, 0);
                acc[i][j] = __builtin_amdgcn_mfma_f32_16x16x32_bf16(al, bh[j], acc[i][j], 0, 0, 0);
            }
        }
        __syncthreads();
    }
    int cr = (lane >> 4) * 4;
    #pragma unroll
    for (int i = 0; i < 2; i++) {
        #pragma unroll
        for (int r = 0; r < 4; r++) {
            int qq = q0 + wm + i * 16 + cr + r;
            float* rowp = &scores[((long)h * kS + qq) * kS + k0 + wn + fr];
            #pragma unroll
            for (int j = 0; j < 4; j++)
                rowp[j * 16] = acc[i][j][r] * 0.125f + mb[k0 + wn + j * 16 + fr];
        }
    }
}

// ---------------- softmax over rows of 512 -> P hi/lo ----------------
__global__ void softmax_split_kernel(const float* __restrict__ scores,
                                     short* __restrict__ ph, short* __restrict__ pl) {
    long row = blockIdx.x;
    const float* p = scores + row * kS;
    int tid = threadIdx.x;
    __shared__ float red[256];
    float x0 = p[tid], x1 = p[tid + 256];
    red[tid] = fmaxf(x0, x1); __syncthreads();
    for (int off = 128; off > 0; off >>= 1) { if (tid < off) red[tid] = fmaxf(red[tid], red[tid + off]); __syncthreads(); }
    float mx = red[0]; __syncthreads();
    float e0 = expf(x0 - mx), e1 = expf(x1 - mx);
    red[tid] = e0 + e1; __syncthreads();
    for (int off = 128; off > 0; off >>= 1) { if (tid < off) red[tid] += red[tid + off]; __syncthreads(); }
    float inv = 1.f / red[0];
    float r0 = e0 * inv, r1 = e1 * inv;
    short h0, l0, h1, l1;
    split2(r0, h0, l0); split2(r1, h1, l1);
    ph[row * kS + tid] = h0; pl[row * kS + tid] = l0;
    ph[row * kS + tid + 256] = h1; pl[row * kS + tid + 256] = l1;
}

// ---------------- ctx partial = P @ V (pre-split, V transposed), 8-way K-split, dbuf ----------------
__global__ __launch_bounds__(256, 4) void attn_ctx64_kernel(
    const short* __restrict__ ph, const short* __restrict__ pl,
    const short* __restrict__ vth, const short* __restrict__ vtl,
    float* __restrict__ part)
{
    __shared__ short As[128 * LDR], Bs[64 * LDR];
    int q0 = blockIdx.x * 128;
    int h = blockIdx.y >> 3, s = blockIdx.y & 7;
    int kbeg = s * 64;
    int tid = threadIdx.x;
    int ar = tid >> 1, aq = (tid & 1) * 16;
    const short* Agh = ph + ((long)h * kS + q0 + ar) * kS + kbeg + aq;
    const short* Agl = pl + ((long)h * kS + q0 + ar) * kS + kbeg + aq;
    int aofs = ar * LDR + aq;
    int brr = tid >> 2, bq = (tid & 3) * 8;
    const short* Bgh = vth + ((long)h * kDH + brr) * kS + kbeg + bq;
    const short* Bgl = vtl + ((long)h * kDH + brr) * kS + kbeg + bq;
    int bofs = brr * LDR + bq;
    int wid = tid >> 6, lane = tid & 63;
    int wm = wid * 32;
    int fr = lane & 15, ko = (lane >> 4) * 8;
    f32x4 acc[2][4];
    #pragma unroll
    for (int i = 0; i < 2; i++)
        #pragma unroll
        for (int j = 0; j < 4; j++) acc[i][j] = (f32x4){0.f, 0.f, 0.f, 0.f};
    bf16x8 pa0 = *(const bf16x8*)(Agh);
    bf16x8 pa1 = *(const bf16x8*)(Agh + 8);
    bf16x8 pa2 = *(const bf16x8*)(Agl);
    bf16x8 pa3 = *(const bf16x8*)(Agl + 8);
    bf16x8 pb0 = *(const bf16x8*)(Bgh);
    bf16x8 pb1 = *(const bf16x8*)(Bgl);
    #pragma unroll
    for (int st = 0; st < 2; ++st) {
        *(bf16x8*)&As[aofs]      = pa0;
        *(bf16x8*)&As[aofs + 8]  = pa1;
        *(bf16x8*)&As[aofs + 32] = pa2;
        *(bf16x8*)&As[aofs + 40] = pa3;
        *(bf16x8*)&Bs[bofs]      = pb0;
        *(bf16x8*)&Bs[bofs + 32] = pb1;
        if (st == 0) {
            pa0 = *(const bf16x8*)(Agh + 32);
            pa1 = *(const bf16x8*)(Agh + 40);
            pa2 = *(const bf16x8*)(Agl + 32);
            pa3 = *(const bf16x8*)(Agl + 40);
            pb0 = *(const bf16x8*)(Bgh + 32);
            pb1 = *(const bf16x8*)(Bgl + 32);
        }
        __syncthreads();
        bf16x8 bh[4], bl[4];
        #pragma unroll
        for (int j = 0; j < 4; j++) {
            int c = (j * 16 + fr) * LDR + ko;
            bh[j] = *(const bf16x8*)&Bs[c];
            bl[j] = *(const bf16x8*)&Bs[c + 32];
        }
        #pragma unroll
        for (int i = 0; i < 2; i++) {
            int r = (wm + i * 16 + fr) * LDR + ko;
            bf16x8 ah = *(const bf16x8*)&As[r];
            bf16x8 al = *(const bf16x8*)&As[r + 32];
            #pragma unroll
            for (int j = 0; j < 4; j++) {
                acc[i][j] = __builtin_amdgcn_mfma_f32_16x16x32_bf16(ah, bh[j], acc[i][j], 0, 0, 0);
                acc[i][j] = __builtin_amdgcn_mfma_f32_16x16x32_bf16(ah, bl[j], acc[i][j], 0, 0, 0);
                acc[i][j] = __builtin_amdgcn_mfma_f32_16x16x32_bf16(al, bh[j], acc[i][j], 0, 0, 0);
            }
        }
        __syncthreads();
    }
    long Pbase = (long)s * ((long)kS * kH);
    int cr = (lane >> 4) * 4;
    #pragma unroll
    for (int i = 0; i < 2; i++) {
        #pragma unroll
        for (int r = 0; r < 4; r++) {
            int gq = q0 + wm + i * 16 + cr + r;
            float* rowp = &part[Pbase + (long)gq * kH + h * kDH + fr];
            #pragma unroll
            for (int j = 0; j < 4; j++) rowp[j * 16] = acc[i][j][r];
        }
    }
}

// ---------------- GCN sparse kernels ----------------
__global__ void maskbias_kernel(const int* mask, float* mb) {
    int i = blockIdx.x * blockDim.x + threadIdx.x;
    if (i < kS) mb[i] = (1.f - (float)mask[i]) * -1e4f;
}

__global__ void cnt_kernel(const int* __restrict__ dst, int* __restrict__ cnt, int E) {
    int e = blockIdx.x * blockDim.x + threadIdx.x;
    if (e < E) atomicAdd(&cnt[dst[e]], 1);
}

__global__ void scan1_kernel(const int* __restrict__ cnt, int* __restrict__ offs,
                             int* __restrict__ bsum, int n) {
    __shared__ int sh[256];
    int i = blockIdx.x * 256 + threadIdx.x;
    int v = (i < n) ? cnt[i] : 0;
    sh[threadIdx.x] = v; __syncthreads();
    for (int off = 1; off < 256; off <<= 1) {
        int t = (threadIdx.x >= off) ? sh[threadIdx.x - off] : 0;
        __syncthreads();
        sh[threadIdx.x] += t;
        __syncthreads();
    }
    if (i < n) offs[i] = sh[threadIdx.x] - v;
    if (threadIdx.x == 255) bsum[blockIdx.x] = sh[255];
}

__global__ void scan2_kernel(int* bsum, int nb, int* offs, int n) {
    if (threadIdx.x == 0) {
        int run = 0;
        for (int b = 0; b < nb; b++) { int t = bsum[b]; bsum[b] = run; run += t; }
        offs[n] = run;
    }
}

__global__ void scan3_kernel(const int* __restrict__ cnt, int* __restrict__ offs,
                             const int* __restrict__ bsum, int* __restrict__ cur,
                             float* __restrict__ dinv, int n) {
    int i = blockIdx.x * 256 + threadIdx.x;
    if (i >= n) return;
    int o = offs[i] + bsum[blockIdx.x];
    offs[i] = o; cur[i] = o;
    dinv[i] = rsqrtf((float)(cnt[i] + 1));
}

__global__ void csrfill_edgew_kernel(const int* __restrict__ src, const int* __restrict__ dst,
                                     int* __restrict__ cur, int* __restrict__ csr,
                                     const float* __restrict__ dinv, float* __restrict__ wsum,
                                     int E) {
    int e = blockIdx.x * blockDim.x + threadIdx.x;
    if (e < E) {
        int s2 = src[e], d = dst[e];
        int slot = atomicAdd(&cur[d], 1);
        csr[slot] = s2;
        atomicAdd(&wsum[s2], dinv[s2] * dinv[d]);
    }
}

__global__ __launch_bounds__(256) void spmm_gather_kernel(const int* __restrict__ offs,
                                                          const int* __restrict__ csr,
                                                          const float* __restrict__ dinv,
                                                          const float* __restrict__ hw,
                                                          const float* __restrict__ b1,
                                                          float* __restrict__ hout, int n) {
    int d = blockIdx.x * 2 + (threadIdx.x >> 7);
    int j = threadIdx.x & 127;
    if (d >= n) return;
    int beg = offs[d], end = offs[d + 1];
    float a0 = 0.f, a1 = 0.f, a2 = 0.f, a3 = 0.f;
    int p = beg;
    for (; p + 4 <= end; p += 4) {
        int s0 = csr[p], s1 = csr[p + 1], s2 = csr[p + 2], s3 = csr[p + 3];
        a0 += dinv[s0] * hw[(long)s0 * kGH + j];
        a1 += dinv[s1] * hw[(long)s1 * kGH + j];
        a2 += dinv[s2] * hw[(long)s2 * kGH + j];
        a3 += dinv[s3] * hw[(long)s3 * kGH + j];
    }
    for (; p < end; ++p) {
        int s4 = csr[p];
        a0 += dinv[s4] * hw[(long)s4 * kGH + j];
    }
    float acc = (a0 + a1) + (a2 + a3);
    float dd = dinv[d];
    float v = acc * dd + dd * dd * hw[(long)d * kGH + j] + b1[j];
    hout[(long)d * kGH + j] = fmaxf(v, 0.f);
}

__global__ void wreduce_kernel(const float* __restrict__ h, const float* __restrict__ w,
                               const float* __restrict__ dinv, float* __restrict__ s, int n) {
    int tid = threadIdx.x; int j = tid & 127; int half = tid >> 7;
    float acc = 0.f;
    for (int u = blockIdx.x * 2 + half; u < n; u += gridDim.x * 2) {
        float di = dinv[u];
        acc += (w[u] + di * di) * h[(long)u * kGH + j];
    }
    __shared__ float red[256];
    red[tid] = acc; __syncthreads();
    if (tid < 128) atomicAdd(&s[j], red[tid] + red[tid + 128]);
}

__global__ void gcn_final_kernel(const float* s, const float* W2, const float* b2, float* g) {
    int j2 = threadIdx.x;
    float acc = 0.f;
    for (int j = 0; j < kGH; j++) acc += s[j] * W2[(long)j * kGH + j2];
    g[j2] = acc * (1.f / (float)kN) + b2[j2];
}

// ---------------- combine head (parallel): partial over 32-row chunks + atomic ----------------
__global__ void combine_part_kernel(const float* __restrict__ cls, const float* __restrict__ gp,
                                    const float* __restrict__ gh, const float* __restrict__ Wc,
                                    float* __restrict__ feat) {
    int i0 = blockIdx.x * 32;
    int tid = threadIdx.x;
    float a0 = 0.f, a1 = 0.f, a2 = 0.f;
    for (int r = 0; r < 32; r++) {
        int i = i0 + r;
        float x = (i < 768) ? cls[i] : (i < 896) ? gp[i - 768]
                : (i < 1664) ? cls[i - 896] : gh[i - 1664];
        const float* row = Wc + (long)i * kH;
        a0 += x * row[tid]; a1 += x * row[tid + 256]; a2 += x * row[tid + 512];
    }
    atomicAdd(&feat[tid], a0);
    atomicAdd(&feat[tid + 256], a1);
    atomicAdd(&feat[tid + 512], a2);
}

__global__ void combine_fin_kernel(float* feat, const float* bc) {
    int o = blockIdx.x * 256 + threadIdx.x;
    if (o < kH) feat[o] = fmaxf(feat[o] + bc[o], 0.f);
}

__global__ void cls_head_kernel(const float* feat, const float* W, const float* b, float* out) {
    int tid = threadIdx.x;
    float a0 = 0.f, a1 = 0.f, a2 = 0.f;
    for (int o = tid; o < kH; o += 256) {
        float f = feat[o];
        a0 += f * W[o * 3 + 0]; a1 += f * W[o * 3 + 1]; a2 += f * W[o * 3 + 2];
    }
    __shared__ float r0[256], r1[256], r2[256];
    r0[tid] = a0; r1[tid] = a1; r2[tid] = a2; __syncthreads();
    for (int off = 128; off > 0; off >>= 1) {
        if (tid < off) { r0[tid] += r0[tid + off]; r1[tid] += r1[tid + off]; r2[tid] += r2[tid + off]; }
        __syncthreads();
    }
    if (tid == 0) { out[0] = r0[0] + b[0]; out[1] = r1[0] + b[1]; out[2] = r2[0] + b[2]; }
}

// ---------------- launch ----------------
extern "C" void kernel_launch(void* const* d_in, const int* in_sizes, int n_in,
                              void* d_out, int out_size, void* d_ws, size_t ws_size,
                              hipStream_t stream) {
    const int*   input_ids = (const int*)d_in[0];
    const int*   attn_mask = (const int*)d_in[1];
    const int*   type_ids  = (const int*)d_in[2];
    const int*   p_edges   = (const int*)d_in[3];
    const int*   h_edges   = (const int*)d_in[4];
    const float* p_nodes   = (const float*)d_in[5];
    const float* h_nodes   = (const float*)d_in[6];
    const float* word_emb  = (const float*)d_in[7];
    const float* pos_emb   = (const float*)d_in[8];
    const float* type_emb  = (const float*)d_in[9];
    const float* eln_s     = (const float*)d_in[10];
    const float* eln_b     = (const float*)d_in[11];
    const float* Wq = (const float*)d_in[12]; const float* bq = (const float*)d_in[13];
    const float* Wk = (const float*)d_in[14]; const float* bk = (const float*)d_in[15];
    const float* Wv = (const float*)d_in[16]; const float* bv = (const float*)d_in[17];
    const float* Wo = (const float*)d_in[18]; const float* bo = (const float*)d_in[19];
    const float* l1s = (const float*)d_in[20]; const float* l1b = (const float*)d_in[21];
    const float* W1 = (const float*)d_in[22]; const float* b1 = (const float*)d_in[23];
    const float* W2 = (const float*)d_in[24]; const float* b2 = (const float*)d_in[25];
    const float* l2s = (const float*)d_in[26]; const float* l2b = (const float*)d_in[27];
    const float* gW1 = (const float*)d_in[28]; const float* gb1 = (const float*)d_in[29];
    const float* gW2 = (const float*)d_in[30]; const float* gb2 = (const float*)d_in[31];
    const float* cW  = (const float*)d_in[32]; const float* cb  = (const float*)d_in[33];
    const float* clsW = (const float*)d_in[34]; const float* clsB = (const float*)d_in[35];
    float* out = (float*)d_out;

    // ---------------- workspace layout ----------------
    float* W = (float*)d_ws;
    size_t off = 0;
    auto alloc = [&](size_t n) { float* p = W + off; off += n; return p; };
    float* h    = alloc((size_t)kS * kH);
    float* h1   = alloc((size_t)kS * kH);
    float* deg  = alloc(kN);
    float* wsum = alloc(kN);
    float* svec = alloc(kGH);
    float* gp   = alloc(kGH);
    float* ghv  = alloc(kGH);
    float* mb   = alloc(kS);
    float* feat = alloc(kH);
    float* big  = W + off;

    // BERT-phase big layout (float slots)
    float* part  = big;
    float* scores = part;
    short* p_h   = (short*)(big + 4718592);
    short* p_l   = p_h + (size_t)3145728;
    short* ffn1_h = (short*)(big + 7864320);
    short* ffn1_l = ffn1_h + (size_t)1572864;
    short* sm    = (short*)(big + 11796480);
    const size_t SMN = (size_t)kS * kH;
    short* q_h = sm;            short* q_l = q_h + SMN;
    short* k_h = q_l + SMN;     short* k_l = k_h + SMN;
    short* v_h = k_l + SMN;     short* v_l = v_h + SMN;
    short* vt_h = v_l + SMN;    short* vt_l = vt_h + SMN;
    short* ctx_h = vt_l + SMN;  short* ctx_l = ctx_h + SMN;
    short* h1_h = ctx_l + SMN;  short* h1_l = h1_h + SMN;
    short* hh_h = h1_l + SMN;   short* hh_l = hh_h + SMN;
    // (BERT span ends at big + ~14.55M floats)

    // GCN-phase overlay on big (ends ~13.85M floats)
    float* hw1 = big;
    float* agg = big + (size_t)kN * kGH;
    int* icnt  = (int*)(big + 2 * (size_t)kN * kGH);
    int* ioffs = icnt + 50048;
    int* icur  = ioffs + 50048;
    int* ibsum = icur + 50048;
    int* icsr  = ibsum + 256;
    short* gwt_h = (short*)(icsr + kE);
    short* gwt_l = gwt_h + (size_t)kH * kGH;

    // Persistent pre-converted weight cache (beyond both overlays): 340 MB
    const size_t QKV_SZ = (size_t)kH * kH;      // 589824
    const size_t FF_SZ  = (size_t)kH * kF;      // 2359296
    short* wc = (short*)(big + 15000000);
    short* qkv_h = wc;                          short* qkv_l = qkv_h + 12 * 3 * QKV_SZ;
    short* wo_h  = qkv_l + 12 * 3 * QKV_SZ;     short* wo_l  = wo_h + 12 * QKV_SZ;
    short* w1_h  = wo_l + 12 * QKV_SZ;          short* w1_l  = w1_h + 12 * FF_SZ;
    short* w2_h  = w1_l + 12 * FF_SZ;           short* w2_l  = w2_h + 12 * FF_SZ;

    const long MN_H = (long)kS * kH;   // 393216
    const long MN_F = (long)kS * kF;   // 1572864
    const long MN_G = (long)kN * kGH;  // 6400000
    const int nScanBlk = CDIV(kN, 256);

    // ---------- pre-convert ALL weights once (6 launches) ----------
    wtrans_all_kernel<<<dim3(24, 24, 12), 256, 0, stream>>>(Wq, qkv_h,              qkv_l,              kH, kH, (long)(3 * QKV_SZ));
    wtrans_all_kernel<<<dim3(24, 24, 12), 256, 0, stream>>>(Wk, qkv_h + QKV_SZ,     qkv_l + QKV_SZ,     kH, kH, (long)(3 * QKV_SZ));
    wtrans_all_kernel<<<dim3(24, 24, 12), 256, 0, stream>>>(Wv, qkv_h + 2 * QKV_SZ, qkv_l + 2 * QKV_SZ, kH, kH, (long)(3 * QKV_SZ));
    wtrans_all_kernel<<<dim3(24, 24, 12), 256, 0, stream>>>(Wo, wo_h, wo_l, kH, kH, (long)QKV_SZ);
    wtrans_all_kernel<<<dim3(96, 24, 12), 256, 0, stream>>>(W1, w1_h, w1_l, kH, kF, (long)FF_SZ);
    wtrans_all_kernel<<<dim3(24, 96, 12), 256, 0, stream>>>(W2, w2_h, w2_l, kF, kH, (long)FF_SZ);

    // ---------- GCN on both graphs ----------
    const int* gsrc[2] = { p_edges, h_edges };
    const int* gdst[2] = { p_edges + kE, h_edges + kE };
    const float* gx[2] = { p_nodes, h_nodes };
    float* gout[2] = { gp, ghv };
    wtrans_all_kernel<<<dim3(kGH / 32, kH / 32, 1), 256, 0, stream>>>(gW1, gwt_h, gwt_l, kH, kGH, 0);
    for (int gi = 0; gi < 2; gi++) {
        gcn_zero_kernel<<<nScanBlk, 256, 0, stream>>>(icnt, wsum, svec);
        cnt_kernel<<<CDIV(kE, 256), 256, 0, stream>>>(gdst[gi], icnt, kE);
        scan1_kernel<<<nScanBlk, 256, 0, stream>>>(icnt, ioffs, ibsum, kN);
        scan2_kernel<<<1, 64, 0, stream>>>(ibsum, nScanBlk, ioffs, kN);
        scan3_kernel<<<nScanBlk, 256, 0, stream>>>(icnt, ioffs, ibsum, icur, deg, kN);
        csrfill_edgew_kernel<<<CDIV(kE, 256), 256, 0, stream>>>(
            gsrc[gi], gdst[gi], icur, icsr, deg, wsum, kE);
        gemm64_gcn<<<dim3(1, CDIV(kN, 64), 2), 256, 0, stream>>>(
            gx[gi], gwt_h, gwt_l, hw1, kN, kGH, kH, 2);
        splitk_epi_f32<<<(int)(MN_G / 4 / 256), 256, 0, stream>>>(hw1, hw1, MN_G, 2);
        spmm_gather_kernel<<<CDIV(kN, 2), 256, 0, stream>>>(ioffs, icsr, deg, hw1, gb1, agg, kN);
        wreduce_kernel<<<512, 256, 0, stream>>>(agg, wsum, deg, svec, kN);
        gcn_final_kernel<<<1, kGH, 0, stream>>>(svec, gW2, gb2, gout[gi]);
    }

    // ---------- BERT ----------
    maskbias_kernel<<<2, 256, 0, stream>>>(attn_mask, mb);
    embed_ln_kernel<<<kS, 256, 0, stream>>>(input_ids, type_ids, word_emb, pos_emb, type_emb,
                                            eln_s, eln_b, h, hh_h, hh_l);
    for (int l = 0; l < kL; l++) {
        const float* bq_l = bq + (size_t)l * kH;
        const float* bk_l = bk + (size_t)l * kH;
        const float* bv_l = bv + (size_t)l * kH;
        const float* bo_l = bo + (size_t)l * kH;
        const float* b1_l = b1 + (size_t)l * kF;
        const float* b2_l = b2 + (size_t)l * kH;
        const float* l1s_l = l1s + (size_t)l * kH; const float* l1b_l = l1b + (size_t)l * kH;
        const float* l2s_l = l2s + (size_t)l * kH; const float* l2b_l = l2b + (size_t)l * kH;
        const short* qkvh_l = qkv_h + (size_t)l * 3 * QKV_SZ;
        const short* qkvl_l = qkv_l + (size_t)l * 3 * QKV_SZ;
        const short* woh_l = wo_h + (size_t)l * QKV_SZ;
        const short* wol_l = wo_l + (size_t)l * QKV_SZ;
        const short* w1h_l = w1_h + (size_t)l * FF_SZ;
        const short* w1l_l = w1_l + (size_t)l * FF_SZ;
        const short* w2h_l = w2_h + (size_t)l * FF_SZ;
        const short* w2l_l = w2_l + (size_t)l * FF_SZ;

        // QKV: S=4, 3 weights -> 576 blocks
        gemm64_pre<<<dim3(kH / 128, kS / 64, 12), 256, 0, stream>>>(
            hh_h, hh_l, qkvh_l, qkvl_l, (long)QKV_SZ, part, kS, kH, kH, 4);
        splitk_epi_qkv_kernel<<<dim3((int)(MN_H / 4 / 256), 3), 256, 0, stream>>>(
            part, Ptr3{{bq_l, bk_l, bv_l}}, q_h, q_l, k_h, k_l, v_h, v_l, 4);
        vtrans_kernel<<<dim3(kS / 32, kNH * 2), 256, 0, stream>>>(v_h, v_l, vt_h, vt_l);
        // scores: 64q x 128k tiles -> 384 blocks
        attn_scores64_kernel<<<dim3(kS / 128, kS / 64, kNH), 256, 0, stream>>>(
            q_h, q_l, k_h, k_l, mb, scores);
        softmax_split_kernel<<<kNH * kS, 256, 0, stream>>>(scores, p_h, p_l);
        // ctx: K-split 8 -> 384 blocks
        attn_ctx64_kernel<<<dim3(kS / 128, kNH * 8), 256, 0, stream>>>(p_h, p_l, vt_h, vt_l, part);
        splitk_epi_sh_kernel<<<(int)(MN_H / 4 / 256), 256, 0, stream>>>(
            part, nullptr, ctx_h, ctx_l, MN_H, kH, 8, 0);
        // Wo: S=12 -> 576 blocks; fused LN
        gemm64_pre<<<dim3(kH / 128, kS / 64, 12), 256, 0, stream>>>(
            ctx_h, ctx_l, woh_l, wol_l, 0, part, kS, kH, kH, 12);
        splitk_epi_ln2_kernel<<<kS, 256, 0, stream>>>(part, bo_l, h, l1s_l, l1b_l, h1, h1_h, h1_l, 12);
        // FFN1: S=4 -> 768 blocks, gelu
        gemm64_pre<<<dim3(kF / 128, kS / 64, 4), 256, 0, stream>>>(
            h1_h, h1_l, w1h_l, w1l_l, 0, part, kS, kF, kH, 4);
        splitk_epi_sh_kernel<<<(int)(MN_F / 4 / 256), 256, 0, stream>>>(
            part, b1_l, ffn1_h, ffn1_l, MN_F, kF, 4, 1);
        // FFN2: S=12 -> 576 blocks; fused LN
        gemm64_pre<<<dim3(kH / 128, kS / 64, 12), 256, 0, stream>>>(
            ffn1_h, ffn1_l, w2h_l, w2l_l, 0, part, kS, kH, kF, 12);
        splitk_epi_ln2_kernel<<<kS, 256, 0, stream>>>(part, b2_l, h1, l2s_l, l2b_l, h, hh_h, hh_l, 12);
    }

    // ---------- combine + classifier ----------
    fill_kernel<<<3, 256, 0, stream>>>(feat, 0.f, kH);
    combine_part_kernel<<<56, 256, 0, stream>>>(h, gp, ghv, cW, feat);
    combine_fin_kernel<<<3, 256, 0, stream>>>(feat, cb);
    cls_head_kernel<<<1, 256, 0, stream>>>(feat, clsW, clsB, out);
}

// Round 9
// 2453.523 us; speedup vs baseline: 1.7699x; 1.0443x over previous
//
#include <hip/hip_runtime.h>
#include <math.h>

// Problem constants
constexpr int kS = 512, kH = 768, kNH = 12, kDH = 64, kF = 3072, kL = 12;
constexpr int kN = 50000, kE = 800000, kGH = 128;

#define CDIV(a,b) (((a)+(b)-1)/(b))

struct Ptr3 { const float* p[3]; };

typedef __attribute__((ext_vector_type(8))) short bf16x8;
typedef __attribute__((ext_vector_type(4))) float f32x4;

__device__ __forceinline__ unsigned short bf16_rne(float f) {
    unsigned int u = __float_as_uint(f);
    u += 0x7fffu + ((u >> 16) & 1u);
    return (unsigned short)(u >> 16);
}
__device__ __forceinline__ float bf16_f32(unsigned short h) {
    return __uint_as_float(((unsigned int)h) << 16);
}
__device__ __forceinline__ void split2(float f, short& hi, short& lo) {
    unsigned short h = bf16_rne(f);
    hi = (short)h;
    lo = (short)bf16_rne(f - bf16_f32(h));
}

constexpr int LDR = 72;  // LDS row: 32 hi | 32 lo | 8 pad shorts (144 B)

// ---------------- generic fill ----------------
__global__ void fill_kernel(float* p, float v, long n) {
    long i = blockIdx.x * (long)blockDim.x + threadIdx.x;
    if (i < n) p[i] = v;
}

// ---------------- GCN per-graph zero init (icnt, wsum, svec) ----------------
__global__ void gcn_zero_kernel(int* icnt, float* wsum, float* svec) {
    int i = blockIdx.x * 256 + threadIdx.x;
    if (i < kN) { icnt[i] = 0; wsum[i] = 0.f; }
    if (i < kGH) svec[i] = 0.f;
}

// ---------------- embeddings + LN (+ hi/lo emit, + maskbias fold) ----------------
__global__ void embed_ln_kernel(const int* ids, const int* tt, const int* mask,
                                const float* we, const float* pe, const float* te,
                                const float* g, const float* b, float* out,
                                short* oh, short* ol, float* mb) {
    int s = blockIdx.x;
    int tid = threadIdx.x;
    __shared__ float red[256];
    if (tid == 0) mb[s] = (1.f - (float)mask[s]) * -1e4f;
    int id = ids[s], t = tt[s];
    float vals[3]; float sum = 0.f;
    #pragma unroll
    for (int r = 0; r < 3; r++) {
        int j = tid + r * 256;
        float x = we[(long)id * kH + j] + pe[(long)s * kH + j] + te[(long)t * kH + j];
        vals[r] = x; sum += x;
    }
    red[tid] = sum; __syncthreads();
    for (int off = 128; off > 0; off >>= 1) { if (tid < off) red[tid] += red[tid + off]; __syncthreads(); }
    float mean = red[0] / kH; __syncthreads();
    float vs = 0.f;
    #pragma unroll
    for (int r = 0; r < 3; r++) { float d = vals[r] - mean; vs += d * d; }
    red[tid] = vs; __syncthreads();
    for (int off = 128; off > 0; off >>= 1) { if (tid < off) red[tid] += red[tid + off]; __syncthreads(); }
    float rstd = rsqrtf(red[0] / kH + 1e-12f);
    #pragma unroll
    for (int r = 0; r < 3; r++) {
        int j = tid + r * 256;
        float o = (vals[r] - mean) * rstd * g[j] + b[j];
        out[(long)s * kH + j] = o;
        short hi, lo; split2(o, hi, lo);
        oh[(long)s * kH + j] = hi; ol[(long)s * kH + j] = lo;
    }
}

// ---------------- batched weight transpose + split: W[z][K][N] -> Th/Tl at z*ostride, [N][K] ----------------
__global__ void wtrans_all_kernel(const float* __restrict__ W, short* __restrict__ Th,
                                  short* __restrict__ Tl, int K, int N, long ostride) {
    int z = blockIdx.z;
    const float* Wm = W + (long)z * K * N;
    long moff = (long)z * ostride;
    __shared__ short th[32][33], tl[32][33];
    int n0 = blockIdx.x * 32, k0 = blockIdx.y * 32;
    int c = threadIdx.x & 31, r = threadIdx.x >> 5;
    #pragma unroll
    for (int p = 0; p < 4; p++) {
        int rr = p * 8 + r;
        float f = Wm[(long)(k0 + rr) * N + n0 + c];
        short hi, lo; split2(f, hi, lo);
        th[rr][c] = hi; tl[rr][c] = lo;
    }
    __syncthreads();
    #pragma unroll
    for (int p = 0; p < 4; p++) {
        int rr = p * 8 + r;
        Th[moff + (long)(n0 + rr) * K + k0 + c] = th[c][rr];
        Tl[moff + (long)(n0 + rr) * K + k0 + c] = tl[c][rr];
    }
}

// ---------------- V transpose: v[s][kH] (head slices) -> vt[h][d][s] ----------------
__global__ void vtrans_kernel(const short* __restrict__ vh, const short* __restrict__ vl,
                              short* __restrict__ vth, short* __restrict__ vtl) {
    __shared__ short th[32][33], tl[32][33];
    int s0 = blockIdx.x * 32;
    int h = blockIdx.y >> 1, d0 = (blockIdx.y & 1) * 32;
    int c = threadIdx.x & 31, r = threadIdx.x >> 5;
    #pragma unroll
    for (int p = 0; p < 4; p++) {
        int rr = p * 8 + r;
        th[rr][c] = vh[(long)(s0 + rr) * kH + h * kDH + d0 + c];
        tl[rr][c] = vl[(long)(s0 + rr) * kH + h * kDH + d0 + c];
    }
    __syncthreads();
    #pragma unroll
    for (int p = 0; p < 4; p++) {
        int rr = p * 8 + r;
        vth[((long)h * kDH + d0 + rr) * kS + s0 + c] = th[c][rr];
        vtl[((long)h * kDH + d0 + rr) * kS + s0 + c] = tl[c][rr];
    }
}

// ======== 64x128-tile pre-split MFMA GEMM, register-prefetch double-buffered ========
__global__ __launch_bounds__(256, 4) void gemm64_pre(
    const short* __restrict__ Ah, const short* __restrict__ Al,
    const short* __restrict__ Bth, const short* __restrict__ Btl, long wstride,
    float* __restrict__ part, int M, int Nn, int K, int S)
{
    __shared__ short As[64 * LDR], Bs[128 * LDR];  // 27648 B
    int w = blockIdx.z / S, s = blockIdx.z % S;
    const short* Bh_ = Bth + (long)w * wstride;
    const short* Bl_ = Btl + (long)w * wstride;
    int Kc = K / S, kbeg = s * Kc;
    int m0 = blockIdx.y * 64, n0 = blockIdx.x * 128;
    int tid = threadIdx.x;
    int ar = tid >> 2, aq = (tid & 3) * 8;
    const short* Agh = Ah + (long)(m0 + ar) * K + kbeg + aq;
    const short* Agl = Al + (long)(m0 + ar) * K + kbeg + aq;
    int aofs = ar * LDR + aq;
    int br = tid >> 1, bq = (tid & 1) * 16;
    const short* Bgh = Bh_ + (long)(n0 + br) * K + kbeg + bq;
    const short* Bgl = Bl_ + (long)(n0 + br) * K + kbeg + bq;
    int bofs = br * LDR + bq;
    int wid = tid >> 6, lane = tid & 63;
    int wm = (wid >> 1) * 32, wn = (wid & 1) * 64;
    int fr = lane & 15, ko = (lane >> 4) * 8;
    f32x4 acc[2][4];
    #pragma unroll
    for (int i = 0; i < 2; i++)
        #pragma unroll
        for (int j = 0; j < 4; j++) acc[i][j] = (f32x4){0.f, 0.f, 0.f, 0.f};
    int nst = Kc / 32;
    bf16x8 pa0 = *(const bf16x8*)(Agh);
    bf16x8 pa1 = *(const bf16x8*)(Agl);
    bf16x8 pb0 = *(const bf16x8*)(Bgh);
    bf16x8 pb1 = *(const bf16x8*)(Bgh + 8);
    bf16x8 pb2 = *(const bf16x8*)(Bgl);
    bf16x8 pb3 = *(const bf16x8*)(Bgl + 8);
    for (int st = 0; st < nst; ++st) {
        *(bf16x8*)&As[aofs]      = pa0;
        *(bf16x8*)&As[aofs + 32] = pa1;
        *(bf16x8*)&Bs[bofs]      = pb0;
        *(bf16x8*)&Bs[bofs + 8]  = pb1;
        *(bf16x8*)&Bs[bofs + 32] = pb2;
        *(bf16x8*)&Bs[bofs + 40] = pb3;
        if (st + 1 < nst) {
            int go = (st + 1) * 32;
            pa0 = *(const bf16x8*)(Agh + go);
            pa1 = *(const bf16x8*)(Agl + go);
            pb0 = *(const bf16x8*)(Bgh + go);
            pb1 = *(const bf16x8*)(Bgh + go + 8);
            pb2 = *(const bf16x8*)(Bgl + go);
            pb3 = *(const bf16x8*)(Bgl + go + 8);
        }
        __syncthreads();
        bf16x8 bh[4], bl[4];
        #pragma unroll
        for (int j = 0; j < 4; j++) {
            int c = (wn + j * 16 + fr) * LDR + ko;
            bh[j] = *(const bf16x8*)&Bs[c];
            bl[j] = *(const bf16x8*)&Bs[c + 32];
        }
        #pragma unroll
        for (int i = 0; i < 2; i++) {
            int r = (wm + i * 16 + fr) * LDR + ko;
            bf16x8 ah = *(const bf16x8*)&As[r];
            bf16x8 al = *(const bf16x8*)&As[r + 32];
            #pragma unroll
            for (int j = 0; j < 4; j++) {
                acc[i][j] = __builtin_amdgcn_mfma_f32_16x16x32_bf16(ah, bh[j], acc[i][j], 0, 0, 0);
                acc[i][j] = __builtin_amdgcn_mfma_f32_16x16x32_bf16(ah, bl[j], acc[i][j], 0, 0, 0);
                acc[i][j] = __builtin_amdgcn_mfma_f32_16x16x32_bf16(al, bh[j], acc[i][j], 0, 0, 0);
            }
        }
        __syncthreads();
    }
    long MN = (long)M * Nn;
    float* Pp = part + (long)(w * S + s) * MN;
    int cr = (lane >> 4) * 4;
    #pragma unroll
    for (int i = 0; i < 2; i++) {
        #pragma unroll
        for (int r = 0; r < 4; r++) {
            int gm = m0 + wm + i * 16 + cr + r;
            float* rowp = &Pp[(long)gm * Nn + n0 + wn + fr];
            #pragma unroll
            for (int j = 0; j < 4; j++) rowp[j * 16] = acc[i][j][r];
        }
    }
}

// ======== GCN GEMM: A fp32 inline-split (prefetched), B pre-split; 64x128 tile; M guard ========
// S=1 direct: part IS the output (no epilogue needed).
__global__ __launch_bounds__(256, 4) void gemm64_gcn(
    const float* __restrict__ A,
    const short* __restrict__ Bth, const short* __restrict__ Btl,
    float* __restrict__ part, int M, int Nn, int K, int S)
{
    __shared__ short As[64 * LDR], Bs[128 * LDR];
    int s = blockIdx.z;
    int Kc = K / S, kbeg = s * Kc;
    int m0 = blockIdx.y * 64, n0 = blockIdx.x * 128;
    int tid = threadIdx.x;
    int ar = tid >> 2, aqf = (tid & 3) * 8;
    int gmA = m0 + ar; if (gmA > M - 1) gmA = M - 1;
    const float* Agf = A + (long)gmA * K + kbeg + aqf;
    int aofs = ar * LDR + aqf;
    int br = tid >> 1, bq = (tid & 1) * 16;
    const short* Bgh = Bth + (long)(n0 + br) * K + kbeg + bq;
    const short* Bgl = Btl + (long)(n0 + br) * K + kbeg + bq;
    int bofs = br * LDR + bq;
    int wid = tid >> 6, lane = tid & 63;
    int wm = (wid >> 1) * 32, wn = (wid & 1) * 64;
    int fr = lane & 15, ko = (lane >> 4) * 8;
    f32x4 acc[2][4];
    #pragma unroll
    for (int i = 0; i < 2; i++)
        #pragma unroll
        for (int j = 0; j < 4; j++) acc[i][j] = (f32x4){0.f, 0.f, 0.f, 0.f};
    int nst = Kc / 32;
    float4 pf0 = *(const float4*)(Agf);
    float4 pf1 = *(const float4*)(Agf + 4);
    bf16x8 pb0 = *(const bf16x8*)(Bgh);
    bf16x8 pb1 = *(const bf16x8*)(Bgh + 8);
    bf16x8 pb2 = *(const bf16x8*)(Bgl);
    bf16x8 pb3 = *(const bf16x8*)(Bgl + 8);
    for (int st = 0; st < nst; ++st) {
        short h0, l0, h1, l1, h2, l2, h3, l3, h4, l4, h5, l5, h6, l6, h7, l7;
        split2(pf0.x, h0, l0); split2(pf0.y, h1, l1); split2(pf0.z, h2, l2); split2(pf0.w, h3, l3);
        split2(pf1.x, h4, l4); split2(pf1.y, h5, l5); split2(pf1.z, h6, l6); split2(pf1.w, h7, l7);
        *(short4*)&As[aofs]      = make_short4(h0, h1, h2, h3);
        *(short4*)&As[aofs + 4]  = make_short4(h4, h5, h6, h7);
        *(short4*)&As[aofs + 32] = make_short4(l0, l1, l2, l3);
        *(short4*)&As[aofs + 36] = make_short4(l4, l5, l6, l7);
        *(bf16x8*)&Bs[bofs]      = pb0;
        *(bf16x8*)&Bs[bofs + 8]  = pb1;
        *(bf16x8*)&Bs[bofs + 32] = pb2;
        *(bf16x8*)&Bs[bofs + 40] = pb3;
        if (st + 1 < nst) {
            int go = (st + 1) * 32;
            pf0 = *(const float4*)(Agf + go);
            pf1 = *(const float4*)(Agf + go + 4);
            pb0 = *(const bf16x8*)(Bgh + go);
            pb1 = *(const bf16x8*)(Bgh + go + 8);
            pb2 = *(const bf16x8*)(Bgl + go);
            pb3 = *(const bf16x8*)(Bgl + go + 8);
        }
        __syncthreads();
        bf16x8 bh[4], bl[4];
        #pragma unroll
        for (int j = 0; j < 4; j++) {
            int c = (wn + j * 16 + fr) * LDR + ko;
            bh[j] = *(const bf16x8*)&Bs[c];
            bl[j] = *(const bf16x8*)&Bs[c + 32];
        }
        #pragma unroll
        for (int i = 0; i < 2; i++) {
            int r = (wm + i * 16 + fr) * LDR + ko;
            bf16x8 ah = *(const bf16x8*)&As[r];
            bf16x8 al = *(const bf16x8*)&As[r + 32];
            #pragma unroll
            for (int j = 0; j < 4; j++) {
                acc[i][j] = __builtin_amdgcn_mfma_f32_16x16x32_bf16(ah, bh[j], acc[i][j], 0, 0, 0);
                acc[i][j] = __builtin_amdgcn_mfma_f32_16x16x32_bf16(ah, bl[j], acc[i][j], 0, 0, 0);
                acc[i][j] = __builtin_amdgcn_mfma_f32_16x16x32_bf16(al, bh[j], acc[i][j], 0, 0, 0);
            }
        }
        __syncthreads();
    }
    long MN = (long)M * Nn;
    float* Pp = part + (long)s * MN;
    int cr = (lane >> 4) * 4;
    #pragma unroll
    for (int i = 0; i < 2; i++) {
        #pragma unroll
        for (int r = 0; r < 4; r++) {
            int gm = m0 + wm + i * 16 + cr + r;
            if (gm >= M) continue;
            float* rowp = &Pp[(long)gm * Nn + n0 + wn + fr];
            #pragma unroll
            for (int j = 0; j < 4; j++) rowp[j * 16] = acc[i][j][r];
        }
    }
}

// ---------------- QKV epilogue: sum partials + bias -> hi/lo shorts ----------------
__global__ void splitk_epi_qkv_kernel(const float* __restrict__ part, Ptr3 bias,
                                      short* __restrict__ qh, short* __restrict__ ql,
                                      short* __restrict__ kh, short* __restrict__ kl,
                                      short* __restrict__ vh, short* __restrict__ vl,
                                      int S) {
    const long MN = (long)kS * kH;
    int w = blockIdx.y;
    long i = ((long)blockIdx.x * blockDim.x + threadIdx.x) * 4;
    if (i >= MN) return;
    const float* P = part + (long)w * S * MN + i;
    float4 a = *(const float4*)P;
    for (int s2 = 1; s2 < S; ++s2) {
        float4 b2 = *(const float4*)(P + (long)s2 * MN);
        a.x += b2.x; a.y += b2.y; a.z += b2.z; a.w += b2.w;
    }
    const float* bw = bias.p[w];
    int n = (int)(i % kH);
    a.x += bw[n]; a.y += bw[n + 1]; a.z += bw[n + 2]; a.w += bw[n + 3];
    short* oh = (w == 0) ? qh : (w == 1) ? kh : vh;
    short* ol = (w == 0) ? ql : (w == 1) ? kl : vl;
    short h0, l0, h1, l1, h2, l2, h3, l3;
    split2(a.x, h0, l0); split2(a.y, h1, l1); split2(a.z, h2, l2); split2(a.w, h3, l3);
    *(short4*)&oh[i] = make_short4(h0, h1, h2, h3);
    *(short4*)&ol[i] = make_short4(l0, l1, l2, l3);
}

// ---------------- generic epilogue: sum partials (+bias, +act) -> hi/lo shorts ----------------
__global__ void splitk_epi_sh_kernel(const float* __restrict__ part, const float* __restrict__ bias,
                                     short* __restrict__ oh, short* __restrict__ ol,
                                     long MN, int Nn, int S, int act) {
    long i = ((long)blockIdx.x * blockDim.x + threadIdx.x) * 4;
    if (i >= MN) return;
    const float* P = part + i;
    float4 a = *(const float4*)P;
    for (int s2 = 1; s2 < S; ++s2) {
        float4 b2 = *(const float4*)(P + (long)s2 * MN);
        a.x += b2.x; a.y += b2.y; a.z += b2.z; a.w += b2.w;
    }
    if (bias) {
        int n = (int)(i % Nn);
        a.x += bias[n]; a.y += bias[n + 1]; a.z += bias[n + 2]; a.w += bias[n + 3];
    }
    if (act == 1) {
        a.x = 0.5f * a.x * (1.f + erff(a.x * 0.70710678118654752f));
        a.y = 0.5f * a.y * (1.f + erff(a.y * 0.70710678118654752f));
        a.z = 0.5f * a.z * (1.f + erff(a.z * 0.70710678118654752f));
        a.w = 0.5f * a.w * (1.f + erff(a.w * 0.70710678118654752f));
    }
    short h0, l0, h1, l1, h2, l2, h3, l3;
    split2(a.x, h0, l0); split2(a.y, h1, l1); split2(a.z, h2, l2); split2(a.w, h3, l3);
    *(short4*)&oh[i] = make_short4(h0, h1, h2, h3);
    *(short4*)&ol[i] = make_short4(l0, l1, l2, l3);
}

// ---------------- fused split-K + bias + residual + LN -> fp32 + hi/lo ----------------
__global__ void splitk_epi_ln2_kernel(const float* __restrict__ part, const float* __restrict__ bias,
                                      const float* __restrict__ res, const float* __restrict__ g,
                                      const float* __restrict__ b, float* __restrict__ out,
                                      short* __restrict__ oh, short* __restrict__ ol, int S) {
    int row = blockIdx.x; int tid = threadIdx.x;
    __shared__ float red[256];
    const long MN = (long)kS * kH;
    float vals[3]; float sum = 0.f;
    #pragma unroll
    for (int r = 0; r < 3; r++) {
        int j = tid + r * 256;
        const float* P = part + (long)row * kH + j;
        float x = res[(long)row * kH + j] + bias[j];
        for (int s2 = 0; s2 < S; ++s2) x += P[(long)s2 * MN];
        vals[r] = x; sum += x;
    }
    red[tid] = sum; __syncthreads();
    for (int off = 128; off > 0; off >>= 1) { if (tid < off) red[tid] += red[tid + off]; __syncthreads(); }
    float mean = red[0] / kH; __syncthreads();
    float vs = 0.f;
    #pragma unroll
    for (int r = 0; r < 3; r++) { float d = vals[r] - mean; vs += d * d; }
    red[tid] = vs; __syncthreads();
    for (int off = 128; off > 0; off >>= 1) { if (tid < off) red[tid] += red[tid + off]; __syncthreads(); }
    float rstd = rsqrtf(red[0] / kH + 1e-12f);
    #pragma unroll
    for (int r = 0; r < 3; r++) {
        int j = tid + r * 256;
        float o = (vals[r] - mean) * rstd * g[j] + b[j];
        out[(long)row * kH + j] = o;
        short hi, lo; split2(o, hi, lo);
        oh[(long)row * kH + j] = hi; ol[(long)row * kH + j] = lo;
    }
}

// ---------------- attention scores: 64(q) x 128(k) tile, dbuf ----------------
__global__ __launch_bounds__(256, 4) void attn_scores64_kernel(
    const short* __restrict__ qh, const short* __restrict__ ql,
    const short* __restrict__ kh, const short* __restrict__ kl,
    const float* __restrict__ mb, float* __restrict__ scores)
{
    __shared__ short As[64 * LDR], Bs[128 * LDR];
    int h = blockIdx.z;
    int k0 = blockIdx.x * 128, q0 = blockIdx.y * 64;
    int tid = threadIdx.x;
    int ar = tid >> 2, aq = (tid & 3) * 8;
    const short* Agh = qh + (long)(q0 + ar) * kH + h * kDH + aq;
    const short* Agl = ql + (long)(q0 + ar) * kH + h * kDH + aq;
    int aofs = ar * LDR + aq;
    int br = tid >> 1, bq = (tid & 1) * 16;
    const short* Bgh = kh + (long)(k0 + br) * kH + h * kDH + bq;
    const short* Bgl = kl + (long)(k0 + br) * kH + h * kDH + bq;
    int bofs = br * LDR + bq;
    int wid = tid >> 6, lane = tid & 63;
    int wm = (wid >> 1) * 32, wn = (wid & 1) * 64;
    int fr = lane & 15, ko = (lane >> 4) * 8;
    f32x4 acc[2][4];
    #pragma unroll
    for (int i = 0; i < 2; i++)
        #pragma unroll
        for (int j = 0; j < 4; j++) acc[i][j] = (f32x4){0.f, 0.f, 0.f, 0.f};
    bf16x8 pa0 = *(const bf16x8*)(Agh);
    bf16x8 pa1 = *(const bf16x8*)(Agl);
    bf16x8 pb0 = *(const bf16x8*)(Bgh);
    bf16x8 pb1 = *(const bf16x8*)(Bgh + 8);
    bf16x8 pb2 = *(const bf16x8*)(Bgl);
    bf16x8 pb3 = *(const bf16x8*)(Bgl + 8);
    #pragma unroll
    for (int st = 0; st < 2; ++st) {
        *(bf16x8*)&As[aofs]      = pa0;
        *(bf16x8*)&As[aofs + 32] = pa1;
        *(bf16x8*)&Bs[bofs]      = pb0;
        *(bf16x8*)&Bs[bofs + 8]  = pb1;
        *(bf16x8*)&Bs[bofs + 32] = pb2;
        *(bf16x8*)&Bs[bofs + 40] = pb3;
        if (st == 0) {
            pa0 = *(const bf16x8*)(Agh + 32);
            pa1 = *(const bf16x8*)(Agl + 32);
            pb0 = *(const bf16x8*)(Bgh + 32);
            pb1 = *(const bf16x8*)(Bgh + 40);
            pb2 = *(const bf16x8*)(Bgl + 32);
            pb3 = *(const bf16x8*)(Bgl + 40);
        }
        __syncthreads();
        bf16x8 bh[4], bl[4];
        #pragma unroll
        for (int j = 0; j < 4; j++) {
            int c = (wn + j * 16 + fr) * LDR + ko;
            bh[j] = *(const bf16x8*)&Bs[c];
            bl[j] = *(const bf16x8*)&Bs[c + 32];
        }
        #pragma unroll
        for (int i = 0; i < 2; i++) {
            int r = (wm + i * 16 + fr) * LDR + ko;
            bf16x8 ah = *(const bf16x8*)&As[r];
            bf16x8 al = *(const bf16x8*)&As[r + 32];
            #pragma unroll
            for (int j = 0; j < 4; j++) {
                acc[i][j] = __builtin_amdgcn_mfma_f32_16x16x32_bf16(ah, bh[j], acc[i][j], 0, 0, 0);
                acc[i][j] = __builtin_amdgcn_mfma_f32_16x16x32_bf16(ah, bl[j], acc[i][j], 0, 0, 0);
                acc[i][j] = __builtin_amdgcn_mfma_f32_16x16x32_bf16(al, bh[j], acc[i][j], 0, 0, 0);
            }
        }
        __syncthreads();
    }
    int cr = (lane >> 4) * 4;
    #pragma unroll
    for (int i = 0; i < 2; i++) {
        #pragma unroll
        for (int r = 0; r < 4; r++) {
            int qq = q0 + wm + i * 16 + cr + r;
            float* rowp = &scores[((long)h * kS + qq) * kS + k0 + wn + fr];
            #pragma unroll
            for (int j = 0; j < 4; j++)
                rowp[j * 16] = acc[i][j][r] * 0.125f + mb[k0 + wn + j * 16 + fr];
        }
    }
}

// ---------------- softmax over rows of 512 -> P hi/lo ----------------
__global__ void softmax_split_kernel(const float* __restrict__ scores,
                                     short* __restrict__ ph, short* __restrict__ pl) {
    long row = blockIdx.x;
    const float* p = scores + row * kS;
    int tid = threadIdx.x;
    __shared__ float red[256];
    float x0 = p[tid], x1 = p[tid + 256];
    red[tid] = fmaxf(x0, x1); __syncthreads();
    for (int off = 128; off > 0; off >>= 1) { if (tid < off) red[tid] = fmaxf(red[tid], red[tid + off]); __syncthreads(); }
    float mx = red[0]; __syncthreads();
    float e0 = expf(x0 - mx), e1 = expf(x1 - mx);
    red[tid] = e0 + e1; __syncthreads();
    for (int off = 128; off > 0; off >>= 1) { if (tid < off) red[tid] += red[tid + off]; __syncthreads(); }
    float inv = 1.f / red[0];
    float r0 = e0 * inv, r1 = e1 * inv;
    short h0, l0, h1, l1;
    split2(r0, h0, l0); split2(r1, h1, l1);
    ph[row * kS + tid] = h0; pl[row * kS + tid] = l0;
    ph[row * kS + tid + 256] = h1; pl[row * kS + tid + 256] = l1;
}

// ---------------- ctx partial = P @ V (pre-split, V transposed), 8-way K-split, dbuf ----------------
__global__ __launch_bounds__(256, 4) void attn_ctx64_kernel(
    const short* __restrict__ ph, const short* __restrict__ pl,
    const short* __restrict__ vth, const short* __restrict__ vtl,
    float* __restrict__ part)
{
    __shared__ short As[128 * LDR], Bs[64 * LDR];
    int q0 = blockIdx.x * 128;
    int h = blockIdx.y >> 3, s = blockIdx.y & 7;
    int kbeg = s * 64;
    int tid = threadIdx.x;
    int ar = tid >> 1, aq = (tid & 1) * 16;
    const short* Agh = ph + ((long)h * kS + q0 + ar) * kS + kbeg + aq;
    const short* Agl = pl + ((long)h * kS + q0 + ar) * kS + kbeg + aq;
    int aofs = ar * LDR + aq;
    int brr = tid >> 2, bq = (tid & 3) * 8;
    const short* Bgh = vth + ((long)h * kDH + brr) * kS + kbeg + bq;
    const short* Bgl = vtl + ((long)h * kDH + brr) * kS + kbeg + bq;
    int bofs = brr * LDR + bq;
    int wid = tid >> 6, lane = tid & 63;
    int wm = wid * 32;
    int fr = lane & 15, ko = (lane >> 4) * 8;
    f32x4 acc[2][4];
    #pragma unroll
    for (int i = 0; i < 2; i++)
        #pragma unroll
        for (int j = 0; j < 4; j++) acc[i][j] = (f32x4){0.f, 0.f, 0.f, 0.f};
    bf16x8 pa0 = *(const bf16x8*)(Agh);
    bf16x8 pa1 = *(const bf16x8*)(Agh + 8);
    bf16x8 pa2 = *(const bf16x8*)(Agl);
    bf16x8 pa3 = *(const bf16x8*)(Agl + 8);
    bf16x8 pb0 = *(const bf16x8*)(Bgh);
    bf16x8 pb1 = *(const bf16x8*)(Bgl);
    #pragma unroll
    for (int st = 0; st < 2; ++st) {
        *(bf16x8*)&As[aofs]      = pa0;
        *(bf16x8*)&As[aofs + 8]  = pa1;
        *(bf16x8*)&As[aofs + 32] = pa2;
        *(bf16x8*)&As[aofs + 40] = pa3;
        *(bf16x8*)&Bs[bofs]      = pb0;
        *(bf16x8*)&Bs[bofs + 32] = pb1;
        if (st == 0) {
            pa0 = *(const bf16x8*)(Agh + 32);
            pa1 = *(const bf16x8*)(Agh + 40);
            pa2 = *(const bf16x8*)(Agl + 32);
            pa3 = *(const bf16x8*)(Agl + 40);
            pb0 = *(const bf16x8*)(Bgh + 32);
            pb1 = *(const bf16x8*)(Bgl + 32);
        }
        __syncthreads();
        bf16x8 bh[4], bl[4];
        #pragma unroll
        for (int j = 0; j < 4; j++) {
            int c = (j * 16 + fr) * LDR + ko;
            bh[j] = *(const bf16x8*)&Bs[c];
            bl[j] = *(const bf16x8*)&Bs[c + 32];
        }
        #pragma unroll
        for (int i = 0; i < 2; i++) {
            int r = (wm + i * 16 + fr) * LDR + ko;
            bf16x8 ah = *(const bf16x8*)&As[r];
            bf16x8 al = *(const bf16x8*)&As[r + 32];
            #pragma unroll
            for (int j = 0; j < 4; j++) {
                acc[i][j] = __builtin_amdgcn_mfma_f32_16x16x32_bf16(ah, bh[j], acc[i][j], 0, 0, 0);
                acc[i][j] = __builtin_amdgcn_mfma_f32_16x16x32_bf16(ah, bl[j], acc[i][j], 0, 0, 0);
                acc[i][j] = __builtin_amdgcn_mfma_f32_16x16x32_bf16(al, bh[j], acc[i][j], 0, 0, 0);
            }
        }
        __syncthreads();
    }
    long Pbase = (long)s * ((long)kS * kH);
    int cr = (lane >> 4) * 4;
    #pragma unroll
    for (int i = 0; i < 2; i++) {
        #pragma unroll
        for (int r = 0; r < 4; r++) {
            int gq = q0 + wm + i * 16 + cr + r;
            float* rowp = &part[Pbase + (long)gq * kH + h * kDH + fr];
            #pragma unroll
            for (int j = 0; j < 4; j++) rowp[j * 16] = acc[i][j][r];
        }
    }
}

// ---------------- GCN sparse kernels ----------------
__global__ void cnt_kernel(const int* __restrict__ dst, int* __restrict__ cnt, int E) {
    int e = blockIdx.x * blockDim.x + threadIdx.x;
    if (e < E) atomicAdd(&cnt[dst[e]], 1);
}

__global__ void scan1_kernel(const int* __restrict__ cnt, int* __restrict__ offs,
                             int* __restrict__ bsum, int n) {
    __shared__ int sh[256];
    int i = blockIdx.x * 256 + threadIdx.x;
    int v = (i < n) ? cnt[i] : 0;
    sh[threadIdx.x] = v; __syncthreads();
    for (int off = 1; off < 256; off <<= 1) {
        int t = (threadIdx.x >= off) ? sh[threadIdx.x - off] : 0;
        __syncthreads();
        sh[threadIdx.x] += t;
        __syncthreads();
    }
    if (i < n) offs[i] = sh[threadIdx.x] - v;
    if (threadIdx.x == 255) bsum[blockIdx.x] = sh[255];
}

__global__ void scan2_kernel(int* bsum, int nb, int* offs, int n) {
    if (threadIdx.x == 0) {
        int run = 0;
        for (int b = 0; b < nb; b++) { int t = bsum[b]; bsum[b] = run; run += t; }
        offs[n] = run;
    }
}

__global__ void scan3_kernel(const int* __restrict__ cnt, int* __restrict__ offs,
                             const int* __restrict__ bsum, int* __restrict__ cur,
                             float* __restrict__ dinv, int n) {
    int i = blockIdx.x * 256 + threadIdx.x;
    if (i >= n) return;
    int o = offs[i] + bsum[blockIdx.x];
    offs[i] = o; cur[i] = o;
    dinv[i] = rsqrtf((float)(cnt[i] + 1));
}

__global__ void csrfill_edgew_kernel(const int* __restrict__ src, const int* __restrict__ dst,
                                     int* __restrict__ cur, int* __restrict__ csr,
                                     const float* __restrict__ dinv, float* __restrict__ wsum,
                                     int E) {
    int e = blockIdx.x * blockDim.x + threadIdx.x;
    if (e < E) {
        int s2 = src[e], d = dst[e];
        int slot = atomicAdd(&cur[d], 1);
        csr[slot] = s2;
        atomicAdd(&wsum[s2], dinv[s2] * dinv[d]);
    }
}

__global__ __launch_bounds__(256) void spmm_gather_kernel(const int* __restrict__ offs,
                                                          const int* __restrict__ csr,
                                                          const float* __restrict__ dinv,
                                                          const float* __restrict__ hw,
                                                          const float* __restrict__ b1,
                                                          float* __restrict__ hout, int n) {
    int d = blockIdx.x * 2 + (threadIdx.x >> 7);
    int j = threadIdx.x & 127;
    if (d >= n) return;
    int beg = offs[d], end = offs[d + 1];
    float a0 = 0.f, a1 = 0.f, a2 = 0.f, a3 = 0.f;
    int p = beg;
    for (; p + 4 <= end; p += 4) {
        int s0 = csr[p], s1 = csr[p + 1], s2 = csr[p + 2], s3 = csr[p + 3];
        a0 += dinv[s0] * hw[(long)s0 * kGH + j];
        a1 += dinv[s1] * hw[(long)s1 * kGH + j];
        a2 += dinv[s2] * hw[(long)s2 * kGH + j];
        a3 += dinv[s3] * hw[(long)s3 * kGH + j];
    }
    for (; p < end; ++p) {
        int s4 = csr[p];
        a0 += dinv[s4] * hw[(long)s4 * kGH + j];
    }
    float acc = (a0 + a1) + (a2 + a3);
    float dd = dinv[d];
    float v = acc * dd + dd * dd * hw[(long)d * kGH + j] + b1[j];
    hout[(long)d * kGH + j] = fmaxf(v, 0.f);
}

__global__ void wreduce_kernel(const float* __restrict__ h, const float* __restrict__ w,
                               const float* __restrict__ dinv, float* __restrict__ s, int n) {
    int tid = threadIdx.x; int j = tid & 127; int half = tid >> 7;
    float acc = 0.f;
    for (int u = blockIdx.x * 2 + half; u < n; u += gridDim.x * 2) {
        float di = dinv[u];
        acc += (w[u] + di * di) * h[(long)u * kGH + j];
    }
    __shared__ float red[256];
    red[tid] = acc; __syncthreads();
    if (tid < 128) atomicAdd(&s[j], red[tid] + red[tid + 128]);
}

__global__ void gcn_final_kernel(const float* s, const float* W2, const float* b2, float* g) {
    int j2 = threadIdx.x;
    float acc = 0.f;
    for (int j = 0; j < kGH; j++) acc += s[j] * W2[(long)j * kGH + j2];
    g[j2] = acc * (1.f / (float)kN) + b2[j2];
}

// ---------------- combine head (parallel): partial over 32-row chunks + atomic ----------------
__global__ void combine_part_kernel(const float* __restrict__ cls, const float* __restrict__ gp,
                                    const float* __restrict__ gh, const float* __restrict__ Wc,
                                    float* __restrict__ feat) {
    int i0 = blockIdx.x * 32;
    int tid = threadIdx.x;
    float a0 = 0.f, a1 = 0.f, a2 = 0.f;
    for (int r = 0; r < 32; r++) {
        int i = i0 + r;
        float x = (i < 768) ? cls[i] : (i < 896) ? gp[i - 768]
                : (i < 1664) ? cls[i - 896] : gh[i - 1664];
        const float* row = Wc + (long)i * kH;
        a0 += x * row[tid]; a1 += x * row[tid + 256]; a2 += x * row[tid + 512];
    }
    atomicAdd(&feat[tid], a0);
    atomicAdd(&feat[tid + 256], a1);
    atomicAdd(&feat[tid + 512], a2);
}

__global__ void combine_fin_kernel(float* feat, const float* bc) {
    int o = blockIdx.x * 256 + threadIdx.x;
    if (o < kH) feat[o] = fmaxf(feat[o] + bc[o], 0.f);
}

__global__ void cls_head_kernel(const float* feat, const float* W, const float* b, float* out) {
    int tid = threadIdx.x;
    float a0 = 0.f, a1 = 0.f, a2 = 0.f;
    for (int o = tid; o < kH; o += 256) {
        float f = feat[o];
        a0 += f * W[o * 3 + 0]; a1 += f * W[o * 3 + 1]; a2 += f * W[o * 3 + 2];
    }
    __shared__ float r0[256], r1[256], r2[256];
    r0[tid] = a0; r1[tid] = a1; r2[tid] = a2; __syncthreads();
    for (int off = 128; off > 0; off >>= 1) {
        if (tid < off) { r0[tid] += r0[tid + off]; r1[tid] += r1[tid + off]; r2[tid] += r2[tid + off]; }
        __syncthreads();
    }
    if (tid == 0) { out[0] = r0[0] + b[0]; out[1] = r1[0] + b[1]; out[2] = r2[0] + b[2]; }
}

// ---------------- launch ----------------
extern "C" void kernel_launch(void* const* d_in, const int* in_sizes, int n_in,
                              void* d_out, int out_size, void* d_ws, size_t ws_size,
                              hipStream_t stream) {
    const int*   input_ids = (const int*)d_in[0];
    const int*   attn_mask = (const int*)d_in[1];
    const int*   type_ids  = (const int*)d_in[2];
    const int*   p_edges   = (const int*)d_in[3];
    const int*   h_edges   = (const int*)d_in[4];
    const float* p_nodes   = (const float*)d_in[5];
    const float* h_nodes   = (const float*)d_in[6];
    const float* word_emb  = (const float*)d_in[7];
    const float* pos_emb   = (const float*)d_in[8];
    const float* type_emb  = (const float*)d_in[9];
    const float* eln_s     = (const float*)d_in[10];
    const float* eln_b     = (const float*)d_in[11];
    const float* Wq = (const float*)d_in[12]; const float* bq = (const float*)d_in[13];
    const float* Wk = (const float*)d_in[14]; const float* bk = (const float*)d_in[15];
    const float* Wv = (const float*)d_in[16]; const float* bv = (const float*)d_in[17];
    const float* Wo = (const float*)d_in[18]; const float* bo = (const float*)d_in[19];
    const float* l1s = (const float*)d_in[20]; const float* l1b = (const float*)d_in[21];
    const float* W1 = (const float*)d_in[22]; const float* b1 = (const float*)d_in[23];
    const float* W2 = (const float*)d_in[24]; const float* b2 = (const float*)d_in[25];
    const float* l2s = (const float*)d_in[26]; const float* l2b = (const float*)d_in[27];
    const float* gW1 = (const float*)d_in[28]; const float* gb1 = (const float*)d_in[29];
    const float* gW2 = (const float*)d_in[30]; const float* gb2 = (const float*)d_in[31];
    const float* cW  = (const float*)d_in[32]; const float* cb  = (const float*)d_in[33];
    const float* clsW = (const float*)d_in[34]; const float* clsB = (const float*)d_in[35];
    float* out = (float*)d_out;

    // ---------------- workspace layout ----------------
    float* W = (float*)d_ws;
    size_t off = 0;
    auto alloc = [&](size_t n) { float* p = W + off; off += n; return p; };
    float* h    = alloc((size_t)kS * kH);
    float* h1   = alloc((size_t)kS * kH);
    float* deg  = alloc(kN);
    float* wsum = alloc(kN);
    float* svec = alloc(kGH);
    float* gp   = alloc(kGH);
    float* ghv  = alloc(kGH);
    float* mb   = alloc(kS);
    float* feat = alloc(kH);
    float* big  = W + off;

    // BERT-phase big layout (float slots)
    float* part  = big;
    float* scores = part;
    short* p_h   = (short*)(big + 4718592);
    short* p_l   = p_h + (size_t)3145728;
    short* ffn1_h = (short*)(big + 7864320);
    short* ffn1_l = ffn1_h + (size_t)1572864;
    short* sm    = (short*)(big + 11796480);
    const size_t SMN = (size_t)kS * kH;
    short* q_h = sm;            short* q_l = q_h + SMN;
    short* k_h = q_l + SMN;     short* k_l = k_h + SMN;
    short* v_h = k_l + SMN;     short* v_l = v_h + SMN;
    short* vt_h = v_l + SMN;    short* vt_l = vt_h + SMN;
    short* ctx_h = vt_l + SMN;  short* ctx_l = ctx_h + SMN;
    short* h1_h = ctx_l + SMN;  short* h1_l = h1_h + SMN;
    short* hh_h = h1_l + SMN;   short* hh_l = hh_h + SMN;

    // GCN-phase overlay on big
    float* hw1 = big;
    float* agg = big + (size_t)kN * kGH;
    int* icnt  = (int*)(big + 2 * (size_t)kN * kGH);
    int* ioffs = icnt + 50048;
    int* icur  = ioffs + 50048;
    int* ibsum = icur + 50048;
    int* icsr  = ibsum + 256;
    short* gwt_h = (short*)(icsr + kE);
    short* gwt_l = gwt_h + (size_t)kH * kGH;

    // Persistent pre-converted weight cache (beyond both overlays)
    const size_t QKV_SZ = (size_t)kH * kH;      // 589824
    const size_t FF_SZ  = (size_t)kH * kF;      // 2359296
    short* wc = (short*)(big + 15000000);
    short* qkv_h = wc;                          short* qkv_l = qkv_h + 12 * 3 * QKV_SZ;
    short* wo_h  = qkv_l + 12 * 3 * QKV_SZ;     short* wo_l  = wo_h + 12 * QKV_SZ;
    short* w1_h  = wo_l + 12 * QKV_SZ;          short* w1_l  = w1_h + 12 * FF_SZ;
    short* w2_h  = w1_l + 12 * FF_SZ;           short* w2_l  = w2_h + 12 * FF_SZ;

    const long MN_H = (long)kS * kH;   // 393216
    const long MN_F = (long)kS * kF;   // 1572864
    const int nScanBlk = CDIV(kN, 256);

    // ---------- pre-convert ALL weights once ----------
    wtrans_all_kernel<<<dim3(24, 24, 12), 256, 0, stream>>>(Wq, qkv_h,              qkv_l,              kH, kH, (long)(3 * QKV_SZ));
    wtrans_all_kernel<<<dim3(24, 24, 12), 256, 0, stream>>>(Wk, qkv_h + QKV_SZ,     qkv_l + QKV_SZ,     kH, kH, (long)(3 * QKV_SZ));
    wtrans_all_kernel<<<dim3(24, 24, 12), 256, 0, stream>>>(Wv, qkv_h + 2 * QKV_SZ, qkv_l + 2 * QKV_SZ, kH, kH, (long)(3 * QKV_SZ));
    wtrans_all_kernel<<<dim3(24, 24, 12), 256, 0, stream>>>(Wo, wo_h, wo_l, kH, kH, (long)QKV_SZ);
    wtrans_all_kernel<<<dim3(96, 24, 12), 256, 0, stream>>>(W1, w1_h, w1_l, kH, kF, (long)FF_SZ);
    wtrans_all_kernel<<<dim3(24, 96, 12), 256, 0, stream>>>(W2, w2_h, w2_l, kF, kH, (long)FF_SZ);

    // ---------- GCN on both graphs ----------
    const int* gsrc[2] = { p_edges, h_edges };
    const int* gdst[2] = { p_edges + kE, h_edges + kE };
    const float* gx[2] = { p_nodes, h_nodes };
    float* gout[2] = { gp, ghv };
    wtrans_all_kernel<<<dim3(kGH / 32, kH / 32, 1), 256, 0, stream>>>(gW1, gwt_h, gwt_l, kH, kGH, 0);
    for (int gi = 0; gi < 2; gi++) {
        gcn_zero_kernel<<<nScanBlk, 256, 0, stream>>>(icnt, wsum, svec);
        cnt_kernel<<<CDIV(kE, 256), 256, 0, stream>>>(gdst[gi], icnt, kE);
        scan1_kernel<<<nScanBlk, 256, 0, stream>>>(icnt, ioffs, ibsum, kN);
        scan2_kernel<<<1, 64, 0, stream>>>(ibsum, nScanBlk, ioffs, kN);
        scan3_kernel<<<nScanBlk, 256, 0, stream>>>(icnt, ioffs, ibsum, icur, deg, kN);
        csrfill_edgew_kernel<<<CDIV(kE, 256), 256, 0, stream>>>(
            gsrc[gi], gdst[gi], icur, icsr, deg, wsum, kE);
        // hw1 = x @ gW1: S=1 direct write (782 blocks), no epilogue
        gemm64_gcn<<<dim3(1, CDIV(kN, 64), 1), 256, 0, stream>>>(
            gx[gi], gwt_h, gwt_l, hw1, kN, kGH, kH, 1);
        spmm_gather_kernel<<<CDIV(kN, 2), 256, 0, stream>>>(ioffs, icsr, deg, hw1, gb1, agg, kN);
        wreduce_kernel<<<512, 256, 0, stream>>>(agg, wsum, deg, svec, kN);
        gcn_final_kernel<<<1, kGH, 0, stream>>>(svec, gW2, gb2, gout[gi]);
    }

    // ---------- BERT ----------
    embed_ln_kernel<<<kS, 256, 0, stream>>>(input_ids, type_ids, attn_mask,
                                            word_emb, pos_emb, type_emb,
                                            eln_s, eln_b, h, hh_h, hh_l, mb);
    for (int l = 0; l < kL; l++) {
        const float* bq_l = bq + (size_t)l * kH;
        const float* bk_l = bk + (size_t)l * kH;
        const float* bv_l = bv + (size_t)l * kH;
        const float* bo_l = bo + (size_t)l * kH;
        const float* b1_l = b1 + (size_t)l * kF;
        const float* b2_l = b2 + (size_t)l * kH;
        const float* l1s_l = l1s + (size_t)l * kH; const float* l1b_l = l1b + (size_t)l * kH;
        const float* l2s_l = l2s + (size_t)l * kH; const float* l2b_l = l2b + (size_t)l * kH;
        const short* qkvh_l = qkv_h + (size_t)l * 3 * QKV_SZ;
        const short* qkvl_l = qkv_l + (size_t)l * 3 * QKV_SZ;
        const short* woh_l = wo_h + (size_t)l * QKV_SZ;
        const short* wol_l = wo_l + (size_t)l * QKV_SZ;
        const short* w1h_l = w1_h + (size_t)l * FF_SZ;
        const short* w1l_l = w1_l + (size_t)l * FF_SZ;
        const short* w2h_l = w2_h + (size_t)l * FF_SZ;
        const short* w2l_l = w2_l + (size_t)l * FF_SZ;

        // QKV: S=4, 3 weights -> 576 blocks, 12 partials
        gemm64_pre<<<dim3(kH / 128, kS / 64, 12), 256, 0, stream>>>(
            hh_h, hh_l, qkvh_l, qkvl_l, (long)QKV_SZ, part, kS, kH, kH, 4);
        splitk_epi_qkv_kernel<<<dim3((int)(MN_H / 4 / 256), 3), 256, 0, stream>>>(
            part, Ptr3{{bq_l, bk_l, bv_l}}, q_h, q_l, k_h, k_l, v_h, v_l, 4);
        vtrans_kernel<<<dim3(kS / 32, kNH * 2), 256, 0, stream>>>(v_h, v_l, vt_h, vt_l);
        // scores: 64q x 128k tiles -> 384 blocks
        attn_scores64_kernel<<<dim3(kS / 128, kS / 64, kNH), 256, 0, stream>>>(
            q_h, q_l, k_h, k_l, mb, scores);
        softmax_split_kernel<<<kNH * kS, 256, 0, stream>>>(scores, p_h, p_l);
        // ctx: K-split 8 -> 384 blocks
        attn_ctx64_kernel<<<dim3(kS / 128, kNH * 8), 256, 0, stream>>>(p_h, p_l, vt_h, vt_l, part);
        splitk_epi_sh_kernel<<<(int)(MN_H / 4 / 256), 256, 0, stream>>>(
            part, nullptr, ctx_h, ctx_l, MN_H, kH, 8, 0);
        // Wo: S=8 -> 384 blocks; fused epi+bias+residual+LN
        gemm64_pre<<<dim3(kH / 128, kS / 64, 8), 256, 0, stream>>>(
            ctx_h, ctx_l, woh_l, wol_l, 0, part, kS, kH, kH, 8);
        splitk_epi_ln2_kernel<<<kS, 256, 0, stream>>>(part, bo_l, h, l1s_l, l1b_l, h1, h1_h, h1_l, 8);
        // FFN1: S=4 -> 768 blocks, gelu
        gemm64_pre<<<dim3(kF / 128, kS / 64, 4), 256, 0, stream>>>(
            h1_h, h1_l, w1h_l, w1l_l, 0, part, kS, kF, kH, 4);
        splitk_epi_sh_kernel<<<(int)(MN_F / 4 / 256), 256, 0, stream>>>(
            part, b1_l, ffn1_h, ffn1_l, MN_F, kF, 4, 1);
        // FFN2: S=8 -> 384 blocks; fused epi+bias+residual+LN
        gemm64_pre<<<dim3(kH / 128, kS / 64, 8), 256, 0, stream>>>(
            ffn1_h, ffn1_l, w2h_l, w2l_l, 0, part, kS, kH, kF, 8);
        splitk_epi_ln2_kernel<<<kS, 256, 0, stream>>>(part, b2_l, h1, l2s_l, l2b_l, h, hh_h, hh_l, 8);
    }

    // ---------- combine + classifier ----------
    fill_kernel<<<3, 256, 0, stream>>>(feat, 0.f, kH);
    combine_part_kernel<<<56, 256, 0, stream>>>(h, gp, ghv, cW, feat);
    combine_fin_kernel<<<3, 256, 0, stream>>>(feat, cb);
    cls_head_kernel<<<1, 256, 0, stream>>>(feat, clsW, clsB, out);
}

// Round 10
// 2418.496 us; speedup vs baseline: 1.7955x; 1.0145x over previous
//
#include <hip/hip_runtime.h>
#include <math.h>

// Problem constants
constexpr int kS = 512, kH = 768, kNH = 12, kDH = 64, kF = 3072, kL = 12;
constexpr int kN = 50000, kE = 800000, kGH = 128;

#define CDIV(a,b) (((a)+(b)-1)/(b))

struct Ptr3 { const float* p[3]; };

typedef __attribute__((ext_vector_type(8))) short bf16x8;
typedef __attribute__((ext_vector_type(4))) float f32x4;

__device__ __forceinline__ unsigned short bf16_rne(float f) {
    unsigned int u = __float_as_uint(f);
    u += 0x7fffu + ((u >> 16) & 1u);
    return (unsigned short)(u >> 16);
}
__device__ __forceinline__ float bf16_f32(unsigned short h) {
    return __uint_as_float(((unsigned int)h) << 16);
}
__device__ __forceinline__ void split2(float f, short& hi, short& lo) {
    unsigned short h = bf16_rne(f);
    hi = (short)h;
    lo = (short)bf16_rne(f - bf16_f32(h));
}

constexpr int LDR = 72;  // LDS row: 32 hi | 32 lo | 8 pad shorts (144 B)

// ---------------- generic fill ----------------
__global__ void fill_kernel(float* p, float v, long n) {
    long i = blockIdx.x * (long)blockDim.x + threadIdx.x;
    if (i < n) p[i] = v;
}

// ---------------- GCN per-graph zero init ----------------
__global__ void gcn_zero_kernel(int* icnt, float* wsum, float* svec) {
    int i = blockIdx.x * 256 + threadIdx.x;
    if (i < kN) { icnt[i] = 0; wsum[i] = 0.f; }
    if (i < kGH) svec[i] = 0.f;
}

// ---------------- embeddings + LN (+ hi/lo emit, + maskbias fold) ----------------
__global__ void embed_ln_kernel(const int* ids, const int* tt, const int* mask,
                                const float* we, const float* pe, const float* te,
                                const float* g, const float* b, float* out,
                                short* oh, short* ol, float* mb) {
    int s = blockIdx.x;
    int tid = threadIdx.x;
    __shared__ float red[256];
    if (tid == 0) mb[s] = (1.f - (float)mask[s]) * -1e4f;
    int id = ids[s], t = tt[s];
    float vals[3]; float sum = 0.f;
    #pragma unroll
    for (int r = 0; r < 3; r++) {
        int j = tid + r * 256;
        float x = we[(long)id * kH + j] + pe[(long)s * kH + j] + te[(long)t * kH + j];
        vals[r] = x; sum += x;
    }
    red[tid] = sum; __syncthreads();
    for (int off = 128; off > 0; off >>= 1) { if (tid < off) red[tid] += red[tid + off]; __syncthreads(); }
    float mean = red[0] / kH; __syncthreads();
    float vs = 0.f;
    #pragma unroll
    for (int r = 0; r < 3; r++) { float d = vals[r] - mean; vs += d * d; }
    red[tid] = vs; __syncthreads();
    for (int off = 128; off > 0; off >>= 1) { if (tid < off) red[tid] += red[tid + off]; __syncthreads(); }
    float rstd = rsqrtf(red[0] / kH + 1e-12f);
    #pragma unroll
    for (int r = 0; r < 3; r++) {
        int j = tid + r * 256;
        float o = (vals[r] - mean) * rstd * g[j] + b[j];
        out[(long)s * kH + j] = o;
        short hi, lo; split2(o, hi, lo);
        oh[(long)s * kH + j] = hi; ol[(long)s * kH + j] = lo;
    }
}

// ---------------- batched weight transpose + split ----------------
__global__ void wtrans_all_kernel(const float* __restrict__ W, short* __restrict__ Th,
                                  short* __restrict__ Tl, int K, int N, long ostride) {
    int z = blockIdx.z;
    const float* Wm = W + (long)z * K * N;
    long moff = (long)z * ostride;
    __shared__ short th[32][33], tl[32][33];
    int n0 = blockIdx.x * 32, k0 = blockIdx.y * 32;
    int c = threadIdx.x & 31, r = threadIdx.x >> 5;
    #pragma unroll
    for (int p = 0; p < 4; p++) {
        int rr = p * 8 + r;
        float f = Wm[(long)(k0 + rr) * N + n0 + c];
        short hi, lo; split2(f, hi, lo);
        th[rr][c] = hi; tl[rr][c] = lo;
    }
    __syncthreads();
    #pragma unroll
    for (int p = 0; p < 4; p++) {
        int rr = p * 8 + r;
        Th[moff + (long)(n0 + rr) * K + k0 + c] = th[c][rr];
        Tl[moff + (long)(n0 + rr) * K + k0 + c] = tl[c][rr];
    }
}

// ---------------- V transpose: v[s][kH] (head slices) -> vt[h][d][s] ----------------
__global__ void vtrans_kernel(const short* __restrict__ vh, const short* __restrict__ vl,
                              short* __restrict__ vth, short* __restrict__ vtl) {
    __shared__ short th[32][33], tl[32][33];
    int s0 = blockIdx.x * 32;
    int h = blockIdx.y >> 1, d0 = (blockIdx.y & 1) * 32;
    int c = threadIdx.x & 31, r = threadIdx.x >> 5;
    #pragma unroll
    for (int p = 0; p < 4; p++) {
        int rr = p * 8 + r;
        th[rr][c] = vh[(long)(s0 + rr) * kH + h * kDH + d0 + c];
        tl[rr][c] = vl[(long)(s0 + rr) * kH + h * kDH + d0 + c];
    }
    __syncthreads();
    #pragma unroll
    for (int p = 0; p < 4; p++) {
        int rr = p * 8 + r;
        vth[((long)h * kDH + d0 + rr) * kS + s0 + c] = th[c][rr];
        vtl[((long)h * kDH + d0 + rr) * kS + s0 + c] = tl[c][rr];
    }
}

// ======== 64x128-tile pre-split MFMA GEMM, register-prefetch double-buffered ========
__global__ __launch_bounds__(256, 4) void gemm64_pre(
    const short* __restrict__ Ah, const short* __restrict__ Al,
    const short* __restrict__ Bth, const short* __restrict__ Btl, long wstride,
    float* __restrict__ part, int M, int Nn, int K, int S)
{
    __shared__ short As[64 * LDR], Bs[128 * LDR];  // 27648 B
    int w = blockIdx.z / S, s = blockIdx.z % S;
    const short* Bh_ = Bth + (long)w * wstride;
    const short* Bl_ = Btl + (long)w * wstride;
    int Kc = K / S, kbeg = s * Kc;
    int m0 = blockIdx.y * 64, n0 = blockIdx.x * 128;
    int tid = threadIdx.x;
    int ar = tid >> 2, aq = (tid & 3) * 8;
    const short* Agh = Ah + (long)(m0 + ar) * K + kbeg + aq;
    const short* Agl = Al + (long)(m0 + ar) * K + kbeg + aq;
    int aofs = ar * LDR + aq;
    int br = tid >> 1, bq = (tid & 1) * 16;
    const short* Bgh = Bh_ + (long)(n0 + br) * K + kbeg + bq;
    const short* Bgl = Bl_ + (long)(n0 + br) * K + kbeg + bq;
    int bofs = br * LDR + bq;
    int wid = tid >> 6, lane = tid & 63;
    int wm = (wid >> 1) * 32, wn = (wid & 1) * 64;
    int fr = lane & 15, ko = (lane >> 4) * 8;
    f32x4 acc[2][4];
    #pragma unroll
    for (int i = 0; i < 2; i++)
        #pragma unroll
        for (int j = 0; j < 4; j++) acc[i][j] = (f32x4){0.f, 0.f, 0.f, 0.f};
    int nst = Kc / 32;
    bf16x8 pa0 = *(const bf16x8*)(Agh);
    bf16x8 pa1 = *(const bf16x8*)(Agl);
    bf16x8 pb0 = *(const bf16x8*)(Bgh);
    bf16x8 pb1 = *(const bf16x8*)(Bgh + 8);
    bf16x8 pb2 = *(const bf16x8*)(Bgl);
    bf16x8 pb3 = *(const bf16x8*)(Bgl + 8);
    for (int st = 0; st < nst; ++st) {
        *(bf16x8*)&As[aofs]      = pa0;
        *(bf16x8*)&As[aofs + 32] = pa1;
        *(bf16x8*)&Bs[bofs]      = pb0;
        *(bf16x8*)&Bs[bofs + 8]  = pb1;
        *(bf16x8*)&Bs[bofs + 32] = pb2;
        *(bf16x8*)&Bs[bofs + 40] = pb3;
        if (st + 1 < nst) {
            int go = (st + 1) * 32;
            pa0 = *(const bf16x8*)(Agh + go);
            pa1 = *(const bf16x8*)(Agl + go);
            pb0 = *(const bf16x8*)(Bgh + go);
            pb1 = *(const bf16x8*)(Bgh + go + 8);
            pb2 = *(const bf16x8*)(Bgl + go);
            pb3 = *(const bf16x8*)(Bgl + go + 8);
        }
        __syncthreads();
        bf16x8 bh[4], bl[4];
        #pragma unroll
        for (int j = 0; j < 4; j++) {
            int c = (wn + j * 16 + fr) * LDR + ko;
            bh[j] = *(const bf16x8*)&Bs[c];
            bl[j] = *(const bf16x8*)&Bs[c + 32];
        }
        #pragma unroll
        for (int i = 0; i < 2; i++) {
            int r = (wm + i * 16 + fr) * LDR + ko;
            bf16x8 ah = *(const bf16x8*)&As[r];
            bf16x8 al = *(const bf16x8*)&As[r + 32];
            #pragma unroll
            for (int j = 0; j < 4; j++) {
                acc[i][j] = __builtin_amdgcn_mfma_f32_16x16x32_bf16(ah, bh[j], acc[i][j], 0, 0, 0);
                acc[i][j] = __builtin_amdgcn_mfma_f32_16x16x32_bf16(ah, bl[j], acc[i][j], 0, 0, 0);
                acc[i][j] = __builtin_amdgcn_mfma_f32_16x16x32_bf16(al, bh[j], acc[i][j], 0, 0, 0);
            }
        }
        __syncthreads();
    }
    long MN = (long)M * Nn;
    float* Pp = part + (long)(w * S + s) * MN;
    int cr = (lane >> 4) * 4;
    #pragma unroll
    for (int i = 0; i < 2; i++) {
        #pragma unroll
        for (int r = 0; r < 4; r++) {
            int gm = m0 + wm + i * 16 + cr + r;
            float* rowp = &Pp[(long)gm * Nn + n0 + wn + fr];
            #pragma unroll
            for (int j = 0; j < 4; j++) rowp[j * 16] = acc[i][j][r];
        }
    }
}

// ======== GCN GEMM: A fp32 inline-split (prefetched), B pre-split; S=1 direct ========
__global__ __launch_bounds__(256, 4) void gemm64_gcn(
    const float* __restrict__ A,
    const short* __restrict__ Bth, const short* __restrict__ Btl,
    float* __restrict__ part, int M, int Nn, int K, int S)
{
    __shared__ short As[64 * LDR], Bs[128 * LDR];
    int s = blockIdx.z;
    int Kc = K / S, kbeg = s * Kc;
    int m0 = blockIdx.y * 64, n0 = blockIdx.x * 128;
    int tid = threadIdx.x;
    int ar = tid >> 2, aqf = (tid & 3) * 8;
    int gmA = m0 + ar; if (gmA > M - 1) gmA = M - 1;
    const float* Agf = A + (long)gmA * K + kbeg + aqf;
    int aofs = ar * LDR + aqf;
    int br = tid >> 1, bq = (tid & 1) * 16;
    const short* Bgh = Bth + (long)(n0 + br) * K + kbeg + bq;
    const short* Bgl = Btl + (long)(n0 + br) * K + kbeg + bq;
    int bofs = br * LDR + bq;
    int wid = tid >> 6, lane = tid & 63;
    int wm = (wid >> 1) * 32, wn = (wid & 1) * 64;
    int fr = lane & 15, ko = (lane >> 4) * 8;
    f32x4 acc[2][4];
    #pragma unroll
    for (int i = 0; i < 2; i++)
        #pragma unroll
        for (int j = 0; j < 4; j++) acc[i][j] = (f32x4){0.f, 0.f, 0.f, 0.f};
    int nst = Kc / 32;
    float4 pf0 = *(const float4*)(Agf);
    float4 pf1 = *(const float4*)(Agf + 4);
    bf16x8 pb0 = *(const bf16x8*)(Bgh);
    bf16x8 pb1 = *(const bf16x8*)(Bgh + 8);
    bf16x8 pb2 = *(const bf16x8*)(Bgl);
    bf16x8 pb3 = *(const bf16x8*)(Bgl + 8);
    for (int st = 0; st < nst; ++st) {
        short h0, l0, h1, l1, h2, l2, h3, l3, h4, l4, h5, l5, h6, l6, h7, l7;
        split2(pf0.x, h0, l0); split2(pf0.y, h1, l1); split2(pf0.z, h2, l2); split2(pf0.w, h3, l3);
        split2(pf1.x, h4, l4); split2(pf1.y, h5, l5); split2(pf1.z, h6, l6); split2(pf1.w, h7, l7);
        *(short4*)&As[aofs]      = make_short4(h0, h1, h2, h3);
        *(short4*)&As[aofs + 4]  = make_short4(h4, h5, h6, h7);
        *(short4*)&As[aofs + 32] = make_short4(l0, l1, l2, l3);
        *(short4*)&As[aofs + 36] = make_short4(l4, l5, l6, l7);
        *(bf16x8*)&Bs[bofs]      = pb0;
        *(bf16x8*)&Bs[bofs + 8]  = pb1;
        *(bf16x8*)&Bs[bofs + 32] = pb2;
        *(bf16x8*)&Bs[bofs + 40] = pb3;
        if (st + 1 < nst) {
            int go = (st + 1) * 32;
            pf0 = *(const float4*)(Agf + go);
            pf1 = *(const float4*)(Agf + go + 4);
            pb0 = *(const bf16x8*)(Bgh + go);
            pb1 = *(const bf16x8*)(Bgh + go + 8);
            pb2 = *(const bf16x8*)(Bgl + go);
            pb3 = *(const bf16x8*)(Bgl + go + 8);
        }
        __syncthreads();
        bf16x8 bh[4], bl[4];
        #pragma unroll
        for (int j = 0; j < 4; j++) {
            int c = (wn + j * 16 + fr) * LDR + ko;
            bh[j] = *(const bf16x8*)&Bs[c];
            bl[j] = *(const bf16x8*)&Bs[c + 32];
        }
        #pragma unroll
        for (int i = 0; i < 2; i++) {
            int r = (wm + i * 16 + fr) * LDR + ko;
            bf16x8 ah = *(const bf16x8*)&As[r];
            bf16x8 al = *(const bf16x8*)&As[r + 32];
            #pragma unroll
            for (int j = 0; j < 4; j++) {
                acc[i][j] = __builtin_amdgcn_mfma_f32_16x16x32_bf16(ah, bh[j], acc[i][j], 0, 0, 0);
                acc[i][j] = __builtin_amdgcn_mfma_f32_16x16x32_bf16(ah, bl[j], acc[i][j], 0, 0, 0);
                acc[i][j] = __builtin_amdgcn_mfma_f32_16x16x32_bf16(al, bh[j], acc[i][j], 0, 0, 0);
            }
        }
        __syncthreads();
    }
    long MN = (long)M * Nn;
    float* Pp = part + (long)s * MN;
    int cr = (lane >> 4) * 4;
    #pragma unroll
    for (int i = 0; i < 2; i++) {
        #pragma unroll
        for (int r = 0; r < 4; r++) {
            int gm = m0 + wm + i * 16 + cr + r;
            if (gm >= M) continue;
            float* rowp = &Pp[(long)gm * Nn + n0 + wn + fr];
            #pragma unroll
            for (int j = 0; j < 4; j++) rowp[j * 16] = acc[i][j][r];
        }
    }
}

// ======== fused flash attention: per (q-block 64, head), 2 waves ========
// out ctx hi/lo directly. Q,K pre-split [s][kH]; V pre-transposed [h][d][s].
__global__ __launch_bounds__(128) void flash_attn_kernel(
    const short* __restrict__ qh, const short* __restrict__ ql,
    const short* __restrict__ kh, const short* __restrict__ kl,
    const short* __restrict__ vth, const short* __restrict__ vtl,
    const float* __restrict__ mb,
    short* __restrict__ ctxh, short* __restrict__ ctxl)
{
    __shared__ short Qs[2 * 64 * LDR];   // [dseg][qrow][32hi|32lo|8pad] = 18432 B
    __shared__ short Ks[128 * LDR];      // K (kv rows) or V (d rows) per k-step = 18432 B
    __shared__ short Ps[4 * 64 * 40];    // [kvseg][qrow][32+8pad] single comp = 20480 B
    int h = blockIdx.y;
    int q0 = blockIdx.x * 64;
    int tid = threadIdx.x;               // 128
    int wid = tid >> 6, lane = tid & 63;
    int wm = wid * 32;
    int fr = lane & 15, ko = (lane >> 4) * 8;
    int cr4 = (lane >> 4) * 4;
    // ---- stage Q once: thread = (row, dseg)
    {
        int row = tid >> 1, dseg = tid & 1;
        const short* gh_ = qh + (long)(q0 + row) * kH + h * kDH + dseg * 32;
        const short* gl_ = ql + (long)(q0 + row) * kH + h * kDH + dseg * 32;
        short* dst = &Qs[(dseg * 64 + row) * LDR];
        #pragma unroll
        for (int c = 0; c < 4; c++) {
            *(bf16x8*)&dst[c * 8]      = *(const bf16x8*)(gh_ + c * 8);
            *(bf16x8*)&dst[32 + c * 8] = *(const bf16x8*)(gl_ + c * 8);
        }
    }
    float mrun[2][4], lrun[2][4];
    f32x4 accO[2][4];
    #pragma unroll
    for (int i = 0; i < 2; i++)
        #pragma unroll
        for (int r = 0; r < 4; r++) { mrun[i][r] = -1e30f; lrun[i][r] = 0.f; }
    #pragma unroll
    for (int i = 0; i < 2; i++)
        #pragma unroll
        for (int j = 0; j < 4; j++) accO[i][j] = (f32x4){0.f, 0.f, 0.f, 0.f};

    for (int t = 0; t < 4; ++t) {
        int k0t = t * 128;
        // ---- S = Q K^T over d (2 k-steps of 32) ----
        f32x4 accS[2][8];
        #pragma unroll
        for (int i = 0; i < 2; i++)
            #pragma unroll
            for (int j = 0; j < 8; j++) accS[i][j] = (f32x4){0.f, 0.f, 0.f, 0.f};
        for (int st = 0; st < 2; ++st) {
            __syncthreads();
            {   // stage K tile: 128 kv rows, this d-seg
                int row = tid;
                const short* gh_ = kh + (long)(k0t + row) * kH + h * kDH + st * 32;
                const short* gl_ = kl + (long)(k0t + row) * kH + h * kDH + st * 32;
                short* dst = &Ks[row * LDR];
                #pragma unroll
                for (int c = 0; c < 4; c++) {
                    *(bf16x8*)&dst[c * 8]      = *(const bf16x8*)(gh_ + c * 8);
                    *(bf16x8*)&dst[32 + c * 8] = *(const bf16x8*)(gl_ + c * 8);
                }
            }
            __syncthreads();
            bf16x8 bh[8], bl[8];
            #pragma unroll
            for (int j = 0; j < 8; j++) {
                int c = (j * 16 + fr) * LDR + ko;
                bh[j] = *(const bf16x8*)&Ks[c];
                bl[j] = *(const bf16x8*)&Ks[c + 32];
            }
            #pragma unroll
            for (int i = 0; i < 2; i++) {
                int r = (st * 64 + wm + i * 16 + fr) * LDR + ko;
                bf16x8 ah = *(const bf16x8*)&Qs[r];
                bf16x8 al = *(const bf16x8*)&Qs[r + 32];
                #pragma unroll
                for (int j = 0; j < 8; j++) {
                    accS[i][j] = __builtin_amdgcn_mfma_f32_16x16x32_bf16(ah, bh[j], accS[i][j], 0, 0, 0);
                    accS[i][j] = __builtin_amdgcn_mfma_f32_16x16x32_bf16(ah, bl[j], accS[i][j], 0, 0, 0);
                    accS[i][j] = __builtin_amdgcn_mfma_f32_16x16x32_bf16(al, bh[j], accS[i][j], 0, 0, 0);
                }
            }
        }
        // ---- online softmax (rows owned by 16-lane groups) ----
        float mbv[8];
        #pragma unroll
        for (int j = 0; j < 8; j++) mbv[j] = mb[k0t + j * 16 + fr];
        #pragma unroll
        for (int i = 0; i < 2; i++) {
            #pragma unroll
            for (int r = 0; r < 4; r++) {
                float mt = -1e30f;
                #pragma unroll
                for (int j = 0; j < 8; j++) {
                    float sv = accS[i][j][r] * 0.125f + mbv[j];
                    accS[i][j][r] = sv;
                    mt = fmaxf(mt, sv);
                }
                #pragma unroll
                for (int mmask = 1; mmask < 16; mmask <<= 1)
                    mt = fmaxf(mt, __shfl_xor(mt, mmask, 64));
                float mn = fmaxf(mrun[i][r], mt);
                float sc = __expf(mrun[i][r] - mn);
                mrun[i][r] = mn;
                lrun[i][r] *= sc;
                #pragma unroll
                for (int jo = 0; jo < 4; jo++) {
                    accO[i][jo][r] *= sc;
                }
                float lt = 0.f;
                #pragma unroll
                for (int j = 0; j < 8; j++) {
                    float p = __expf(accS[i][j][r] - mn);
                    accS[i][j][r] = p;
                    lt += p;
                }
                #pragma unroll
                for (int mmask = 1; mmask < 16; mmask <<= 1)
                    lt += __shfl_xor(lt, mmask, 64);
                lrun[i][r] += lt;
            }
        }
        // ---- write P_hi to LDS ----
        #pragma unroll
        for (int i = 0; i < 2; i++)
            #pragma unroll
            for (int j = 0; j < 8; j++)
                #pragma unroll
                for (int r = 0; r < 4; r++) {
                    int rowp = wm + i * 16 + cr4 + r;
                    Ps[(j >> 1) * 2560 + rowp * 40 + (j & 1) * 16 + fr] =
                        (short)bf16_rne(accS[i][j][r]);
                }
        // ---- PV pass 1: Ph*(Vh+Vl), 4 k-steps of 32 kv ----
        for (int st2 = 0; st2 < 4; ++st2) {
            __syncthreads();
            {   // stage V: 64 d rows x 32 kv (this k-step)
                int row = tid >> 1, half = tid & 1;
                const short* gh_ = vth + ((long)h * kDH + row) * kS + k0t + st2 * 32 + half * 16;
                const short* gl_ = vtl + ((long)h * kDH + row) * kS + k0t + st2 * 32 + half * 16;
                short* dst = &Ks[row * LDR + half * 16];
                *(bf16x8*)&dst[0]  = *(const bf16x8*)(gh_);
                *(bf16x8*)&dst[8]  = *(const bf16x8*)(gh_ + 8);
                *(bf16x8*)&dst[32] = *(const bf16x8*)(gl_);
                *(bf16x8*)&dst[40] = *(const bf16x8*)(gl_ + 8);
            }
            __syncthreads();
            bf16x8 vh_[4], vl_[4];
            #pragma unroll
            for (int j = 0; j < 4; j++) {
                int c = (j * 16 + fr) * LDR + ko;
                vh_[j] = *(const bf16x8*)&Ks[c];
                vl_[j] = *(const bf16x8*)&Ks[c + 32];
            }
            #pragma unroll
            for (int i = 0; i < 2; i++) {
                bf16x8 pa = *(const bf16x8*)&Ps[st2 * 2560 + (wm + i * 16 + fr) * 40 + ko];
                #pragma unroll
                for (int j = 0; j < 4; j++) {
                    accO[i][j] = __builtin_amdgcn_mfma_f32_16x16x32_bf16(pa, vh_[j], accO[i][j], 0, 0, 0);
                    accO[i][j] = __builtin_amdgcn_mfma_f32_16x16x32_bf16(pa, vl_[j], accO[i][j], 0, 0, 0);
                }
            }
        }
        __syncthreads();
        // ---- write P_lo, PV pass 2: Pl*Vh ----
        #pragma unroll
        for (int i = 0; i < 2; i++)
            #pragma unroll
            for (int j = 0; j < 8; j++)
                #pragma unroll
                for (int r = 0; r < 4; r++) {
                    int rowp = wm + i * 16 + cr4 + r;
                    float p = accS[i][j][r];
                    unsigned short ph = bf16_rne(p);
                    Ps[(j >> 1) * 2560 + rowp * 40 + (j & 1) * 16 + fr] =
                        (short)bf16_rne(p - bf16_f32(ph));
                }
        for (int st2 = 0; st2 < 4; ++st2) {
            __syncthreads();
            {
                int row = tid >> 1, half = tid & 1;
                const short* gh_ = vth + ((long)h * kDH + row) * kS + k0t + st2 * 32 + half * 16;
                short* dst = &Ks[row * LDR + half * 16];
                *(bf16x8*)&dst[0] = *(const bf16x8*)(gh_);
                *(bf16x8*)&dst[8] = *(const bf16x8*)(gh_ + 8);
            }
            __syncthreads();
            bf16x8 vh_[4];
            #pragma unroll
            for (int j = 0; j < 4; j++)
                vh_[j] = *(const bf16x8*)&Ks[(j * 16 + fr) * LDR + ko];
            #pragma unroll
            for (int i = 0; i < 2; i++) {
                bf16x8 pa = *(const bf16x8*)&Ps[st2 * 2560 + (wm + i * 16 + fr) * 40 + ko];
                #pragma unroll
                for (int j = 0; j < 4; j++)
                    accO[i][j] = __builtin_amdgcn_mfma_f32_16x16x32_bf16(pa, vh_[j], accO[i][j], 0, 0, 0);
            }
        }
        __syncthreads();   // protect Ps/Ks before next tile
    }
    // ---- finalize: out = accO / l, write ctx hi/lo ----
    #pragma unroll
    for (int i = 0; i < 2; i++) {
        #pragma unroll
        for (int r = 0; r < 4; r++) {
            float inv = 1.f / lrun[i][r];
            int q = q0 + wm + i * 16 + cr4 + r;
            #pragma unroll
            for (int j = 0; j < 4; j++) {
                float o = accO[i][j][r] * inv;
                int col = h * kDH + j * 16 + fr;
                short hi, lo; split2(o, hi, lo);
                ctxh[(long)q * kH + col] = hi;
                ctxl[(long)q * kH + col] = lo;
            }
        }
    }
}

// ---------------- QKV epilogue: sum partials + bias -> hi/lo shorts ----------------
__global__ void splitk_epi_qkv_kernel(const float* __restrict__ part, Ptr3 bias,
                                      short* __restrict__ qh, short* __restrict__ ql,
                                      short* __restrict__ kh, short* __restrict__ kl,
                                      short* __restrict__ vh, short* __restrict__ vl,
                                      int S) {
    const long MN = (long)kS * kH;
    int w = blockIdx.y;
    long i = ((long)blockIdx.x * blockDim.x + threadIdx.x) * 4;
    if (i >= MN) return;
    const float* P = part + (long)w * S * MN + i;
    float4 a = *(const float4*)P;
    for (int s2 = 1; s2 < S; ++s2) {
        float4 b2 = *(const float4*)(P + (long)s2 * MN);
        a.x += b2.x; a.y += b2.y; a.z += b2.z; a.w += b2.w;
    }
    const float* bw = bias.p[w];
    int n = (int)(i % kH);
    a.x += bw[n]; a.y += bw[n + 1]; a.z += bw[n + 2]; a.w += bw[n + 3];
    short* oh = (w == 0) ? qh : (w == 1) ? kh : vh;
    short* ol = (w == 0) ? ql : (w == 1) ? kl : vl;
    short h0, l0, h1, l1, h2, l2, h3, l3;
    split2(a.x, h0, l0); split2(a.y, h1, l1); split2(a.z, h2, l2); split2(a.w, h3, l3);
    *(short4*)&oh[i] = make_short4(h0, h1, h2, h3);
    *(short4*)&ol[i] = make_short4(l0, l1, l2, l3);
}

// ---------------- generic epilogue: sum partials (+bias, +act) -> hi/lo shorts ----------------
__global__ void splitk_epi_sh_kernel(const float* __restrict__ part, const float* __restrict__ bias,
                                     short* __restrict__ oh, short* __restrict__ ol,
                                     long MN, int Nn, int S, int act) {
    long i = ((long)blockIdx.x * blockDim.x + threadIdx.x) * 4;
    if (i >= MN) return;
    const float* P = part + i;
    float4 a = *(const float4*)P;
    for (int s2 = 1; s2 < S; ++s2) {
        float4 b2 = *(const float4*)(P + (long)s2 * MN);
        a.x += b2.x; a.y += b2.y; a.z += b2.z; a.w += b2.w;
    }
    if (bias) {
        int n = (int)(i % Nn);
        a.x += bias[n]; a.y += bias[n + 1]; a.z += bias[n + 2]; a.w += bias[n + 3];
    }
    if (act == 1) {
        a.x = 0.5f * a.x * (1.f + erff(a.x * 0.70710678118654752f));
        a.y = 0.5f * a.y * (1.f + erff(a.y * 0.70710678118654752f));
        a.z = 0.5f * a.z * (1.f + erff(a.z * 0.70710678118654752f));
        a.w = 0.5f * a.w * (1.f + erff(a.w * 0.70710678118654752f));
    }
    short h0, l0, h1, l1, h2, l2, h3, l3;
    split2(a.x, h0, l0); split2(a.y, h1, l1); split2(a.z, h2, l2); split2(a.w, h3, l3);
    *(short4*)&oh[i] = make_short4(h0, h1, h2, h3);
    *(short4*)&ol[i] = make_short4(l0, l1, l2, l3);
}

// ---------------- fused split-K + bias + residual + LN -> fp32 + hi/lo ----------------
__global__ void splitk_epi_ln2_kernel(const float* __restrict__ part, const float* __restrict__ bias,
                                      const float* __restrict__ res, const float* __restrict__ g,
                                      const float* __restrict__ b, float* __restrict__ out,
                                      short* __restrict__ oh, short* __restrict__ ol, int S) {
    int row = blockIdx.x; int tid = threadIdx.x;
    __shared__ float red[256];
    const long MN = (long)kS * kH;
    float vals[3]; float sum = 0.f;
    #pragma unroll
    for (int r = 0; r < 3; r++) {
        int j = tid + r * 256;
        const float* P = part + (long)row * kH + j;
        float x = res[(long)row * kH + j] + bias[j];
        for (int s2 = 0; s2 < S; ++s2) x += P[(long)s2 * MN];
        vals[r] = x; sum += x;
    }
    red[tid] = sum; __syncthreads();
    for (int off = 128; off > 0; off >>= 1) { if (tid < off) red[tid] += red[tid + off]; __syncthreads(); }
    float mean = red[0] / kH; __syncthreads();
    float vs = 0.f;
    #pragma unroll
    for (int r = 0; r < 3; r++) { float d = vals[r] - mean; vs += d * d; }
    red[tid] = vs; __syncthreads();
    for (int off = 128; off > 0; off >>= 1) { if (tid < off) red[tid] += red[tid + off]; __syncthreads(); }
    float rstd = rsqrtf(red[0] / kH + 1e-12f);
    #pragma unroll
    for (int r = 0; r < 3; r++) {
        int j = tid + r * 256;
        float o = (vals[r] - mean) * rstd * g[j] + b[j];
        out[(long)row * kH + j] = o;
        short hi, lo; split2(o, hi, lo);
        oh[(long)row * kH + j] = hi; ol[(long)row * kH + j] = lo;
    }
}

// ---------------- GCN sparse kernels ----------------
__global__ void cnt_kernel(const int* __restrict__ dst, int* __restrict__ cnt, int E) {
    int e = blockIdx.x * blockDim.x + threadIdx.x;
    if (e < E) atomicAdd(&cnt[dst[e]], 1);
}

__global__ void scan1_kernel(const int* __restrict__ cnt, int* __restrict__ offs,
                             int* __restrict__ bsum, int n) {
    __shared__ int sh[256];
    int i = blockIdx.x * 256 + threadIdx.x;
    int v = (i < n) ? cnt[i] : 0;
    sh[threadIdx.x] = v; __syncthreads();
    for (int off = 1; off < 256; off <<= 1) {
        int t = (threadIdx.x >= off) ? sh[threadIdx.x - off] : 0;
        __syncthreads();
        sh[threadIdx.x] += t;
        __syncthreads();
    }
    if (i < n) offs[i] = sh[threadIdx.x] - v;
    if (threadIdx.x == 255) bsum[blockIdx.x] = sh[255];
}

__global__ void scan2_kernel(int* bsum, int nb, int* offs, int n) {
    if (threadIdx.x == 0) {
        int run = 0;
        for (int b = 0; b < nb; b++) { int t = bsum[b]; bsum[b] = run; run += t; }
        offs[n] = run;
    }
}

__global__ void scan3_kernel(const int* __restrict__ cnt, int* __restrict__ offs,
                             const int* __restrict__ bsum, int* __restrict__ cur,
                             float* __restrict__ dinv, int n) {
    int i = blockIdx.x * 256 + threadIdx.x;
    if (i >= n) return;
    int o = offs[i] + bsum[blockIdx.x];
    offs[i] = o; cur[i] = o;
    dinv[i] = rsqrtf((float)(cnt[i] + 1));
}

__global__ void csrfill_edgew_kernel(const int* __restrict__ src, const int* __restrict__ dst,
                                     int* __restrict__ cur, int* __restrict__ csr,
                                     const float* __restrict__ dinv, float* __restrict__ wsum,
                                     int E) {
    int e = blockIdx.x * blockDim.x + threadIdx.x;
    if (e < E) {
        int s2 = src[e], d = dst[e];
        int slot = atomicAdd(&cur[d], 1);
        csr[slot] = s2;
        atomicAdd(&wsum[s2], dinv[s2] * dinv[d]);
    }
}

// gather SpMM + fused self-loop/bias/relu, 8-way ILP unroll
__global__ __launch_bounds__(256) void spmm_gather_kernel(const int* __restrict__ offs,
                                                          const int* __restrict__ csr,
                                                          const float* __restrict__ dinv,
                                                          const float* __restrict__ hw,
                                                          const float* __restrict__ b1,
                                                          float* __restrict__ hout, int n) {
    int d = blockIdx.x * 2 + (threadIdx.x >> 7);
    int j = threadIdx.x & 127;
    if (d >= n) return;
    int beg = offs[d], end = offs[d + 1];
    float a0 = 0.f, a1 = 0.f, a2 = 0.f, a3 = 0.f;
    float a4 = 0.f, a5 = 0.f, a6 = 0.f, a7 = 0.f;
    int p = beg;
    for (; p + 8 <= end; p += 8) {
        int s0 = csr[p], s1 = csr[p + 1], s2 = csr[p + 2], s3 = csr[p + 3];
        int s4 = csr[p + 4], s5 = csr[p + 5], s6 = csr[p + 6], s7 = csr[p + 7];
        a0 += dinv[s0] * hw[(long)s0 * kGH + j];
        a1 += dinv[s1] * hw[(long)s1 * kGH + j];
        a2 += dinv[s2] * hw[(long)s2 * kGH + j];
        a3 += dinv[s3] * hw[(long)s3 * kGH + j];
        a4 += dinv[s4] * hw[(long)s4 * kGH + j];
        a5 += dinv[s5] * hw[(long)s5 * kGH + j];
        a6 += dinv[s6] * hw[(long)s6 * kGH + j];
        a7 += dinv[s7] * hw[(long)s7 * kGH + j];
    }
    for (; p < end; ++p) {
        int s8 = csr[p];
        a0 += dinv[s8] * hw[(long)s8 * kGH + j];
    }
    float acc = ((a0 + a1) + (a2 + a3)) + ((a4 + a5) + (a6 + a7));
    float dd = dinv[d];
    float v = acc * dd + dd * dd * hw[(long)d * kGH + j] + b1[j];
    hout[(long)d * kGH + j] = fmaxf(v, 0.f);
}

__global__ void wreduce_kernel(const float* __restrict__ h, const float* __restrict__ w,
                               const float* __restrict__ dinv, float* __restrict__ s, int n) {
    int tid = threadIdx.x; int j = tid & 127; int half = tid >> 7;
    float acc = 0.f;
    for (int u = blockIdx.x * 2 + half; u < n; u += gridDim.x * 2) {
        float di = dinv[u];
        acc += (w[u] + di * di) * h[(long)u * kGH + j];
    }
    __shared__ float red[256];
    red[tid] = acc; __syncthreads();
    if (tid < 128) atomicAdd(&s[j], red[tid] + red[tid + 128]);
}

__global__ void gcn_final_kernel(const float* s, const float* W2, const float* b2, float* g) {
    int j2 = threadIdx.x;
    float acc = 0.f;
    for (int j = 0; j < kGH; j++) acc += s[j] * W2[(long)j * kGH + j2];
    g[j2] = acc * (1.f / (float)kN) + b2[j2];
}

// ---------------- combine head ----------------
__global__ void combine_part_kernel(const float* __restrict__ cls, const float* __restrict__ gp,
                                    const float* __restrict__ gh, const float* __restrict__ Wc,
                                    float* __restrict__ feat) {
    int i0 = blockIdx.x * 32;
    int tid = threadIdx.x;
    float a0 = 0.f, a1 = 0.f, a2 = 0.f;
    for (int r = 0; r < 32; r++) {
        int i = i0 + r;
        float x = (i < 768) ? cls[i] : (i < 896) ? gp[i - 768]
                : (i < 1664) ? cls[i - 896] : gh[i - 1664];
        const float* row = Wc + (long)i * kH;
        a0 += x * row[tid]; a1 += x * row[tid + 256]; a2 += x * row[tid + 512];
    }
    atomicAdd(&feat[tid], a0);
    atomicAdd(&feat[tid + 256], a1);
    atomicAdd(&feat[tid + 512], a2);
}

__global__ void combine_fin_kernel(float* feat, const float* bc) {
    int o = blockIdx.x * 256 + threadIdx.x;
    if (o < kH) feat[o] = fmaxf(feat[o] + bc[o], 0.f);
}

__global__ void cls_head_kernel(const float* feat, const float* W, const float* b, float* out) {
    int tid = threadIdx.x;
    float a0 = 0.f, a1 = 0.f, a2 = 0.f;
    for (int o = tid; o < kH; o += 256) {
        float f = feat[o];
        a0 += f * W[o * 3 + 0]; a1 += f * W[o * 3 + 1]; a2 += f * W[o * 3 + 2];
    }
    __shared__ float r0[256], r1[256], r2[256];
    r0[tid] = a0; r1[tid] = a1; r2[tid] = a2; __syncthreads();
    for (int off = 128; off > 0; off >>= 1) {
        if (tid < off) { r0[tid] += r0[tid + off]; r1[tid] += r1[tid + off]; r2[tid] += r2[tid + off]; }
        __syncthreads();
    }
    if (tid == 0) { out[0] = r0[0] + b[0]; out[1] = r1[0] + b[1]; out[2] = r2[0] + b[2]; }
}

// ---------------- launch ----------------
extern "C" void kernel_launch(void* const* d_in, const int* in_sizes, int n_in,
                              void* d_out, int out_size, void* d_ws, size_t ws_size,
                              hipStream_t stream) {
    const int*   input_ids = (const int*)d_in[0];
    const int*   attn_mask = (const int*)d_in[1];
    const int*   type_ids  = (const int*)d_in[2];
    const int*   p_edges   = (const int*)d_in[3];
    const int*   h_edges   = (const int*)d_in[4];
    const float* p_nodes   = (const float*)d_in[5];
    const float* h_nodes   = (const float*)d_in[6];
    const float* word_emb  = (const float*)d_in[7];
    const float* pos_emb   = (const float*)d_in[8];
    const float* type_emb  = (const float*)d_in[9];
    const float* eln_s     = (const float*)d_in[10];
    const float* eln_b     = (const float*)d_in[11];
    const float* Wq = (const float*)d_in[12]; const float* bq = (const float*)d_in[13];
    const float* Wk = (const float*)d_in[14]; const float* bk = (const float*)d_in[15];
    const float* Wv = (const float*)d_in[16]; const float* bv = (const float*)d_in[17];
    const float* Wo = (const float*)d_in[18]; const float* bo = (const float*)d_in[19];
    const float* l1s = (const float*)d_in[20]; const float* l1b = (const float*)d_in[21];
    const float* W1 = (const float*)d_in[22]; const float* b1 = (const float*)d_in[23];
    const float* W2 = (const float*)d_in[24]; const float* b2 = (const float*)d_in[25];
    const float* l2s = (const float*)d_in[26]; const float* l2b = (const float*)d_in[27];
    const float* gW1 = (const float*)d_in[28]; const float* gb1 = (const float*)d_in[29];
    const float* gW2 = (const float*)d_in[30]; const float* gb2 = (const float*)d_in[31];
    const float* cW  = (const float*)d_in[32]; const float* cb  = (const float*)d_in[33];
    const float* clsW = (const float*)d_in[34]; const float* clsB = (const float*)d_in[35];
    float* out = (float*)d_out;

    // ---------------- workspace layout ----------------
    float* W = (float*)d_ws;
    size_t off = 0;
    auto alloc = [&](size_t n) { float* p = W + off; off += n; return p; };
    float* h    = alloc((size_t)kS * kH);
    float* h1   = alloc((size_t)kS * kH);
    float* deg  = alloc(kN);
    float* wsum = alloc(kN);
    float* svec = alloc(kGH);
    float* gp   = alloc(kGH);
    float* ghv  = alloc(kGH);
    float* mb   = alloc(kS);
    float* feat = alloc(kH);
    float* big  = W + off;

    // BERT-phase big layout (float slots)
    float* part  = big;
    short* ffn1_h = (short*)(big + 7864320);
    short* ffn1_l = ffn1_h + (size_t)1572864;
    short* sm    = (short*)(big + 11796480);
    const size_t SMN = (size_t)kS * kH;
    short* q_h = sm;            short* q_l = q_h + SMN;
    short* k_h = q_l + SMN;     short* k_l = k_h + SMN;
    short* v_h = k_l + SMN;     short* v_l = v_h + SMN;
    short* vt_h = v_l + SMN;    short* vt_l = vt_h + SMN;
    short* ctx_h = vt_l + SMN;  short* ctx_l = ctx_h + SMN;
    short* h1_h = ctx_l + SMN;  short* h1_l = h1_h + SMN;
    short* hh_h = h1_l + SMN;   short* hh_l = hh_h + SMN;

    // GCN-phase overlay on big
    float* hw1 = big;
    float* agg = big + (size_t)kN * kGH;
    int* icnt  = (int*)(big + 2 * (size_t)kN * kGH);
    int* ioffs = icnt + 50048;
    int* icur  = ioffs + 50048;
    int* ibsum = icur + 50048;
    int* icsr  = ibsum + 256;
    short* gwt_h = (short*)(icsr + kE);
    short* gwt_l = gwt_h + (size_t)kH * kGH;

    // Persistent pre-converted weight cache (beyond both overlays)
    const size_t QKV_SZ = (size_t)kH * kH;      // 589824
    const size_t FF_SZ  = (size_t)kH * kF;      // 2359296
    short* wc = (short*)(big + 15000000);
    short* qkv_h = wc;                          short* qkv_l = qkv_h + 12 * 3 * QKV_SZ;
    short* wo_h  = qkv_l + 12 * 3 * QKV_SZ;     short* wo_l  = wo_h + 12 * QKV_SZ;
    short* w1_h  = wo_l + 12 * QKV_SZ;          short* w1_l  = w1_h + 12 * FF_SZ;
    short* w2_h  = w1_l + 12 * FF_SZ;           short* w2_l  = w2_h + 12 * FF_SZ;

    const long MN_H = (long)kS * kH;   // 393216
    const long MN_F = (long)kS * kF;   // 1572864
    const int nScanBlk = CDIV(kN, 256);

    // ---------- pre-convert ALL weights once ----------
    wtrans_all_kernel<<<dim3(24, 24, 12), 256, 0, stream>>>(Wq, qkv_h,              qkv_l,              kH, kH, (long)(3 * QKV_SZ));
    wtrans_all_kernel<<<dim3(24, 24, 12), 256, 0, stream>>>(Wk, qkv_h + QKV_SZ,     qkv_l + QKV_SZ,     kH, kH, (long)(3 * QKV_SZ));
    wtrans_all_kernel<<<dim3(24, 24, 12), 256, 0, stream>>>(Wv, qkv_h + 2 * QKV_SZ, qkv_l + 2 * QKV_SZ, kH, kH, (long)(3 * QKV_SZ));
    wtrans_all_kernel<<<dim3(24, 24, 12), 256, 0, stream>>>(Wo, wo_h, wo_l, kH, kH, (long)QKV_SZ);
    wtrans_all_kernel<<<dim3(96, 24, 12), 256, 0, stream>>>(W1, w1_h, w1_l, kH, kF, (long)FF_SZ);
    wtrans_all_kernel<<<dim3(24, 96, 12), 256, 0, stream>>>(W2, w2_h, w2_l, kF, kH, (long)FF_SZ);

    // ---------- GCN on both graphs ----------
    const int* gsrc[2] = { p_edges, h_edges };
    const int* gdst[2] = { p_edges + kE, h_edges + kE };
    const float* gx[2] = { p_nodes, h_nodes };
    float* gout[2] = { gp, ghv };
    wtrans_all_kernel<<<dim3(kGH / 32, kH / 32, 1), 256, 0, stream>>>(gW1, gwt_h, gwt_l, kH, kGH, 0);
    for (int gi = 0; gi < 2; gi++) {
        gcn_zero_kernel<<<nScanBlk, 256, 0, stream>>>(icnt, wsum, svec);
        cnt_kernel<<<CDIV(kE, 256), 256, 0, stream>>>(gdst[gi], icnt, kE);
        scan1_kernel<<<nScanBlk, 256, 0, stream>>>(icnt, ioffs, ibsum, kN);
        scan2_kernel<<<1, 64, 0, stream>>>(ibsum, nScanBlk, ioffs, kN);
        scan3_kernel<<<nScanBlk, 256, 0, stream>>>(icnt, ioffs, ibsum, icur, deg, kN);
        csrfill_edgew_kernel<<<CDIV(kE, 256), 256, 0, stream>>>(
            gsrc[gi], gdst[gi], icur, icsr, deg, wsum, kE);
        gemm64_gcn<<<dim3(1, CDIV(kN, 64), 1), 256, 0, stream>>>(
            gx[gi], gwt_h, gwt_l, hw1, kN, kGH, kH, 1);
        spmm_gather_kernel<<<CDIV(kN, 2), 256, 0, stream>>>(ioffs, icsr, deg, hw1, gb1, agg, kN);
        wreduce_kernel<<<512, 256, 0, stream>>>(agg, wsum, deg, svec, kN);
        gcn_final_kernel<<<1, kGH, 0, stream>>>(svec, gW2, gb2, gout[gi]);
    }

    // ---------- BERT ----------
    embed_ln_kernel<<<kS, 256, 0, stream>>>(input_ids, type_ids, attn_mask,
                                            word_emb, pos_emb, type_emb,
                                            eln_s, eln_b, h, hh_h, hh_l, mb);
    for (int l = 0; l < kL; l++) {
        const float* bq_l = bq + (size_t)l * kH;
        const float* bk_l = bk + (size_t)l * kH;
        const float* bv_l = bv + (size_t)l * kH;
        const float* bo_l = bo + (size_t)l * kH;
        const float* b1_l = b1 + (size_t)l * kF;
        const float* b2_l = b2 + (size_t)l * kH;
        const float* l1s_l = l1s + (size_t)l * kH; const float* l1b_l = l1b + (size_t)l * kH;
        const float* l2s_l = l2s + (size_t)l * kH; const float* l2b_l = l2b + (size_t)l * kH;
        const short* qkvh_l = qkv_h + (size_t)l * 3 * QKV_SZ;
        const short* qkvl_l = qkv_l + (size_t)l * 3 * QKV_SZ;
        const short* woh_l = wo_h + (size_t)l * QKV_SZ;
        const short* wol_l = wo_l + (size_t)l * QKV_SZ;
        const short* w1h_l = w1_h + (size_t)l * FF_SZ;
        const short* w1l_l = w1_l + (size_t)l * FF_SZ;
        const short* w2h_l = w2_h + (size_t)l * FF_SZ;
        const short* w2l_l = w2_l + (size_t)l * FF_SZ;

        // QKV: S=4, 3 weights -> 576 blocks, 12 partials
        gemm64_pre<<<dim3(kH / 128, kS / 64, 12), 256, 0, stream>>>(
            hh_h, hh_l, qkvh_l, qkvl_l, (long)QKV_SZ, part, kS, kH, kH, 4);
        splitk_epi_qkv_kernel<<<dim3((int)(MN_H / 4 / 256), 3), 256, 0, stream>>>(
            part, Ptr3{{bq_l, bk_l, bv_l}}, q_h, q_l, k_h, k_l, v_h, v_l, 4);
        vtrans_kernel<<<dim3(kS / 32, kNH * 2), 256, 0, stream>>>(v_h, v_l, vt_h, vt_l);
        // fused flash attention -> ctx hi/lo (96 blocks x 128 threads)
        flash_attn_kernel<<<dim3(kS / 64, kNH), 128, 0, stream>>>(
            q_h, q_l, k_h, k_l, vt_h, vt_l, mb, ctx_h, ctx_l);
        // Wo: S=8 -> 384 blocks; fused epi+bias+residual+LN
        gemm64_pre<<<dim3(kH / 128, kS / 64, 8), 256, 0, stream>>>(
            ctx_h, ctx_l, woh_l, wol_l, 0, part, kS, kH, kH, 8);
        splitk_epi_ln2_kernel<<<kS, 256, 0, stream>>>(part, bo_l, h, l1s_l, l1b_l, h1, h1_h, h1_l, 8);
        // FFN1: S=4 -> 768 blocks, gelu
        gemm64_pre<<<dim3(kF / 128, kS / 64, 4), 256, 0, stream>>>(
            h1_h, h1_l, w1h_l, w1l_l, 0, part, kS, kF, kH, 4);
        splitk_epi_sh_kernel<<<(int)(MN_F / 4 / 256), 256, 0, stream>>>(
            part, b1_l, ffn1_h, ffn1_l, MN_F, kF, 4, 1);
        // FFN2: S=8 -> 384 blocks; fused epi+bias+residual+LN
        gemm64_pre<<<dim3(kH / 128, kS / 64, 8), 256, 0, stream>>>(
            ffn1_h, ffn1_l, w2h_l, w2l_l, 0, part, kS, kH, kF, 8);
        splitk_epi_ln2_kernel<<<kS, 256, 0, stream>>>(part, b2_l, h1, l2s_l, l2b_l, h, hh_h, hh_l, 8);
    }

    // ---------- combine + classifier ----------
    fill_kernel<<<3, 256, 0, stream>>>(feat, 0.f, kH);
    combine_part_kernel<<<56, 256, 0, stream>>>(h, gp, ghv, cW, feat);
    combine_fin_kernel<<<3, 256, 0, stream>>>(feat, cb);
    cls_head_kernel<<<1, 256, 0, stream>>>(feat, clsW, clsB, out);
}